// Round 16
// baseline (509.667 us; speedup 1.0000x reference)
//
#include <hip/hip_runtime.h>
#include <hip/hip_bf16.h>

// MPNN on MI355X — fused 16-node-tile msg kernel + MFMA GRU, fully pre-sorted streams.
// msg[e,o] = sum_k t[e,k]*Q[src,k,o] + q0[src,o],  Q[n] = h[n] @ W2ext
// Edges sorted by src NODE (2-level counting sort). k_msgF16: per 16-node src tile,
// MFMA Q (16x1056 bf16) into LDS; each 8-lane group owns ONE node, loads its Q-row
// slice into registers once (33 ushort4), then streams the node's edges (t rows via
// same-address L1 broadcast, no shfl). Edge encoder algebraically folded.
// k_gruAgg4: split-bf16 MFMA GRU. No global atomics (MODE1).

#define NN 100000
#define NE 320000
#define QC 1056
#define NTS 6250      // NN/16 src tiles
#define NT_D 3125     // NN/32 dst tiles
#define HB 256        // bucketing blocks
#define EPB (NE / HB) // 1250
#define QSTRH 1068    // sQ row stride (shorts)

typedef short bf16x8 __attribute__((ext_vector_type(8)));
typedef float f32x4  __attribute__((ext_vector_type(4)));

__device__ __forceinline__ float bf2f(unsigned short u) {
    return __uint_as_float(((unsigned int)u) << 16);
}
__device__ __forceinline__ unsigned short f2bf(float f) {
    unsigned int x = __float_as_uint(f);
    unsigned int r = (x + 0x7fffu + ((x >> 16) & 1u)) >> 16;
    return (unsigned short)r;
}
__device__ __forceinline__ float sigm(float x) {
    return 1.f / (1.f + __expf(-x));
}

// ---- build W2ext [32][1056] (fp32, msgC fallback only)
__global__ __launch_bounds__(256) void k_w2ext(const float* __restrict__ W2,
                                               const float* __restrict__ b2,
                                               float* __restrict__ W2ext) {
    int idx = blockIdx.x * 256 + threadIdx.x;
    if (idx >= 32 * QC) return;
    int i = idx / QC, c = idx % QC;
    float v;
    if (c < 1024) { int k = c >> 5, o = c & 31; v = W2[k * 1024 + i * 32 + o]; }
    else          { v = b2[i * 32 + (c - 1024)]; }
    W2ext[idx] = v;
}

// ---- pack W2ext into bf16 B-fragment layout
__global__ __launch_bounds__(256) void k_w2prep(const float* __restrict__ W2,
                                                const float* __restrict__ b2,
                                                unsigned short* __restrict__ W2bf) {
    int idx = blockIdx.x * 256 + threadIdx.x;
    if (idx >= 66 * 512) return;
    int ct = idx >> 9, l = (idx >> 3) & 63, j = idx & 7;
    int kk = ((j >> 2) << 4) + ((l >> 4) << 2) + (j & 3);
    int c = ct * 16 + (l & 15);
    float v;
    if (c < 1024) { int kb = c >> 5, o = c & 31; v = W2[kb * 1024 + kk * 32 + o]; }
    else          { v = b2[kk * 32 + (c - 1024)]; }
    W2bf[idx] = f2bf(v);
}

// ---- pack combined GRU weights into B-frag bf16 hi/lo
__global__ __launch_bounds__(256) void k_wgru(const float* __restrict__ Wi,
                                              const float* __restrict__ Wh,
                                              unsigned short* __restrict__ Whi,
                                              unsigned short* __restrict__ Wlo) {
    int idx = blockIdx.x * 256 + threadIdx.x;
    if (idx >= 6144) return;
    int j = idx & 7, l = (idx >> 3) & 63, kt = (idx >> 9) & 1, nt = idx >> 10;
    int k = ((j >> 2) << 4) + ((l >> 4) << 2) + (j & 3);
    int col = nt * 16 + (l & 15);
    float v = kt ? Wh[k * 96 + col] : Wi[k * 96 + col];
    unsigned short hi = f2bf(v);
    Whi[idx] = hi;
    Wlo[idx] = f2bf(v - bf2f(hi));
}

// ---- fold edge encoder
__global__ __launch_bounds__(544) void k_wcomb(const float* __restrict__ eencW,
                                               const float* __restrict__ eencB,
                                               const float* __restrict__ enW1,
                                               const float* __restrict__ enB1,
                                               float* __restrict__ Wcomb,
                                               float* __restrict__ bcomb) {
    int tid = threadIdx.x;
    if (tid < 512) {
        int i = tid >> 5, o = tid & 31;
        float acc = 0.f;
        #pragma unroll 8
        for (int j = 0; j < 32; ++j) acc += eencW[i * 32 + j] * enW1[j * 32 + o];
        Wcomb[i * 32 + o] = acc;
    } else {
        int o = tid - 512;
        float acc = enB1[o];
        #pragma unroll 8
        for (int j = 0; j < 32; ++j) acc += eencB[j] * enW1[j * 32 + o];
        bcomb[o] = acc;
    }
}

// ---- node encoder + projection
__global__ __launch_bounds__(256) void k_node_enc(
    const int* __restrict__ nfeats, const float* __restrict__ emb,
    const float* __restrict__ encW, const float* __restrict__ encB,
    const float* __restrict__ projW, const float* __restrict__ projB,
    float* __restrict__ h) {
    __shared__ float sEncW[1024], sProjW[1024], sEncB[32], sProjB[32];
    __shared__ float sEmb[8][33], sNh[8][33];
    int tid = threadIdx.x;
    for (int i = tid; i < 1024; i += 256) { sEncW[i] = encW[i]; sProjW[i] = projW[i]; }
    if (tid < 32) { sEncB[tid] = encB[tid]; sProjB[tid] = projB[tid]; }
    int ln = tid >> 5, o = tid & 31;
    int node = blockIdx.x * 8 + ln;
    int nt = nfeats[node];
    sEmb[ln][o] = fmaxf(emb[nt * 32 + o], 0.f);
    __syncthreads();
    float acc = sEncB[o];
    #pragma unroll
    for (int i = 0; i < 32; ++i) acc += sEmb[ln][i] * sEncW[i * 32 + o];
    sNh[ln][o] = fmaxf(acc, 0.f);
    __syncthreads();
    float acc2 = sProjB[o];
    #pragma unroll
    for (int i = 0; i < 32; ++i) acc2 += sNh[ln][i] * sProjW[i * 32 + o];
    h[node * 32 + o] = fmaxf(acc2, 0.f);
}

// ---- edge encoder (folded): 128 edges/block, weights in registers, no barriers
__global__ __launch_bounds__(256) void k_edge_t3(
    const float* __restrict__ efeats, const float* __restrict__ Wcomb,
    const float* __restrict__ bcomb, const int* __restrict__ eperm,
    float* __restrict__ tS) {
    int tid = threadIdx.x;
    int el = tid >> 3, l8 = tid & 7;
    int gbase = (tid & 63) & 56;
    int c0 = l8 << 2;
    float4 w[16];
    #pragma unroll
    for (int i = 0; i < 16; ++i) w[i] = *(const float4*)(Wcomb + i * 32 + c0);
    float4 bb = *(const float4*)(bcomb + c0);
    #pragma unroll
    for (int it = 0; it < 4; ++it) {
        int p = blockIdx.x * 128 + it * 32 + el;
        int e = eperm ? eperm[p] : p;
        float2 efv = *(const float2*)(efeats + (size_t)e * 16 + (l8 << 1));
        float a0 = bb.x, a1 = bb.y, a2 = bb.z, a3 = bb.w;
        #pragma unroll
        for (int i = 0; i < 8; ++i) {
            float f0 = __shfl(efv.x, gbase + i, 64);
            float f1 = __shfl(efv.y, gbase + i, 64);
            float4 w0 = w[2 * i], w1 = w[2 * i + 1];
            a0 += f0 * w0.x + f1 * w1.x;
            a1 += f0 * w0.y + f1 * w1.y;
            a2 += f0 * w0.z + f1 * w1.z;
            a3 += f0 * w0.w + f1 * w1.w;
        }
        *(float4*)(tS + (size_t)p * 32 + c0) =
            make_float4(fmaxf(a0, 0.f), fmaxf(a1, 0.f), fmaxf(a2, 0.f), fmaxf(a3, 0.f));
    }
}

// ---- generic counting-sort bucketing
template<int NT, int SHIFT>
__global__ __launch_bounds__(256) void k_histT(const int* __restrict__ keys,
                                               int* __restrict__ blockCounts) {
    __shared__ int sHist[NT];
    int tid = threadIdx.x, b = blockIdx.x;
    for (int c = tid; c < NT; c += 256) sHist[c] = 0;
    __syncthreads();
    int beg = b * EPB, end = min(beg + EPB, NE);
    for (int e = beg + tid; e < end; e += 256)
        atomicAdd(&sHist[keys[e] >> SHIFT], 1);
    __syncthreads();
    for (int c = tid; c < NT; c += 256) blockCounts[b * NT + c] = sHist[c];
}

template<int NT>
__global__ __launch_bounds__(256) void k_colsumT(const int* __restrict__ blockCounts,
                                                 int* __restrict__ blockStart,
                                                 int* __restrict__ tileTot) {
    int c = blockIdx.x * 256 + threadIdx.x;
    if (c >= NT) return;
    int running = 0;
    #pragma unroll 8
    for (int b = 0; b < HB; ++b) {
        blockStart[b * NT + c] = running;
        running += blockCounts[b * NT + c];
    }
    tileTot[c] = running;
}

template<int NT, int SEG>
__global__ __launch_bounds__(256) void k_scanT(const int* __restrict__ tileTot,
                                               int* __restrict__ offs) {
    __shared__ int sTot[NT];
    __shared__ int sPart[257];
    int tid = threadIdx.x;
    for (int c = tid; c < NT; c += 256) sTot[c] = tileTot[c];
    __syncthreads();
    int base = tid * SEG;
    int loc = 0;
    for (int j = 0; j < SEG; ++j) {
        int c = base + j;
        if (c < NT) { int v = sTot[c]; sTot[c] = loc; loc += v; }
    }
    sPart[tid] = loc;
    __syncthreads();
    if (tid == 0) {
        int s = 0;
        for (int i = 0; i < 256; ++i) { int v = sPart[i]; sPart[i] = s; s += v; }
        sPart[256] = s;
    }
    __syncthreads();
    int add = sPart[tid];
    for (int j = 0; j < SEG; ++j) {
        int c = base + j;
        if (c < NT) sTot[c] += add;
    }
    __syncthreads();
    for (int c = tid; c < NT; c += 256) offs[c] = sTot[c];
    if (tid == 0) offs[NT] = sPart[256];
}

template<int NT, int SHIFT>
__global__ __launch_bounds__(256) void k_scatterT(const int* __restrict__ keys,
                                                  const int* __restrict__ blockStart,
                                                  const int* __restrict__ offs,
                                                  int* __restrict__ eperm) {
    __shared__ int sCur[NT];
    int tid = threadIdx.x, b = blockIdx.x;
    for (int c = tid; c < NT; c += 256)
        sCur[c] = offs[c] + blockStart[b * NT + c];
    __syncthreads();
    int beg = b * EPB, end = min(beg + EPB, NE);
    for (int e = beg + tid; e < end; e += 256) {
        int pos = atomicAdd(&sCur[keys[e] >> SHIFT], 1);
        eperm[pos] = e;
    }
}

// ---- second-level sort by node within tile (NB bins of NBITS mask)
template<int NB, int MASK, int TPB>
__global__ __launch_bounds__(256) void k_sortNodeT(
    const int* __restrict__ epermIn, const int* __restrict__ key,
    const int* __restrict__ offsT, int* __restrict__ epermOut,
    int* __restrict__ nodeOffs, int lastTile) {
    __shared__ int sCnt[NB], sStart[NB];
    int tid = threadIdx.x, d = blockIdx.x;
    int beg = offsT[d], end = offsT[d + 1];
    if (tid < NB) sCnt[tid] = 0;
    __syncthreads();
    for (int p = beg + tid; p < end; p += 256)
        atomicAdd(&sCnt[key[epermIn[p]] & MASK], 1);
    __syncthreads();
    if (tid == 0) {
        int s = beg;
        for (int r = 0; r < NB; ++r) { sStart[r] = s; s += sCnt[r]; }
    }
    __syncthreads();
    if (tid < NB) {
        nodeOffs[d * NB + tid] = sStart[tid];
        sCnt[tid] = sStart[tid];
    }
    if (d == lastTile && tid == 0) nodeOffs[NN] = end;
    __syncthreads();
    for (int p = beg + tid; p < end; p += 256) {
        int e = epermIn[p];
        int pos = atomicAdd(&sCnt[key[e] & MASK], 1);
        epermOut[pos] = e;
    }
}

// ---- inverse permutation: pos[eperm[p]] = p
__global__ __launch_bounds__(256) void k_invperm(const int* __restrict__ eperm,
                                                 int* __restrict__ pos) {
    int p = blockIdx.x * 256 + threadIdx.x;
    if (p < NE) pos[eperm[p]] = p;
}

// ---- gather key into sorted positions
__global__ __launch_bounds__(256) void k_gatherKey(const int* __restrict__ eperm,
                                                   const int* __restrict__ key,
                                                   int* __restrict__ out) {
    int p = blockIdx.x * 256 + threadIdx.x;
    if (p < NE) out[p] = key[eperm[p]];
}

// ---- idxS[posS[epermD2[q]]] = q
__global__ __launch_bounds__(256) void k_scatterIdx(const int* __restrict__ epermD2,
                                                    const int* __restrict__ posS,
                                                    int* __restrict__ idxS) {
    int q = blockIdx.x * 256 + threadIdx.x;
    if (q < NE) idxS[posS[epermD2[q]]] = q;
}

// ---- fused per-16-node-src-tile: MFMA Q -> bf16 LDS; per-node Q held in regs;
// each 8-lane group owns node g>>1 (parity split over its edges).
// MODE 0: atomicAdd into agg[idxS=dst]; MODE 1: store to msgbuf[idxS=slot].
template<int MODE>
__global__ __launch_bounds__(256) void k_msgF16(
    const float* __restrict__ h, const unsigned short* __restrict__ W2bf,
    const float* __restrict__ tS, const int* __restrict__ nodeOffsS,
    const int* __restrict__ idxS, float* __restrict__ outbuf) {
    __shared__ unsigned short sQ[16 * QSTRH];   // 34176 B
    int tid = threadIdx.x;
    int tile = blockIdx.x;
    int tBeg = nodeOffsS[tile * 16], tEnd = nodeOffsS[tile * 16 + 16];
    if (tBeg >= tEnd) return;
    int nodeBase = tile * 16;
    int wave = tid >> 6, lane = tid & 63;

    int arow = lane & 15;
    const float* hp = h + (size_t)(nodeBase + arow) * 32 + ((lane >> 4) << 2);
    float4 x0 = *(const float4*)hp;
    float4 x1 = *(const float4*)(hp + 16);
    bf16x8 a;
    a[0] = (short)f2bf(x0.x); a[1] = (short)f2bf(x0.y);
    a[2] = (short)f2bf(x0.z); a[3] = (short)f2bf(x0.w);
    a[4] = (short)f2bf(x1.x); a[5] = (short)f2bf(x1.y);
    a[6] = (short)f2bf(x1.z); a[7] = (short)f2bf(x1.w);

    f32x4 z = {0.f, 0.f, 0.f, 0.f};
    int crow0 = (lane >> 4) << 2;
    int ccol = lane & 15;
    for (int ct = wave; ct < 66; ct += 4) {
        bf16x8 b = *(const bf16x8*)(W2bf + (size_t)((ct << 6) + lane) * 8);
        f32x4 acc = __builtin_amdgcn_mfma_f32_16x16x32_bf16(a, b, z, 0, 0, 0);
        unsigned short* qp = sQ + crow0 * QSTRH + (ct << 4) + ccol;
        qp[0 * QSTRH] = f2bf(acc[0]); qp[1 * QSTRH] = f2bf(acc[1]);
        qp[2 * QSTRH] = f2bf(acc[2]); qp[3 * QSTRH] = f2bf(acc[3]);
    }
    __syncthreads();   // the only barrier

    int grp = tid >> 3, l8 = tid & 7;
    int node = grp >> 1, par = grp & 1;
    int beg = nodeOffsS[tile * 16 + node];
    int end = nodeOffsS[tile * 16 + node + 1];
    if (beg + par >= end) return;

    // load this node's Q-row slice into registers (33 x ushort4)
    const unsigned short* qp = sQ + node * QSTRH + (l8 << 2);
    ushort4 qr[33];
    #pragma unroll
    for (int k = 0; k < 33; ++k) qr[k] = *(const ushort4*)(qp + (k << 5));
    float qb0 = bf2f(qr[32].x), qb1 = bf2f(qr[32].y),
          qb2 = bf2f(qr[32].z), qb3 = bf2f(qr[32].w);

    for (int p = beg + par; p < end; p += 2) {
        int widx = idxS[p];
        float4 tq[8];
        #pragma unroll
        for (int i = 0; i < 8; ++i)
            tq[i] = *(const float4*)(tS + (size_t)p * 32 + (i << 2));
        float a0 = qb0, a1 = qb1, a2 = qb2, a3 = qb3;
        #pragma unroll
        for (int kk = 0; kk < 8; ++kk) {
            float t0 = tq[kk].x, t1 = tq[kk].y, t2 = tq[kk].z, t3 = tq[kk].w;
            ushort4 q0 = qr[(kk << 2) + 0];
            ushort4 q1 = qr[(kk << 2) + 1];
            ushort4 q2 = qr[(kk << 2) + 2];
            ushort4 q3 = qr[(kk << 2) + 3];
            a0 += t0 * bf2f(q0.x); a1 += t0 * bf2f(q0.y);
            a2 += t0 * bf2f(q0.z); a3 += t0 * bf2f(q0.w);
            a0 += t1 * bf2f(q1.x); a1 += t1 * bf2f(q1.y);
            a2 += t1 * bf2f(q1.z); a3 += t1 * bf2f(q1.w);
            a0 += t2 * bf2f(q2.x); a1 += t2 * bf2f(q2.y);
            a2 += t2 * bf2f(q2.z); a3 += t2 * bf2f(q2.w);
            a0 += t3 * bf2f(q3.x); a1 += t3 * bf2f(q3.y);
            a2 += t3 * bf2f(q3.z); a3 += t3 * bf2f(q3.w);
        }
        if (MODE) {
            *(float4*)(outbuf + (size_t)widx * 32 + (l8 << 2)) =
                make_float4(a0, a1, a2, a3);
        } else {
            float* ap = outbuf + (size_t)widx * 32 + (l8 << 2);
            atomicAdd(ap + 0, a0); atomicAdd(ap + 1, a1);
            atomicAdd(ap + 2, a2); atomicAdd(ap + 3, a3);
        }
    }
}

// ---- fallback msg (tiny ws): recompute We per edge (t in original order)
__global__ __launch_bounds__(256) void k_msgC(
    const float* __restrict__ t, const int* __restrict__ src, const int* __restrict__ dst,
    const float* __restrict__ h, const float* __restrict__ W2ext, float* __restrict__ agg) {
    __shared__ float sT[32][33], sH[32][33];
    __shared__ int sSrc[32], sDst[32];
    int tid = threadIdx.x;
    int e0 = blockIdx.x * 32;
    if (tid < 32) sSrc[tid] = src[e0 + tid];
    else if (tid < 64) sDst[tid - 32] = dst[e0 + tid - 32];
    __syncthreads();
    for (int idx = tid; idx < 1024; idx += 256) {
        int el = idx >> 5, k = idx & 31;
        sT[el][k] = t[(e0 + el) * 32 + k];
        sH[el][k] = h[(size_t)sSrc[el] * 32 + k];
    }
    __syncthreads();
    int el = tid >> 3, l8 = tid & 7;
    int c0 = l8 * 4;
    float m0 = 0.f, m1 = 0.f, m2 = 0.f, m3 = 0.f;
    for (int i = 0; i < 32; ++i) {
        const float* wrow = W2ext + i * QC;
        float4 wb = *(const float4*)(wrow + 1024 + c0);
        float w0 = wb.x, w1 = wb.y, w2 = wb.z, w3 = wb.w;
        #pragma unroll 8
        for (int k = 0; k < 32; ++k) {
            float tk = sT[el][k];
            float4 w = *(const float4*)(wrow + k * 32 + c0);
            w0 += tk * w.x; w1 += tk * w.y; w2 += tk * w.z; w3 += tk * w.w;
        }
        float hi = sH[el][i];
        m0 += hi * w0; m1 += hi * w1; m2 += hi * w2; m3 += hi * w3;
    }
    float* ap = agg + (size_t)sDst[el] * 32 + c0;
    atomicAdd(ap + 0, m0); atomicAdd(ap + 1, m1);
    atomicAdd(ap + 2, m2); atomicAdd(ap + 3, m3);
}

// ---- GRU step reading agg[] (MODE 0 / fallback)
__global__ __launch_bounds__(256) void k_gru(
    const float* __restrict__ agg, const float* __restrict__ convB,
    const float* __restrict__ Wi, const float* __restrict__ Wh,
    const float* __restrict__ bi, const float* __restrict__ bh,
    float* __restrict__ h) {
    __shared__ float sWi[3072], sWh[3072], sBi[96], sBh[96], sCb[32];
    __shared__ float sX[8][33], sH[8][33];
    int tid = threadIdx.x;
    for (int i = tid; i < 3072; i += 256) { sWi[i] = Wi[i]; sWh[i] = Wh[i]; }
    if (tid < 96) { sBi[tid] = bi[tid]; sBh[tid] = bh[tid]; }
    if (tid < 32) sCb[tid] = convB[tid];
    int ln = tid >> 5, o = tid & 31;
    for (int g = 0; g < 4; ++g) {
        int node = blockIdx.x * 32 + g * 8 + ln;
        float hv = h[node * 32 + o];
        float av = agg[node * 32 + o];
        __syncthreads();
        sX[ln][o] = fmaxf(av + sCb[o], 0.f);
        sH[ln][o] = hv;
        __syncthreads();
        float air = sBi[o], aiz = sBi[o + 32], ain = sBi[o + 64];
        float ahr = sBh[o], ahz = sBh[o + 32], ahn = sBh[o + 64];
        #pragma unroll 8
        for (int i = 0; i < 32; ++i) {
            float x = sX[ln][i], hh = sH[ln][i];
            air += x * sWi[i * 96 + o];      ahr += hh * sWh[i * 96 + o];
            aiz += x * sWi[i * 96 + o + 32]; ahz += hh * sWh[i * 96 + o + 32];
            ain += x * sWi[i * 96 + o + 64]; ahn += hh * sWh[i * 96 + o + 64];
        }
        float r = sigm(air + ahr);
        float zz = sigm(aiz + ahz);
        float ng = tanhf(ain + r * ahn);
        h[node * 32 + o] = (1.f - zz) * ng + zz * hv;
    }
}

// ---- MODE 1: per 32-node dst tile: segment-sum -> X in LDS, GRU via split-bf16 MFMA.
__global__ __launch_bounds__(256) void k_gruAgg4(
    const float* __restrict__ msgbuf, const int* __restrict__ nodeOffs,
    const float* __restrict__ convB,
    const unsigned short* __restrict__ Whi, const unsigned short* __restrict__ Wlo,
    const float* __restrict__ bi, const float* __restrict__ bh,
    float* __restrict__ h) {
    __shared__ float sAgg[32 * 33];
    int tid = threadIdx.x;
    int d = blockIdx.x;
    int base = d * 32;

    {
        int n8 = tid >> 3, l8 = tid & 7;
        int node = base + n8;
        int nb = nodeOffs[node], ne2 = nodeOffs[node + 1];
        float a0 = 0.f, a1 = 0.f, a2 = 0.f, a3 = 0.f;
        for (int p = nb; p < ne2; ++p) {
            float4 v = *(const float4*)(msgbuf + (size_t)p * 32 + (l8 << 2));
            a0 += v.x; a1 += v.y; a2 += v.z; a3 += v.w;
        }
        int c0 = l8 << 2;
        float4 cb = *(const float4*)(convB + c0);
        float* sp = sAgg + n8 * 33 + c0;
        sp[0] = fmaxf(a0 + cb.x, 0.f);
        sp[1] = fmaxf(a1 + cb.y, 0.f);
        sp[2] = fmaxf(a2 + cb.z, 0.f);
        sp[3] = fmaxf(a3 + cb.w, 0.f);
    }
    __syncthreads();

    int wave = tid >> 6, lane = tid & 63;
    int m = wave >> 1, c = wave & 1;
    int arow = lane & 15, kg = (lane >> 4) << 2;

    bf16x8 xhi, xlo, hhi, hlo;
    {
        const float* xp = sAgg + (m * 16 + arow) * 33 + kg;
        float4 v0 = *(const float4*)xp;
        float4 v1 = *(const float4*)(xp + 16);
        float xv[8] = {v0.x, v0.y, v0.z, v0.w, v1.x, v1.y, v1.z, v1.w};
        #pragma unroll
        for (int j = 0; j < 8; ++j) {
            unsigned short hi16 = f2bf(xv[j]);
            xhi[j] = (short)hi16;
            xlo[j] = (short)f2bf(xv[j] - bf2f(hi16));
        }
        const float* hp = h + (size_t)(base + m * 16 + arow) * 32 + kg;
        float4 w0 = *(const float4*)hp;
        float4 w1 = *(const float4*)(hp + 16);
        float hv8[8] = {w0.x, w0.y, w0.z, w0.w, w1.x, w1.y, w1.z, w1.w};
        #pragma unroll
        for (int j = 0; j < 8; ++j) {
            unsigned short hi16 = f2bf(hv8[j]);
            hhi[j] = (short)hi16;
            hlo[j] = (short)f2bf(hv8[j] - bf2f(hi16));
        }
    }

    int ccol = lane & 15, crow0 = (lane >> 4) << 2;
    int o = c * 16 + ccol;
    auto Bf = [&](int nt, int kt, const unsigned short* W) {
        return *(const bf16x8*)(W + (size_t)(((nt * 2 + kt) * 64 + lane) << 3));
    };
    f32x4 accR = {0.f, 0.f, 0.f, 0.f}, accZ = {0.f, 0.f, 0.f, 0.f};
    f32x4 accIN = {0.f, 0.f, 0.f, 0.f}, accHN = {0.f, 0.f, 0.f, 0.f};
    {
        int nt = c;
        bf16x8 b0h = Bf(nt, 0, Whi), b0l = Bf(nt, 0, Wlo);
        bf16x8 b1h = Bf(nt, 1, Whi), b1l = Bf(nt, 1, Wlo);
        accR = __builtin_amdgcn_mfma_f32_16x16x32_bf16(xhi, b0h, accR, 0, 0, 0);
        accR = __builtin_amdgcn_mfma_f32_16x16x32_bf16(xlo, b0h, accR, 0, 0, 0);
        accR = __builtin_amdgcn_mfma_f32_16x16x32_bf16(xhi, b0l, accR, 0, 0, 0);
        accR = __builtin_amdgcn_mfma_f32_16x16x32_bf16(hhi, b1h, accR, 0, 0, 0);
        accR = __builtin_amdgcn_mfma_f32_16x16x32_bf16(hlo, b1h, accR, 0, 0, 0);
        accR = __builtin_amdgcn_mfma_f32_16x16x32_bf16(hhi, b1l, accR, 0, 0, 0);
    }
    {
        int nt = 2 + c;
        bf16x8 b0h = Bf(nt, 0, Whi), b0l = Bf(nt, 0, Wlo);
        bf16x8 b1h = Bf(nt, 1, Whi), b1l = Bf(nt, 1, Wlo);
        accZ = __builtin_amdgcn_mfma_f32_16x16x32_bf16(xhi, b0h, accZ, 0, 0, 0);
        accZ = __builtin_amdgcn_mfma_f32_16x16x32_bf16(xlo, b0h, accZ, 0, 0, 0);
        accZ = __builtin_amdgcn_mfma_f32_16x16x32_bf16(xhi, b0l, accZ, 0, 0, 0);
        accZ = __builtin_amdgcn_mfma_f32_16x16x32_bf16(hhi, b1h, accZ, 0, 0, 0);
        accZ = __builtin_amdgcn_mfma_f32_16x16x32_bf16(hlo, b1h, accZ, 0, 0, 0);
        accZ = __builtin_amdgcn_mfma_f32_16x16x32_bf16(hhi, b1l, accZ, 0, 0, 0);
    }
    {
        int nt = 4 + c;
        bf16x8 b0h = Bf(nt, 0, Whi), b0l = Bf(nt, 0, Wlo);
        bf16x8 b1h = Bf(nt, 1, Whi), b1l = Bf(nt, 1, Wlo);
        accIN = __builtin_amdgcn_mfma_f32_16x16x32_bf16(xhi, b0h, accIN, 0, 0, 0);
        accIN = __builtin_amdgcn_mfma_f32_16x16x32_bf16(xlo, b0h, accIN, 0, 0, 0);
        accIN = __builtin_amdgcn_mfma_f32_16x16x32_bf16(xhi, b0l, accIN, 0, 0, 0);
        accHN = __builtin_amdgcn_mfma_f32_16x16x32_bf16(hhi, b1h, accHN, 0, 0, 0);
        accHN = __builtin_amdgcn_mfma_f32_16x16x32_bf16(hlo, b1h, accHN, 0, 0, 0);
        accHN = __builtin_amdgcn_mfma_f32_16x16x32_bf16(hhi, b1l, accHN, 0, 0, 0);
    }

    float bir = bi[o], biz = bi[32 + o], bin = bi[64 + o];
    float bhr = bh[o], bhz = bh[32 + o], bhn = bh[64 + o];
    float hv[4];
    #pragma unroll
    for (int j = 0; j < 4; ++j)
        hv[j] = h[(size_t)(base + m * 16 + crow0 + j) * 32 + o];
    __syncthreads();
    #pragma unroll
    for (int j = 0; j < 4; ++j) {
        float r  = sigm(accR[j] + bir + bhr);
        float zz = sigm(accZ[j] + biz + bhz);
        float ng = tanhf(accIN[j] + bin + r * (accHN[j] + bhn));
        h[(size_t)(base + m * 16 + crow0 + j) * 32 + o] = (1.f - zz) * ng + zz * hv[j];
    }
}

// ---- decoder
__global__ __launch_bounds__(256) void k_dec(
    const float* __restrict__ h,
    const float* __restrict__ W1, const float* __restrict__ b1, const float* __restrict__ a1,
    const float* __restrict__ W2, const float* __restrict__ b2, const float* __restrict__ a2,
    const float* __restrict__ W3, const float* __restrict__ b3, const float* __restrict__ a3,
    const float* __restrict__ W4, const float* __restrict__ b4,
    float* __restrict__ out) {
    __shared__ float sW1[1024], sW2[1024], sW3[1024], sW4[96];
    __shared__ float sB1[32], sB2[32], sB3[32], sB4[3];
    __shared__ float sYa[8][33], sYb[8][33];
    int tid = threadIdx.x;
    for (int i = tid; i < 1024; i += 256) { sW1[i] = W1[i]; sW2[i] = W2[i]; sW3[i] = W3[i]; }
    if (tid < 96) sW4[tid] = W4[tid];
    if (tid < 32) { sB1[tid] = b1[tid]; sB2[tid] = b2[tid]; sB3[tid] = b3[tid]; }
    if (tid < 3) sB4[tid] = b4[tid];
    float A1 = a1[0], A2 = a2[0], A3 = a3[0];
    int ln = tid >> 5, o = tid & 31;
    int node = blockIdx.x * 8 + ln;
    sYa[ln][o] = h[node * 32 + o];
    __syncthreads();
    float acc = sB1[o];
    #pragma unroll
    for (int i = 0; i < 32; ++i) acc += sYa[ln][i] * sW1[i * 32 + o];
    acc = acc >= 0.f ? acc : A1 * acc;
    sYb[ln][o] = acc;
    __syncthreads();
    acc = sB2[o];
    #pragma unroll
    for (int i = 0; i < 32; ++i) acc += sYb[ln][i] * sW2[i * 32 + o];
    acc = acc >= 0.f ? acc : A2 * acc;
    __syncthreads();
    sYa[ln][o] = acc;
    __syncthreads();
    acc = sB3[o];
    #pragma unroll
    for (int i = 0; i < 32; ++i) acc += sYa[ln][i] * sW3[i * 32 + o];
    acc = acc >= 0.f ? acc : A3 * acc;
    __syncthreads();
    sYb[ln][o] = acc;
    __syncthreads();
    if (o < 3) {
        float r = sB4[o];
        #pragma unroll
        for (int i = 0; i < 32; ++i) r += sYb[ln][i] * sW4[i * 3 + o];
        out[node * 3 + o] = r;
    }
}

extern "C" void kernel_launch(void* const* d_in, const int* in_sizes, int n_in,
                              void* d_out, int out_size, void* d_ws, size_t ws_size,
                              hipStream_t stream) {
    const int*   nfeats = (const int*)d_in[0];
    const float* efeats = (const float*)d_in[1];
    const int*   src    = (const int*)d_in[2];
    const int*   dst    = (const int*)d_in[3];
    const float* emb    = (const float*)d_in[4];
    const float* encW   = (const float*)d_in[5];
    const float* encB   = (const float*)d_in[6];
    const float* eencW  = (const float*)d_in[7];
    const float* eencB  = (const float*)d_in[8];
    const float* projW  = (const float*)d_in[9];
    const float* projB  = (const float*)d_in[10];
    const float* enW1   = (const float*)d_in[11];
    const float* enB1   = (const float*)d_in[12];
    const float* enW2   = (const float*)d_in[13];
    const float* enB2   = (const float*)d_in[14];
    const float* convB  = (const float*)d_in[15];
    const float* gruWi  = (const float*)d_in[16];
    const float* gruWh  = (const float*)d_in[17];
    const float* gruBi  = (const float*)d_in[18];
    const float* gruBh  = (const float*)d_in[19];
    const float* dW1 = (const float*)d_in[20]; const float* db1 = (const float*)d_in[21]; const float* da1 = (const float*)d_in[22];
    const float* dW2 = (const float*)d_in[23]; const float* db2 = (const float*)d_in[24]; const float* da2 = (const float*)d_in[25];
    const float* dW3 = (const float*)d_in[26]; const float* db3 = (const float*)d_in[27]; const float* da3 = (const float*)d_in[28];
    const float* dW4 = (const float*)d_in[29]; const float* db4 = (const float*)d_in[30];
    float* out = (float*)d_out;
    char* ws = (char*)d_ws;

    // bump allocator (256-B aligned)
    size_t cur = 0;
    auto alloc = [&](size_t n) { size_t p = cur; cur = (cur + n + 255) & ~(size_t)255; return p; };
    size_t o_h   = alloc((size_t)NN * 32 * 4);
    size_t o_t   = alloc((size_t)NE * 32 * 4);      // tS (or t in fallback)
    size_t o_w2e = alloc((size_t)32 * QC * 4);
    size_t afterCommon = cur;                       // fallback agg goes here
    size_t o_w2b = alloc((size_t)66 * 512 * 2);
    size_t o_epS = alloc((size_t)NE * 4);
    size_t o_ofS = alloc((size_t)(NTS + 1) * 4);
    size_t o_epS2 = alloc((size_t)NE * 4);
    size_t o_noffS = alloc((size_t)(NN + 1) * 4);
    size_t o_posS = alloc((size_t)NE * 4);
    size_t o_idxS = alloc((size_t)NE * 4);
    size_t o_wcomb = alloc((size_t)(512 + 32) * 4);
    size_t baseEnd = cur;                           // MODE0 agg goes here
    size_t o_epD  = alloc((size_t)NE * 4);
    size_t o_ofD  = alloc((size_t)(NT_D + 1) * 4);
    size_t o_epD2 = alloc((size_t)NE * 4);
    size_t o_noff = alloc((size_t)(NN + 1) * 4);
    size_t o_whi  = alloc((size_t)6144 * 2);
    size_t o_wlo  = alloc((size_t)6144 * 2);
    size_t o_msg  = alloc((size_t)NE * 32 * 4);     // MODE1 msgbuf
    size_t need1 = cur;
    size_t need0 = baseEnd + (size_t)NN * 32 * 4;

    int mode;                                       // 1: node-sorted, 0: atomic, -1: msgC
    if (ws_size >= need1) mode = 1;
    else if (ws_size >= need0) mode = 0;
    else mode = -1;

    float* h     = (float*)(ws + o_h);
    float* tS    = (float*)(ws + o_t);
    float* W2ext = (float*)(ws + o_w2e);
    unsigned short* W2bf = (unsigned short*)(ws + o_w2b);
    int* epermS  = (int*)(ws + o_epS);
    int* offsS   = (int*)(ws + o_ofS);
    int* epermS2 = (int*)(ws + o_epS2);
    int* nodeOffsS = (int*)(ws + o_noffS);
    int* posS    = (int*)(ws + o_posS);
    int* idxS    = (int*)(ws + o_idxS);
    float* Wcomb = (float*)(ws + o_wcomb);
    float* bcomb = Wcomb + 512;
    int* epermD  = (int*)(ws + o_epD);
    int* offsD   = (int*)(ws + o_ofD);
    int* epermD2 = (int*)(ws + o_epD2);
    int* nodeOffs = (int*)(ws + o_noff);
    unsigned short* gWhi = (unsigned short*)(ws + o_whi);
    unsigned short* gWlo = (unsigned short*)(ws + o_wlo);
    float* outbuf = (mode == 1) ? (float*)(ws + o_msg)
                  : (mode == 0) ? (float*)(ws + baseEnd)
                                : (float*)(ws + afterCommon);
    // scratch (prologue only) unions into outbuf region
    int* blockCounts = (int*)outbuf;
    int* blockStart  = blockCounts + (size_t)HB * NTS;
    int* tileTot     = blockStart + (size_t)HB * NTS;

    k_node_enc<<<NN / 8, 256, 0, stream>>>(nfeats, emb, encW, encB, projW, projB, h);
    k_wcomb<<<1, 544, 0, stream>>>(eencW, eencB, enW1, enB1, Wcomb, bcomb);

    if (mode >= 0) {
        k_w2prep<<<(66 * 512 + 255) / 256, 256, 0, stream>>>(enW2, enB2, W2bf);
        // src bucketing (16-node tiles) -> per-node second-level sort
        k_histT<NTS, 4><<<HB, 256, 0, stream>>>(src, blockCounts);
        k_colsumT<NTS><<<(NTS + 255) / 256, 256, 0, stream>>>(blockCounts, blockStart, tileTot);
        k_scanT<NTS, 25><<<1, 256, 0, stream>>>(tileTot, offsS);
        k_scatterT<NTS, 4><<<HB, 256, 0, stream>>>(src, blockStart, offsS, epermS);
        k_sortNodeT<16, 15, 256><<<NTS, 256, 0, stream>>>(epermS, src, offsS, epermS2,
                                                          nodeOffsS, NTS - 1);
        k_invperm<<<(NE + 255) / 256, 256, 0, stream>>>(epermS2, posS);
        if (mode == 1) {
            k_wgru<<<(6144 + 255) / 256, 256, 0, stream>>>(gruWi, gruWh, gWhi, gWlo);
            k_histT<NT_D, 5><<<HB, 256, 0, stream>>>(dst, blockCounts);
            k_colsumT<NT_D><<<(NT_D + 255) / 256, 256, 0, stream>>>(blockCounts, blockStart, tileTot);
            k_scanT<NT_D, 13><<<1, 256, 0, stream>>>(tileTot, offsD);
            k_scatterT<NT_D, 5><<<HB, 256, 0, stream>>>(dst, blockStart, offsD, epermD);
            k_sortNodeT<32, 31, 256><<<NT_D, 256, 0, stream>>>(epermD, dst, offsD, epermD2,
                                                               nodeOffs, NT_D - 1);
            k_scatterIdx<<<(NE + 255) / 256, 256, 0, stream>>>(epermD2, posS, idxS);
        } else {
            k_gatherKey<<<(NE + 255) / 256, 256, 0, stream>>>(epermS2, dst, idxS);
        }
        k_edge_t3<<<NE / 128, 256, 0, stream>>>(efeats, Wcomb, bcomb, epermS2, tS);
    } else {
        k_w2ext<<<(32 * QC + 255) / 256, 256, 0, stream>>>(enW2, enB2, W2ext);
        k_edge_t3<<<NE / 128, 256, 0, stream>>>(efeats, Wcomb, bcomb, nullptr, tS);
    }

    for (int s = 0; s < 3; ++s) {
        if (mode == 1) {
            k_msgF16<1><<<NTS, 256, 0, stream>>>(h, W2bf, tS, nodeOffsS, idxS, outbuf);
            k_gruAgg4<<<NT_D, 256, 0, stream>>>(outbuf, nodeOffs, convB,
                                                gWhi, gWlo, gruBi, gruBh, h);
        } else if (mode == 0) {
            hipMemsetAsync(outbuf, 0, (size_t)NN * 32 * 4, stream);
            k_msgF16<0><<<NTS, 256, 0, stream>>>(h, W2bf, tS, nodeOffsS, idxS, outbuf);
            k_gru<<<NN / 32, 256, 0, stream>>>(outbuf, convB, gruWi, gruWh, gruBi, gruBh, h);
        } else {
            hipMemsetAsync(outbuf, 0, (size_t)NN * 32 * 4, stream);
            k_msgC<<<NE / 32, 256, 0, stream>>>(tS, src, dst, h, W2ext, outbuf);
            k_gru<<<NN / 32, 256, 0, stream>>>(outbuf, convB, gruWi, gruWh, gruBi, gruBh, h);
        }
    }
    k_dec<<<NN / 8, 256, 0, stream>>>(h, dW1, db1, da1, dW2, db2, da2, dW3, db3, da3, dW4, db4, out);
}

// Round 17
// 441.279 us; speedup vs baseline: 1.1550x; 1.1550x over previous
//
#include <hip/hip_runtime.h>
#include <hip/hip_bf16.h>

// MPNN on MI355X — fused 16-node-tile msg kernel + MFMA GRU, fully pre-sorted streams.
// msg[e,o] = sum_k t[e,k]*Q[src,k,o] + q0[src,o],  Q[n] = h[n] @ W2ext
// k_msgF16: per 16-node src tile, MFMA Q (16x1056 bf16) into LDS (QSTRH=1072 ->
// 16B-aligned rows), then a barrier-free edge stream: 4 lanes/edge x 8 outputs,
// Q read as ds_read_b128 (33/lane), t rows via same-address L1 broadcast (no shfl).
// Edge encoder algebraically folded. k_gruAgg4: split-bf16 MFMA GRU. No global atomics.

#define NN 100000
#define NE 320000
#define QC 1056
#define NTS 6250      // NN/16 src tiles
#define NT_D 3125     // NN/32 dst tiles
#define HB 256        // bucketing blocks
#define EPB (NE / HB) // 1250
#define QSTRH 1072    // sQ row stride (shorts); 2144 B/row -> 16B aligned slices

typedef short bf16x8 __attribute__((ext_vector_type(8)));
typedef float f32x4  __attribute__((ext_vector_type(4)));

__device__ __forceinline__ float bf2f(unsigned short u) {
    return __uint_as_float(((unsigned int)u) << 16);
}
__device__ __forceinline__ unsigned short f2bf(float f) {
    unsigned int x = __float_as_uint(f);
    unsigned int r = (x + 0x7fffu + ((x >> 16) & 1u)) >> 16;
    return (unsigned short)r;
}
__device__ __forceinline__ float sigm(float x) {
    return 1.f / (1.f + __expf(-x));
}

// ---- build W2ext [32][1056] (fp32, msgC fallback only)
__global__ __launch_bounds__(256) void k_w2ext(const float* __restrict__ W2,
                                               const float* __restrict__ b2,
                                               float* __restrict__ W2ext) {
    int idx = blockIdx.x * 256 + threadIdx.x;
    if (idx >= 32 * QC) return;
    int i = idx / QC, c = idx % QC;
    float v;
    if (c < 1024) { int k = c >> 5, o = c & 31; v = W2[k * 1024 + i * 32 + o]; }
    else          { v = b2[i * 32 + (c - 1024)]; }
    W2ext[idx] = v;
}

// ---- pack W2ext into bf16 B-fragment layout
__global__ __launch_bounds__(256) void k_w2prep(const float* __restrict__ W2,
                                                const float* __restrict__ b2,
                                                unsigned short* __restrict__ W2bf) {
    int idx = blockIdx.x * 256 + threadIdx.x;
    if (idx >= 66 * 512) return;
    int ct = idx >> 9, l = (idx >> 3) & 63, j = idx & 7;
    int kk = ((j >> 2) << 4) + ((l >> 4) << 2) + (j & 3);
    int c = ct * 16 + (l & 15);
    float v;
    if (c < 1024) { int kb = c >> 5, o = c & 31; v = W2[kb * 1024 + kk * 32 + o]; }
    else          { v = b2[kk * 32 + (c - 1024)]; }
    W2bf[idx] = f2bf(v);
}

// ---- pack combined GRU weights into B-frag bf16 hi/lo
__global__ __launch_bounds__(256) void k_wgru(const float* __restrict__ Wi,
                                              const float* __restrict__ Wh,
                                              unsigned short* __restrict__ Whi,
                                              unsigned short* __restrict__ Wlo) {
    int idx = blockIdx.x * 256 + threadIdx.x;
    if (idx >= 6144) return;
    int j = idx & 7, l = (idx >> 3) & 63, kt = (idx >> 9) & 1, nt = idx >> 10;
    int k = ((j >> 2) << 4) + ((l >> 4) << 2) + (j & 3);
    int col = nt * 16 + (l & 15);
    float v = kt ? Wh[k * 96 + col] : Wi[k * 96 + col];
    unsigned short hi = f2bf(v);
    Whi[idx] = hi;
    Wlo[idx] = f2bf(v - bf2f(hi));
}

// ---- fold edge encoder
__global__ __launch_bounds__(544) void k_wcomb(const float* __restrict__ eencW,
                                               const float* __restrict__ eencB,
                                               const float* __restrict__ enW1,
                                               const float* __restrict__ enB1,
                                               float* __restrict__ Wcomb,
                                               float* __restrict__ bcomb) {
    int tid = threadIdx.x;
    if (tid < 512) {
        int i = tid >> 5, o = tid & 31;
        float acc = 0.f;
        #pragma unroll 8
        for (int j = 0; j < 32; ++j) acc += eencW[i * 32 + j] * enW1[j * 32 + o];
        Wcomb[i * 32 + o] = acc;
    } else {
        int o = tid - 512;
        float acc = enB1[o];
        #pragma unroll 8
        for (int j = 0; j < 32; ++j) acc += eencB[j] * enW1[j * 32 + o];
        bcomb[o] = acc;
    }
}

// ---- node encoder + projection
__global__ __launch_bounds__(256) void k_node_enc(
    const int* __restrict__ nfeats, const float* __restrict__ emb,
    const float* __restrict__ encW, const float* __restrict__ encB,
    const float* __restrict__ projW, const float* __restrict__ projB,
    float* __restrict__ h) {
    __shared__ float sEncW[1024], sProjW[1024], sEncB[32], sProjB[32];
    __shared__ float sEmb[8][33], sNh[8][33];
    int tid = threadIdx.x;
    for (int i = tid; i < 1024; i += 256) { sEncW[i] = encW[i]; sProjW[i] = projW[i]; }
    if (tid < 32) { sEncB[tid] = encB[tid]; sProjB[tid] = projB[tid]; }
    int ln = tid >> 5, o = tid & 31;
    int node = blockIdx.x * 8 + ln;
    int nt = nfeats[node];
    sEmb[ln][o] = fmaxf(emb[nt * 32 + o], 0.f);
    __syncthreads();
    float acc = sEncB[o];
    #pragma unroll
    for (int i = 0; i < 32; ++i) acc += sEmb[ln][i] * sEncW[i * 32 + o];
    sNh[ln][o] = fmaxf(acc, 0.f);
    __syncthreads();
    float acc2 = sProjB[o];
    #pragma unroll
    for (int i = 0; i < 32; ++i) acc2 += sNh[ln][i] * sProjW[i * 32 + o];
    h[node * 32 + o] = fmaxf(acc2, 0.f);
}

// ---- edge encoder (folded): 128 edges/block, weights in registers, no barriers
__global__ __launch_bounds__(256) void k_edge_t3(
    const float* __restrict__ efeats, const float* __restrict__ Wcomb,
    const float* __restrict__ bcomb, const int* __restrict__ eperm,
    float* __restrict__ tS) {
    int tid = threadIdx.x;
    int el = tid >> 3, l8 = tid & 7;
    int gbase = (tid & 63) & 56;
    int c0 = l8 << 2;
    float4 w[16];
    #pragma unroll
    for (int i = 0; i < 16; ++i) w[i] = *(const float4*)(Wcomb + i * 32 + c0);
    float4 bb = *(const float4*)(bcomb + c0);
    #pragma unroll
    for (int it = 0; it < 4; ++it) {
        int p = blockIdx.x * 128 + it * 32 + el;
        int e = eperm ? eperm[p] : p;
        float2 efv = *(const float2*)(efeats + (size_t)e * 16 + (l8 << 1));
        float a0 = bb.x, a1 = bb.y, a2 = bb.z, a3 = bb.w;
        #pragma unroll
        for (int i = 0; i < 8; ++i) {
            float f0 = __shfl(efv.x, gbase + i, 64);
            float f1 = __shfl(efv.y, gbase + i, 64);
            float4 w0 = w[2 * i], w1 = w[2 * i + 1];
            a0 += f0 * w0.x + f1 * w1.x;
            a1 += f0 * w0.y + f1 * w1.y;
            a2 += f0 * w0.z + f1 * w1.z;
            a3 += f0 * w0.w + f1 * w1.w;
        }
        *(float4*)(tS + (size_t)p * 32 + c0) =
            make_float4(fmaxf(a0, 0.f), fmaxf(a1, 0.f), fmaxf(a2, 0.f), fmaxf(a3, 0.f));
    }
}

// ---- generic counting-sort bucketing
template<int NT, int SHIFT>
__global__ __launch_bounds__(256) void k_histT(const int* __restrict__ keys,
                                               int* __restrict__ blockCounts) {
    __shared__ int sHist[NT];
    int tid = threadIdx.x, b = blockIdx.x;
    for (int c = tid; c < NT; c += 256) sHist[c] = 0;
    __syncthreads();
    int beg = b * EPB, end = min(beg + EPB, NE);
    for (int e = beg + tid; e < end; e += 256)
        atomicAdd(&sHist[keys[e] >> SHIFT], 1);
    __syncthreads();
    for (int c = tid; c < NT; c += 256) blockCounts[b * NT + c] = sHist[c];
}

template<int NT>
__global__ __launch_bounds__(256) void k_colsumT(const int* __restrict__ blockCounts,
                                                 int* __restrict__ blockStart,
                                                 int* __restrict__ tileTot) {
    int c = blockIdx.x * 256 + threadIdx.x;
    if (c >= NT) return;
    int running = 0;
    #pragma unroll 8
    for (int b = 0; b < HB; ++b) {
        blockStart[b * NT + c] = running;
        running += blockCounts[b * NT + c];
    }
    tileTot[c] = running;
}

template<int NT, int SEG>
__global__ __launch_bounds__(256) void k_scanT(const int* __restrict__ tileTot,
                                               int* __restrict__ offs) {
    __shared__ int sTot[NT];
    __shared__ int sPart[257];
    int tid = threadIdx.x;
    for (int c = tid; c < NT; c += 256) sTot[c] = tileTot[c];
    __syncthreads();
    int base = tid * SEG;
    int loc = 0;
    for (int j = 0; j < SEG; ++j) {
        int c = base + j;
        if (c < NT) { int v = sTot[c]; sTot[c] = loc; loc += v; }
    }
    sPart[tid] = loc;
    __syncthreads();
    if (tid == 0) {
        int s = 0;
        for (int i = 0; i < 256; ++i) { int v = sPart[i]; sPart[i] = s; s += v; }
        sPart[256] = s;
    }
    __syncthreads();
    int add = sPart[tid];
    for (int j = 0; j < SEG; ++j) {
        int c = base + j;
        if (c < NT) sTot[c] += add;
    }
    __syncthreads();
    for (int c = tid; c < NT; c += 256) offs[c] = sTot[c];
    if (tid == 0) offs[NT] = sPart[256];
}

template<int NT, int SHIFT>
__global__ __launch_bounds__(256) void k_scatterT(const int* __restrict__ keys,
                                                  const int* __restrict__ blockStart,
                                                  const int* __restrict__ offs,
                                                  int* __restrict__ eperm) {
    __shared__ int sCur[NT];
    int tid = threadIdx.x, b = blockIdx.x;
    for (int c = tid; c < NT; c += 256)
        sCur[c] = offs[c] + blockStart[b * NT + c];
    __syncthreads();
    int beg = b * EPB, end = min(beg + EPB, NE);
    for (int e = beg + tid; e < end; e += 256) {
        int pos = atomicAdd(&sCur[keys[e] >> SHIFT], 1);
        eperm[pos] = e;
    }
}

// ---- second-level sort: within each dst tile, sort by node (32 LDS bins)
__global__ __launch_bounds__(256) void k_sortNode(
    const int* __restrict__ epermD, const int* __restrict__ dst,
    const int* __restrict__ offsD, int* __restrict__ epermD2,
    int* __restrict__ nodeOffs) {
    __shared__ int sCnt[32], sStart[32];
    int tid = threadIdx.x, d = blockIdx.x;
    int beg = offsD[d], end = offsD[d + 1];
    if (tid < 32) sCnt[tid] = 0;
    __syncthreads();
    for (int p = beg + tid; p < end; p += 256)
        atomicAdd(&sCnt[dst[epermD[p]] & 31], 1);
    __syncthreads();
    if (tid == 0) {
        int s = beg;
        for (int r = 0; r < 32; ++r) { sStart[r] = s; s += sCnt[r]; }
    }
    __syncthreads();
    if (tid < 32) {
        nodeOffs[d * 32 + tid] = sStart[tid];
        sCnt[tid] = sStart[tid];
    }
    if (d == NT_D - 1 && tid == 0) nodeOffs[NN] = end;
    __syncthreads();
    for (int p = beg + tid; p < end; p += 256) {
        int e = epermD[p];
        int pos = atomicAdd(&sCnt[dst[e] & 31], 1);
        epermD2[pos] = e;
    }
}

// ---- inverse permutation: pos[eperm[p]] = p
__global__ __launch_bounds__(256) void k_invperm(const int* __restrict__ eperm,
                                                 int* __restrict__ pos) {
    int p = blockIdx.x * 256 + threadIdx.x;
    if (p < NE) pos[eperm[p]] = p;
}

// ---- gather key into src-sorted positions
__global__ __launch_bounds__(256) void k_gatherKey(const int* __restrict__ epermS,
                                                   const int* __restrict__ key,
                                                   int* __restrict__ out) {
    int p = blockIdx.x * 256 + threadIdx.x;
    if (p < NE) out[p] = key[epermS[p]];
}

// ---- idxS[posS[epermD2[q]]] = q
__global__ __launch_bounds__(256) void k_scatterIdx(const int* __restrict__ epermD2,
                                                    const int* __restrict__ posS,
                                                    int* __restrict__ idxS) {
    int q = blockIdx.x * 256 + threadIdx.x;
    if (q < NE) idxS[posS[epermD2[q]]] = q;
}

// ---- fused per-16-node-src-tile: MFMA Q -> bf16 LDS; edge stream 4 lanes/edge x
// 8 outputs with ds_read_b128. MODE 0: atomicAdd; MODE 1: store to msgbuf slot.
template<int MODE>
__global__ __launch_bounds__(256) void k_msgF16(
    const float* __restrict__ h, const unsigned short* __restrict__ W2bf,
    const float* __restrict__ tS, const int* __restrict__ srcS,
    const int* __restrict__ idxS, const int* __restrict__ offs,
    float* __restrict__ outbuf) {
    __shared__ unsigned short sQ[16 * QSTRH];   // 34304 B
    int tid = threadIdx.x;
    int tile = blockIdx.x;
    int beg = offs[tile], end = offs[tile + 1];
    if (beg >= end) return;
    int nodeBase = tile * 16;
    int wave = tid >> 6, lane = tid & 63;

    int arow = lane & 15;
    const float* hp = h + (size_t)(nodeBase + arow) * 32 + ((lane >> 4) << 2);
    float4 x0 = *(const float4*)hp;
    float4 x1 = *(const float4*)(hp + 16);
    bf16x8 a;
    a[0] = (short)f2bf(x0.x); a[1] = (short)f2bf(x0.y);
    a[2] = (short)f2bf(x0.z); a[3] = (short)f2bf(x0.w);
    a[4] = (short)f2bf(x1.x); a[5] = (short)f2bf(x1.y);
    a[6] = (short)f2bf(x1.z); a[7] = (short)f2bf(x1.w);

    f32x4 z = {0.f, 0.f, 0.f, 0.f};
    int crow0 = (lane >> 4) << 2;
    int ccol = lane & 15;
    for (int ct = wave; ct < 66; ct += 4) {
        bf16x8 b = *(const bf16x8*)(W2bf + (size_t)((ct << 6) + lane) * 8);
        f32x4 acc = __builtin_amdgcn_mfma_f32_16x16x32_bf16(a, b, z, 0, 0, 0);
        unsigned short* qp = sQ + crow0 * QSTRH + (ct << 4) + ccol;
        qp[0 * QSTRH] = f2bf(acc[0]); qp[1 * QSTRH] = f2bf(acc[1]);
        qp[2 * QSTRH] = f2bf(acc[2]); qp[3 * QSTRH] = f2bf(acc[3]);
    }
    __syncthreads();   // the only barrier

    int el = tid >> 2, l4 = tid & 3;   // 64 edges in flight, 8 outputs/lane
    for (int p = beg + el; p < end; p += 64) {
        int row = srcS[p] - nodeBase;      // 4 lanes same addr -> broadcast
        int widx = idxS[p];
        float4 tq[8];
        #pragma unroll
        for (int i = 0; i < 8; ++i)
            tq[i] = *(const float4*)(tS + (size_t)p * 32 + (i << 2));
        const unsigned short* qp = sQ + row * QSTRH + (l4 << 3);
        bf16x8 qb = *(const bf16x8*)(qp + 1024);
        float acc[8];
        #pragma unroll
        for (int j = 0; j < 8; ++j) acc[j] = bf2f((unsigned short)qb[j]);
        #pragma unroll
        for (int kk = 0; kk < 8; ++kk) {
            float tv[4] = {tq[kk].x, tq[kk].y, tq[kk].z, tq[kk].w};
            #pragma unroll
            for (int m = 0; m < 4; ++m) {
                bf16x8 q = *(const bf16x8*)(qp + ((kk << 2) + m) * 32);
                float tk = tv[m];
                #pragma unroll
                for (int j = 0; j < 8; ++j)
                    acc[j] += tk * bf2f((unsigned short)q[j]);
            }
        }
        if (MODE) {
            float* op = outbuf + (size_t)widx * 32 + (l4 << 3);
            *(float4*)op = make_float4(acc[0], acc[1], acc[2], acc[3]);
            *(float4*)(op + 4) = make_float4(acc[4], acc[5], acc[6], acc[7]);
        } else {
            float* op = outbuf + (size_t)widx * 32 + (l4 << 3);
            #pragma unroll
            for (int j = 0; j < 8; ++j) atomicAdd(op + j, acc[j]);
        }
    }
}

// ---- fallback msg (tiny ws): recompute We per edge (t in original order)
__global__ __launch_bounds__(256) void k_msgC(
    const float* __restrict__ t, const int* __restrict__ src, const int* __restrict__ dst,
    const float* __restrict__ h, const float* __restrict__ W2ext, float* __restrict__ agg) {
    __shared__ float sT[32][33], sH[32][33];
    __shared__ int sSrc[32], sDst[32];
    int tid = threadIdx.x;
    int e0 = blockIdx.x * 32;
    if (tid < 32) sSrc[tid] = src[e0 + tid];
    else if (tid < 64) sDst[tid - 32] = dst[e0 + tid - 32];
    __syncthreads();
    for (int idx = tid; idx < 1024; idx += 256) {
        int el = idx >> 5, k = idx & 31;
        sT[el][k] = t[(e0 + el) * 32 + k];
        sH[el][k] = h[(size_t)sSrc[el] * 32 + k];
    }
    __syncthreads();
    int el = tid >> 3, l8 = tid & 7;
    int c0 = l8 * 4;
    float m0 = 0.f, m1 = 0.f, m2 = 0.f, m3 = 0.f;
    for (int i = 0; i < 32; ++i) {
        const float* wrow = W2ext + i * QC;
        float4 wb = *(const float4*)(wrow + 1024 + c0);
        float w0 = wb.x, w1 = wb.y, w2 = wb.z, w3 = wb.w;
        #pragma unroll 8
        for (int k = 0; k < 32; ++k) {
            float tk = sT[el][k];
            float4 w = *(const float4*)(wrow + k * 32 + c0);
            w0 += tk * w.x; w1 += tk * w.y; w2 += tk * w.z; w3 += tk * w.w;
        }
        float hi = sH[el][i];
        m0 += hi * w0; m1 += hi * w1; m2 += hi * w2; m3 += hi * w3;
    }
    float* ap = agg + (size_t)sDst[el] * 32 + c0;
    atomicAdd(ap + 0, m0); atomicAdd(ap + 1, m1);
    atomicAdd(ap + 2, m2); atomicAdd(ap + 3, m3);
}

// ---- GRU step reading agg[] (MODE 0 / fallback)
__global__ __launch_bounds__(256) void k_gru(
    const float* __restrict__ agg, const float* __restrict__ convB,
    const float* __restrict__ Wi, const float* __restrict__ Wh,
    const float* __restrict__ bi, const float* __restrict__ bh,
    float* __restrict__ h) {
    __shared__ float sWi[3072], sWh[3072], sBi[96], sBh[96], sCb[32];
    __shared__ float sX[8][33], sH[8][33];
    int tid = threadIdx.x;
    for (int i = tid; i < 3072; i += 256) { sWi[i] = Wi[i]; sWh[i] = Wh[i]; }
    if (tid < 96) { sBi[tid] = bi[tid]; sBh[tid] = bh[tid]; }
    if (tid < 32) sCb[tid] = convB[tid];
    int ln = tid >> 5, o = tid & 31;
    for (int g = 0; g < 4; ++g) {
        int node = blockIdx.x * 32 + g * 8 + ln;
        float hv = h[node * 32 + o];
        float av = agg[node * 32 + o];
        __syncthreads();
        sX[ln][o] = fmaxf(av + sCb[o], 0.f);
        sH[ln][o] = hv;
        __syncthreads();
        float air = sBi[o], aiz = sBi[o + 32], ain = sBi[o + 64];
        float ahr = sBh[o], ahz = sBh[o + 32], ahn = sBh[o + 64];
        #pragma unroll 8
        for (int i = 0; i < 32; ++i) {
            float x = sX[ln][i], hh = sH[ln][i];
            air += x * sWi[i * 96 + o];      ahr += hh * sWh[i * 96 + o];
            aiz += x * sWi[i * 96 + o + 32]; ahz += hh * sWh[i * 96 + o + 32];
            ain += x * sWi[i * 96 + o + 64]; ahn += hh * sWh[i * 96 + o + 64];
        }
        float r = sigm(air + ahr);
        float zz = sigm(aiz + ahz);
        float ng = tanhf(ain + r * ahn);
        h[node * 32 + o] = (1.f - zz) * ng + zz * hv;
    }
}

// ---- MODE 1: per 32-node dst tile: segment-sum -> X in LDS, GRU via split-bf16 MFMA.
__global__ __launch_bounds__(256) void k_gruAgg4(
    const float* __restrict__ msgbuf, const int* __restrict__ nodeOffs,
    const float* __restrict__ convB,
    const unsigned short* __restrict__ Whi, const unsigned short* __restrict__ Wlo,
    const float* __restrict__ bi, const float* __restrict__ bh,
    float* __restrict__ h) {
    __shared__ float sAgg[32 * 33];
    int tid = threadIdx.x;
    int d = blockIdx.x;
    int base = d * 32;

    {
        int n8 = tid >> 3, l8 = tid & 7;
        int node = base + n8;
        int nb = nodeOffs[node], ne2 = nodeOffs[node + 1];
        float a0 = 0.f, a1 = 0.f, a2 = 0.f, a3 = 0.f;
        for (int p = nb; p < ne2; ++p) {
            float4 v = *(const float4*)(msgbuf + (size_t)p * 32 + (l8 << 2));
            a0 += v.x; a1 += v.y; a2 += v.z; a3 += v.w;
        }
        int c0 = l8 << 2;
        float4 cb = *(const float4*)(convB + c0);
        float* sp = sAgg + n8 * 33 + c0;
        sp[0] = fmaxf(a0 + cb.x, 0.f);
        sp[1] = fmaxf(a1 + cb.y, 0.f);
        sp[2] = fmaxf(a2 + cb.z, 0.f);
        sp[3] = fmaxf(a3 + cb.w, 0.f);
    }
    __syncthreads();

    int wave = tid >> 6, lane = tid & 63;
    int m = wave >> 1, c = wave & 1;
    int arow = lane & 15, kg = (lane >> 4) << 2;

    bf16x8 xhi, xlo, hhi, hlo;
    {
        const float* xp = sAgg + (m * 16 + arow) * 33 + kg;
        float4 v0 = *(const float4*)xp;
        float4 v1 = *(const float4*)(xp + 16);
        float xv[8] = {v0.x, v0.y, v0.z, v0.w, v1.x, v1.y, v1.z, v1.w};
        #pragma unroll
        for (int j = 0; j < 8; ++j) {
            unsigned short hi16 = f2bf(xv[j]);
            xhi[j] = (short)hi16;
            xlo[j] = (short)f2bf(xv[j] - bf2f(hi16));
        }
        const float* hp = h + (size_t)(base + m * 16 + arow) * 32 + kg;
        float4 w0 = *(const float4*)hp;
        float4 w1 = *(const float4*)(hp + 16);
        float hv8[8] = {w0.x, w0.y, w0.z, w0.w, w1.x, w1.y, w1.z, w1.w};
        #pragma unroll
        for (int j = 0; j < 8; ++j) {
            unsigned short hi16 = f2bf(hv8[j]);
            hhi[j] = (short)hi16;
            hlo[j] = (short)f2bf(hv8[j] - bf2f(hi16));
        }
    }

    int ccol = lane & 15, crow0 = (lane >> 4) << 2;
    int o = c * 16 + ccol;
    auto Bf = [&](int nt, int kt, const unsigned short* W) {
        return *(const bf16x8*)(W + (size_t)(((nt * 2 + kt) * 64 + lane) << 3));
    };
    f32x4 accR = {0.f, 0.f, 0.f, 0.f}, accZ = {0.f, 0.f, 0.f, 0.f};
    f32x4 accIN = {0.f, 0.f, 0.f, 0.f}, accHN = {0.f, 0.f, 0.f, 0.f};
    {
        int nt = c;
        bf16x8 b0h = Bf(nt, 0, Whi), b0l = Bf(nt, 0, Wlo);
        bf16x8 b1h = Bf(nt, 1, Whi), b1l = Bf(nt, 1, Wlo);
        accR = __builtin_amdgcn_mfma_f32_16x16x32_bf16(xhi, b0h, accR, 0, 0, 0);
        accR = __builtin_amdgcn_mfma_f32_16x16x32_bf16(xlo, b0h, accR, 0, 0, 0);
        accR = __builtin_amdgcn_mfma_f32_16x16x32_bf16(xhi, b0l, accR, 0, 0, 0);
        accR = __builtin_amdgcn_mfma_f32_16x16x32_bf16(hhi, b1h, accR, 0, 0, 0);
        accR = __builtin_amdgcn_mfma_f32_16x16x32_bf16(hlo, b1h, accR, 0, 0, 0);
        accR = __builtin_amdgcn_mfma_f32_16x16x32_bf16(hhi, b1l, accR, 0, 0, 0);
    }
    {
        int nt = 2 + c;
        bf16x8 b0h = Bf(nt, 0, Whi), b0l = Bf(nt, 0, Wlo);
        bf16x8 b1h = Bf(nt, 1, Whi), b1l = Bf(nt, 1, Wlo);
        accZ = __builtin_amdgcn_mfma_f32_16x16x32_bf16(xhi, b0h, accZ, 0, 0, 0);
        accZ = __builtin_amdgcn_mfma_f32_16x16x32_bf16(xlo, b0h, accZ, 0, 0, 0);
        accZ = __builtin_amdgcn_mfma_f32_16x16x32_bf16(xhi, b0l, accZ, 0, 0, 0);
        accZ = __builtin_amdgcn_mfma_f32_16x16x32_bf16(hhi, b1h, accZ, 0, 0, 0);
        accZ = __builtin_amdgcn_mfma_f32_16x16x32_bf16(hlo, b1h, accZ, 0, 0, 0);
        accZ = __builtin_amdgcn_mfma_f32_16x16x32_bf16(hhi, b1l, accZ, 0, 0, 0);
    }
    {
        int nt = 4 + c;
        bf16x8 b0h = Bf(nt, 0, Whi), b0l = Bf(nt, 0, Wlo);
        bf16x8 b1h = Bf(nt, 1, Whi), b1l = Bf(nt, 1, Wlo);
        accIN = __builtin_amdgcn_mfma_f32_16x16x32_bf16(xhi, b0h, accIN, 0, 0, 0);
        accIN = __builtin_amdgcn_mfma_f32_16x16x32_bf16(xlo, b0h, accIN, 0, 0, 0);
        accIN = __builtin_amdgcn_mfma_f32_16x16x32_bf16(xhi, b0l, accIN, 0, 0, 0);
        accHN = __builtin_amdgcn_mfma_f32_16x16x32_bf16(hhi, b1h, accHN, 0, 0, 0);
        accHN = __builtin_amdgcn_mfma_f32_16x16x32_bf16(hlo, b1h, accHN, 0, 0, 0);
        accHN = __builtin_amdgcn_mfma_f32_16x16x32_bf16(hhi, b1l, accHN, 0, 0, 0);
    }

    float bir = bi[o], biz = bi[32 + o], bin = bi[64 + o];
    float bhr = bh[o], bhz = bh[32 + o], bhn = bh[64 + o];
    float hv[4];
    #pragma unroll
    for (int j = 0; j < 4; ++j)
        hv[j] = h[(size_t)(base + m * 16 + crow0 + j) * 32 + o];
    __syncthreads();
    #pragma unroll
    for (int j = 0; j < 4; ++j) {
        float r  = sigm(accR[j] + bir + bhr);
        float zz = sigm(accZ[j] + biz + bhz);
        float ng = tanhf(accIN[j] + bin + r * (accHN[j] + bhn));
        h[(size_t)(base + m * 16 + crow0 + j) * 32 + o] = (1.f - zz) * ng + zz * hv[j];
    }
}

// ---- decoder
__global__ __launch_bounds__(256) void k_dec(
    const float* __restrict__ h,
    const float* __restrict__ W1, const float* __restrict__ b1, const float* __restrict__ a1,
    const float* __restrict__ W2, const float* __restrict__ b2, const float* __restrict__ a2,
    const float* __restrict__ W3, const float* __restrict__ b3, const float* __restrict__ a3,
    const float* __restrict__ W4, const float* __restrict__ b4,
    float* __restrict__ out) {
    __shared__ float sW1[1024], sW2[1024], sW3[1024], sW4[96];
    __shared__ float sB1[32], sB2[32], sB3[32], sB4[3];
    __shared__ float sYa[8][33], sYb[8][33];
    int tid = threadIdx.x;
    for (int i = tid; i < 1024; i += 256) { sW1[i] = W1[i]; sW2[i] = W2[i]; sW3[i] = W3[i]; }
    if (tid < 96) sW4[tid] = W4[tid];
    if (tid < 32) { sB1[tid] = b1[tid]; sB2[tid] = b2[tid]; sB3[tid] = b3[tid]; }
    if (tid < 3) sB4[tid] = b4[tid];
    float A1 = a1[0], A2 = a2[0], A3 = a3[0];
    int ln = tid >> 5, o = tid & 31;
    int node = blockIdx.x * 8 + ln;
    sYa[ln][o] = h[node * 32 + o];
    __syncthreads();
    float acc = sB1[o];
    #pragma unroll
    for (int i = 0; i < 32; ++i) acc += sYa[ln][i] * sW1[i * 32 + o];
    acc = acc >= 0.f ? acc : A1 * acc;
    sYb[ln][o] = acc;
    __syncthreads();
    acc = sB2[o];
    #pragma unroll
    for (int i = 0; i < 32; ++i) acc += sYb[ln][i] * sW2[i * 32 + o];
    acc = acc >= 0.f ? acc : A2 * acc;
    __syncthreads();
    sYa[ln][o] = acc;
    __syncthreads();
    acc = sB3[o];
    #pragma unroll
    for (int i = 0; i < 32; ++i) acc += sYa[ln][i] * sW3[i * 32 + o];
    acc = acc >= 0.f ? acc : A3 * acc;
    __syncthreads();
    sYb[ln][o] = acc;
    __syncthreads();
    if (o < 3) {
        float r = sB4[o];
        #pragma unroll
        for (int i = 0; i < 32; ++i) r += sYb[ln][i] * sW4[i * 3 + o];
        out[node * 3 + o] = r;
    }
}

extern "C" void kernel_launch(void* const* d_in, const int* in_sizes, int n_in,
                              void* d_out, int out_size, void* d_ws, size_t ws_size,
                              hipStream_t stream) {
    const int*   nfeats = (const int*)d_in[0];
    const float* efeats = (const float*)d_in[1];
    const int*   src    = (const int*)d_in[2];
    const int*   dst    = (const int*)d_in[3];
    const float* emb    = (const float*)d_in[4];
    const float* encW   = (const float*)d_in[5];
    const float* encB   = (const float*)d_in[6];
    const float* eencW  = (const float*)d_in[7];
    const float* eencB  = (const float*)d_in[8];
    const float* projW  = (const float*)d_in[9];
    const float* projB  = (const float*)d_in[10];
    const float* enW1   = (const float*)d_in[11];
    const float* enB1   = (const float*)d_in[12];
    const float* enW2   = (const float*)d_in[13];
    const float* enB2   = (const float*)d_in[14];
    const float* convB  = (const float*)d_in[15];
    const float* gruWi  = (const float*)d_in[16];
    const float* gruWh  = (const float*)d_in[17];
    const float* gruBi  = (const float*)d_in[18];
    const float* gruBh  = (const float*)d_in[19];
    const float* dW1 = (const float*)d_in[20]; const float* db1 = (const float*)d_in[21]; const float* da1 = (const float*)d_in[22];
    const float* dW2 = (const float*)d_in[23]; const float* db2 = (const float*)d_in[24]; const float* da2 = (const float*)d_in[25];
    const float* dW3 = (const float*)d_in[26]; const float* db3 = (const float*)d_in[27]; const float* da3 = (const float*)d_in[28];
    const float* dW4 = (const float*)d_in[29]; const float* db4 = (const float*)d_in[30];
    float* out = (float*)d_out;
    char* ws = (char*)d_ws;

    // bump allocator (256-B aligned)
    size_t cur = 0;
    auto alloc = [&](size_t n) { size_t p = cur; cur = (cur + n + 255) & ~(size_t)255; return p; };
    size_t o_h   = alloc((size_t)NN * 32 * 4);
    size_t o_t   = alloc((size_t)NE * 32 * 4);      // tS (or t in fallback)
    size_t o_w2e = alloc((size_t)32 * QC * 4);
    size_t afterCommon = cur;                       // fallback agg goes here
    size_t o_w2b = alloc((size_t)66 * 512 * 2);
    size_t o_epS = alloc((size_t)NE * 4);
    size_t o_ofS = alloc((size_t)(NTS + 1) * 4);
    size_t o_posS = alloc((size_t)NE * 4);
    size_t o_srcS = alloc((size_t)NE * 4);
    size_t o_idxS = alloc((size_t)NE * 4);
    size_t o_wcomb = alloc((size_t)(512 + 32) * 4);
    size_t baseEnd = cur;                           // MODE0 agg goes here
    size_t o_epD  = alloc((size_t)NE * 4);
    size_t o_ofD  = alloc((size_t)(NT_D + 1) * 4);
    size_t o_epD2 = alloc((size_t)NE * 4);
    size_t o_noff = alloc((size_t)(NN + 1) * 4);
    size_t o_whi  = alloc((size_t)6144 * 2);
    size_t o_wlo  = alloc((size_t)6144 * 2);
    size_t o_msg  = alloc((size_t)NE * 32 * 4);     // MODE1 msgbuf
    size_t need1 = cur;
    size_t need0 = baseEnd + (size_t)NN * 32 * 4;

    int mode;                                       // 1: node-sorted, 0: atomic, -1: msgC
    if (ws_size >= need1) mode = 1;
    else if (ws_size >= need0) mode = 0;
    else mode = -1;

    float* h     = (float*)(ws + o_h);
    float* tS    = (float*)(ws + o_t);
    float* W2ext = (float*)(ws + o_w2e);
    unsigned short* W2bf = (unsigned short*)(ws + o_w2b);
    int* epermS  = (int*)(ws + o_epS);
    int* offsS   = (int*)(ws + o_ofS);
    int* posS    = (int*)(ws + o_posS);
    int* srcS    = (int*)(ws + o_srcS);
    int* idxS    = (int*)(ws + o_idxS);
    float* Wcomb = (float*)(ws + o_wcomb);
    float* bcomb = Wcomb + 512;
    int* epermD  = (int*)(ws + o_epD);
    int* offsD   = (int*)(ws + o_ofD);
    int* epermD2 = (int*)(ws + o_epD2);
    int* nodeOffs = (int*)(ws + o_noff);
    unsigned short* gWhi = (unsigned short*)(ws + o_whi);
    unsigned short* gWlo = (unsigned short*)(ws + o_wlo);
    float* outbuf = (mode == 1) ? (float*)(ws + o_msg)
                  : (mode == 0) ? (float*)(ws + baseEnd)
                                : (float*)(ws + afterCommon);
    // scratch (prologue only) unions into outbuf region
    int* blockCounts = (int*)outbuf;
    int* blockStart  = blockCounts + (size_t)HB * NTS;
    int* tileTot     = blockStart + (size_t)HB * NTS;

    k_node_enc<<<NN / 8, 256, 0, stream>>>(nfeats, emb, encW, encB, projW, projB, h);
    k_wcomb<<<1, 544, 0, stream>>>(eencW, eencB, enW1, enB1, Wcomb, bcomb);

    if (mode >= 0) {
        k_w2prep<<<(66 * 512 + 255) / 256, 256, 0, stream>>>(enW2, enB2, W2bf);
        // src bucketing (16-node tiles)
        k_histT<NTS, 4><<<HB, 256, 0, stream>>>(src, blockCounts);
        k_colsumT<NTS><<<(NTS + 255) / 256, 256, 0, stream>>>(blockCounts, blockStart, tileTot);
        k_scanT<NTS, 25><<<1, 256, 0, stream>>>(tileTot, offsS);
        k_scatterT<NTS, 4><<<HB, 256, 0, stream>>>(src, blockStart, offsS, epermS);
        k_invperm<<<(NE + 255) / 256, 256, 0, stream>>>(epermS, posS);
        k_gatherKey<<<(NE + 255) / 256, 256, 0, stream>>>(epermS, src, srcS);
        if (mode == 1) {
            k_wgru<<<(6144 + 255) / 256, 256, 0, stream>>>(gruWi, gruWh, gWhi, gWlo);
            k_histT<NT_D, 5><<<HB, 256, 0, stream>>>(dst, blockCounts);
            k_colsumT<NT_D><<<(NT_D + 255) / 256, 256, 0, stream>>>(blockCounts, blockStart, tileTot);
            k_scanT<NT_D, 13><<<1, 256, 0, stream>>>(tileTot, offsD);
            k_scatterT<NT_D, 5><<<HB, 256, 0, stream>>>(dst, blockStart, offsD, epermD);
            k_sortNode<<<NT_D, 256, 0, stream>>>(epermD, dst, offsD, epermD2, nodeOffs);
            k_scatterIdx<<<(NE + 255) / 256, 256, 0, stream>>>(epermD2, posS, idxS);
        } else {
            k_gatherKey<<<(NE + 255) / 256, 256, 0, stream>>>(epermS, dst, idxS);
        }
        k_edge_t3<<<NE / 128, 256, 0, stream>>>(efeats, Wcomb, bcomb, epermS, tS);
    } else {
        k_w2ext<<<(32 * QC + 255) / 256, 256, 0, stream>>>(enW2, enB2, W2ext);
        k_edge_t3<<<NE / 128, 256, 0, stream>>>(efeats, Wcomb, bcomb, nullptr, tS);
    }

    for (int s = 0; s < 3; ++s) {
        if (mode == 1) {
            k_msgF16<1><<<NTS, 256, 0, stream>>>(h, W2bf, tS, srcS, idxS, offsS, outbuf);
            k_gruAgg4<<<NT_D, 256, 0, stream>>>(outbuf, nodeOffs, convB,
                                                gWhi, gWlo, gruBi, gruBh, h);
        } else if (mode == 0) {
            hipMemsetAsync(outbuf, 0, (size_t)NN * 32 * 4, stream);
            k_msgF16<0><<<NTS, 256, 0, stream>>>(h, W2bf, tS, srcS, idxS, offsS, outbuf);
            k_gru<<<NN / 32, 256, 0, stream>>>(outbuf, convB, gruWi, gruWh, gruBi, gruBh, h);
        } else {
            hipMemsetAsync(outbuf, 0, (size_t)NN * 32 * 4, stream);
            k_msgC<<<NE / 32, 256, 0, stream>>>(tS, src, dst, h, W2ext, outbuf);
            k_gru<<<NN / 32, 256, 0, stream>>>(outbuf, convB, gruWi, gruWh, gruBi, gruBh, h);
        }
    }
    k_dec<<<NN / 8, 256, 0, stream>>>(h, dW1, db1, da1, dW2, db2, da2, dW3, db3, da3, dW4, db4, out);
}

// Round 18
// 413.963 us; speedup vs baseline: 1.2312x; 1.0660x over previous
//
#include <hip/hip_runtime.h>
#include <hip/hip_bf16.h>

// MPNN on MI355X — fused 16-node-tile msg kernel + MFMA GRU, fully pre-sorted streams.
// msg[e,o] = sum_k t[e,k]*Q[src,k,o] + q0[src,o],  Q[n] = h[n] @ W2ext
// k_msgF16: per 16-node src tile, MFMA Q (16x1056 bf16) into LDS (QSTRH=1072),
// barrier-free edge stream: 4 lanes/edge x 8 outputs, Q via ds_read_b128,
// t rows via same-address L1 broadcast. Edge encoder algebraically folded.
// k_gruAgg4: split-bf16 MFMA GRU. No global atomics (MODE1).
// Prologue consolidated: prepAll / histB / colsumB / scanB / scatterB / invgather.

#define NN 100000
#define NE 320000
#define QC 1056
#define NTS 6250      // NN/16 src tiles
#define NT_D 3125     // NN/32 dst tiles
#define HB 256        // bucketing blocks
#define EPB (NE / HB) // 1250
#define QSTRH 1072    // sQ row stride (shorts)

typedef short bf16x8 __attribute__((ext_vector_type(8)));
typedef float f32x4  __attribute__((ext_vector_type(4)));

__device__ __forceinline__ float bf2f(unsigned short u) {
    return __uint_as_float(((unsigned int)u) << 16);
}
__device__ __forceinline__ unsigned short f2bf(float f) {
    unsigned int x = __float_as_uint(f);
    unsigned int r = (x + 0x7fffu + ((x >> 16) & 1u)) >> 16;
    return (unsigned short)r;
}
__device__ __forceinline__ float sigm(float x) {
    return 1.f / (1.f + __expf(-x));
}

// ---- build W2ext [32][1056] (fp32, msgC fallback only)
__global__ __launch_bounds__(256) void k_w2ext(const float* __restrict__ W2,
                                               const float* __restrict__ b2,
                                               float* __restrict__ W2ext) {
    int idx = blockIdx.x * 256 + threadIdx.x;
    if (idx >= 32 * QC) return;
    int i = idx / QC, c = idx % QC;
    float v;
    if (c < 1024) { int k = c >> 5, o = c & 31; v = W2[k * 1024 + i * 32 + o]; }
    else          { v = b2[i * 32 + (c - 1024)]; }
    W2ext[idx] = v;
}

// ---- merged weight prep: W2bf (33792) + GRU hi/lo (6144) + Wcomb/bcomb (544)
__global__ __launch_bounds__(256) void k_prepAll(
    const float* __restrict__ W2, const float* __restrict__ b2,
    unsigned short* __restrict__ W2bf,
    const float* __restrict__ Wi, const float* __restrict__ Wh,
    unsigned short* __restrict__ Whi, unsigned short* __restrict__ Wlo,
    const float* __restrict__ eencW, const float* __restrict__ eencB,
    const float* __restrict__ enW1, const float* __restrict__ enB1,
    float* __restrict__ Wcomb, float* __restrict__ bcomb) {
    int idx = blockIdx.x * 256 + threadIdx.x;
    if (idx < 66 * 512) {
        int ct = idx >> 9, l = (idx >> 3) & 63, j = idx & 7;
        int kk = ((j >> 2) << 4) + ((l >> 4) << 2) + (j & 3);
        int c = ct * 16 + (l & 15);
        float v;
        if (c < 1024) { int kb = c >> 5, o = c & 31; v = W2[kb * 1024 + kk * 32 + o]; }
        else          { v = b2[kk * 32 + (c - 1024)]; }
        W2bf[idx] = f2bf(v);
    } else if (idx < 66 * 512 + 6144) {
        int q = idx - 66 * 512;
        int j = q & 7, l = (q >> 3) & 63, kt = (q >> 9) & 1, nt = q >> 10;
        int k = ((j >> 2) << 4) + ((l >> 4) << 2) + (j & 3);
        int col = nt * 16 + (l & 15);
        float v = kt ? Wh[k * 96 + col] : Wi[k * 96 + col];
        unsigned short hi = f2bf(v);
        Whi[q] = hi;
        Wlo[q] = f2bf(v - bf2f(hi));
    } else if (idx < 66 * 512 + 6144 + 544) {
        int q = idx - 66 * 512 - 6144;
        if (q < 512) {
            int i = q >> 5, o = q & 31;
            float acc = 0.f;
            #pragma unroll 8
            for (int j = 0; j < 32; ++j) acc += eencW[i * 32 + j] * enW1[j * 32 + o];
            Wcomb[i * 32 + o] = acc;
        } else {
            int o = q - 512;
            float acc = enB1[o];
            #pragma unroll 8
            for (int j = 0; j < 32; ++j) acc += eencB[j] * enW1[j * 32 + o];
            bcomb[o] = acc;
        }
    }
}

// ---- merged histograms: blocks [0,HB) src/NTS, [HB,2HB) dst/NT_D
__global__ __launch_bounds__(256) void k_histB(const int* __restrict__ src,
                                               const int* __restrict__ dst,
                                               int* __restrict__ bcS,
                                               int* __restrict__ bcD) {
    __shared__ int sHist[NTS];
    int tid = threadIdx.x, b = blockIdx.x;
    bool isS = b < HB;
    int bb = isS ? b : b - HB;
    const int* keys = isS ? src : dst;
    int NT = isS ? NTS : NT_D;
    int SH = isS ? 4 : 5;
    for (int c = tid; c < NT; c += 256) sHist[c] = 0;
    __syncthreads();
    int beg = bb * EPB, end = min(beg + EPB, NE);
    for (int e = beg + tid; e < end; e += 256)
        atomicAdd(&sHist[keys[e] >> SH], 1);
    __syncthreads();
    int* out = isS ? bcS : bcD;
    for (int c = tid; c < NT; c += 256) out[bb * NT + c] = sHist[c];
}

// ---- merged column sums
__global__ __launch_bounds__(256) void k_colsumB(const int* __restrict__ bcS,
                                                 const int* __restrict__ bcD,
                                                 int* __restrict__ bsS,
                                                 int* __restrict__ bsD,
                                                 int* __restrict__ totS,
                                                 int* __restrict__ totD) {
    int c = blockIdx.x * 256 + threadIdx.x;
    if (c < NTS) {
        int running = 0;
        #pragma unroll 8
        for (int b = 0; b < HB; ++b) {
            bsS[b * NTS + c] = running;
            running += bcS[b * NTS + c];
        }
        totS[c] = running;
    } else if (c < NTS + NT_D) {
        int cc = c - NTS;
        int running = 0;
        #pragma unroll 8
        for (int b = 0; b < HB; ++b) {
            bsD[b * NT_D + cc] = running;
            running += bcD[b * NT_D + cc];
        }
        totD[cc] = running;
    }
}

// ---- merged scans (block 0: src, block 1: dst)
__global__ __launch_bounds__(256) void k_scanB(const int* __restrict__ totS,
                                               const int* __restrict__ totD,
                                               int* __restrict__ offS,
                                               int* __restrict__ offD) {
    __shared__ int sTot[NTS];
    __shared__ int sPart[257];
    int tid = threadIdx.x;
    const int* tot = (blockIdx.x == 0) ? totS : totD;
    int* offs = (blockIdx.x == 0) ? offS : offD;
    int NT = (blockIdx.x == 0) ? NTS : NT_D;
    int SEG = (blockIdx.x == 0) ? 25 : 13;
    for (int c = tid; c < NT; c += 256) sTot[c] = tot[c];
    __syncthreads();
    int base = tid * SEG;
    int loc = 0;
    for (int j = 0; j < SEG; ++j) {
        int c = base + j;
        if (c < NT) { int v = sTot[c]; sTot[c] = loc; loc += v; }
    }
    sPart[tid] = loc;
    __syncthreads();
    if (tid == 0) {
        int s = 0;
        for (int i = 0; i < 256; ++i) { int v = sPart[i]; sPart[i] = s; s += v; }
        sPart[256] = s;
    }
    __syncthreads();
    int add = sPart[tid];
    for (int j = 0; j < SEG; ++j) {
        int c = base + j;
        if (c < NT) sTot[c] += add;
    }
    __syncthreads();
    for (int c = tid; c < NT; c += 256) offs[c] = sTot[c];
    if (tid == 0) offs[NT] = sPart[256];
}

// ---- merged scatters
__global__ __launch_bounds__(256) void k_scatterB(const int* __restrict__ src,
                                                  const int* __restrict__ dst,
                                                  const int* __restrict__ bsS,
                                                  const int* __restrict__ bsD,
                                                  const int* __restrict__ offS,
                                                  const int* __restrict__ offD,
                                                  int* __restrict__ epS,
                                                  int* __restrict__ epD) {
    __shared__ int sCur[NTS];
    int tid = threadIdx.x, b = blockIdx.x;
    bool isS = b < HB;
    int bb = isS ? b : b - HB;
    const int* keys = isS ? src : dst;
    const int* bs = isS ? bsS : bsD;
    const int* offs = isS ? offS : offD;
    int* ep = isS ? epS : epD;
    int NT = isS ? NTS : NT_D;
    int SH = isS ? 4 : 5;
    for (int c = tid; c < NT; c += 256)
        sCur[c] = offs[c] + bs[bb * NT + c];
    __syncthreads();
    int beg = bb * EPB, end = min(beg + EPB, NE);
    for (int e = beg + tid; e < end; e += 256) {
        int pos = atomicAdd(&sCur[keys[e] >> SH], 1);
        ep[pos] = e;
    }
}

// ---- merged invperm + src gather: posS[epermS[p]]=p ; srcS[p]=src[epermS[p]]
__global__ __launch_bounds__(256) void k_invgather(const int* __restrict__ epermS,
                                                   const int* __restrict__ src,
                                                   int* __restrict__ posS,
                                                   int* __restrict__ srcS) {
    int p = blockIdx.x * 256 + threadIdx.x;
    if (p < NE) {
        int e = epermS[p];
        posS[e] = p;
        srcS[p] = src[e];
    }
}

// ---- node encoder + projection
__global__ __launch_bounds__(256) void k_node_enc(
    const int* __restrict__ nfeats, const float* __restrict__ emb,
    const float* __restrict__ encW, const float* __restrict__ encB,
    const float* __restrict__ projW, const float* __restrict__ projB,
    float* __restrict__ h) {
    __shared__ float sEncW[1024], sProjW[1024], sEncB[32], sProjB[32];
    __shared__ float sEmb[8][33], sNh[8][33];
    int tid = threadIdx.x;
    for (int i = tid; i < 1024; i += 256) { sEncW[i] = encW[i]; sProjW[i] = projW[i]; }
    if (tid < 32) { sEncB[tid] = encB[tid]; sProjB[tid] = projB[tid]; }
    int ln = tid >> 5, o = tid & 31;
    int node = blockIdx.x * 8 + ln;
    int nt = nfeats[node];
    sEmb[ln][o] = fmaxf(emb[nt * 32 + o], 0.f);
    __syncthreads();
    float acc = sEncB[o];
    #pragma unroll
    for (int i = 0; i < 32; ++i) acc += sEmb[ln][i] * sEncW[i * 32 + o];
    sNh[ln][o] = fmaxf(acc, 0.f);
    __syncthreads();
    float acc2 = sProjB[o];
    #pragma unroll
    for (int i = 0; i < 32; ++i) acc2 += sNh[ln][i] * sProjW[i * 32 + o];
    h[node * 32 + o] = fmaxf(acc2, 0.f);
}

// ---- edge encoder (folded): 128 edges/block, weights in registers, no barriers
__global__ __launch_bounds__(256) void k_edge_t3(
    const float* __restrict__ efeats, const float* __restrict__ Wcomb,
    const float* __restrict__ bcomb, const int* __restrict__ eperm,
    float* __restrict__ tS) {
    int tid = threadIdx.x;
    int el = tid >> 3, l8 = tid & 7;
    int gbase = (tid & 63) & 56;
    int c0 = l8 << 2;
    float4 w[16];
    #pragma unroll
    for (int i = 0; i < 16; ++i) w[i] = *(const float4*)(Wcomb + i * 32 + c0);
    float4 bb = *(const float4*)(bcomb + c0);
    #pragma unroll
    for (int it = 0; it < 4; ++it) {
        int p = blockIdx.x * 128 + it * 32 + el;
        int e = eperm ? eperm[p] : p;
        float2 efv = *(const float2*)(efeats + (size_t)e * 16 + (l8 << 1));
        float a0 = bb.x, a1 = bb.y, a2 = bb.z, a3 = bb.w;
        #pragma unroll
        for (int i = 0; i < 8; ++i) {
            float f0 = __shfl(efv.x, gbase + i, 64);
            float f1 = __shfl(efv.y, gbase + i, 64);
            float4 w0 = w[2 * i], w1 = w[2 * i + 1];
            a0 += f0 * w0.x + f1 * w1.x;
            a1 += f0 * w0.y + f1 * w1.y;
            a2 += f0 * w0.z + f1 * w1.z;
            a3 += f0 * w0.w + f1 * w1.w;
        }
        *(float4*)(tS + (size_t)p * 32 + c0) =
            make_float4(fmaxf(a0, 0.f), fmaxf(a1, 0.f), fmaxf(a2, 0.f), fmaxf(a3, 0.f));
    }
}

// ---- legacy single-purpose bucketing kernels (fallback modes only)
template<int NT, int SHIFT>
__global__ __launch_bounds__(256) void k_histT(const int* __restrict__ keys,
                                               int* __restrict__ blockCounts) {
    __shared__ int sHist[NT];
    int tid = threadIdx.x, b = blockIdx.x;
    for (int c = tid; c < NT; c += 256) sHist[c] = 0;
    __syncthreads();
    int beg = b * EPB, end = min(beg + EPB, NE);
    for (int e = beg + tid; e < end; e += 256)
        atomicAdd(&sHist[keys[e] >> SHIFT], 1);
    __syncthreads();
    for (int c = tid; c < NT; c += 256) blockCounts[b * NT + c] = sHist[c];
}

template<int NT>
__global__ __launch_bounds__(256) void k_colsumT(const int* __restrict__ blockCounts,
                                                 int* __restrict__ blockStart,
                                                 int* __restrict__ tileTot) {
    int c = blockIdx.x * 256 + threadIdx.x;
    if (c >= NT) return;
    int running = 0;
    #pragma unroll 8
    for (int b = 0; b < HB; ++b) {
        blockStart[b * NT + c] = running;
        running += blockCounts[b * NT + c];
    }
    tileTot[c] = running;
}

template<int NT, int SEG>
__global__ __launch_bounds__(256) void k_scanT(const int* __restrict__ tileTot,
                                               int* __restrict__ offs) {
    __shared__ int sTot[NT];
    __shared__ int sPart[257];
    int tid = threadIdx.x;
    for (int c = tid; c < NT; c += 256) sTot[c] = tileTot[c];
    __syncthreads();
    int base = tid * SEG;
    int loc = 0;
    for (int j = 0; j < SEG; ++j) {
        int c = base + j;
        if (c < NT) { int v = sTot[c]; sTot[c] = loc; loc += v; }
    }
    sPart[tid] = loc;
    __syncthreads();
    if (tid == 0) {
        int s = 0;
        for (int i = 0; i < 256; ++i) { int v = sPart[i]; sPart[i] = s; s += v; }
        sPart[256] = s;
    }
    __syncthreads();
    int add = sPart[tid];
    for (int j = 0; j < SEG; ++j) {
        int c = base + j;
        if (c < NT) sTot[c] += add;
    }
    __syncthreads();
    for (int c = tid; c < NT; c += 256) offs[c] = sTot[c];
    if (tid == 0) offs[NT] = sPart[256];
}

template<int NT, int SHIFT>
__global__ __launch_bounds__(256) void k_scatterT(const int* __restrict__ keys,
                                                  const int* __restrict__ blockStart,
                                                  const int* __restrict__ offs,
                                                  int* __restrict__ eperm) {
    __shared__ int sCur[NT];
    int tid = threadIdx.x, b = blockIdx.x;
    for (int c = tid; c < NT; c += 256)
        sCur[c] = offs[c] + blockStart[b * NT + c];
    __syncthreads();
    int beg = b * EPB, end = min(beg + EPB, NE);
    for (int e = beg + tid; e < end; e += 256) {
        int pos = atomicAdd(&sCur[keys[e] >> SHIFT], 1);
        eperm[pos] = e;
    }
}

// ---- second-level sort: within each dst tile, sort by node (32 LDS bins)
__global__ __launch_bounds__(256) void k_sortNode(
    const int* __restrict__ epermD, const int* __restrict__ dst,
    const int* __restrict__ offsD, int* __restrict__ epermD2,
    int* __restrict__ nodeOffs) {
    __shared__ int sCnt[32], sStart[32];
    int tid = threadIdx.x, d = blockIdx.x;
    int beg = offsD[d], end = offsD[d + 1];
    if (tid < 32) sCnt[tid] = 0;
    __syncthreads();
    for (int p = beg + tid; p < end; p += 256)
        atomicAdd(&sCnt[dst[epermD[p]] & 31], 1);
    __syncthreads();
    if (tid == 0) {
        int s = beg;
        for (int r = 0; r < 32; ++r) { sStart[r] = s; s += sCnt[r]; }
    }
    __syncthreads();
    if (tid < 32) {
        nodeOffs[d * 32 + tid] = sStart[tid];
        sCnt[tid] = sStart[tid];
    }
    if (d == NT_D - 1 && tid == 0) nodeOffs[NN] = end;
    __syncthreads();
    for (int p = beg + tid; p < end; p += 256) {
        int e = epermD[p];
        int pos = atomicAdd(&sCnt[dst[e] & 31], 1);
        epermD2[pos] = e;
    }
}

// ---- inverse permutation (fallback path)
__global__ __launch_bounds__(256) void k_invperm(const int* __restrict__ eperm,
                                                 int* __restrict__ pos) {
    int p = blockIdx.x * 256 + threadIdx.x;
    if (p < NE) pos[eperm[p]] = p;
}

// ---- gather key into src-sorted positions (fallback path)
__global__ __launch_bounds__(256) void k_gatherKey(const int* __restrict__ epermS,
                                                   const int* __restrict__ key,
                                                   int* __restrict__ out) {
    int p = blockIdx.x * 256 + threadIdx.x;
    if (p < NE) out[p] = key[epermS[p]];
}

// ---- idxS[posS[epermD2[q]]] = q
__global__ __launch_bounds__(256) void k_scatterIdx(const int* __restrict__ epermD2,
                                                    const int* __restrict__ posS,
                                                    int* __restrict__ idxS) {
    int q = blockIdx.x * 256 + threadIdx.x;
    if (q < NE) idxS[posS[epermD2[q]]] = q;
}

// ---- fused per-16-node-src-tile: MFMA Q -> bf16 LDS; edge stream 4 lanes/edge x
// 8 outputs with ds_read_b128. MODE 0: atomicAdd; MODE 1: store to msgbuf slot.
template<int MODE>
__global__ __launch_bounds__(256) void k_msgF16(
    const float* __restrict__ h, const unsigned short* __restrict__ W2bf,
    const float* __restrict__ tS, const int* __restrict__ srcS,
    const int* __restrict__ idxS, const int* __restrict__ offs,
    float* __restrict__ outbuf) {
    __shared__ unsigned short sQ[16 * QSTRH];   // 34304 B
    int tid = threadIdx.x;
    int tile = blockIdx.x;
    int beg = offs[tile], end = offs[tile + 1];
    if (beg >= end) return;
    int nodeBase = tile * 16;
    int wave = tid >> 6, lane = tid & 63;

    int arow = lane & 15;
    const float* hp = h + (size_t)(nodeBase + arow) * 32 + ((lane >> 4) << 2);
    float4 x0 = *(const float4*)hp;
    float4 x1 = *(const float4*)(hp + 16);
    bf16x8 a;
    a[0] = (short)f2bf(x0.x); a[1] = (short)f2bf(x0.y);
    a[2] = (short)f2bf(x0.z); a[3] = (short)f2bf(x0.w);
    a[4] = (short)f2bf(x1.x); a[5] = (short)f2bf(x1.y);
    a[6] = (short)f2bf(x1.z); a[7] = (short)f2bf(x1.w);

    f32x4 z = {0.f, 0.f, 0.f, 0.f};
    int crow0 = (lane >> 4) << 2;
    int ccol = lane & 15;
    for (int ct = wave; ct < 66; ct += 4) {
        bf16x8 b = *(const bf16x8*)(W2bf + (size_t)((ct << 6) + lane) * 8);
        f32x4 acc = __builtin_amdgcn_mfma_f32_16x16x32_bf16(a, b, z, 0, 0, 0);
        unsigned short* qp = sQ + crow0 * QSTRH + (ct << 4) + ccol;
        qp[0 * QSTRH] = f2bf(acc[0]); qp[1 * QSTRH] = f2bf(acc[1]);
        qp[2 * QSTRH] = f2bf(acc[2]); qp[3 * QSTRH] = f2bf(acc[3]);
    }
    __syncthreads();   // the only barrier

    int el = tid >> 2, l4 = tid & 3;   // 64 edges in flight, 8 outputs/lane
    for (int p = beg + el; p < end; p += 64) {
        int row = srcS[p] - nodeBase;      // 4 lanes same addr -> broadcast
        int widx = idxS[p];
        float4 tq[8];
        #pragma unroll
        for (int i = 0; i < 8; ++i)
            tq[i] = *(const float4*)(tS + (size_t)p * 32 + (i << 2));
        const unsigned short* qp = sQ + row * QSTRH + (l4 << 3);
        bf16x8 qb = *(const bf16x8*)(qp + 1024);
        float acc[8];
        #pragma unroll
        for (int j = 0; j < 8; ++j) acc[j] = bf2f((unsigned short)qb[j]);
        #pragma unroll
        for (int kk = 0; kk < 8; ++kk) {
            float tv[4] = {tq[kk].x, tq[kk].y, tq[kk].z, tq[kk].w};
            #pragma unroll
            for (int m = 0; m < 4; ++m) {
                bf16x8 q = *(const bf16x8*)(qp + ((kk << 2) + m) * 32);
                float tk = tv[m];
                #pragma unroll
                for (int j = 0; j < 8; ++j)
                    acc[j] += tk * bf2f((unsigned short)q[j]);
            }
        }
        if (MODE) {
            float* op = outbuf + (size_t)widx * 32 + (l4 << 3);
            *(float4*)op = make_float4(acc[0], acc[1], acc[2], acc[3]);
            *(float4*)(op + 4) = make_float4(acc[4], acc[5], acc[6], acc[7]);
        } else {
            float* op = outbuf + (size_t)widx * 32 + (l4 << 3);
            #pragma unroll
            for (int j = 0; j < 8; ++j) atomicAdd(op + j, acc[j]);
        }
    }
}

// ---- fallback msg (tiny ws): recompute We per edge (t in original order)
__global__ __launch_bounds__(256) void k_msgC(
    const float* __restrict__ t, const int* __restrict__ src, const int* __restrict__ dst,
    const float* __restrict__ h, const float* __restrict__ W2ext, float* __restrict__ agg) {
    __shared__ float sT[32][33], sH[32][33];
    __shared__ int sSrc[32], sDst[32];
    int tid = threadIdx.x;
    int e0 = blockIdx.x * 32;
    if (tid < 32) sSrc[tid] = src[e0 + tid];
    else if (tid < 64) sDst[tid - 32] = dst[e0 + tid - 32];
    __syncthreads();
    for (int idx = tid; idx < 1024; idx += 256) {
        int el = idx >> 5, k = idx & 31;
        sT[el][k] = t[(e0 + el) * 32 + k];
        sH[el][k] = h[(size_t)sSrc[el] * 32 + k];
    }
    __syncthreads();
    int el = tid >> 3, l8 = tid & 7;
    int c0 = l8 * 4;
    float m0 = 0.f, m1 = 0.f, m2 = 0.f, m3 = 0.f;
    for (int i = 0; i < 32; ++i) {
        const float* wrow = W2ext + i * QC;
        float4 wb = *(const float4*)(wrow + 1024 + c0);
        float w0 = wb.x, w1 = wb.y, w2 = wb.z, w3 = wb.w;
        #pragma unroll 8
        for (int k = 0; k < 32; ++k) {
            float tk = sT[el][k];
            float4 w = *(const float4*)(wrow + k * 32 + c0);
            w0 += tk * w.x; w1 += tk * w.y; w2 += tk * w.z; w3 += tk * w.w;
        }
        float hi = sH[el][i];
        m0 += hi * w0; m1 += hi * w1; m2 += hi * w2; m3 += hi * w3;
    }
    float* ap = agg + (size_t)sDst[el] * 32 + c0;
    atomicAdd(ap + 0, m0); atomicAdd(ap + 1, m1);
    atomicAdd(ap + 2, m2); atomicAdd(ap + 3, m3);
}

// ---- GRU step reading agg[] (MODE 0 / fallback)
__global__ __launch_bounds__(256) void k_gru(
    const float* __restrict__ agg, const float* __restrict__ convB,
    const float* __restrict__ Wi, const float* __restrict__ Wh,
    const float* __restrict__ bi, const float* __restrict__ bh,
    float* __restrict__ h) {
    __shared__ float sWi[3072], sWh[3072], sBi[96], sBh[96], sCb[32];
    __shared__ float sX[8][33], sH[8][33];
    int tid = threadIdx.x;
    for (int i = tid; i < 3072; i += 256) { sWi[i] = Wi[i]; sWh[i] = Wh[i]; }
    if (tid < 96) { sBi[tid] = bi[tid]; sBh[tid] = bh[tid]; }
    if (tid < 32) sCb[tid] = convB[tid];
    int ln = tid >> 5, o = tid & 31;
    for (int g = 0; g < 4; ++g) {
        int node = blockIdx.x * 32 + g * 8 + ln;
        float hv = h[node * 32 + o];
        float av = agg[node * 32 + o];
        __syncthreads();
        sX[ln][o] = fmaxf(av + sCb[o], 0.f);
        sH[ln][o] = hv;
        __syncthreads();
        float air = sBi[o], aiz = sBi[o + 32], ain = sBi[o + 64];
        float ahr = sBh[o], ahz = sBh[o + 32], ahn = sBh[o + 64];
        #pragma unroll 8
        for (int i = 0; i < 32; ++i) {
            float x = sX[ln][i], hh = sH[ln][i];
            air += x * sWi[i * 96 + o];      ahr += hh * sWh[i * 96 + o];
            aiz += x * sWi[i * 96 + o + 32]; ahz += hh * sWh[i * 96 + o + 32];
            ain += x * sWi[i * 96 + o + 64]; ahn += hh * sWh[i * 96 + o + 64];
        }
        float r = sigm(air + ahr);
        float zz = sigm(aiz + ahz);
        float ng = tanhf(ain + r * ahn);
        h[node * 32 + o] = (1.f - zz) * ng + zz * hv;
    }
}

// ---- MODE 1: per 32-node dst tile: segment-sum -> X in LDS, GRU via split-bf16 MFMA.
__global__ __launch_bounds__(256) void k_gruAgg4(
    const float* __restrict__ msgbuf, const int* __restrict__ nodeOffs,
    const float* __restrict__ convB,
    const unsigned short* __restrict__ Whi, const unsigned short* __restrict__ Wlo,
    const float* __restrict__ bi, const float* __restrict__ bh,
    float* __restrict__ h) {
    __shared__ float sAgg[32 * 33];
    int tid = threadIdx.x;
    int d = blockIdx.x;
    int base = d * 32;

    {
        int n8 = tid >> 3, l8 = tid & 7;
        int node = base + n8;
        int nb = nodeOffs[node], ne2 = nodeOffs[node + 1];
        float a0 = 0.f, a1 = 0.f, a2 = 0.f, a3 = 0.f;
        for (int p = nb; p < ne2; ++p) {
            float4 v = *(const float4*)(msgbuf + (size_t)p * 32 + (l8 << 2));
            a0 += v.x; a1 += v.y; a2 += v.z; a3 += v.w;
        }
        int c0 = l8 << 2;
        float4 cb = *(const float4*)(convB + c0);
        float* sp = sAgg + n8 * 33 + c0;
        sp[0] = fmaxf(a0 + cb.x, 0.f);
        sp[1] = fmaxf(a1 + cb.y, 0.f);
        sp[2] = fmaxf(a2 + cb.z, 0.f);
        sp[3] = fmaxf(a3 + cb.w, 0.f);
    }
    __syncthreads();

    int wave = tid >> 6, lane = tid & 63;
    int m = wave >> 1, c = wave & 1;
    int arow = lane & 15, kg = (lane >> 4) << 2;

    bf16x8 xhi, xlo, hhi, hlo;
    {
        const float* xp = sAgg + (m * 16 + arow) * 33 + kg;
        float4 v0 = *(const float4*)xp;
        float4 v1 = *(const float4*)(xp + 16);
        float xv[8] = {v0.x, v0.y, v0.z, v0.w, v1.x, v1.y, v1.z, v1.w};
        #pragma unroll
        for (int j = 0; j < 8; ++j) {
            unsigned short hi16 = f2bf(xv[j]);
            xhi[j] = (short)hi16;
            xlo[j] = (short)f2bf(xv[j] - bf2f(hi16));
        }
        const float* hp = h + (size_t)(base + m * 16 + arow) * 32 + kg;
        float4 w0 = *(const float4*)hp;
        float4 w1 = *(const float4*)(hp + 16);
        float hv8[8] = {w0.x, w0.y, w0.z, w0.w, w1.x, w1.y, w1.z, w1.w};
        #pragma unroll
        for (int j = 0; j < 8; ++j) {
            unsigned short hi16 = f2bf(hv8[j]);
            hhi[j] = (short)hi16;
            hlo[j] = (short)f2bf(hv8[j] - bf2f(hi16));
        }
    }

    int ccol = lane & 15, crow0 = (lane >> 4) << 2;
    int o = c * 16 + ccol;
    auto Bf = [&](int nt, int kt, const unsigned short* W) {
        return *(const bf16x8*)(W + (size_t)(((nt * 2 + kt) * 64 + lane) << 3));
    };
    f32x4 accR = {0.f, 0.f, 0.f, 0.f}, accZ = {0.f, 0.f, 0.f, 0.f};
    f32x4 accIN = {0.f, 0.f, 0.f, 0.f}, accHN = {0.f, 0.f, 0.f, 0.f};
    {
        int nt = c;
        bf16x8 b0h = Bf(nt, 0, Whi), b0l = Bf(nt, 0, Wlo);
        bf16x8 b1h = Bf(nt, 1, Whi), b1l = Bf(nt, 1, Wlo);
        accR = __builtin_amdgcn_mfma_f32_16x16x32_bf16(xhi, b0h, accR, 0, 0, 0);
        accR = __builtin_amdgcn_mfma_f32_16x16x32_bf16(xlo, b0h, accR, 0, 0, 0);
        accR = __builtin_amdgcn_mfma_f32_16x16x32_bf16(xhi, b0l, accR, 0, 0, 0);
        accR = __builtin_amdgcn_mfma_f32_16x16x32_bf16(hhi, b1h, accR, 0, 0, 0);
        accR = __builtin_amdgcn_mfma_f32_16x16x32_bf16(hlo, b1h, accR, 0, 0, 0);
        accR = __builtin_amdgcn_mfma_f32_16x16x32_bf16(hhi, b1l, accR, 0, 0, 0);
    }
    {
        int nt = 2 + c;
        bf16x8 b0h = Bf(nt, 0, Whi), b0l = Bf(nt, 0, Wlo);
        bf16x8 b1h = Bf(nt, 1, Whi), b1l = Bf(nt, 1, Wlo);
        accZ = __builtin_amdgcn_mfma_f32_16x16x32_bf16(xhi, b0h, accZ, 0, 0, 0);
        accZ = __builtin_amdgcn_mfma_f32_16x16x32_bf16(xlo, b0h, accZ, 0, 0, 0);
        accZ = __builtin_amdgcn_mfma_f32_16x16x32_bf16(xhi, b0l, accZ, 0, 0, 0);
        accZ = __builtin_amdgcn_mfma_f32_16x16x32_bf16(hhi, b1h, accZ, 0, 0, 0);
        accZ = __builtin_amdgcn_mfma_f32_16x16x32_bf16(hlo, b1h, accZ, 0, 0, 0);
        accZ = __builtin_amdgcn_mfma_f32_16x16x32_bf16(hhi, b1l, accZ, 0, 0, 0);
    }
    {
        int nt = 4 + c;
        bf16x8 b0h = Bf(nt, 0, Whi), b0l = Bf(nt, 0, Wlo);
        bf16x8 b1h = Bf(nt, 1, Whi), b1l = Bf(nt, 1, Wlo);
        accIN = __builtin_amdgcn_mfma_f32_16x16x32_bf16(xhi, b0h, accIN, 0, 0, 0);
        accIN = __builtin_amdgcn_mfma_f32_16x16x32_bf16(xlo, b0h, accIN, 0, 0, 0);
        accIN = __builtin_amdgcn_mfma_f32_16x16x32_bf16(xhi, b0l, accIN, 0, 0, 0);
        accHN = __builtin_amdgcn_mfma_f32_16x16x32_bf16(hhi, b1h, accHN, 0, 0, 0);
        accHN = __builtin_amdgcn_mfma_f32_16x16x32_bf16(hlo, b1h, accHN, 0, 0, 0);
        accHN = __builtin_amdgcn_mfma_f32_16x16x32_bf16(hhi, b1l, accHN, 0, 0, 0);
    }

    float bir = bi[o], biz = bi[32 + o], bin = bi[64 + o];
    float bhr = bh[o], bhz = bh[32 + o], bhn = bh[64 + o];
    float hv[4];
    #pragma unroll
    for (int j = 0; j < 4; ++j)
        hv[j] = h[(size_t)(base + m * 16 + crow0 + j) * 32 + o];
    __syncthreads();
    #pragma unroll
    for (int j = 0; j < 4; ++j) {
        float r  = sigm(accR[j] + bir + bhr);
        float zz = sigm(accZ[j] + biz + bhz);
        float ng = tanhf(accIN[j] + bin + r * (accHN[j] + bhn));
        h[(size_t)(base + m * 16 + crow0 + j) * 32 + o] = (1.f - zz) * ng + zz * hv[j];
    }
}

// ---- decoder
__global__ __launch_bounds__(256) void k_dec(
    const float* __restrict__ h,
    const float* __restrict__ W1, const float* __restrict__ b1, const float* __restrict__ a1,
    const float* __restrict__ W2, const float* __restrict__ b2, const float* __restrict__ a2,
    const float* __restrict__ W3, const float* __restrict__ b3, const float* __restrict__ a3,
    const float* __restrict__ W4, const float* __restrict__ b4,
    float* __restrict__ out) {
    __shared__ float sW1[1024], sW2[1024], sW3[1024], sW4[96];
    __shared__ float sB1[32], sB2[32], sB3[32], sB4[3];
    __shared__ float sYa[8][33], sYb[8][33];
    int tid = threadIdx.x;
    for (int i = tid; i < 1024; i += 256) { sW1[i] = W1[i]; sW2[i] = W2[i]; sW3[i] = W3[i]; }
    if (tid < 96) sW4[tid] = W4[tid];
    if (tid < 32) { sB1[tid] = b1[tid]; sB2[tid] = b2[tid]; sB3[tid] = b3[tid]; }
    if (tid < 3) sB4[tid] = b4[tid];
    float A1 = a1[0], A2 = a2[0], A3 = a3[0];
    int ln = tid >> 5, o = tid & 31;
    int node = blockIdx.x * 8 + ln;
    sYa[ln][o] = h[node * 32 + o];
    __syncthreads();
    float acc = sB1[o];
    #pragma unroll
    for (int i = 0; i < 32; ++i) acc += sYa[ln][i] * sW1[i * 32 + o];
    acc = acc >= 0.f ? acc : A1 * acc;
    sYb[ln][o] = acc;
    __syncthreads();
    acc = sB2[o];
    #pragma unroll
    for (int i = 0; i < 32; ++i) acc += sYb[ln][i] * sW2[i * 32 + o];
    acc = acc >= 0.f ? acc : A2 * acc;
    __syncthreads();
    sYa[ln][o] = acc;
    __syncthreads();
    acc = sB3[o];
    #pragma unroll
    for (int i = 0; i < 32; ++i) acc += sYa[ln][i] * sW3[i * 32 + o];
    acc = acc >= 0.f ? acc : A3 * acc;
    __syncthreads();
    sYb[ln][o] = acc;
    __syncthreads();
    if (o < 3) {
        float r = sB4[o];
        #pragma unroll
        for (int i = 0; i < 32; ++i) r += sYb[ln][i] * sW4[i * 3 + o];
        out[node * 3 + o] = r;
    }
}

extern "C" void kernel_launch(void* const* d_in, const int* in_sizes, int n_in,
                              void* d_out, int out_size, void* d_ws, size_t ws_size,
                              hipStream_t stream) {
    const int*   nfeats = (const int*)d_in[0];
    const float* efeats = (const float*)d_in[1];
    const int*   src    = (const int*)d_in[2];
    const int*   dst    = (const int*)d_in[3];
    const float* emb    = (const float*)d_in[4];
    const float* encW   = (const float*)d_in[5];
    const float* encB   = (const float*)d_in[6];
    const float* eencW  = (const float*)d_in[7];
    const float* eencB  = (const float*)d_in[8];
    const float* projW  = (const float*)d_in[9];
    const float* projB  = (const float*)d_in[10];
    const float* enW1   = (const float*)d_in[11];
    const float* enB1   = (const float*)d_in[12];
    const float* enW2   = (const float*)d_in[13];
    const float* enB2   = (const float*)d_in[14];
    const float* convB  = (const float*)d_in[15];
    const float* gruWi  = (const float*)d_in[16];
    const float* gruWh  = (const float*)d_in[17];
    const float* gruBi  = (const float*)d_in[18];
    const float* gruBh  = (const float*)d_in[19];
    const float* dW1 = (const float*)d_in[20]; const float* db1 = (const float*)d_in[21]; const float* da1 = (const float*)d_in[22];
    const float* dW2 = (const float*)d_in[23]; const float* db2 = (const float*)d_in[24]; const float* da2 = (const float*)d_in[25];
    const float* dW3 = (const float*)d_in[26]; const float* db3 = (const float*)d_in[27]; const float* da3 = (const float*)d_in[28];
    const float* dW4 = (const float*)d_in[29]; const float* db4 = (const float*)d_in[30];
    float* out = (float*)d_out;
    char* ws = (char*)d_ws;

    // bump allocator (256-B aligned)
    size_t cur = 0;
    auto alloc = [&](size_t n) { size_t p = cur; cur = (cur + n + 255) & ~(size_t)255; return p; };
    size_t o_h   = alloc((size_t)NN * 32 * 4);
    size_t o_t   = alloc((size_t)NE * 32 * 4);      // tS (or t in fallback)
    size_t o_w2e = alloc((size_t)32 * QC * 4);
    size_t afterCommon = cur;                       // fallback agg goes here
    size_t o_w2b = alloc((size_t)66 * 512 * 2);
    size_t o_epS = alloc((size_t)NE * 4);
    size_t o_ofS = alloc((size_t)(NTS + 1) * 4);
    size_t o_posS = alloc((size_t)NE * 4);
    size_t o_srcS = alloc((size_t)NE * 4);
    size_t o_idxS = alloc((size_t)NE * 4);
    size_t o_wcomb = alloc((size_t)(512 + 32) * 4);
    size_t baseEnd = cur;                           // MODE0 agg goes here
    size_t o_epD  = alloc((size_t)NE * 4);
    size_t o_ofD  = alloc((size_t)(NT_D + 1) * 4);
    size_t o_epD2 = alloc((size_t)NE * 4);
    size_t o_noff = alloc((size_t)(NN + 1) * 4);
    size_t o_whi  = alloc((size_t)6144 * 2);
    size_t o_wlo  = alloc((size_t)6144 * 2);
    size_t o_msg  = alloc((size_t)NE * 32 * 4);     // MODE1 msgbuf (also prologue scratch)
    size_t need1 = cur;
    size_t need0 = baseEnd + (size_t)NN * 32 * 4;

    int mode;                                       // 1: node-sorted, 0: atomic, -1: msgC
    if (ws_size >= need1) mode = 1;
    else if (ws_size >= need0) mode = 0;
    else mode = -1;

    float* h     = (float*)(ws + o_h);
    float* tS    = (float*)(ws + o_t);
    float* W2ext = (float*)(ws + o_w2e);
    unsigned short* W2bf = (unsigned short*)(ws + o_w2b);
    int* epermS  = (int*)(ws + o_epS);
    int* offsS   = (int*)(ws + o_ofS);
    int* posS    = (int*)(ws + o_posS);
    int* srcS    = (int*)(ws + o_srcS);
    int* idxS    = (int*)(ws + o_idxS);
    float* Wcomb = (float*)(ws + o_wcomb);
    float* bcomb = Wcomb + 512;
    int* epermD  = (int*)(ws + o_epD);
    int* offsD   = (int*)(ws + o_ofD);
    int* epermD2 = (int*)(ws + o_epD2);
    int* nodeOffs = (int*)(ws + o_noff);
    unsigned short* gWhi = (unsigned short*)(ws + o_whi);
    unsigned short* gWlo = (unsigned short*)(ws + o_wlo);
    float* outbuf = (mode == 1) ? (float*)(ws + o_msg)
                  : (mode == 0) ? (float*)(ws + baseEnd)
                                : (float*)(ws + afterCommon);
    // prologue scratch (unions into outbuf region; concurrent S+D in MODE1):
    int* bcS = (int*)outbuf;                        // HB*NTS
    int* bsS = bcS + (size_t)HB * NTS;              // HB*NTS
    int* bcD = bsS + (size_t)HB * NTS;              // HB*NT_D
    int* bsD = bcD + (size_t)HB * NT_D;             // HB*NT_D
    int* totS = bsD + (size_t)HB * NT_D;            // NTS
    int* totD = totS + NTS;                         // NT_D

    k_node_enc<<<NN / 8, 256, 0, stream>>>(nfeats, emb, encW, encB, projW, projB, h);

    if (mode == 1) {
        k_prepAll<<<(66 * 512 + 6144 + 544 + 255) / 256, 256, 0, stream>>>(
            enW2, enB2, W2bf, gruWi, gruWh, gWhi, gWlo,
            eencW, eencB, enW1, enB1, Wcomb, bcomb);
        k_histB<<<2 * HB, 256, 0, stream>>>(src, dst, bcS, bcD);
        k_colsumB<<<(NTS + NT_D + 255) / 256, 256, 0, stream>>>(bcS, bcD, bsS, bsD, totS, totD);
        k_scanB<<<2, 256, 0, stream>>>(totS, totD, offsS, offsD);
        k_scatterB<<<2 * HB, 256, 0, stream>>>(src, dst, bsS, bsD, offsS, offsD, epermS, epermD);
        k_invgather<<<(NE + 255) / 256, 256, 0, stream>>>(epermS, src, posS, srcS);
        k_sortNode<<<NT_D, 256, 0, stream>>>(epermD, dst, offsD, epermD2, nodeOffs);
        k_scatterIdx<<<(NE + 255) / 256, 256, 0, stream>>>(epermD2, posS, idxS);
        k_edge_t3<<<NE / 128, 256, 0, stream>>>(efeats, Wcomb, bcomb, epermS, tS);
    } else if (mode == 0) {
        int* blockCounts = (int*)outbuf;
        int* blockStart  = blockCounts + (size_t)HB * NTS;
        int* tileTot     = blockStart + (size_t)HB * NTS;
        k_prepAll<<<(66 * 512 + 6144 + 544 + 255) / 256, 256, 0, stream>>>(
            enW2, enB2, W2bf, gruWi, gruWh, gWhi, gWlo,
            eencW, eencB, enW1, enB1, Wcomb, bcomb);
        k_histT<NTS, 4><<<HB, 256, 0, stream>>>(src, blockCounts);
        k_colsumT<NTS><<<(NTS + 255) / 256, 256, 0, stream>>>(blockCounts, blockStart, tileTot);
        k_scanT<NTS, 25><<<1, 256, 0, stream>>>(tileTot, offsS);
        k_scatterT<NTS, 4><<<HB, 256, 0, stream>>>(src, blockStart, offsS, epermS);
        k_invperm<<<(NE + 255) / 256, 256, 0, stream>>>(epermS, posS);
        k_gatherKey<<<(NE + 255) / 256, 256, 0, stream>>>(epermS, src, srcS);
        k_gatherKey<<<(NE + 255) / 256, 256, 0, stream>>>(epermS, dst, idxS);
        k_edge_t3<<<NE / 128, 256, 0, stream>>>(efeats, Wcomb, bcomb, epermS, tS);
    } else {
        k_prepAll<<<(66 * 512 + 6144 + 544 + 255) / 256, 256, 0, stream>>>(
            enW2, enB2, W2bf, gruWi, gruWh, gWhi, gWlo,
            eencW, eencB, enW1, enB1, Wcomb, bcomb);
        k_w2ext<<<(32 * QC + 255) / 256, 256, 0, stream>>>(enW2, enB2, W2ext);
        k_edge_t3<<<NE / 128, 256, 0, stream>>>(efeats, Wcomb, bcomb, nullptr, tS);
    }

    for (int s = 0; s < 3; ++s) {
        if (mode == 1) {
            k_msgF16<1><<<NTS, 256, 0, stream>>>(h, W2bf, tS, srcS, idxS, offsS, outbuf);
            k_gruAgg4<<<NT_D, 256, 0, stream>>>(outbuf, nodeOffs, convB,
                                                gWhi, gWlo, gruBi, gruBh, h);
        } else if (mode == 0) {
            hipMemsetAsync(outbuf, 0, (size_t)NN * 32 * 4, stream);
            k_msgF16<0><<<NTS, 256, 0, stream>>>(h, W2bf, tS, srcS, idxS, offsS, outbuf);
            k_gru<<<NN / 32, 256, 0, stream>>>(outbuf, convB, gruWi, gruWh, gruBi, gruBh, h);
        } else {
            hipMemsetAsync(outbuf, 0, (size_t)NN * 32 * 4, stream);
            k_msgC<<<NE / 32, 256, 0, stream>>>(tS, src, dst, h, W2ext, outbuf);
            k_gru<<<NN / 32, 256, 0, stream>>>(outbuf, convB, gruWi, gruWh, gruBi, gruBh, h);
        }
    }
    k_dec<<<NN / 8, 256, 0, stream>>>(h, dW1, db1, da1, dW2, db2, da2, dW3, db3, da3, dW4, db4, out);
}

// Round 19
// 394.383 us; speedup vs baseline: 1.2923x; 1.0496x over previous
//
#include <hip/hip_runtime.h>
#include <hip/hip_bf16.h>

// MPNN on MI355X — fused 16-node-tile msg kernel + MFMA GRU, fully pre-sorted streams.
// msg[e,o] = sum_k t[e,k]*Q[src,k,o] + q0[src,o],  Q[n] = h[n] @ W2ext
// k_msgF16: per 16-node src tile, MFMA Q (16x1056) into LDS as F16 in k-pair-
// interleaved layout; barrier-free edge stream: 4 lanes/edge x 8 outputs via
// v_dot2_f32_f16 (t stored f16, same-address L1 broadcast). Edge encoder folded.
// k_gruAgg4: split-bf16 MFMA GRU. No global atomics (MODE1).

#define NN 100000
#define NE 320000
#define QC 1056
#define NTS 6250      // NN/16 src tiles
#define NT_D 3125     // NN/32 dst tiles
#define HB 256        // bucketing blocks
#define EPB (NE / HB) // 1250
#define QSTRH 1072    // sQ row stride (halves); 2144 B/row, 16B-aligned slices

typedef short bf16x8 __attribute__((ext_vector_type(8)));
typedef float f32x4  __attribute__((ext_vector_type(4)));
typedef _Float16 h16x2 __attribute__((ext_vector_type(2)));
typedef _Float16 h16x8 __attribute__((ext_vector_type(8)));

__device__ __forceinline__ float bf2f(unsigned short u) {
    return __uint_as_float(((unsigned int)u) << 16);
}
__device__ __forceinline__ unsigned short f2bf(float f) {
    unsigned int x = __float_as_uint(f);
    unsigned int r = (x + 0x7fffu + ((x >> 16) & 1u)) >> 16;
    return (unsigned short)r;
}
__device__ __forceinline__ float sigm(float x) {
    return 1.f / (1.f + __expf(-x));
}
__device__ __forceinline__ float dot2h(h16x2 a, h16x2 b, float c) {
#if __has_builtin(__builtin_amdgcn_fdot2)
    return __builtin_amdgcn_fdot2(a, b, c, false);
#else
    return c + (float)a[0] * (float)b[0] + (float)a[1] * (float)b[1];
#endif
}

// ---- build W2ext [32][1056] (fp32, msgC fallback only)
__global__ __launch_bounds__(256) void k_w2ext(const float* __restrict__ W2,
                                               const float* __restrict__ b2,
                                               float* __restrict__ W2ext) {
    int idx = blockIdx.x * 256 + threadIdx.x;
    if (idx >= 32 * QC) return;
    int i = idx / QC, c = idx % QC;
    float v;
    if (c < 1024) { int k = c >> 5, o = c & 31; v = W2[k * 1024 + i * 32 + o]; }
    else          { v = b2[i * 32 + (c - 1024)]; }
    W2ext[idx] = v;
}

// ---- merged weight prep: W2bf (33792) + GRU hi/lo (6144) + Wcomb/bcomb (544)
__global__ __launch_bounds__(256) void k_prepAll(
    const float* __restrict__ W2, const float* __restrict__ b2,
    unsigned short* __restrict__ W2bf,
    const float* __restrict__ Wi, const float* __restrict__ Wh,
    unsigned short* __restrict__ Whi, unsigned short* __restrict__ Wlo,
    const float* __restrict__ eencW, const float* __restrict__ eencB,
    const float* __restrict__ enW1, const float* __restrict__ enB1,
    float* __restrict__ Wcomb, float* __restrict__ bcomb) {
    int idx = blockIdx.x * 256 + threadIdx.x;
    if (idx < 66 * 512) {
        int ct = idx >> 9, l = (idx >> 3) & 63, j = idx & 7;
        int kk = ((j >> 2) << 4) + ((l >> 4) << 2) + (j & 3);
        int c = ct * 16 + (l & 15);
        float v;
        if (c < 1024) { int kb = c >> 5, o = c & 31; v = W2[kb * 1024 + kk * 32 + o]; }
        else          { v = b2[kk * 32 + (c - 1024)]; }
        W2bf[idx] = f2bf(v);
    } else if (idx < 66 * 512 + 6144) {
        int q = idx - 66 * 512;
        int j = q & 7, l = (q >> 3) & 63, kt = (q >> 9) & 1, nt = q >> 10;
        int k = ((j >> 2) << 4) + ((l >> 4) << 2) + (j & 3);
        int col = nt * 16 + (l & 15);
        float v = kt ? Wh[k * 96 + col] : Wi[k * 96 + col];
        unsigned short hi = f2bf(v);
        Whi[q] = hi;
        Wlo[q] = f2bf(v - bf2f(hi));
    } else if (idx < 66 * 512 + 6144 + 544) {
        int q = idx - 66 * 512 - 6144;
        if (q < 512) {
            int i = q >> 5, o = q & 31;
            float acc = 0.f;
            #pragma unroll 8
            for (int j = 0; j < 32; ++j) acc += eencW[i * 32 + j] * enW1[j * 32 + o];
            Wcomb[i * 32 + o] = acc;
        } else {
            int o = q - 512;
            float acc = enB1[o];
            #pragma unroll 8
            for (int j = 0; j < 32; ++j) acc += eencB[j] * enW1[j * 32 + o];
            bcomb[o] = acc;
        }
    }
}

// ---- merged histograms: blocks [0,HB) src/NTS, [HB,2HB) dst/NT_D
__global__ __launch_bounds__(256) void k_histB(const int* __restrict__ src,
                                               const int* __restrict__ dst,
                                               int* __restrict__ bcS,
                                               int* __restrict__ bcD) {
    __shared__ int sHist[NTS];
    int tid = threadIdx.x, b = blockIdx.x;
    bool isS = b < HB;
    int bb = isS ? b : b - HB;
    const int* keys = isS ? src : dst;
    int NT = isS ? NTS : NT_D;
    int SH = isS ? 4 : 5;
    for (int c = tid; c < NT; c += 256) sHist[c] = 0;
    __syncthreads();
    int beg = bb * EPB, end = min(beg + EPB, NE);
    for (int e = beg + tid; e < end; e += 256)
        atomicAdd(&sHist[keys[e] >> SH], 1);
    __syncthreads();
    int* out = isS ? bcS : bcD;
    for (int c = tid; c < NT; c += 256) out[bb * NT + c] = sHist[c];
}

// ---- merged column sums
__global__ __launch_bounds__(256) void k_colsumB(const int* __restrict__ bcS,
                                                 const int* __restrict__ bcD,
                                                 int* __restrict__ bsS,
                                                 int* __restrict__ bsD,
                                                 int* __restrict__ totS,
                                                 int* __restrict__ totD) {
    int c = blockIdx.x * 256 + threadIdx.x;
    if (c < NTS) {
        int running = 0;
        #pragma unroll 8
        for (int b = 0; b < HB; ++b) {
            bsS[b * NTS + c] = running;
            running += bcS[b * NTS + c];
        }
        totS[c] = running;
    } else if (c < NTS + NT_D) {
        int cc = c - NTS;
        int running = 0;
        #pragma unroll 8
        for (int b = 0; b < HB; ++b) {
            bsD[b * NT_D + cc] = running;
            running += bcD[b * NT_D + cc];
        }
        totD[cc] = running;
    }
}

// ---- merged scans (block 0: src, block 1: dst)
__global__ __launch_bounds__(256) void k_scanB(const int* __restrict__ totS,
                                               const int* __restrict__ totD,
                                               int* __restrict__ offS,
                                               int* __restrict__ offD) {
    __shared__ int sTot[NTS];
    __shared__ int sPart[257];
    int tid = threadIdx.x;
    const int* tot = (blockIdx.x == 0) ? totS : totD;
    int* offs = (blockIdx.x == 0) ? offS : offD;
    int NT = (blockIdx.x == 0) ? NTS : NT_D;
    int SEG = (blockIdx.x == 0) ? 25 : 13;
    for (int c = tid; c < NT; c += 256) sTot[c] = tot[c];
    __syncthreads();
    int base = tid * SEG;
    int loc = 0;
    for (int j = 0; j < SEG; ++j) {
        int c = base + j;
        if (c < NT) { int v = sTot[c]; sTot[c] = loc; loc += v; }
    }
    sPart[tid] = loc;
    __syncthreads();
    if (tid == 0) {
        int s = 0;
        for (int i = 0; i < 256; ++i) { int v = sPart[i]; sPart[i] = s; s += v; }
        sPart[256] = s;
    }
    __syncthreads();
    int add = sPart[tid];
    for (int j = 0; j < SEG; ++j) {
        int c = base + j;
        if (c < NT) sTot[c] += add;
    }
    __syncthreads();
    for (int c = tid; c < NT; c += 256) offs[c] = sTot[c];
    if (tid == 0) offs[NT] = sPart[256];
}

// ---- merged scatters
__global__ __launch_bounds__(256) void k_scatterB(const int* __restrict__ src,
                                                  const int* __restrict__ dst,
                                                  const int* __restrict__ bsS,
                                                  const int* __restrict__ bsD,
                                                  const int* __restrict__ offS,
                                                  const int* __restrict__ offD,
                                                  int* __restrict__ epS,
                                                  int* __restrict__ epD) {
    __shared__ int sCur[NTS];
    int tid = threadIdx.x, b = blockIdx.x;
    bool isS = b < HB;
    int bb = isS ? b : b - HB;
    const int* keys = isS ? src : dst;
    const int* bs = isS ? bsS : bsD;
    const int* offs = isS ? offS : offD;
    int* ep = isS ? epS : epD;
    int NT = isS ? NTS : NT_D;
    int SH = isS ? 4 : 5;
    for (int c = tid; c < NT; c += 256)
        sCur[c] = offs[c] + bs[bb * NT + c];
    __syncthreads();
    int beg = bb * EPB, end = min(beg + EPB, NE);
    for (int e = beg + tid; e < end; e += 256) {
        int pos = atomicAdd(&sCur[keys[e] >> SH], 1);
        ep[pos] = e;
    }
}

// ---- merged invperm + src gather
__global__ __launch_bounds__(256) void k_invgather(const int* __restrict__ epermS,
                                                   const int* __restrict__ src,
                                                   int* __restrict__ posS,
                                                   int* __restrict__ srcS) {
    int p = blockIdx.x * 256 + threadIdx.x;
    if (p < NE) {
        int e = epermS[p];
        posS[e] = p;
        srcS[p] = src[e];
    }
}

// ---- node encoder + projection
__global__ __launch_bounds__(256) void k_node_enc(
    const int* __restrict__ nfeats, const float* __restrict__ emb,
    const float* __restrict__ encW, const float* __restrict__ encB,
    const float* __restrict__ projW, const float* __restrict__ projB,
    float* __restrict__ h) {
    __shared__ float sEncW[1024], sProjW[1024], sEncB[32], sProjB[32];
    __shared__ float sEmb[8][33], sNh[8][33];
    int tid = threadIdx.x;
    for (int i = tid; i < 1024; i += 256) { sEncW[i] = encW[i]; sProjW[i] = projW[i]; }
    if (tid < 32) { sEncB[tid] = encB[tid]; sProjB[tid] = projB[tid]; }
    int ln = tid >> 5, o = tid & 31;
    int node = blockIdx.x * 8 + ln;
    int nt = nfeats[node];
    sEmb[ln][o] = fmaxf(emb[nt * 32 + o], 0.f);
    __syncthreads();
    float acc = sEncB[o];
    #pragma unroll
    for (int i = 0; i < 32; ++i) acc += sEmb[ln][i] * sEncW[i * 32 + o];
    sNh[ln][o] = fmaxf(acc, 0.f);
    __syncthreads();
    float acc2 = sProjB[o];
    #pragma unroll
    for (int i = 0; i < 32; ++i) acc2 += sNh[ln][i] * sProjW[i * 32 + o];
    h[node * 32 + o] = fmaxf(acc2, 0.f);
}

// ---- edge encoder (folded), f16 output: 128 edges/block, weights in registers
__global__ __launch_bounds__(256) void k_edge_t3h(
    const float* __restrict__ efeats, const float* __restrict__ Wcomb,
    const float* __restrict__ bcomb, const int* __restrict__ eperm,
    unsigned short* __restrict__ tS) {
    int tid = threadIdx.x;
    int el = tid >> 3, l8 = tid & 7;
    int gbase = (tid & 63) & 56;
    int c0 = l8 << 2;
    float4 w[16];
    #pragma unroll
    for (int i = 0; i < 16; ++i) w[i] = *(const float4*)(Wcomb + i * 32 + c0);
    float4 bb = *(const float4*)(bcomb + c0);
    #pragma unroll
    for (int it = 0; it < 4; ++it) {
        int p = blockIdx.x * 128 + it * 32 + el;
        int e = eperm ? eperm[p] : p;
        float2 efv = *(const float2*)(efeats + (size_t)e * 16 + (l8 << 1));
        float a0 = bb.x, a1 = bb.y, a2 = bb.z, a3 = bb.w;
        #pragma unroll
        for (int i = 0; i < 8; ++i) {
            float f0 = __shfl(efv.x, gbase + i, 64);
            float f1 = __shfl(efv.y, gbase + i, 64);
            float4 w0 = w[2 * i], w1 = w[2 * i + 1];
            a0 += f0 * w0.x + f1 * w1.x;
            a1 += f0 * w0.y + f1 * w1.y;
            a2 += f0 * w0.z + f1 * w1.z;
            a3 += f0 * w0.w + f1 * w1.w;
        }
        _Float16 h0 = (_Float16)fmaxf(a0, 0.f);
        _Float16 h1 = (_Float16)fmaxf(a1, 0.f);
        _Float16 h2 = (_Float16)fmaxf(a2, 0.f);
        _Float16 h3 = (_Float16)fmaxf(a3, 0.f);
        ushort4 o4;
        o4.x = *(unsigned short*)&h0; o4.y = *(unsigned short*)&h1;
        o4.z = *(unsigned short*)&h2; o4.w = *(unsigned short*)&h3;
        *(ushort4*)(tS + (size_t)p * 32 + c0) = o4;
    }
}

// ---- edge encoder fp32 output (msgC fallback only)
__global__ __launch_bounds__(256) void k_edge_t3(
    const float* __restrict__ efeats, const float* __restrict__ Wcomb,
    const float* __restrict__ bcomb, const int* __restrict__ eperm,
    float* __restrict__ tS) {
    int tid = threadIdx.x;
    int el = tid >> 3, l8 = tid & 7;
    int gbase = (tid & 63) & 56;
    int c0 = l8 << 2;
    float4 w[16];
    #pragma unroll
    for (int i = 0; i < 16; ++i) w[i] = *(const float4*)(Wcomb + i * 32 + c0);
    float4 bb = *(const float4*)(bcomb + c0);
    #pragma unroll
    for (int it = 0; it < 4; ++it) {
        int p = blockIdx.x * 128 + it * 32 + el;
        int e = eperm ? eperm[p] : p;
        float2 efv = *(const float2*)(efeats + (size_t)e * 16 + (l8 << 1));
        float a0 = bb.x, a1 = bb.y, a2 = bb.z, a3 = bb.w;
        #pragma unroll
        for (int i = 0; i < 8; ++i) {
            float f0 = __shfl(efv.x, gbase + i, 64);
            float f1 = __shfl(efv.y, gbase + i, 64);
            float4 w0 = w[2 * i], w1 = w[2 * i + 1];
            a0 += f0 * w0.x + f1 * w1.x;
            a1 += f0 * w0.y + f1 * w1.y;
            a2 += f0 * w0.z + f1 * w1.z;
            a3 += f0 * w0.w + f1 * w1.w;
        }
        *(float4*)(tS + (size_t)p * 32 + c0) =
            make_float4(fmaxf(a0, 0.f), fmaxf(a1, 0.f), fmaxf(a2, 0.f), fmaxf(a3, 0.f));
    }
}

// ---- legacy single-purpose bucketing kernels (fallback modes only)
template<int NT, int SHIFT>
__global__ __launch_bounds__(256) void k_histT(const int* __restrict__ keys,
                                               int* __restrict__ blockCounts) {
    __shared__ int sHist[NT];
    int tid = threadIdx.x, b = blockIdx.x;
    for (int c = tid; c < NT; c += 256) sHist[c] = 0;
    __syncthreads();
    int beg = b * EPB, end = min(beg + EPB, NE);
    for (int e = beg + tid; e < end; e += 256)
        atomicAdd(&sHist[keys[e] >> SHIFT], 1);
    __syncthreads();
    for (int c = tid; c < NT; c += 256) blockCounts[b * NT + c] = sHist[c];
}

template<int NT>
__global__ __launch_bounds__(256) void k_colsumT(const int* __restrict__ blockCounts,
                                                 int* __restrict__ blockStart,
                                                 int* __restrict__ tileTot) {
    int c = blockIdx.x * 256 + threadIdx.x;
    if (c >= NT) return;
    int running = 0;
    #pragma unroll 8
    for (int b = 0; b < HB; ++b) {
        blockStart[b * NT + c] = running;
        running += blockCounts[b * NT + c];
    }
    tileTot[c] = running;
}

template<int NT, int SEG>
__global__ __launch_bounds__(256) void k_scanT(const int* __restrict__ tileTot,
                                               int* __restrict__ offs) {
    __shared__ int sTot[NT];
    __shared__ int sPart[257];
    int tid = threadIdx.x;
    for (int c = tid; c < NT; c += 256) sTot[c] = tileTot[c];
    __syncthreads();
    int base = tid * SEG;
    int loc = 0;
    for (int j = 0; j < SEG; ++j) {
        int c = base + j;
        if (c < NT) { int v = sTot[c]; sTot[c] = loc; loc += v; }
    }
    sPart[tid] = loc;
    __syncthreads();
    if (tid == 0) {
        int s = 0;
        for (int i = 0; i < 256; ++i) { int v = sPart[i]; sPart[i] = s; s += v; }
        sPart[256] = s;
    }
    __syncthreads();
    int add = sPart[tid];
    for (int j = 0; j < SEG; ++j) {
        int c = base + j;
        if (c < NT) sTot[c] += add;
    }
    __syncthreads();
    for (int c = tid; c < NT; c += 256) offs[c] = sTot[c];
    if (tid == 0) offs[NT] = sPart[256];
}

template<int NT, int SHIFT>
__global__ __launch_bounds__(256) void k_scatterT(const int* __restrict__ keys,
                                                  const int* __restrict__ blockStart,
                                                  const int* __restrict__ offs,
                                                  int* __restrict__ eperm) {
    __shared__ int sCur[NT];
    int tid = threadIdx.x, b = blockIdx.x;
    for (int c = tid; c < NT; c += 256)
        sCur[c] = offs[c] + blockStart[b * NT + c];
    __syncthreads();
    int beg = b * EPB, end = min(beg + EPB, NE);
    for (int e = beg + tid; e < end; e += 256) {
        int pos = atomicAdd(&sCur[keys[e] >> SHIFT], 1);
        eperm[pos] = e;
    }
}

// ---- second-level sort: within each dst tile, sort by node (32 LDS bins)
__global__ __launch_bounds__(256) void k_sortNode(
    const int* __restrict__ epermD, const int* __restrict__ dst,
    const int* __restrict__ offsD, int* __restrict__ epermD2,
    int* __restrict__ nodeOffs) {
    __shared__ int sCnt[32], sStart[32];
    int tid = threadIdx.x, d = blockIdx.x;
    int beg = offsD[d], end = offsD[d + 1];
    if (tid < 32) sCnt[tid] = 0;
    __syncthreads();
    for (int p = beg + tid; p < end; p += 256)
        atomicAdd(&sCnt[dst[epermD[p]] & 31], 1);
    __syncthreads();
    if (tid == 0) {
        int s = beg;
        for (int r = 0; r < 32; ++r) { sStart[r] = s; s += sCnt[r]; }
    }
    __syncthreads();
    if (tid < 32) {
        nodeOffs[d * 32 + tid] = sStart[tid];
        sCnt[tid] = sStart[tid];
    }
    if (d == NT_D - 1 && tid == 0) nodeOffs[NN] = end;
    __syncthreads();
    for (int p = beg + tid; p < end; p += 256) {
        int e = epermD[p];
        int pos = atomicAdd(&sCnt[dst[e] & 31], 1);
        epermD2[pos] = e;
    }
}

// ---- inverse permutation (fallback path)
__global__ __launch_bounds__(256) void k_invperm(const int* __restrict__ eperm,
                                                 int* __restrict__ pos) {
    int p = blockIdx.x * 256 + threadIdx.x;
    if (p < NE) pos[eperm[p]] = p;
}

// ---- gather key (fallback path)
__global__ __launch_bounds__(256) void k_gatherKey(const int* __restrict__ epermS,
                                                   const int* __restrict__ key,
                                                   int* __restrict__ out) {
    int p = blockIdx.x * 256 + threadIdx.x;
    if (p < NE) out[p] = key[epermS[p]];
}

// ---- idxS[posS[epermD2[q]]] = q
__global__ __launch_bounds__(256) void k_scatterIdx(const int* __restrict__ epermD2,
                                                    const int* __restrict__ posS,
                                                    int* __restrict__ idxS) {
    int q = blockIdx.x * 256 + threadIdx.x;
    if (q < NE) idxS[posS[epermD2[q]]] = q;
}

// ---- fused per-16-node-src-tile: MFMA Q -> f16 LDS (k-pair interleaved),
// edge stream: 4 lanes/edge x 8 outputs via v_dot2_f32_f16.
// MODE 0: atomicAdd; MODE 1: store to msgbuf slot.
template<int MODE>
__global__ __launch_bounds__(256) void k_msgF16(
    const float* __restrict__ h, const unsigned short* __restrict__ W2bf,
    const unsigned short* __restrict__ tS, const int* __restrict__ srcS,
    const int* __restrict__ idxS, const int* __restrict__ offs,
    float* __restrict__ outbuf) {
    __shared__ unsigned short sQ[16 * QSTRH];   // 34304 B (f16 bits)
    int tid = threadIdx.x;
    int tile = blockIdx.x;
    int beg = offs[tile], end = offs[tile + 1];
    if (beg >= end) return;
    int nodeBase = tile * 16;
    int wave = tid >> 6, lane = tid & 63;

    int arow = lane & 15;
    const float* hp = h + (size_t)(nodeBase + arow) * 32 + ((lane >> 4) << 2);
    float4 x0 = *(const float4*)hp;
    float4 x1 = *(const float4*)(hp + 16);
    bf16x8 a;
    a[0] = (short)f2bf(x0.x); a[1] = (short)f2bf(x0.y);
    a[2] = (short)f2bf(x0.z); a[3] = (short)f2bf(x0.w);
    a[4] = (short)f2bf(x1.x); a[5] = (short)f2bf(x1.y);
    a[6] = (short)f2bf(x1.z); a[7] = (short)f2bf(x1.w);

    f32x4 z = {0.f, 0.f, 0.f, 0.f};
    int crow0 = (lane >> 4) << 2;
    int ccol = lane & 15;
    for (int ct = wave; ct < 66; ct += 4) {
        bf16x8 b = *(const bf16x8*)(W2bf + (size_t)((ct << 6) + lane) * 8);
        f32x4 acc = __builtin_amdgcn_mfma_f32_16x16x32_bf16(a, b, z, 0, 0, 0);
        int c = (ct << 4) + ccol;
        int idx;
        if (c < 1024) {
            int k = c >> 5, o = c & 31;
            idx = ((k >> 1) << 6) + (o << 1) + (k & 1);   // k-pair interleaved
        } else {
            idx = 1024 + (c - 1024);                      // bias block
        }
        unsigned short* qp = sQ + crow0 * QSTRH + idx;
        _Float16 v0 = (_Float16)acc[0], v1 = (_Float16)acc[1];
        _Float16 v2 = (_Float16)acc[2], v3 = (_Float16)acc[3];
        qp[0 * QSTRH] = *(unsigned short*)&v0;
        qp[1 * QSTRH] = *(unsigned short*)&v1;
        qp[2 * QSTRH] = *(unsigned short*)&v2;
        qp[3 * QSTRH] = *(unsigned short*)&v3;
    }
    __syncthreads();   // the only barrier

    int el = tid >> 2, l4 = tid & 3;   // 64 edges in flight, 8 outputs/lane
    int o0 = l4 << 3;
    for (int p = beg + el; p < end; p += 64) {
        int row = srcS[p] - nodeBase;      // 4 lanes same addr -> broadcast
        int widx = idxS[p];
        h16x8 trow[4];
        #pragma unroll
        for (int i = 0; i < 4; ++i)
            trow[i] = *(const h16x8*)(tS + (size_t)p * 32 + (i << 3));
        const unsigned short* qp = sQ + row * QSTRH;
        h16x8 qb = *(const h16x8*)(qp + 1024 + o0);
        float acc[8];
        #pragma unroll
        for (int j = 0; j < 8; ++j) acc[j] = (float)qb[j];
        #pragma unroll
        for (int kp = 0; kp < 16; ++kp) {
            h16x2 t2;
            t2[0] = trow[kp >> 2][(kp & 3) * 2];
            t2[1] = trow[kp >> 2][(kp & 3) * 2 + 1];
            h16x8 qa = *(const h16x8*)(qp + (kp << 6) + (o0 << 1));
            h16x8 qc = *(const h16x8*)(qp + (kp << 6) + (o0 << 1) + 8);
            #pragma unroll
            for (int j = 0; j < 4; ++j) {
                h16x2 q2a; q2a[0] = qa[2 * j]; q2a[1] = qa[2 * j + 1];
                h16x2 q2c; q2c[0] = qc[2 * j]; q2c[1] = qc[2 * j + 1];
                acc[j]     = dot2h(t2, q2a, acc[j]);
                acc[4 + j] = dot2h(t2, q2c, acc[4 + j]);
            }
        }
        if (MODE) {
            float* op = outbuf + (size_t)widx * 32 + o0;
            *(float4*)op = make_float4(acc[0], acc[1], acc[2], acc[3]);
            *(float4*)(op + 4) = make_float4(acc[4], acc[5], acc[6], acc[7]);
        } else {
            float* op = outbuf + (size_t)widx * 32 + o0;
            #pragma unroll
            for (int j = 0; j < 8; ++j) atomicAdd(op + j, acc[j]);
        }
    }
}

// ---- fallback msg (tiny ws): recompute We per edge (t fp32, original order)
__global__ __launch_bounds__(256) void k_msgC(
    const float* __restrict__ t, const int* __restrict__ src, const int* __restrict__ dst,
    const float* __restrict__ h, const float* __restrict__ W2ext, float* __restrict__ agg) {
    __shared__ float sT[32][33], sH[32][33];
    __shared__ int sSrc[32], sDst[32];
    int tid = threadIdx.x;
    int e0 = blockIdx.x * 32;
    if (tid < 32) sSrc[tid] = src[e0 + tid];
    else if (tid < 64) sDst[tid - 32] = dst[e0 + tid - 32];
    __syncthreads();
    for (int idx = tid; idx < 1024; idx += 256) {
        int el = idx >> 5, k = idx & 31;
        sT[el][k] = t[(e0 + el) * 32 + k];
        sH[el][k] = h[(size_t)sSrc[el] * 32 + k];
    }
    __syncthreads();
    int el = tid >> 3, l8 = tid & 7;
    int c0 = l8 * 4;
    float m0 = 0.f, m1 = 0.f, m2 = 0.f, m3 = 0.f;
    for (int i = 0; i < 32; ++i) {
        const float* wrow = W2ext + i * QC;
        float4 wb = *(const float4*)(wrow + 1024 + c0);
        float w0 = wb.x, w1 = wb.y, w2 = wb.z, w3 = wb.w;
        #pragma unroll 8
        for (int k = 0; k < 32; ++k) {
            float tk = sT[el][k];
            float4 w = *(const float4*)(wrow + k * 32 + c0);
            w0 += tk * w.x; w1 += tk * w.y; w2 += tk * w.z; w3 += tk * w.w;
        }
        float hi = sH[el][i];
        m0 += hi * w0; m1 += hi * w1; m2 += hi * w2; m3 += hi * w3;
    }
    float* ap = agg + (size_t)sDst[el] * 32 + c0;
    atomicAdd(ap + 0, m0); atomicAdd(ap + 1, m1);
    atomicAdd(ap + 2, m2); atomicAdd(ap + 3, m3);
}

// ---- GRU step reading agg[] (MODE 0 / fallback)
__global__ __launch_bounds__(256) void k_gru(
    const float* __restrict__ agg, const float* __restrict__ convB,
    const float* __restrict__ Wi, const float* __restrict__ Wh,
    const float* __restrict__ bi, const float* __restrict__ bh,
    float* __restrict__ h) {
    __shared__ float sWi[3072], sWh[3072], sBi[96], sBh[96], sCb[32];
    __shared__ float sX[8][33], sH[8][33];
    int tid = threadIdx.x;
    for (int i = tid; i < 3072; i += 256) { sWi[i] = Wi[i]; sWh[i] = Wh[i]; }
    if (tid < 96) { sBi[tid] = bi[tid]; sBh[tid] = bh[tid]; }
    if (tid < 32) sCb[tid] = convB[tid];
    int ln = tid >> 5, o = tid & 31;
    for (int g = 0; g < 4; ++g) {
        int node = blockIdx.x * 32 + g * 8 + ln;
        float hv = h[node * 32 + o];
        float av = agg[node * 32 + o];
        __syncthreads();
        sX[ln][o] = fmaxf(av + sCb[o], 0.f);
        sH[ln][o] = hv;
        __syncthreads();
        float air = sBi[o], aiz = sBi[o + 32], ain = sBi[o + 64];
        float ahr = sBh[o], ahz = sBh[o + 32], ahn = sBh[o + 64];
        #pragma unroll 8
        for (int i = 0; i < 32; ++i) {
            float x = sX[ln][i], hh = sH[ln][i];
            air += x * sWi[i * 96 + o];      ahr += hh * sWh[i * 96 + o];
            aiz += x * sWi[i * 96 + o + 32]; ahz += hh * sWh[i * 96 + o + 32];
            ain += x * sWi[i * 96 + o + 64]; ahn += hh * sWh[i * 96 + o + 64];
        }
        float r = sigm(air + ahr);
        float zz = sigm(aiz + ahz);
        float ng = tanhf(ain + r * ahn);
        h[node * 32 + o] = (1.f - zz) * ng + zz * hv;
    }
}

// ---- MODE 1: per 32-node dst tile: segment-sum -> X in LDS, GRU via split-bf16 MFMA.
__global__ __launch_bounds__(256) void k_gruAgg4(
    const float* __restrict__ msgbuf, const int* __restrict__ nodeOffs,
    const float* __restrict__ convB,
    const unsigned short* __restrict__ Whi, const unsigned short* __restrict__ Wlo,
    const float* __restrict__ bi, const float* __restrict__ bh,
    float* __restrict__ h) {
    __shared__ float sAgg[32 * 33];
    int tid = threadIdx.x;
    int d = blockIdx.x;
    int base = d * 32;

    {
        int n8 = tid >> 3, l8 = tid & 7;
        int node = base + n8;
        int nb = nodeOffs[node], ne2 = nodeOffs[node + 1];
        float a0 = 0.f, a1 = 0.f, a2 = 0.f, a3 = 0.f;
        for (int p = nb; p < ne2; ++p) {
            float4 v = *(const float4*)(msgbuf + (size_t)p * 32 + (l8 << 2));
            a0 += v.x; a1 += v.y; a2 += v.z; a3 += v.w;
        }
        int c0 = l8 << 2;
        float4 cb = *(const float4*)(convB + c0);
        float* sp = sAgg + n8 * 33 + c0;
        sp[0] = fmaxf(a0 + cb.x, 0.f);
        sp[1] = fmaxf(a1 + cb.y, 0.f);
        sp[2] = fmaxf(a2 + cb.z, 0.f);
        sp[3] = fmaxf(a3 + cb.w, 0.f);
    }
    __syncthreads();

    int wave = tid >> 6, lane = tid & 63;
    int m = wave >> 1, c = wave & 1;
    int arow = lane & 15, kg = (lane >> 4) << 2;

    bf16x8 xhi, xlo, hhi, hlo;
    {
        const float* xp = sAgg + (m * 16 + arow) * 33 + kg;
        float4 v0 = *(const float4*)xp;
        float4 v1 = *(const float4*)(xp + 16);
        float xv[8] = {v0.x, v0.y, v0.z, v0.w, v1.x, v1.y, v1.z, v1.w};
        #pragma unroll
        for (int j = 0; j < 8; ++j) {
            unsigned short hi16 = f2bf(xv[j]);
            xhi[j] = (short)hi16;
            xlo[j] = (short)f2bf(xv[j] - bf2f(hi16));
        }
        const float* hp = h + (size_t)(base + m * 16 + arow) * 32 + kg;
        float4 w0 = *(const float4*)hp;
        float4 w1 = *(const float4*)(hp + 16);
        float hv8[8] = {w0.x, w0.y, w0.z, w0.w, w1.x, w1.y, w1.z, w1.w};
        #pragma unroll
        for (int j = 0; j < 8; ++j) {
            unsigned short hi16 = f2bf(hv8[j]);
            hhi[j] = (short)hi16;
            hlo[j] = (short)f2bf(hv8[j] - bf2f(hi16));
        }
    }

    int ccol = lane & 15, crow0 = (lane >> 4) << 2;
    int o = c * 16 + ccol;
    auto Bf = [&](int nt, int kt, const unsigned short* W) {
        return *(const bf16x8*)(W + (size_t)(((nt * 2 + kt) * 64 + lane) << 3));
    };
    f32x4 accR = {0.f, 0.f, 0.f, 0.f}, accZ = {0.f, 0.f, 0.f, 0.f};
    f32x4 accIN = {0.f, 0.f, 0.f, 0.f}, accHN = {0.f, 0.f, 0.f, 0.f};
    {
        int nt = c;
        bf16x8 b0h = Bf(nt, 0, Whi), b0l = Bf(nt, 0, Wlo);
        bf16x8 b1h = Bf(nt, 1, Whi), b1l = Bf(nt, 1, Wlo);
        accR = __builtin_amdgcn_mfma_f32_16x16x32_bf16(xhi, b0h, accR, 0, 0, 0);
        accR = __builtin_amdgcn_mfma_f32_16x16x32_bf16(xlo, b0h, accR, 0, 0, 0);
        accR = __builtin_amdgcn_mfma_f32_16x16x32_bf16(xhi, b0l, accR, 0, 0, 0);
        accR = __builtin_amdgcn_mfma_f32_16x16x32_bf16(hhi, b1h, accR, 0, 0, 0);
        accR = __builtin_amdgcn_mfma_f32_16x16x32_bf16(hlo, b1h, accR, 0, 0, 0);
        accR = __builtin_amdgcn_mfma_f32_16x16x32_bf16(hhi, b1l, accR, 0, 0, 0);
    }
    {
        int nt = 2 + c;
        bf16x8 b0h = Bf(nt, 0, Whi), b0l = Bf(nt, 0, Wlo);
        bf16x8 b1h = Bf(nt, 1, Whi), b1l = Bf(nt, 1, Wlo);
        accZ = __builtin_amdgcn_mfma_f32_16x16x32_bf16(xhi, b0h, accZ, 0, 0, 0);
        accZ = __builtin_amdgcn_mfma_f32_16x16x32_bf16(xlo, b0h, accZ, 0, 0, 0);
        accZ = __builtin_amdgcn_mfma_f32_16x16x32_bf16(xhi, b0l, accZ, 0, 0, 0);
        accZ = __builtin_amdgcn_mfma_f32_16x16x32_bf16(hhi, b1h, accZ, 0, 0, 0);
        accZ = __builtin_amdgcn_mfma_f32_16x16x32_bf16(hlo, b1h, accZ, 0, 0, 0);
        accZ = __builtin_amdgcn_mfma_f32_16x16x32_bf16(hhi, b1l, accZ, 0, 0, 0);
    }
    {
        int nt = 4 + c;
        bf16x8 b0h = Bf(nt, 0, Whi), b0l = Bf(nt, 0, Wlo);
        bf16x8 b1h = Bf(nt, 1, Whi), b1l = Bf(nt, 1, Wlo);
        accIN = __builtin_amdgcn_mfma_f32_16x16x32_bf16(xhi, b0h, accIN, 0, 0, 0);
        accIN = __builtin_amdgcn_mfma_f32_16x16x32_bf16(xlo, b0h, accIN, 0, 0, 0);
        accIN = __builtin_amdgcn_mfma_f32_16x16x32_bf16(xhi, b0l, accIN, 0, 0, 0);
        accHN = __builtin_amdgcn_mfma_f32_16x16x32_bf16(hhi, b1h, accHN, 0, 0, 0);
        accHN = __builtin_amdgcn_mfma_f32_16x16x32_bf16(hlo, b1h, accHN, 0, 0, 0);
        accHN = __builtin_amdgcn_mfma_f32_16x16x32_bf16(hhi, b1l, accHN, 0, 0, 0);
    }

    float bir = bi[o], biz = bi[32 + o], bin = bi[64 + o];
    float bhr = bh[o], bhz = bh[32 + o], bhn = bh[64 + o];
    float hv[4];
    #pragma unroll
    for (int j = 0; j < 4; ++j)
        hv[j] = h[(size_t)(base + m * 16 + crow0 + j) * 32 + o];
    __syncthreads();
    #pragma unroll
    for (int j = 0; j < 4; ++j) {
        float r  = sigm(accR[j] + bir + bhr);
        float zz = sigm(accZ[j] + biz + bhz);
        float ng = tanhf(accIN[j] + bin + r * (accHN[j] + bhn));
        h[(size_t)(base + m * 16 + crow0 + j) * 32 + o] = (1.f - zz) * ng + zz * hv[j];
    }
}

// ---- decoder
__global__ __launch_bounds__(256) void k_dec(
    const float* __restrict__ h,
    const float* __restrict__ W1, const float* __restrict__ b1, const float* __restrict__ a1,
    const float* __restrict__ W2, const float* __restrict__ b2, const float* __restrict__ a2,
    const float* __restrict__ W3, const float* __restrict__ b3, const float* __restrict__ a3,
    const float* __restrict__ W4, const float* __restrict__ b4,
    float* __restrict__ out) {
    __shared__ float sW1[1024], sW2[1024], sW3[1024], sW4[96];
    __shared__ float sB1[32], sB2[32], sB3[32], sB4[3];
    __shared__ float sYa[8][33], sYb[8][33];
    int tid = threadIdx.x;
    for (int i = tid; i < 1024; i += 256) { sW1[i] = W1[i]; sW2[i] = W2[i]; sW3[i] = W3[i]; }
    if (tid < 96) sW4[tid] = W4[tid];
    if (tid < 32) { sB1[tid] = b1[tid]; sB2[tid] = b2[tid]; sB3[tid] = b3[tid]; }
    if (tid < 3) sB4[tid] = b4[tid];
    float A1 = a1[0], A2 = a2[0], A3 = a3[0];
    int ln = tid >> 5, o = tid & 31;
    int node = blockIdx.x * 8 + ln;
    sYa[ln][o] = h[node * 32 + o];
    __syncthreads();
    float acc = sB1[o];
    #pragma unroll
    for (int i = 0; i < 32; ++i) acc += sYa[ln][i] * sW1[i * 32 + o];
    acc = acc >= 0.f ? acc : A1 * acc;
    sYb[ln][o] = acc;
    __syncthreads();
    acc = sB2[o];
    #pragma unroll
    for (int i = 0; i < 32; ++i) acc += sYb[ln][i] * sW2[i * 32 + o];
    acc = acc >= 0.f ? acc : A2 * acc;
    __syncthreads();
    sYa[ln][o] = acc;
    __syncthreads();
    acc = sB3[o];
    #pragma unroll
    for (int i = 0; i < 32; ++i) acc += sYa[ln][i] * sW3[i * 32 + o];
    acc = acc >= 0.f ? acc : A3 * acc;
    __syncthreads();
    sYb[ln][o] = acc;
    __syncthreads();
    if (o < 3) {
        float r = sB4[o];
        #pragma unroll
        for (int i = 0; i < 32; ++i) r += sYb[ln][i] * sW4[i * 3 + o];
        out[node * 3 + o] = r;
    }
}

extern "C" void kernel_launch(void* const* d_in, const int* in_sizes, int n_in,
                              void* d_out, int out_size, void* d_ws, size_t ws_size,
                              hipStream_t stream) {
    const int*   nfeats = (const int*)d_in[0];
    const float* efeats = (const float*)d_in[1];
    const int*   src    = (const int*)d_in[2];
    const int*   dst    = (const int*)d_in[3];
    const float* emb    = (const float*)d_in[4];
    const float* encW   = (const float*)d_in[5];
    const float* encB   = (const float*)d_in[6];
    const float* eencW  = (const float*)d_in[7];
    const float* eencB  = (const float*)d_in[8];
    const float* projW  = (const float*)d_in[9];
    const float* projB  = (const float*)d_in[10];
    const float* enW1   = (const float*)d_in[11];
    const float* enB1   = (const float*)d_in[12];
    const float* enW2   = (const float*)d_in[13];
    const float* enB2   = (const float*)d_in[14];
    const float* convB  = (const float*)d_in[15];
    const float* gruWi  = (const float*)d_in[16];
    const float* gruWh  = (const float*)d_in[17];
    const float* gruBi  = (const float*)d_in[18];
    const float* gruBh  = (const float*)d_in[19];
    const float* dW1 = (const float*)d_in[20]; const float* db1 = (const float*)d_in[21]; const float* da1 = (const float*)d_in[22];
    const float* dW2 = (const float*)d_in[23]; const float* db2 = (const float*)d_in[24]; const float* da2 = (const float*)d_in[25];
    const float* dW3 = (const float*)d_in[26]; const float* db3 = (const float*)d_in[27]; const float* da3 = (const float*)d_in[28];
    const float* dW4 = (const float*)d_in[29]; const float* db4 = (const float*)d_in[30];
    float* out = (float*)d_out;
    char* ws = (char*)d_ws;

    // bump allocator (256-B aligned)
    size_t cur = 0;
    auto alloc = [&](size_t n) { size_t p = cur; cur = (cur + n + 255) & ~(size_t)255; return p; };
    size_t o_h   = alloc((size_t)NN * 32 * 4);
    size_t o_t   = alloc((size_t)NE * 32 * 4);      // tS (f16 uses half; fp32 fallback full)
    size_t o_w2e = alloc((size_t)32 * QC * 4);
    size_t afterCommon = cur;                       // fallback agg goes here
    size_t o_w2b = alloc((size_t)66 * 512 * 2);
    size_t o_epS = alloc((size_t)NE * 4);
    size_t o_ofS = alloc((size_t)(NTS + 1) * 4);
    size_t o_posS = alloc((size_t)NE * 4);
    size_t o_srcS = alloc((size_t)NE * 4);
    size_t o_idxS = alloc((size_t)NE * 4);
    size_t o_wcomb = alloc((size_t)(512 + 32) * 4);
    size_t baseEnd = cur;                           // MODE0 agg goes here
    size_t o_epD  = alloc((size_t)NE * 4);
    size_t o_ofD  = alloc((size_t)(NT_D + 1) * 4);
    size_t o_epD2 = alloc((size_t)NE * 4);
    size_t o_noff = alloc((size_t)(NN + 1) * 4);
    size_t o_whi  = alloc((size_t)6144 * 2);
    size_t o_wlo  = alloc((size_t)6144 * 2);
    size_t o_msg  = alloc((size_t)NE * 32 * 4);     // MODE1 msgbuf (also prologue scratch)
    size_t need1 = cur;
    size_t need0 = baseEnd + (size_t)NN * 32 * 4;

    int mode;                                       // 1: node-sorted, 0: atomic, -1: msgC
    if (ws_size >= need1) mode = 1;
    else if (ws_size >= need0) mode = 0;
    else mode = -1;

    float* h     = (float*)(ws + o_h);
    float* tSf   = (float*)(ws + o_t);
    unsigned short* tSh = (unsigned short*)(ws + o_t);
    float* W2ext = (float*)(ws + o_w2e);
    unsigned short* W2bf = (unsigned short*)(ws + o_w2b);
    int* epermS  = (int*)(ws + o_epS);
    int* offsS   = (int*)(ws + o_ofS);
    int* posS    = (int*)(ws + o_posS);
    int* srcS    = (int*)(ws + o_srcS);
    int* idxS    = (int*)(ws + o_idxS);
    float* Wcomb = (float*)(ws + o_wcomb);
    float* bcomb = Wcomb + 512;
    int* epermD  = (int*)(ws + o_epD);
    int* offsD   = (int*)(ws + o_ofD);
    int* epermD2 = (int*)(ws + o_epD2);
    int* nodeOffs = (int*)(ws + o_noff);
    unsigned short* gWhi = (unsigned short*)(ws + o_whi);
    unsigned short* gWlo = (unsigned short*)(ws + o_wlo);
    float* outbuf = (mode == 1) ? (float*)(ws + o_msg)
                  : (mode == 0) ? (float*)(ws + baseEnd)
                                : (float*)(ws + afterCommon);
    // prologue scratch (unions into outbuf region)
    int* bcS = (int*)outbuf;
    int* bsS = bcS + (size_t)HB * NTS;
    int* bcD = bsS + (size_t)HB * NTS;
    int* bsD = bcD + (size_t)HB * NT_D;
    int* totS = bsD + (size_t)HB * NT_D;
    int* totD = totS + NTS;

    k_node_enc<<<NN / 8, 256, 0, stream>>>(nfeats, emb, encW, encB, projW, projB, h);

    if (mode == 1) {
        k_prepAll<<<(66 * 512 + 6144 + 544 + 255) / 256, 256, 0, stream>>>(
            enW2, enB2, W2bf, gruWi, gruWh, gWhi, gWlo,
            eencW, eencB, enW1, enB1, Wcomb, bcomb);
        k_histB<<<2 * HB, 256, 0, stream>>>(src, dst, bcS, bcD);
        k_colsumB<<<(NTS + NT_D + 255) / 256, 256, 0, stream>>>(bcS, bcD, bsS, bsD, totS, totD);
        k_scanB<<<2, 256, 0, stream>>>(totS, totD, offsS, offsD);
        k_scatterB<<<2 * HB, 256, 0, stream>>>(src, dst, bsS, bsD, offsS, offsD, epermS, epermD);
        k_invgather<<<(NE + 255) / 256, 256, 0, stream>>>(epermS, src, posS, srcS);
        k_sortNode<<<NT_D, 256, 0, stream>>>(epermD, dst, offsD, epermD2, nodeOffs);
        k_scatterIdx<<<(NE + 255) / 256, 256, 0, stream>>>(epermD2, posS, idxS);
        k_edge_t3h<<<NE / 128, 256, 0, stream>>>(efeats, Wcomb, bcomb, epermS, tSh);
    } else if (mode == 0) {
        int* blockCounts = (int*)outbuf;
        int* blockStart  = blockCounts + (size_t)HB * NTS;
        int* tileTot     = blockStart + (size_t)HB * NTS;
        k_prepAll<<<(66 * 512 + 6144 + 544 + 255) / 256, 256, 0, stream>>>(
            enW2, enB2, W2bf, gruWi, gruWh, gWhi, gWlo,
            eencW, eencB, enW1, enB1, Wcomb, bcomb);
        k_histT<NTS, 4><<<HB, 256, 0, stream>>>(src, blockCounts);
        k_colsumT<NTS><<<(NTS + 255) / 256, 256, 0, stream>>>(blockCounts, blockStart, tileTot);
        k_scanT<NTS, 25><<<1, 256, 0, stream>>>(tileTot, offsS);
        k_scatterT<NTS, 4><<<HB, 256, 0, stream>>>(src, blockStart, offsS, epermS);
        k_invperm<<<(NE + 255) / 256, 256, 0, stream>>>(epermS, posS);
        k_gatherKey<<<(NE + 255) / 256, 256, 0, stream>>>(epermS, src, srcS);
        k_gatherKey<<<(NE + 255) / 256, 256, 0, stream>>>(epermS, dst, idxS);
        k_edge_t3h<<<NE / 128, 256, 0, stream>>>(efeats, Wcomb, bcomb, epermS, tSh);
    } else {
        k_prepAll<<<(66 * 512 + 6144 + 544 + 255) / 256, 256, 0, stream>>>(
            enW2, enB2, W2bf, gruWi, gruWh, gWhi, gWlo,
            eencW, eencB, enW1, enB1, Wcomb, bcomb);
        k_w2ext<<<(32 * QC + 255) / 256, 256, 0, stream>>>(enW2, enB2, W2ext);
        k_edge_t3<<<NE / 128, 256, 0, stream>>>(efeats, Wcomb, bcomb, nullptr, tSf);
    }

    for (int s = 0; s < 3; ++s) {
        if (mode == 1) {
            k_msgF16<1><<<NTS, 256, 0, stream>>>(h, W2bf, tSh, srcS, idxS, offsS, outbuf);
            k_gruAgg4<<<NT_D, 256, 0, stream>>>(outbuf, nodeOffs, convB,
                                                gWhi, gWlo, gruBi, gruBh, h);
        } else if (mode == 0) {
            hipMemsetAsync(outbuf, 0, (size_t)NN * 32 * 4, stream);
            k_msgF16<0><<<NTS, 256, 0, stream>>>(h, W2bf, tSh, srcS, idxS, offsS, outbuf);
            k_gru<<<NN / 32, 256, 0, stream>>>(outbuf, convB, gruWi, gruWh, gruBi, gruBh, h);
        } else {
            hipMemsetAsync(outbuf, 0, (size_t)NN * 32 * 4, stream);
            k_msgC<<<NE / 32, 256, 0, stream>>>(tSf, src, dst, h, W2ext, outbuf);
            k_gru<<<NN / 32, 256, 0, stream>>>(outbuf, convB, gruWi, gruWh, gruBi, gruBh, h);
        }
    }
    k_dec<<<NN / 8, 256, 0, stream>>>(h, dW1, db1, da1, dW2, db2, da2, dW3, db3, da3, dW4, db4, out);
}

// Round 20
// 393.949 us; speedup vs baseline: 1.2937x; 1.0011x over previous
//
#include <hip/hip_runtime.h>
#include <hip/hip_bf16.h>

// MPNN on MI355X — fused 16-node-tile msg kernel + MFMA GRU, fully pre-sorted streams.
// msg[e,o] = sum_k t[e,k]*Q[src,k,o] + q0[src,o],  Q[n] = h[n] @ W2ext
// k_msgF16: per 16-node src tile, MFMA Q (16x1056) into LDS as F16 (k-pair
// interleaved); barrier-free edge stream via v_dot2_f32_f16 (t stored f16).
// Edge encoder folded. k_gruAgg4: split-bf16 MFMA GRU. No global atomics (MODE1).
// Encoders/decoder: 32 nodes/block (weights staged once per 4 groups).

#define NN 100000
#define NE 320000
#define QC 1056
#define NTS 6250      // NN/16 src tiles
#define NT_D 3125     // NN/32 dst tiles
#define HB 256        // bucketing blocks
#define EPB (NE / HB) // 1250
#define QSTRH 1072    // sQ row stride (halves)

typedef short bf16x8 __attribute__((ext_vector_type(8)));
typedef float f32x4  __attribute__((ext_vector_type(4)));
typedef _Float16 h16x2 __attribute__((ext_vector_type(2)));
typedef _Float16 h16x8 __attribute__((ext_vector_type(8)));

__device__ __forceinline__ float bf2f(unsigned short u) {
    return __uint_as_float(((unsigned int)u) << 16);
}
__device__ __forceinline__ unsigned short f2bf(float f) {
    unsigned int x = __float_as_uint(f);
    unsigned int r = (x + 0x7fffu + ((x >> 16) & 1u)) >> 16;
    return (unsigned short)r;
}
__device__ __forceinline__ float sigm(float x) {
    return 1.f / (1.f + __expf(-x));
}
__device__ __forceinline__ float dot2h(h16x2 a, h16x2 b, float c) {
#if __has_builtin(__builtin_amdgcn_fdot2)
    return __builtin_amdgcn_fdot2(a, b, c, false);
#else
    return c + (float)a[0] * (float)b[0] + (float)a[1] * (float)b[1];
#endif
}

// ---- build W2ext [32][1056] (fp32, msgC fallback only)
__global__ __launch_bounds__(256) void k_w2ext(const float* __restrict__ W2,
                                               const float* __restrict__ b2,
                                               float* __restrict__ W2ext) {
    int idx = blockIdx.x * 256 + threadIdx.x;
    if (idx >= 32 * QC) return;
    int i = idx / QC, c = idx % QC;
    float v;
    if (c < 1024) { int k = c >> 5, o = c & 31; v = W2[k * 1024 + i * 32 + o]; }
    else          { v = b2[i * 32 + (c - 1024)]; }
    W2ext[idx] = v;
}

// ---- merged weight prep
__global__ __launch_bounds__(256) void k_prepAll(
    const float* __restrict__ W2, const float* __restrict__ b2,
    unsigned short* __restrict__ W2bf,
    const float* __restrict__ Wi, const float* __restrict__ Wh,
    unsigned short* __restrict__ Whi, unsigned short* __restrict__ Wlo,
    const float* __restrict__ eencW, const float* __restrict__ eencB,
    const float* __restrict__ enW1, const float* __restrict__ enB1,
    float* __restrict__ Wcomb, float* __restrict__ bcomb) {
    int idx = blockIdx.x * 256 + threadIdx.x;
    if (idx < 66 * 512) {
        int ct = idx >> 9, l = (idx >> 3) & 63, j = idx & 7;
        int kk = ((j >> 2) << 4) + ((l >> 4) << 2) + (j & 3);
        int c = ct * 16 + (l & 15);
        float v;
        if (c < 1024) { int kb = c >> 5, o = c & 31; v = W2[kb * 1024 + kk * 32 + o]; }
        else          { v = b2[kk * 32 + (c - 1024)]; }
        W2bf[idx] = f2bf(v);
    } else if (idx < 66 * 512 + 6144) {
        int q = idx - 66 * 512;
        int j = q & 7, l = (q >> 3) & 63, kt = (q >> 9) & 1, nt = q >> 10;
        int k = ((j >> 2) << 4) + ((l >> 4) << 2) + (j & 3);
        int col = nt * 16 + (l & 15);
        float v = kt ? Wh[k * 96 + col] : Wi[k * 96 + col];
        unsigned short hi = f2bf(v);
        Whi[q] = hi;
        Wlo[q] = f2bf(v - bf2f(hi));
    } else if (idx < 66 * 512 + 6144 + 544) {
        int q = idx - 66 * 512 - 6144;
        if (q < 512) {
            int i = q >> 5, o = q & 31;
            float acc = 0.f;
            #pragma unroll 8
            for (int j = 0; j < 32; ++j) acc += eencW[i * 32 + j] * enW1[j * 32 + o];
            Wcomb[i * 32 + o] = acc;
        } else {
            int o = q - 512;
            float acc = enB1[o];
            #pragma unroll 8
            for (int j = 0; j < 32; ++j) acc += eencB[j] * enW1[j * 32 + o];
            bcomb[o] = acc;
        }
    }
}

// ---- merged histograms
__global__ __launch_bounds__(256) void k_histB(const int* __restrict__ src,
                                               const int* __restrict__ dst,
                                               int* __restrict__ bcS,
                                               int* __restrict__ bcD) {
    __shared__ int sHist[NTS];
    int tid = threadIdx.x, b = blockIdx.x;
    bool isS = b < HB;
    int bb = isS ? b : b - HB;
    const int* keys = isS ? src : dst;
    int NT = isS ? NTS : NT_D;
    int SH = isS ? 4 : 5;
    for (int c = tid; c < NT; c += 256) sHist[c] = 0;
    __syncthreads();
    int beg = bb * EPB, end = min(beg + EPB, NE);
    for (int e = beg + tid; e < end; e += 256)
        atomicAdd(&sHist[keys[e] >> SH], 1);
    __syncthreads();
    int* out = isS ? bcS : bcD;
    for (int c = tid; c < NT; c += 256) out[bb * NT + c] = sHist[c];
}

// ---- merged column sums
__global__ __launch_bounds__(256) void k_colsumB(const int* __restrict__ bcS,
                                                 const int* __restrict__ bcD,
                                                 int* __restrict__ bsS,
                                                 int* __restrict__ bsD,
                                                 int* __restrict__ totS,
                                                 int* __restrict__ totD) {
    int c = blockIdx.x * 256 + threadIdx.x;
    if (c < NTS) {
        int running = 0;
        #pragma unroll 8
        for (int b = 0; b < HB; ++b) {
            bsS[b * NTS + c] = running;
            running += bcS[b * NTS + c];
        }
        totS[c] = running;
    } else if (c < NTS + NT_D) {
        int cc = c - NTS;
        int running = 0;
        #pragma unroll 8
        for (int b = 0; b < HB; ++b) {
            bsD[b * NT_D + cc] = running;
            running += bcD[b * NT_D + cc];
        }
        totD[cc] = running;
    }
}

// ---- merged scans
__global__ __launch_bounds__(256) void k_scanB(const int* __restrict__ totS,
                                               const int* __restrict__ totD,
                                               int* __restrict__ offS,
                                               int* __restrict__ offD) {
    __shared__ int sTot[NTS];
    __shared__ int sPart[257];
    int tid = threadIdx.x;
    const int* tot = (blockIdx.x == 0) ? totS : totD;
    int* offs = (blockIdx.x == 0) ? offS : offD;
    int NT = (blockIdx.x == 0) ? NTS : NT_D;
    int SEG = (blockIdx.x == 0) ? 25 : 13;
    for (int c = tid; c < NT; c += 256) sTot[c] = tot[c];
    __syncthreads();
    int base = tid * SEG;
    int loc = 0;
    for (int j = 0; j < SEG; ++j) {
        int c = base + j;
        if (c < NT) { int v = sTot[c]; sTot[c] = loc; loc += v; }
    }
    sPart[tid] = loc;
    __syncthreads();
    if (tid == 0) {
        int s = 0;
        for (int i = 0; i < 256; ++i) { int v = sPart[i]; sPart[i] = s; s += v; }
        sPart[256] = s;
    }
    __syncthreads();
    int add = sPart[tid];
    for (int j = 0; j < SEG; ++j) {
        int c = base + j;
        if (c < NT) sTot[c] += add;
    }
    __syncthreads();
    for (int c = tid; c < NT; c += 256) offs[c] = sTot[c];
    if (tid == 0) offs[NT] = sPart[256];
}

// ---- merged scatters
__global__ __launch_bounds__(256) void k_scatterB(const int* __restrict__ src,
                                                  const int* __restrict__ dst,
                                                  const int* __restrict__ bsS,
                                                  const int* __restrict__ bsD,
                                                  const int* __restrict__ offS,
                                                  const int* __restrict__ offD,
                                                  int* __restrict__ epS,
                                                  int* __restrict__ epD) {
    __shared__ int sCur[NTS];
    int tid = threadIdx.x, b = blockIdx.x;
    bool isS = b < HB;
    int bb = isS ? b : b - HB;
    const int* keys = isS ? src : dst;
    const int* bs = isS ? bsS : bsD;
    const int* offs = isS ? offS : offD;
    int* ep = isS ? epS : epD;
    int NT = isS ? NTS : NT_D;
    int SH = isS ? 4 : 5;
    for (int c = tid; c < NT; c += 256)
        sCur[c] = offs[c] + bs[bb * NT + c];
    __syncthreads();
    int beg = bb * EPB, end = min(beg + EPB, NE);
    for (int e = beg + tid; e < end; e += 256) {
        int pos = atomicAdd(&sCur[keys[e] >> SH], 1);
        ep[pos] = e;
    }
}

// ---- merged invperm + src gather
__global__ __launch_bounds__(256) void k_invgather(const int* __restrict__ epermS,
                                                   const int* __restrict__ src,
                                                   int* __restrict__ posS,
                                                   int* __restrict__ srcS) {
    int p = blockIdx.x * 256 + threadIdx.x;
    if (p < NE) {
        int e = epermS[p];
        posS[e] = p;
        srcS[p] = src[e];
    }
}

// ---- node encoder + projection: 32 nodes/block
__global__ __launch_bounds__(256) void k_node_enc(
    const int* __restrict__ nfeats, const float* __restrict__ emb,
    const float* __restrict__ encW, const float* __restrict__ encB,
    const float* __restrict__ projW, const float* __restrict__ projB,
    float* __restrict__ h) {
    __shared__ float sEncW[1024], sProjW[1024], sEncB[32], sProjB[32];
    __shared__ float sEmb[8][33], sNh[8][33];
    int tid = threadIdx.x;
    for (int i = tid; i < 1024; i += 256) { sEncW[i] = encW[i]; sProjW[i] = projW[i]; }
    if (tid < 32) { sEncB[tid] = encB[tid]; sProjB[tid] = projB[tid]; }
    int ln = tid >> 5, o = tid & 31;
    for (int g = 0; g < 4; ++g) {
        int node = blockIdx.x * 32 + g * 8 + ln;
        int nt = nfeats[node];
        float ev = fmaxf(emb[nt * 32 + o], 0.f);
        __syncthreads();               // prev group's reads done (and weights ready g=0)
        sEmb[ln][o] = ev;
        __syncthreads();
        float acc = sEncB[o];
        #pragma unroll
        for (int i = 0; i < 32; ++i) acc += sEmb[ln][i] * sEncW[i * 32 + o];
        sNh[ln][o] = fmaxf(acc, 0.f);
        __syncthreads();
        float acc2 = sProjB[o];
        #pragma unroll
        for (int i = 0; i < 32; ++i) acc2 += sNh[ln][i] * sProjW[i * 32 + o];
        h[node * 32 + o] = fmaxf(acc2, 0.f);
    }
}

// ---- edge encoder (folded), f16 output
__global__ __launch_bounds__(256) void k_edge_t3h(
    const float* __restrict__ efeats, const float* __restrict__ Wcomb,
    const float* __restrict__ bcomb, const int* __restrict__ eperm,
    unsigned short* __restrict__ tS) {
    int tid = threadIdx.x;
    int el = tid >> 3, l8 = tid & 7;
    int gbase = (tid & 63) & 56;
    int c0 = l8 << 2;
    float4 w[16];
    #pragma unroll
    for (int i = 0; i < 16; ++i) w[i] = *(const float4*)(Wcomb + i * 32 + c0);
    float4 bb = *(const float4*)(bcomb + c0);
    #pragma unroll
    for (int it = 0; it < 4; ++it) {
        int p = blockIdx.x * 128 + it * 32 + el;
        int e = eperm ? eperm[p] : p;
        float2 efv = *(const float2*)(efeats + (size_t)e * 16 + (l8 << 1));
        float a0 = bb.x, a1 = bb.y, a2 = bb.z, a3 = bb.w;
        #pragma unroll
        for (int i = 0; i < 8; ++i) {
            float f0 = __shfl(efv.x, gbase + i, 64);
            float f1 = __shfl(efv.y, gbase + i, 64);
            float4 w0 = w[2 * i], w1 = w[2 * i + 1];
            a0 += f0 * w0.x + f1 * w1.x;
            a1 += f0 * w0.y + f1 * w1.y;
            a2 += f0 * w0.z + f1 * w1.z;
            a3 += f0 * w0.w + f1 * w1.w;
        }
        _Float16 h0 = (_Float16)fmaxf(a0, 0.f);
        _Float16 h1 = (_Float16)fmaxf(a1, 0.f);
        _Float16 h2 = (_Float16)fmaxf(a2, 0.f);
        _Float16 h3 = (_Float16)fmaxf(a3, 0.f);
        ushort4 o4;
        o4.x = *(unsigned short*)&h0; o4.y = *(unsigned short*)&h1;
        o4.z = *(unsigned short*)&h2; o4.w = *(unsigned short*)&h3;
        *(ushort4*)(tS + (size_t)p * 32 + c0) = o4;
    }
}

// ---- edge encoder fp32 output (msgC fallback only)
__global__ __launch_bounds__(256) void k_edge_t3(
    const float* __restrict__ efeats, const float* __restrict__ Wcomb,
    const float* __restrict__ bcomb, const int* __restrict__ eperm,
    float* __restrict__ tS) {
    int tid = threadIdx.x;
    int el = tid >> 3, l8 = tid & 7;
    int gbase = (tid & 63) & 56;
    int c0 = l8 << 2;
    float4 w[16];
    #pragma unroll
    for (int i = 0; i < 16; ++i) w[i] = *(const float4*)(Wcomb + i * 32 + c0);
    float4 bb = *(const float4*)(bcomb + c0);
    #pragma unroll
    for (int it = 0; it < 4; ++it) {
        int p = blockIdx.x * 128 + it * 32 + el;
        int e = eperm ? eperm[p] : p;
        float2 efv = *(const float2*)(efeats + (size_t)e * 16 + (l8 << 1));
        float a0 = bb.x, a1 = bb.y, a2 = bb.z, a3 = bb.w;
        #pragma unroll
        for (int i = 0; i < 8; ++i) {
            float f0 = __shfl(efv.x, gbase + i, 64);
            float f1 = __shfl(efv.y, gbase + i, 64);
            float4 w0 = w[2 * i], w1 = w[2 * i + 1];
            a0 += f0 * w0.x + f1 * w1.x;
            a1 += f0 * w0.y + f1 * w1.y;
            a2 += f0 * w0.z + f1 * w1.z;
            a3 += f0 * w0.w + f1 * w1.w;
        }
        *(float4*)(tS + (size_t)p * 32 + c0) =
            make_float4(fmaxf(a0, 0.f), fmaxf(a1, 0.f), fmaxf(a2, 0.f), fmaxf(a3, 0.f));
    }
}

// ---- legacy single-purpose bucketing kernels (fallback modes only)
template<int NT, int SHIFT>
__global__ __launch_bounds__(256) void k_histT(const int* __restrict__ keys,
                                               int* __restrict__ blockCounts) {
    __shared__ int sHist[NT];
    int tid = threadIdx.x, b = blockIdx.x;
    for (int c = tid; c < NT; c += 256) sHist[c] = 0;
    __syncthreads();
    int beg = b * EPB, end = min(beg + EPB, NE);
    for (int e = beg + tid; e < end; e += 256)
        atomicAdd(&sHist[keys[e] >> SHIFT], 1);
    __syncthreads();
    for (int c = tid; c < NT; c += 256) blockCounts[b * NT + c] = sHist[c];
}

template<int NT>
__global__ __launch_bounds__(256) void k_colsumT(const int* __restrict__ blockCounts,
                                                 int* __restrict__ blockStart,
                                                 int* __restrict__ tileTot) {
    int c = blockIdx.x * 256 + threadIdx.x;
    if (c >= NT) return;
    int running = 0;
    #pragma unroll 8
    for (int b = 0; b < HB; ++b) {
        blockStart[b * NT + c] = running;
        running += blockCounts[b * NT + c];
    }
    tileTot[c] = running;
}

template<int NT, int SEG>
__global__ __launch_bounds__(256) void k_scanT(const int* __restrict__ tileTot,
                                               int* __restrict__ offs) {
    __shared__ int sTot[NT];
    __shared__ int sPart[257];
    int tid = threadIdx.x;
    for (int c = tid; c < NT; c += 256) sTot[c] = tileTot[c];
    __syncthreads();
    int base = tid * SEG;
    int loc = 0;
    for (int j = 0; j < SEG; ++j) {
        int c = base + j;
        if (c < NT) { int v = sTot[c]; sTot[c] = loc; loc += v; }
    }
    sPart[tid] = loc;
    __syncthreads();
    if (tid == 0) {
        int s = 0;
        for (int i = 0; i < 256; ++i) { int v = sPart[i]; sPart[i] = s; s += v; }
        sPart[256] = s;
    }
    __syncthreads();
    int add = sPart[tid];
    for (int j = 0; j < SEG; ++j) {
        int c = base + j;
        if (c < NT) sTot[c] += add;
    }
    __syncthreads();
    for (int c = tid; c < NT; c += 256) offs[c] = sTot[c];
    if (tid == 0) offs[NT] = sPart[256];
}

template<int NT, int SHIFT>
__global__ __launch_bounds__(256) void k_scatterT(const int* __restrict__ keys,
                                                  const int* __restrict__ blockStart,
                                                  const int* __restrict__ offs,
                                                  int* __restrict__ eperm) {
    __shared__ int sCur[NT];
    int tid = threadIdx.x, b = blockIdx.x;
    for (int c = tid; c < NT; c += 256)
        sCur[c] = offs[c] + blockStart[b * NT + c];
    __syncthreads();
    int beg = b * EPB, end = min(beg + EPB, NE);
    for (int e = beg + tid; e < end; e += 256) {
        int pos = atomicAdd(&sCur[keys[e] >> SHIFT], 1);
        eperm[pos] = e;
    }
}

// ---- second-level sort: within each dst tile, sort by node (32 LDS bins)
__global__ __launch_bounds__(256) void k_sortNode(
    const int* __restrict__ epermD, const int* __restrict__ dst,
    const int* __restrict__ offsD, int* __restrict__ epermD2,
    int* __restrict__ nodeOffs) {
    __shared__ int sCnt[32], sStart[32];
    int tid = threadIdx.x, d = blockIdx.x;
    int beg = offsD[d], end = offsD[d + 1];
    if (tid < 32) sCnt[tid] = 0;
    __syncthreads();
    for (int p = beg + tid; p < end; p += 256)
        atomicAdd(&sCnt[dst[epermD[p]] & 31], 1);
    __syncthreads();
    if (tid == 0) {
        int s = beg;
        for (int r = 0; r < 32; ++r) { sStart[r] = s; s += sCnt[r]; }
    }
    __syncthreads();
    if (tid < 32) {
        nodeOffs[d * 32 + tid] = sStart[tid];
        sCnt[tid] = sStart[tid];
    }
    if (d == NT_D - 1 && tid == 0) nodeOffs[NN] = end;
    __syncthreads();
    for (int p = beg + tid; p < end; p += 256) {
        int e = epermD[p];
        int pos = atomicAdd(&sCnt[dst[e] & 31], 1);
        epermD2[pos] = e;
    }
}

// ---- inverse permutation (fallback path)
__global__ __launch_bounds__(256) void k_invperm(const int* __restrict__ eperm,
                                                 int* __restrict__ pos) {
    int p = blockIdx.x * 256 + threadIdx.x;
    if (p < NE) pos[eperm[p]] = p;
}

// ---- gather key (fallback path)
__global__ __launch_bounds__(256) void k_gatherKey(const int* __restrict__ epermS,
                                                   const int* __restrict__ key,
                                                   int* __restrict__ out) {
    int p = blockIdx.x * 256 + threadIdx.x;
    if (p < NE) out[p] = key[epermS[p]];
}

// ---- idxS[posS[epermD2[q]]] = q
__global__ __launch_bounds__(256) void k_scatterIdx(const int* __restrict__ epermD2,
                                                    const int* __restrict__ posS,
                                                    int* __restrict__ idxS) {
    int q = blockIdx.x * 256 + threadIdx.x;
    if (q < NE) idxS[posS[epermD2[q]]] = q;
}

// ---- fused per-16-node-src-tile: MFMA Q -> f16 LDS (k-pair interleaved),
// edge stream: 4 lanes/edge x 8 outputs via v_dot2_f32_f16.
template<int MODE>
__global__ __launch_bounds__(256) void k_msgF16(
    const float* __restrict__ h, const unsigned short* __restrict__ W2bf,
    const unsigned short* __restrict__ tS, const int* __restrict__ srcS,
    const int* __restrict__ idxS, const int* __restrict__ offs,
    float* __restrict__ outbuf) {
    __shared__ unsigned short sQ[16 * QSTRH];
    int tid = threadIdx.x;
    int tile = blockIdx.x;
    int beg = offs[tile], end = offs[tile + 1];
    if (beg >= end) return;
    int nodeBase = tile * 16;
    int wave = tid >> 6, lane = tid & 63;

    int arow = lane & 15;
    const float* hp = h + (size_t)(nodeBase + arow) * 32 + ((lane >> 4) << 2);
    float4 x0 = *(const float4*)hp;
    float4 x1 = *(const float4*)(hp + 16);
    bf16x8 a;
    a[0] = (short)f2bf(x0.x); a[1] = (short)f2bf(x0.y);
    a[2] = (short)f2bf(x0.z); a[3] = (short)f2bf(x0.w);
    a[4] = (short)f2bf(x1.x); a[5] = (short)f2bf(x1.y);
    a[6] = (short)f2bf(x1.z); a[7] = (short)f2bf(x1.w);

    f32x4 z = {0.f, 0.f, 0.f, 0.f};
    int crow0 = (lane >> 4) << 2;
    int ccol = lane & 15;
    for (int ct = wave; ct < 66; ct += 4) {
        bf16x8 b = *(const bf16x8*)(W2bf + (size_t)((ct << 6) + lane) * 8);
        f32x4 acc = __builtin_amdgcn_mfma_f32_16x16x32_bf16(a, b, z, 0, 0, 0);
        int c = (ct << 4) + ccol;
        int idx;
        if (c < 1024) {
            int k = c >> 5, o = c & 31;
            idx = ((k >> 1) << 6) + (o << 1) + (k & 1);
        } else {
            idx = 1024 + (c - 1024);
        }
        unsigned short* qp = sQ + crow0 * QSTRH + idx;
        _Float16 v0 = (_Float16)acc[0], v1 = (_Float16)acc[1];
        _Float16 v2 = (_Float16)acc[2], v3 = (_Float16)acc[3];
        qp[0 * QSTRH] = *(unsigned short*)&v0;
        qp[1 * QSTRH] = *(unsigned short*)&v1;
        qp[2 * QSTRH] = *(unsigned short*)&v2;
        qp[3 * QSTRH] = *(unsigned short*)&v3;
    }
    __syncthreads();

    int el = tid >> 2, l4 = tid & 3;
    int o0 = l4 << 3;
    for (int p = beg + el; p < end; p += 64) {
        int row = srcS[p] - nodeBase;
        int widx = idxS[p];
        h16x8 trow[4];
        #pragma unroll
        for (int i = 0; i < 4; ++i)
            trow[i] = *(const h16x8*)(tS + (size_t)p * 32 + (i << 3));
        const unsigned short* qp = sQ + row * QSTRH;
        h16x8 qb = *(const h16x8*)(qp + 1024 + o0);
        float acc[8];
        #pragma unroll
        for (int j = 0; j < 8; ++j) acc[j] = (float)qb[j];
        #pragma unroll
        for (int kp = 0; kp < 16; ++kp) {
            h16x2 t2;
            t2[0] = trow[kp >> 2][(kp & 3) * 2];
            t2[1] = trow[kp >> 2][(kp & 3) * 2 + 1];
            h16x8 qa = *(const h16x8*)(qp + (kp << 6) + (o0 << 1));
            h16x8 qc = *(const h16x8*)(qp + (kp << 6) + (o0 << 1) + 8);
            #pragma unroll
            for (int j = 0; j < 4; ++j) {
                h16x2 q2a; q2a[0] = qa[2 * j]; q2a[1] = qa[2 * j + 1];
                h16x2 q2c; q2c[0] = qc[2 * j]; q2c[1] = qc[2 * j + 1];
                acc[j]     = dot2h(t2, q2a, acc[j]);
                acc[4 + j] = dot2h(t2, q2c, acc[4 + j]);
            }
        }
        if (MODE) {
            float* op = outbuf + (size_t)widx * 32 + o0;
            *(float4*)op = make_float4(acc[0], acc[1], acc[2], acc[3]);
            *(float4*)(op + 4) = make_float4(acc[4], acc[5], acc[6], acc[7]);
        } else {
            float* op = outbuf + (size_t)widx * 32 + o0;
            #pragma unroll
            for (int j = 0; j < 8; ++j) atomicAdd(op + j, acc[j]);
        }
    }
}

// ---- fallback msg (tiny ws)
__global__ __launch_bounds__(256) void k_msgC(
    const float* __restrict__ t, const int* __restrict__ src, const int* __restrict__ dst,
    const float* __restrict__ h, const float* __restrict__ W2ext, float* __restrict__ agg) {
    __shared__ float sT[32][33], sH[32][33];
    __shared__ int sSrc[32], sDst[32];
    int tid = threadIdx.x;
    int e0 = blockIdx.x * 32;
    if (tid < 32) sSrc[tid] = src[e0 + tid];
    else if (tid < 64) sDst[tid - 32] = dst[e0 + tid - 32];
    __syncthreads();
    for (int idx = tid; idx < 1024; idx += 256) {
        int el = idx >> 5, k = idx & 31;
        sT[el][k] = t[(e0 + el) * 32 + k];
        sH[el][k] = h[(size_t)sSrc[el] * 32 + k];
    }
    __syncthreads();
    int el = tid >> 3, l8 = tid & 7;
    int c0 = l8 * 4;
    float m0 = 0.f, m1 = 0.f, m2 = 0.f, m3 = 0.f;
    for (int i = 0; i < 32; ++i) {
        const float* wrow = W2ext + i * QC;
        float4 wb = *(const float4*)(wrow + 1024 + c0);
        float w0 = wb.x, w1 = wb.y, w2 = wb.z, w3 = wb.w;
        #pragma unroll 8
        for (int k = 0; k < 32; ++k) {
            float tk = sT[el][k];
            float4 w = *(const float4*)(wrow + k * 32 + c0);
            w0 += tk * w.x; w1 += tk * w.y; w2 += tk * w.z; w3 += tk * w.w;
        }
        float hi = sH[el][i];
        m0 += hi * w0; m1 += hi * w1; m2 += hi * w2; m3 += hi * w3;
    }
    float* ap = agg + (size_t)sDst[el] * 32 + c0;
    atomicAdd(ap + 0, m0); atomicAdd(ap + 1, m1);
    atomicAdd(ap + 2, m2); atomicAdd(ap + 3, m3);
}

// ---- GRU step reading agg[] (MODE 0 / fallback)
__global__ __launch_bounds__(256) void k_gru(
    const float* __restrict__ agg, const float* __restrict__ convB,
    const float* __restrict__ Wi, const float* __restrict__ Wh,
    const float* __restrict__ bi, const float* __restrict__ bh,
    float* __restrict__ h) {
    __shared__ float sWi[3072], sWh[3072], sBi[96], sBh[96], sCb[32];
    __shared__ float sX[8][33], sH[8][33];
    int tid = threadIdx.x;
    for (int i = tid; i < 3072; i += 256) { sWi[i] = Wi[i]; sWh[i] = Wh[i]; }
    if (tid < 96) { sBi[tid] = bi[tid]; sBh[tid] = bh[tid]; }
    if (tid < 32) sCb[tid] = convB[tid];
    int ln = tid >> 5, o = tid & 31;
    for (int g = 0; g < 4; ++g) {
        int node = blockIdx.x * 32 + g * 8 + ln;
        float hv = h[node * 32 + o];
        float av = agg[node * 32 + o];
        __syncthreads();
        sX[ln][o] = fmaxf(av + sCb[o], 0.f);
        sH[ln][o] = hv;
        __syncthreads();
        float air = sBi[o], aiz = sBi[o + 32], ain = sBi[o + 64];
        float ahr = sBh[o], ahz = sBh[o + 32], ahn = sBh[o + 64];
        #pragma unroll 8
        for (int i = 0; i < 32; ++i) {
            float x = sX[ln][i], hh = sH[ln][i];
            air += x * sWi[i * 96 + o];      ahr += hh * sWh[i * 96 + o];
            aiz += x * sWi[i * 96 + o + 32]; ahz += hh * sWh[i * 96 + o + 32];
            ain += x * sWi[i * 96 + o + 64]; ahn += hh * sWh[i * 96 + o + 64];
        }
        float r = sigm(air + ahr);
        float zz = sigm(aiz + ahz);
        float ng = tanhf(ain + r * ahn);
        h[node * 32 + o] = (1.f - zz) * ng + zz * hv;
    }
}

// ---- MODE 1: per 32-node dst tile: segment-sum -> X in LDS, GRU via split-bf16 MFMA.
__global__ __launch_bounds__(256) void k_gruAgg4(
    const float* __restrict__ msgbuf, const int* __restrict__ nodeOffs,
    const float* __restrict__ convB,
    const unsigned short* __restrict__ Whi, const unsigned short* __restrict__ Wlo,
    const float* __restrict__ bi, const float* __restrict__ bh,
    float* __restrict__ h) {
    __shared__ float sAgg[32 * 33];
    int tid = threadIdx.x;
    int d = blockIdx.x;
    int base = d * 32;

    {
        int n8 = tid >> 3, l8 = tid & 7;
        int node = base + n8;
        int nb = nodeOffs[node], ne2 = nodeOffs[node + 1];
        float a0 = 0.f, a1 = 0.f, a2 = 0.f, a3 = 0.f;
        for (int p = nb; p < ne2; ++p) {
            float4 v = *(const float4*)(msgbuf + (size_t)p * 32 + (l8 << 2));
            a0 += v.x; a1 += v.y; a2 += v.z; a3 += v.w;
        }
        int c0 = l8 << 2;
        float4 cb = *(const float4*)(convB + c0);
        float* sp = sAgg + n8 * 33 + c0;
        sp[0] = fmaxf(a0 + cb.x, 0.f);
        sp[1] = fmaxf(a1 + cb.y, 0.f);
        sp[2] = fmaxf(a2 + cb.z, 0.f);
        sp[3] = fmaxf(a3 + cb.w, 0.f);
    }
    __syncthreads();

    int wave = tid >> 6, lane = tid & 63;
    int m = wave >> 1, c = wave & 1;
    int arow = lane & 15, kg = (lane >> 4) << 2;

    bf16x8 xhi, xlo, hhi, hlo;
    {
        const float* xp = sAgg + (m * 16 + arow) * 33 + kg;
        float4 v0 = *(const float4*)xp;
        float4 v1 = *(const float4*)(xp + 16);
        float xv[8] = {v0.x, v0.y, v0.z, v0.w, v1.x, v1.y, v1.z, v1.w};
        #pragma unroll
        for (int j = 0; j < 8; ++j) {
            unsigned short hi16 = f2bf(xv[j]);
            xhi[j] = (short)hi16;
            xlo[j] = (short)f2bf(xv[j] - bf2f(hi16));
        }
        const float* hp = h + (size_t)(base + m * 16 + arow) * 32 + kg;
        float4 w0 = *(const float4*)hp;
        float4 w1 = *(const float4*)(hp + 16);
        float hv8[8] = {w0.x, w0.y, w0.z, w0.w, w1.x, w1.y, w1.z, w1.w};
        #pragma unroll
        for (int j = 0; j < 8; ++j) {
            unsigned short hi16 = f2bf(hv8[j]);
            hhi[j] = (short)hi16;
            hlo[j] = (short)f2bf(hv8[j] - bf2f(hi16));
        }
    }

    int ccol = lane & 15, crow0 = (lane >> 4) << 2;
    int o = c * 16 + ccol;
    auto Bf = [&](int nt, int kt, const unsigned short* W) {
        return *(const bf16x8*)(W + (size_t)(((nt * 2 + kt) * 64 + lane) << 3));
    };
    f32x4 accR = {0.f, 0.f, 0.f, 0.f}, accZ = {0.f, 0.f, 0.f, 0.f};
    f32x4 accIN = {0.f, 0.f, 0.f, 0.f}, accHN = {0.f, 0.f, 0.f, 0.f};
    {
        int nt = c;
        bf16x8 b0h = Bf(nt, 0, Whi), b0l = Bf(nt, 0, Wlo);
        bf16x8 b1h = Bf(nt, 1, Whi), b1l = Bf(nt, 1, Wlo);
        accR = __builtin_amdgcn_mfma_f32_16x16x32_bf16(xhi, b0h, accR, 0, 0, 0);
        accR = __builtin_amdgcn_mfma_f32_16x16x32_bf16(xlo, b0h, accR, 0, 0, 0);
        accR = __builtin_amdgcn_mfma_f32_16x16x32_bf16(xhi, b0l, accR, 0, 0, 0);
        accR = __builtin_amdgcn_mfma_f32_16x16x32_bf16(hhi, b1h, accR, 0, 0, 0);
        accR = __builtin_amdgcn_mfma_f32_16x16x32_bf16(hlo, b1h, accR, 0, 0, 0);
        accR = __builtin_amdgcn_mfma_f32_16x16x32_bf16(hhi, b1l, accR, 0, 0, 0);
    }
    {
        int nt = 2 + c;
        bf16x8 b0h = Bf(nt, 0, Whi), b0l = Bf(nt, 0, Wlo);
        bf16x8 b1h = Bf(nt, 1, Whi), b1l = Bf(nt, 1, Wlo);
        accZ = __builtin_amdgcn_mfma_f32_16x16x32_bf16(xhi, b0h, accZ, 0, 0, 0);
        accZ = __builtin_amdgcn_mfma_f32_16x16x32_bf16(xlo, b0h, accZ, 0, 0, 0);
        accZ = __builtin_amdgcn_mfma_f32_16x16x32_bf16(xhi, b0l, accZ, 0, 0, 0);
        accZ = __builtin_amdgcn_mfma_f32_16x16x32_bf16(hhi, b1h, accZ, 0, 0, 0);
        accZ = __builtin_amdgcn_mfma_f32_16x16x32_bf16(hlo, b1h, accZ, 0, 0, 0);
        accZ = __builtin_amdgcn_mfma_f32_16x16x32_bf16(hhi, b1l, accZ, 0, 0, 0);
    }
    {
        int nt = 4 + c;
        bf16x8 b0h = Bf(nt, 0, Whi), b0l = Bf(nt, 0, Wlo);
        bf16x8 b1h = Bf(nt, 1, Whi), b1l = Bf(nt, 1, Wlo);
        accIN = __builtin_amdgcn_mfma_f32_16x16x32_bf16(xhi, b0h, accIN, 0, 0, 0);
        accIN = __builtin_amdgcn_mfma_f32_16x16x32_bf16(xlo, b0h, accIN, 0, 0, 0);
        accIN = __builtin_amdgcn_mfma_f32_16x16x32_bf16(xhi, b0l, accIN, 0, 0, 0);
        accHN = __builtin_amdgcn_mfma_f32_16x16x32_bf16(hhi, b1h, accHN, 0, 0, 0);
        accHN = __builtin_amdgcn_mfma_f32_16x16x32_bf16(hlo, b1h, accHN, 0, 0, 0);
        accHN = __builtin_amdgcn_mfma_f32_16x16x32_bf16(hhi, b1l, accHN, 0, 0, 0);
    }

    float bir = bi[o], biz = bi[32 + o], bin = bi[64 + o];
    float bhr = bh[o], bhz = bh[32 + o], bhn = bh[64 + o];
    float hv[4];
    #pragma unroll
    for (int j = 0; j < 4; ++j)
        hv[j] = h[(size_t)(base + m * 16 + crow0 + j) * 32 + o];
    __syncthreads();
    #pragma unroll
    for (int j = 0; j < 4; ++j) {
        float r  = sigm(accR[j] + bir + bhr);
        float zz = sigm(accZ[j] + biz + bhz);
        float ng = tanhf(accIN[j] + bin + r * (accHN[j] + bhn));
        h[(size_t)(base + m * 16 + crow0 + j) * 32 + o] = (1.f - zz) * ng + zz * hv[j];
    }
}

// ---- decoder: 32 nodes/block (weights staged once)
__global__ __launch_bounds__(256) void k_dec(
    const float* __restrict__ h,
    const float* __restrict__ W1, const float* __restrict__ b1, const float* __restrict__ a1,
    const float* __restrict__ W2, const float* __restrict__ b2, const float* __restrict__ a2,
    const float* __restrict__ W3, const float* __restrict__ b3, const float* __restrict__ a3,
    const float* __restrict__ W4, const float* __restrict__ b4,
    float* __restrict__ out) {
    __shared__ float sW1[1024], sW2[1024], sW3[1024], sW4[96];
    __shared__ float sB1[32], sB2[32], sB3[32], sB4[3];
    __shared__ float sYa[8][33], sYb[8][33];
    int tid = threadIdx.x;
    for (int i = tid; i < 1024; i += 256) { sW1[i] = W1[i]; sW2[i] = W2[i]; sW3[i] = W3[i]; }
    if (tid < 96) sW4[tid] = W4[tid];
    if (tid < 32) { sB1[tid] = b1[tid]; sB2[tid] = b2[tid]; sB3[tid] = b3[tid]; }
    if (tid < 3) sB4[tid] = b4[tid];
    float A1 = a1[0], A2 = a2[0], A3 = a3[0];
    int ln = tid >> 5, o = tid & 31;
    for (int g = 0; g < 4; ++g) {
        int node = blockIdx.x * 32 + g * 8 + ln;
        float hv = h[node * 32 + o];
        __syncthreads();               // prev group's reads done (weights ready g=0)
        sYa[ln][o] = hv;
        __syncthreads();
        float acc = sB1[o];
        #pragma unroll
        for (int i = 0; i < 32; ++i) acc += sYa[ln][i] * sW1[i * 32 + o];
        acc = acc >= 0.f ? acc : A1 * acc;
        sYb[ln][o] = acc;
        __syncthreads();
        acc = sB2[o];
        #pragma unroll
        for (int i = 0; i < 32; ++i) acc += sYb[ln][i] * sW2[i * 32 + o];
        acc = acc >= 0.f ? acc : A2 * acc;
        __syncthreads();               // everyone done reading sYa
        sYa[ln][o] = acc;
        __syncthreads();
        acc = sB3[o];
        #pragma unroll
        for (int i = 0; i < 32; ++i) acc += sYa[ln][i] * sW3[i * 32 + o];
        acc = acc >= 0.f ? acc : A3 * acc;
        __syncthreads();               // everyone done reading sYb
        sYb[ln][o] = acc;
        __syncthreads();
        if (o < 3) {
            float r = sB4[o];
            #pragma unroll
            for (int i = 0; i < 32; ++i) r += sYb[ln][i] * sW4[i * 3 + o];
            out[node * 3 + o] = r;
        }
    }
}

extern "C" void kernel_launch(void* const* d_in, const int* in_sizes, int n_in,
                              void* d_out, int out_size, void* d_ws, size_t ws_size,
                              hipStream_t stream) {
    const int*   nfeats = (const int*)d_in[0];
    const float* efeats = (const float*)d_in[1];
    const int*   src    = (const int*)d_in[2];
    const int*   dst    = (const int*)d_in[3];
    const float* emb    = (const float*)d_in[4];
    const float* encW   = (const float*)d_in[5];
    const float* encB   = (const float*)d_in[6];
    const float* eencW  = (const float*)d_in[7];
    const float* eencB  = (const float*)d_in[8];
    const float* projW  = (const float*)d_in[9];
    const float* projB  = (const float*)d_in[10];
    const float* enW1   = (const float*)d_in[11];
    const float* enB1   = (const float*)d_in[12];
    const float* enW2   = (const float*)d_in[13];
    const float* enB2   = (const float*)d_in[14];
    const float* convB  = (const float*)d_in[15];
    const float* gruWi  = (const float*)d_in[16];
    const float* gruWh  = (const float*)d_in[17];
    const float* gruBi  = (const float*)d_in[18];
    const float* gruBh  = (const float*)d_in[19];
    const float* dW1 = (const float*)d_in[20]; const float* db1 = (const float*)d_in[21]; const float* da1 = (const float*)d_in[22];
    const float* dW2 = (const float*)d_in[23]; const float* db2 = (const float*)d_in[24]; const float* da2 = (const float*)d_in[25];
    const float* dW3 = (const float*)d_in[26]; const float* db3 = (const float*)d_in[27]; const float* da3 = (const float*)d_in[28];
    const float* dW4 = (const float*)d_in[29]; const float* db4 = (const float*)d_in[30];
    float* out = (float*)d_out;
    char* ws = (char*)d_ws;

    // bump allocator (256-B aligned)
    size_t cur = 0;
    auto alloc = [&](size_t n) { size_t p = cur; cur = (cur + n + 255) & ~(size_t)255; return p; };
    size_t o_h   = alloc((size_t)NN * 32 * 4);
    size_t o_t   = alloc((size_t)NE * 32 * 4);
    size_t o_w2e = alloc((size_t)32 * QC * 4);
    size_t afterCommon = cur;
    size_t o_w2b = alloc((size_t)66 * 512 * 2);
    size_t o_epS = alloc((size_t)NE * 4);
    size_t o_ofS = alloc((size_t)(NTS + 1) * 4);
    size_t o_posS = alloc((size_t)NE * 4);
    size_t o_srcS = alloc((size_t)NE * 4);
    size_t o_idxS = alloc((size_t)NE * 4);
    size_t o_wcomb = alloc((size_t)(512 + 32) * 4);
    size_t baseEnd = cur;
    size_t o_epD  = alloc((size_t)NE * 4);
    size_t o_ofD  = alloc((size_t)(NT_D + 1) * 4);
    size_t o_epD2 = alloc((size_t)NE * 4);
    size_t o_noff = alloc((size_t)(NN + 1) * 4);
    size_t o_whi  = alloc((size_t)6144 * 2);
    size_t o_wlo  = alloc((size_t)6144 * 2);
    size_t o_msg  = alloc((size_t)NE * 32 * 4);
    size_t need1 = cur;
    size_t need0 = baseEnd + (size_t)NN * 32 * 4;

    int mode;
    if (ws_size >= need1) mode = 1;
    else if (ws_size >= need0) mode = 0;
    else mode = -1;

    float* h     = (float*)(ws + o_h);
    float* tSf   = (float*)(ws + o_t);
    unsigned short* tSh = (unsigned short*)(ws + o_t);
    float* W2ext = (float*)(ws + o_w2e);
    unsigned short* W2bf = (unsigned short*)(ws + o_w2b);
    int* epermS  = (int*)(ws + o_epS);
    int* offsS   = (int*)(ws + o_ofS);
    int* posS    = (int*)(ws + o_posS);
    int* srcS    = (int*)(ws + o_srcS);
    int* idxS    = (int*)(ws + o_idxS);
    float* Wcomb = (float*)(ws + o_wcomb);
    float* bcomb = Wcomb + 512;
    int* epermD  = (int*)(ws + o_epD);
    int* offsD   = (int*)(ws + o_ofD);
    int* epermD2 = (int*)(ws + o_epD2);
    int* nodeOffs = (int*)(ws + o_noff);
    unsigned short* gWhi = (unsigned short*)(ws + o_whi);
    unsigned short* gWlo = (unsigned short*)(ws + o_wlo);
    float* outbuf = (mode == 1) ? (float*)(ws + o_msg)
                  : (mode == 0) ? (float*)(ws + baseEnd)
                                : (float*)(ws + afterCommon);
    int* bcS = (int*)outbuf;
    int* bsS = bcS + (size_t)HB * NTS;
    int* bcD = bsS + (size_t)HB * NTS;
    int* bsD = bcD + (size_t)HB * NT_D;
    int* totS = bsD + (size_t)HB * NT_D;
    int* totD = totS + NTS;

    k_node_enc<<<NN / 32, 256, 0, stream>>>(nfeats, emb, encW, encB, projW, projB, h);

    if (mode == 1) {
        k_prepAll<<<(66 * 512 + 6144 + 544 + 255) / 256, 256, 0, stream>>>(
            enW2, enB2, W2bf, gruWi, gruWh, gWhi, gWlo,
            eencW, eencB, enW1, enB1, Wcomb, bcomb);
        k_histB<<<2 * HB, 256, 0, stream>>>(src, dst, bcS, bcD);
        k_colsumB<<<(NTS + NT_D + 255) / 256, 256, 0, stream>>>(bcS, bcD, bsS, bsD, totS, totD);
        k_scanB<<<2, 256, 0, stream>>>(totS, totD, offsS, offsD);
        k_scatterB<<<2 * HB, 256, 0, stream>>>(src, dst, bsS, bsD, offsS, offsD, epermS, epermD);
        k_invgather<<<(NE + 255) / 256, 256, 0, stream>>>(epermS, src, posS, srcS);
        k_sortNode<<<NT_D, 256, 0, stream>>>(epermD, dst, offsD, epermD2, nodeOffs);
        k_scatterIdx<<<(NE + 255) / 256, 256, 0, stream>>>(epermD2, posS, idxS);
        k_edge_t3h<<<NE / 128, 256, 0, stream>>>(efeats, Wcomb, bcomb, epermS, tSh);
    } else if (mode == 0) {
        int* blockCounts = (int*)outbuf;
        int* blockStart  = blockCounts + (size_t)HB * NTS;
        int* tileTot     = blockStart + (size_t)HB * NTS;
        k_prepAll<<<(66 * 512 + 6144 + 544 + 255) / 256, 256, 0, stream>>>(
            enW2, enB2, W2bf, gruWi, gruWh, gWhi, gWlo,
            eencW, eencB, enW1, enB1, Wcomb, bcomb);
        k_histT<NTS, 4><<<HB, 256, 0, stream>>>(src, blockCounts);
        k_colsumT<NTS><<<(NTS + 255) / 256, 256, 0, stream>>>(blockCounts, blockStart, tileTot);
        k_scanT<NTS, 25><<<1, 256, 0, stream>>>(tileTot, offsS);
        k_scatterT<NTS, 4><<<HB, 256, 0, stream>>>(src, blockStart, offsS, epermS);
        k_invperm<<<(NE + 255) / 256, 256, 0, stream>>>(epermS, posS);
        k_gatherKey<<<(NE + 255) / 256, 256, 0, stream>>>(epermS, src, srcS);
        k_gatherKey<<<(NE + 255) / 256, 256, 0, stream>>>(epermS, dst, idxS);
        k_edge_t3h<<<NE / 128, 256, 0, stream>>>(efeats, Wcomb, bcomb, epermS, tSh);
    } else {
        k_prepAll<<<(66 * 512 + 6144 + 544 + 255) / 256, 256, 0, stream>>>(
            enW2, enB2, W2bf, gruWi, gruWh, gWhi, gWlo,
            eencW, eencB, enW1, enB1, Wcomb, bcomb);
        k_w2ext<<<(32 * QC + 255) / 256, 256, 0, stream>>>(enW2, enB2, W2ext);
        k_edge_t3<<<NE / 128, 256, 0, stream>>>(efeats, Wcomb, bcomb, nullptr, tSf);
    }

    for (int s = 0; s < 3; ++s) {
        if (mode == 1) {
            k_msgF16<1><<<NTS, 256, 0, stream>>>(h, W2bf, tSh, srcS, idxS, offsS, outbuf);
            k_gruAgg4<<<NT_D, 256, 0, stream>>>(outbuf, nodeOffs, convB,
                                                gWhi, gWlo, gruBi, gruBh, h);
        } else if (mode == 0) {
            hipMemsetAsync(outbuf, 0, (size_t)NN * 32 * 4, stream);
            k_msgF16<0><<<NTS, 256, 0, stream>>>(h, W2bf, tSh, srcS, idxS, offsS, outbuf);
            k_gru<<<NN / 32, 256, 0, stream>>>(outbuf, convB, gruWi, gruWh, gruBi, gruBh, h);
        } else {
            hipMemsetAsync(outbuf, 0, (size_t)NN * 32 * 4, stream);
            k_msgC<<<NE / 32, 256, 0, stream>>>(tSf, src, dst, h, W2ext, outbuf);
            k_gru<<<NN / 32, 256, 0, stream>>>(outbuf, convB, gruWi, gruWh, gruBi, gruBh, h);
        }
    }
    k_dec<<<NN / 32, 256, 0, stream>>>(h, dW1, db1, da1, dW2, db2, da2, dW3, db3, da3, dW4, db4, out);
}

// Round 21
// 381.717 us; speedup vs baseline: 1.3352x; 1.0320x over previous
//
#include <hip/hip_runtime.h>
#include <hip/hip_bf16.h>

// MPNN on MI355X — fused 16-node-tile msg kernel + MFMA GRU, fully pre-sorted streams.
// msg[e,o] = sum_k t[e,k]*Q[src,k,o] + q0[src,o],  Q[n] = h[n] @ W2ext
// k_msgF16: per 16-node src tile, MFMA Q (16x1056) into LDS as F16 (k-pair
// interleaved); barrier-free edge stream via v_dot2_f32_f16 (t stored f16).
// Edge encoder folded. k_gruAgg4<DEC>: split-bf16 MFMA GRU; last step fuses the
// 4-layer decoder in-block (no separate k_dec dispatch). No global atomics (MODE1).

#define NN 100000
#define NE 320000
#define QC 1056
#define NTS 6250      // NN/16 src tiles
#define NT_D 3125     // NN/32 dst tiles
#define HB 256        // bucketing blocks
#define EPB (NE / HB) // 1250
#define QSTRH 1072    // sQ row stride (halves)

typedef short bf16x8 __attribute__((ext_vector_type(8)));
typedef float f32x4  __attribute__((ext_vector_type(4)));
typedef _Float16 h16x2 __attribute__((ext_vector_type(2)));
typedef _Float16 h16x8 __attribute__((ext_vector_type(8)));

__device__ __forceinline__ float bf2f(unsigned short u) {
    return __uint_as_float(((unsigned int)u) << 16);
}
__device__ __forceinline__ unsigned short f2bf(float f) {
    unsigned int x = __float_as_uint(f);
    unsigned int r = (x + 0x7fffu + ((x >> 16) & 1u)) >> 16;
    return (unsigned short)r;
}
__device__ __forceinline__ float sigm(float x) {
    return 1.f / (1.f + __expf(-x));
}
__device__ __forceinline__ float dot2h(h16x2 a, h16x2 b, float c) {
#if __has_builtin(__builtin_amdgcn_fdot2)
    return __builtin_amdgcn_fdot2(a, b, c, false);
#else
    return c + (float)a[0] * (float)b[0] + (float)a[1] * (float)b[1];
#endif
}

// ---- build W2ext [32][1056] (fp32, msgC fallback only)
__global__ __launch_bounds__(256) void k_w2ext(const float* __restrict__ W2,
                                               const float* __restrict__ b2,
                                               float* __restrict__ W2ext) {
    int idx = blockIdx.x * 256 + threadIdx.x;
    if (idx >= 32 * QC) return;
    int i = idx / QC, c = idx % QC;
    float v;
    if (c < 1024) { int k = c >> 5, o = c & 31; v = W2[k * 1024 + i * 32 + o]; }
    else          { v = b2[i * 32 + (c - 1024)]; }
    W2ext[idx] = v;
}

// ---- merged weight prep
__global__ __launch_bounds__(256) void k_prepAll(
    const float* __restrict__ W2, const float* __restrict__ b2,
    unsigned short* __restrict__ W2bf,
    const float* __restrict__ Wi, const float* __restrict__ Wh,
    unsigned short* __restrict__ Whi, unsigned short* __restrict__ Wlo,
    const float* __restrict__ eencW, const float* __restrict__ eencB,
    const float* __restrict__ enW1, const float* __restrict__ enB1,
    float* __restrict__ Wcomb, float* __restrict__ bcomb) {
    int idx = blockIdx.x * 256 + threadIdx.x;
    if (idx < 66 * 512) {
        int ct = idx >> 9, l = (idx >> 3) & 63, j = idx & 7;
        int kk = ((j >> 2) << 4) + ((l >> 4) << 2) + (j & 3);
        int c = ct * 16 + (l & 15);
        float v;
        if (c < 1024) { int kb = c >> 5, o = c & 31; v = W2[kb * 1024 + kk * 32 + o]; }
        else          { v = b2[kk * 32 + (c - 1024)]; }
        W2bf[idx] = f2bf(v);
    } else if (idx < 66 * 512 + 6144) {
        int q = idx - 66 * 512;
        int j = q & 7, l = (q >> 3) & 63, kt = (q >> 9) & 1, nt = q >> 10;
        int k = ((j >> 2) << 4) + ((l >> 4) << 2) + (j & 3);
        int col = nt * 16 + (l & 15);
        float v = kt ? Wh[k * 96 + col] : Wi[k * 96 + col];
        unsigned short hi = f2bf(v);
        Whi[q] = hi;
        Wlo[q] = f2bf(v - bf2f(hi));
    } else if (idx < 66 * 512 + 6144 + 544) {
        int q = idx - 66 * 512 - 6144;
        if (q < 512) {
            int i = q >> 5, o = q & 31;
            float acc = 0.f;
            #pragma unroll 8
            for (int j = 0; j < 32; ++j) acc += eencW[i * 32 + j] * enW1[j * 32 + o];
            Wcomb[i * 32 + o] = acc;
        } else {
            int o = q - 512;
            float acc = enB1[o];
            #pragma unroll 8
            for (int j = 0; j < 32; ++j) acc += eencB[j] * enW1[j * 32 + o];
            bcomb[o] = acc;
        }
    }
}

// ---- merged histograms
__global__ __launch_bounds__(256) void k_histB(const int* __restrict__ src,
                                               const int* __restrict__ dst,
                                               int* __restrict__ bcS,
                                               int* __restrict__ bcD) {
    __shared__ int sHist[NTS];
    int tid = threadIdx.x, b = blockIdx.x;
    bool isS = b < HB;
    int bb = isS ? b : b - HB;
    const int* keys = isS ? src : dst;
    int NT = isS ? NTS : NT_D;
    int SH = isS ? 4 : 5;
    for (int c = tid; c < NT; c += 256) sHist[c] = 0;
    __syncthreads();
    int beg = bb * EPB, end = min(beg + EPB, NE);
    for (int e = beg + tid; e < end; e += 256)
        atomicAdd(&sHist[keys[e] >> SH], 1);
    __syncthreads();
    int* out = isS ? bcS : bcD;
    for (int c = tid; c < NT; c += 256) out[bb * NT + c] = sHist[c];
}

// ---- merged column sums
__global__ __launch_bounds__(256) void k_colsumB(const int* __restrict__ bcS,
                                                 const int* __restrict__ bcD,
                                                 int* __restrict__ bsS,
                                                 int* __restrict__ bsD,
                                                 int* __restrict__ totS,
                                                 int* __restrict__ totD) {
    int c = blockIdx.x * 256 + threadIdx.x;
    if (c < NTS) {
        int running = 0;
        #pragma unroll 8
        for (int b = 0; b < HB; ++b) {
            bsS[b * NTS + c] = running;
            running += bcS[b * NTS + c];
        }
        totS[c] = running;
    } else if (c < NTS + NT_D) {
        int cc = c - NTS;
        int running = 0;
        #pragma unroll 8
        for (int b = 0; b < HB; ++b) {
            bsD[b * NT_D + cc] = running;
            running += bcD[b * NT_D + cc];
        }
        totD[cc] = running;
    }
}

// ---- merged scans
__global__ __launch_bounds__(256) void k_scanB(const int* __restrict__ totS,
                                               const int* __restrict__ totD,
                                               int* __restrict__ offS,
                                               int* __restrict__ offD) {
    __shared__ int sTot[NTS];
    __shared__ int sPart[257];
    int tid = threadIdx.x;
    const int* tot = (blockIdx.x == 0) ? totS : totD;
    int* offs = (blockIdx.x == 0) ? offS : offD;
    int NT = (blockIdx.x == 0) ? NTS : NT_D;
    int SEG = (blockIdx.x == 0) ? 25 : 13;
    for (int c = tid; c < NT; c += 256) sTot[c] = tot[c];
    __syncthreads();
    int base = tid * SEG;
    int loc = 0;
    for (int j = 0; j < SEG; ++j) {
        int c = base + j;
        if (c < NT) { int v = sTot[c]; sTot[c] = loc; loc += v; }
    }
    sPart[tid] = loc;
    __syncthreads();
    if (tid == 0) {
        int s = 0;
        for (int i = 0; i < 256; ++i) { int v = sPart[i]; sPart[i] = s; s += v; }
        sPart[256] = s;
    }
    __syncthreads();
    int add = sPart[tid];
    for (int j = 0; j < SEG; ++j) {
        int c = base + j;
        if (c < NT) sTot[c] += add;
    }
    __syncthreads();
    for (int c = tid; c < NT; c += 256) offs[c] = sTot[c];
    if (tid == 0) offs[NT] = sPart[256];
}

// ---- merged scatters
__global__ __launch_bounds__(256) void k_scatterB(const int* __restrict__ src,
                                                  const int* __restrict__ dst,
                                                  const int* __restrict__ bsS,
                                                  const int* __restrict__ bsD,
                                                  const int* __restrict__ offS,
                                                  const int* __restrict__ offD,
                                                  int* __restrict__ epS,
                                                  int* __restrict__ epD) {
    __shared__ int sCur[NTS];
    int tid = threadIdx.x, b = blockIdx.x;
    bool isS = b < HB;
    int bb = isS ? b : b - HB;
    const int* keys = isS ? src : dst;
    const int* bs = isS ? bsS : bsD;
    const int* offs = isS ? offS : offD;
    int* ep = isS ? epS : epD;
    int NT = isS ? NTS : NT_D;
    int SH = isS ? 4 : 5;
    for (int c = tid; c < NT; c += 256)
        sCur[c] = offs[c] + bs[bb * NT + c];
    __syncthreads();
    int beg = bb * EPB, end = min(beg + EPB, NE);
    for (int e = beg + tid; e < end; e += 256) {
        int pos = atomicAdd(&sCur[keys[e] >> SH], 1);
        ep[pos] = e;
    }
}

// ---- merged invperm + src gather
__global__ __launch_bounds__(256) void k_invgather(const int* __restrict__ epermS,
                                                   const int* __restrict__ src,
                                                   int* __restrict__ posS,
                                                   int* __restrict__ srcS) {
    int p = blockIdx.x * 256 + threadIdx.x;
    if (p < NE) {
        int e = epermS[p];
        posS[e] = p;
        srcS[p] = src[e];
    }
}

// ---- node encoder + projection: 32 nodes/block
__global__ __launch_bounds__(256) void k_node_enc(
    const int* __restrict__ nfeats, const float* __restrict__ emb,
    const float* __restrict__ encW, const float* __restrict__ encB,
    const float* __restrict__ projW, const float* __restrict__ projB,
    float* __restrict__ h) {
    __shared__ float sEncW[1024], sProjW[1024], sEncB[32], sProjB[32];
    __shared__ float sEmb[8][33], sNh[8][33];
    int tid = threadIdx.x;
    for (int i = tid; i < 1024; i += 256) { sEncW[i] = encW[i]; sProjW[i] = projW[i]; }
    if (tid < 32) { sEncB[tid] = encB[tid]; sProjB[tid] = projB[tid]; }
    int ln = tid >> 5, o = tid & 31;
    for (int g = 0; g < 4; ++g) {
        int node = blockIdx.x * 32 + g * 8 + ln;
        int nt = nfeats[node];
        float ev = fmaxf(emb[nt * 32 + o], 0.f);
        __syncthreads();
        sEmb[ln][o] = ev;
        __syncthreads();
        float acc = sEncB[o];
        #pragma unroll
        for (int i = 0; i < 32; ++i) acc += sEmb[ln][i] * sEncW[i * 32 + o];
        sNh[ln][o] = fmaxf(acc, 0.f);
        __syncthreads();
        float acc2 = sProjB[o];
        #pragma unroll
        for (int i = 0; i < 32; ++i) acc2 += sNh[ln][i] * sProjW[i * 32 + o];
        h[node * 32 + o] = fmaxf(acc2, 0.f);
    }
}

// ---- edge encoder (folded), f16 output
__global__ __launch_bounds__(256) void k_edge_t3h(
    const float* __restrict__ efeats, const float* __restrict__ Wcomb,
    const float* __restrict__ bcomb, const int* __restrict__ eperm,
    unsigned short* __restrict__ tS) {
    int tid = threadIdx.x;
    int el = tid >> 3, l8 = tid & 7;
    int gbase = (tid & 63) & 56;
    int c0 = l8 << 2;
    float4 w[16];
    #pragma unroll
    for (int i = 0; i < 16; ++i) w[i] = *(const float4*)(Wcomb + i * 32 + c0);
    float4 bb = *(const float4*)(bcomb + c0);
    #pragma unroll
    for (int it = 0; it < 4; ++it) {
        int p = blockIdx.x * 128 + it * 32 + el;
        int e = eperm ? eperm[p] : p;
        float2 efv = *(const float2*)(efeats + (size_t)e * 16 + (l8 << 1));
        float a0 = bb.x, a1 = bb.y, a2 = bb.z, a3 = bb.w;
        #pragma unroll
        for (int i = 0; i < 8; ++i) {
            float f0 = __shfl(efv.x, gbase + i, 64);
            float f1 = __shfl(efv.y, gbase + i, 64);
            float4 w0 = w[2 * i], w1 = w[2 * i + 1];
            a0 += f0 * w0.x + f1 * w1.x;
            a1 += f0 * w0.y + f1 * w1.y;
            a2 += f0 * w0.z + f1 * w1.z;
            a3 += f0 * w0.w + f1 * w1.w;
        }
        _Float16 h0 = (_Float16)fmaxf(a0, 0.f);
        _Float16 h1 = (_Float16)fmaxf(a1, 0.f);
        _Float16 h2 = (_Float16)fmaxf(a2, 0.f);
        _Float16 h3 = (_Float16)fmaxf(a3, 0.f);
        ushort4 o4;
        o4.x = *(unsigned short*)&h0; o4.y = *(unsigned short*)&h1;
        o4.z = *(unsigned short*)&h2; o4.w = *(unsigned short*)&h3;
        *(ushort4*)(tS + (size_t)p * 32 + c0) = o4;
    }
}

// ---- edge encoder fp32 output (msgC fallback only)
__global__ __launch_bounds__(256) void k_edge_t3(
    const float* __restrict__ efeats, const float* __restrict__ Wcomb,
    const float* __restrict__ bcomb, const int* __restrict__ eperm,
    float* __restrict__ tS) {
    int tid = threadIdx.x;
    int el = tid >> 3, l8 = tid & 7;
    int gbase = (tid & 63) & 56;
    int c0 = l8 << 2;
    float4 w[16];
    #pragma unroll
    for (int i = 0; i < 16; ++i) w[i] = *(const float4*)(Wcomb + i * 32 + c0);
    float4 bb = *(const float4*)(bcomb + c0);
    #pragma unroll
    for (int it = 0; it < 4; ++it) {
        int p = blockIdx.x * 128 + it * 32 + el;
        int e = eperm ? eperm[p] : p;
        float2 efv = *(const float2*)(efeats + (size_t)e * 16 + (l8 << 1));
        float a0 = bb.x, a1 = bb.y, a2 = bb.z, a3 = bb.w;
        #pragma unroll
        for (int i = 0; i < 8; ++i) {
            float f0 = __shfl(efv.x, gbase + i, 64);
            float f1 = __shfl(efv.y, gbase + i, 64);
            float4 w0 = w[2 * i], w1 = w[2 * i + 1];
            a0 += f0 * w0.x + f1 * w1.x;
            a1 += f0 * w0.y + f1 * w1.y;
            a2 += f0 * w0.z + f1 * w1.z;
            a3 += f0 * w0.w + f1 * w1.w;
        }
        *(float4*)(tS + (size_t)p * 32 + c0) =
            make_float4(fmaxf(a0, 0.f), fmaxf(a1, 0.f), fmaxf(a2, 0.f), fmaxf(a3, 0.f));
    }
}

// ---- legacy single-purpose bucketing kernels (fallback modes only)
template<int NT, int SHIFT>
__global__ __launch_bounds__(256) void k_histT(const int* __restrict__ keys,
                                               int* __restrict__ blockCounts) {
    __shared__ int sHist[NT];
    int tid = threadIdx.x, b = blockIdx.x;
    for (int c = tid; c < NT; c += 256) sHist[c] = 0;
    __syncthreads();
    int beg = b * EPB, end = min(beg + EPB, NE);
    for (int e = beg + tid; e < end; e += 256)
        atomicAdd(&sHist[keys[e] >> SHIFT], 1);
    __syncthreads();
    for (int c = tid; c < NT; c += 256) blockCounts[b * NT + c] = sHist[c];
}

template<int NT>
__global__ __launch_bounds__(256) void k_colsumT(const int* __restrict__ blockCounts,
                                                 int* __restrict__ blockStart,
                                                 int* __restrict__ tileTot) {
    int c = blockIdx.x * 256 + threadIdx.x;
    if (c >= NT) return;
    int running = 0;
    #pragma unroll 8
    for (int b = 0; b < HB; ++b) {
        blockStart[b * NT + c] = running;
        running += blockCounts[b * NT + c];
    }
    tileTot[c] = running;
}

template<int NT, int SEG>
__global__ __launch_bounds__(256) void k_scanT(const int* __restrict__ tileTot,
                                               int* __restrict__ offs) {
    __shared__ int sTot[NT];
    __shared__ int sPart[257];
    int tid = threadIdx.x;
    for (int c = tid; c < NT; c += 256) sTot[c] = tileTot[c];
    __syncthreads();
    int base = tid * SEG;
    int loc = 0;
    for (int j = 0; j < SEG; ++j) {
        int c = base + j;
        if (c < NT) { int v = sTot[c]; sTot[c] = loc; loc += v; }
    }
    sPart[tid] = loc;
    __syncthreads();
    if (tid == 0) {
        int s = 0;
        for (int i = 0; i < 256; ++i) { int v = sPart[i]; sPart[i] = s; s += v; }
        sPart[256] = s;
    }
    __syncthreads();
    int add = sPart[tid];
    for (int j = 0; j < SEG; ++j) {
        int c = base + j;
        if (c < NT) sTot[c] += add;
    }
    __syncthreads();
    for (int c = tid; c < NT; c += 256) offs[c] = sTot[c];
    if (tid == 0) offs[NT] = sPart[256];
}

template<int NT, int SHIFT>
__global__ __launch_bounds__(256) void k_scatterT(const int* __restrict__ keys,
                                                  const int* __restrict__ blockStart,
                                                  const int* __restrict__ offs,
                                                  int* __restrict__ eperm) {
    __shared__ int sCur[NT];
    int tid = threadIdx.x, b = blockIdx.x;
    for (int c = tid; c < NT; c += 256)
        sCur[c] = offs[c] + blockStart[b * NT + c];
    __syncthreads();
    int beg = b * EPB, end = min(beg + EPB, NE);
    for (int e = beg + tid; e < end; e += 256) {
        int pos = atomicAdd(&sCur[keys[e] >> SHIFT], 1);
        eperm[pos] = e;
    }
}

// ---- second-level sort: within each dst tile, sort by node (32 LDS bins)
__global__ __launch_bounds__(256) void k_sortNode(
    const int* __restrict__ epermD, const int* __restrict__ dst,
    const int* __restrict__ offsD, int* __restrict__ epermD2,
    int* __restrict__ nodeOffs) {
    __shared__ int sCnt[32], sStart[32];
    int tid = threadIdx.x, d = blockIdx.x;
    int beg = offsD[d], end = offsD[d + 1];
    if (tid < 32) sCnt[tid] = 0;
    __syncthreads();
    for (int p = beg + tid; p < end; p += 256)
        atomicAdd(&sCnt[dst[epermD[p]] & 31], 1);
    __syncthreads();
    if (tid == 0) {
        int s = beg;
        for (int r = 0; r < 32; ++r) { sStart[r] = s; s += sCnt[r]; }
    }
    __syncthreads();
    if (tid < 32) {
        nodeOffs[d * 32 + tid] = sStart[tid];
        sCnt[tid] = sStart[tid];
    }
    if (d == NT_D - 1 && tid == 0) nodeOffs[NN] = end;
    __syncthreads();
    for (int p = beg + tid; p < end; p += 256) {
        int e = epermD[p];
        int pos = atomicAdd(&sCnt[dst[e] & 31], 1);
        epermD2[pos] = e;
    }
}

// ---- inverse permutation (fallback path)
__global__ __launch_bounds__(256) void k_invperm(const int* __restrict__ eperm,
                                                 int* __restrict__ pos) {
    int p = blockIdx.x * 256 + threadIdx.x;
    if (p < NE) pos[eperm[p]] = p;
}

// ---- gather key (fallback path)
__global__ __launch_bounds__(256) void k_gatherKey(const int* __restrict__ epermS,
                                                   const int* __restrict__ key,
                                                   int* __restrict__ out) {
    int p = blockIdx.x * 256 + threadIdx.x;
    if (p < NE) out[p] = key[epermS[p]];
}

// ---- idxS[posS[epermD2[q]]] = q
__global__ __launch_bounds__(256) void k_scatterIdx(const int* __restrict__ epermD2,
                                                    const int* __restrict__ posS,
                                                    int* __restrict__ idxS) {
    int q = blockIdx.x * 256 + threadIdx.x;
    if (q < NE) idxS[posS[epermD2[q]]] = q;
}

// ---- fused per-16-node-src-tile: MFMA Q -> f16 LDS (k-pair interleaved),
// edge stream: 4 lanes/edge x 8 outputs via v_dot2_f32_f16.
template<int MODE>
__global__ __launch_bounds__(256) void k_msgF16(
    const float* __restrict__ h, const unsigned short* __restrict__ W2bf,
    const unsigned short* __restrict__ tS, const int* __restrict__ srcS,
    const int* __restrict__ idxS, const int* __restrict__ offs,
    float* __restrict__ outbuf) {
    __shared__ unsigned short sQ[16 * QSTRH];
    int tid = threadIdx.x;
    int tile = blockIdx.x;
    int beg = offs[tile], end = offs[tile + 1];
    if (beg >= end) return;
    int nodeBase = tile * 16;
    int wave = tid >> 6, lane = tid & 63;

    int arow = lane & 15;
    const float* hp = h + (size_t)(nodeBase + arow) * 32 + ((lane >> 4) << 2);
    float4 x0 = *(const float4*)hp;
    float4 x1 = *(const float4*)(hp + 16);
    bf16x8 a;
    a[0] = (short)f2bf(x0.x); a[1] = (short)f2bf(x0.y);
    a[2] = (short)f2bf(x0.z); a[3] = (short)f2bf(x0.w);
    a[4] = (short)f2bf(x1.x); a[5] = (short)f2bf(x1.y);
    a[6] = (short)f2bf(x1.z); a[7] = (short)f2bf(x1.w);

    f32x4 z = {0.f, 0.f, 0.f, 0.f};
    int crow0 = (lane >> 4) << 2;
    int ccol = lane & 15;
    for (int ct = wave; ct < 66; ct += 4) {
        bf16x8 b = *(const bf16x8*)(W2bf + (size_t)((ct << 6) + lane) * 8);
        f32x4 acc = __builtin_amdgcn_mfma_f32_16x16x32_bf16(a, b, z, 0, 0, 0);
        int c = (ct << 4) + ccol;
        int idx;
        if (c < 1024) {
            int k = c >> 5, o = c & 31;
            idx = ((k >> 1) << 6) + (o << 1) + (k & 1);
        } else {
            idx = 1024 + (c - 1024);
        }
        unsigned short* qp = sQ + crow0 * QSTRH + idx;
        _Float16 v0 = (_Float16)acc[0], v1 = (_Float16)acc[1];
        _Float16 v2 = (_Float16)acc[2], v3 = (_Float16)acc[3];
        qp[0 * QSTRH] = *(unsigned short*)&v0;
        qp[1 * QSTRH] = *(unsigned short*)&v1;
        qp[2 * QSTRH] = *(unsigned short*)&v2;
        qp[3 * QSTRH] = *(unsigned short*)&v3;
    }
    __syncthreads();

    int el = tid >> 2, l4 = tid & 3;
    int o0 = l4 << 3;
    for (int p = beg + el; p < end; p += 64) {
        int row = srcS[p] - nodeBase;
        int widx = idxS[p];
        h16x8 trow[4];
        #pragma unroll
        for (int i = 0; i < 4; ++i)
            trow[i] = *(const h16x8*)(tS + (size_t)p * 32 + (i << 3));
        const unsigned short* qp = sQ + row * QSTRH;
        h16x8 qb = *(const h16x8*)(qp + 1024 + o0);
        float acc[8];
        #pragma unroll
        for (int j = 0; j < 8; ++j) acc[j] = (float)qb[j];
        #pragma unroll
        for (int kp = 0; kp < 16; ++kp) {
            h16x2 t2;
            t2[0] = trow[kp >> 2][(kp & 3) * 2];
            t2[1] = trow[kp >> 2][(kp & 3) * 2 + 1];
            h16x8 qa = *(const h16x8*)(qp + (kp << 6) + (o0 << 1));
            h16x8 qc = *(const h16x8*)(qp + (kp << 6) + (o0 << 1) + 8);
            #pragma unroll
            for (int j = 0; j < 4; ++j) {
                h16x2 q2a; q2a[0] = qa[2 * j]; q2a[1] = qa[2 * j + 1];
                h16x2 q2c; q2c[0] = qc[2 * j]; q2c[1] = qc[2 * j + 1];
                acc[j]     = dot2h(t2, q2a, acc[j]);
                acc[4 + j] = dot2h(t2, q2c, acc[4 + j]);
            }
        }
        if (MODE) {
            float* op = outbuf + (size_t)widx * 32 + o0;
            *(float4*)op = make_float4(acc[0], acc[1], acc[2], acc[3]);
            *(float4*)(op + 4) = make_float4(acc[4], acc[5], acc[6], acc[7]);
        } else {
            float* op = outbuf + (size_t)widx * 32 + o0;
            #pragma unroll
            for (int j = 0; j < 8; ++j) atomicAdd(op + j, acc[j]);
        }
    }
}

// ---- fallback msg (tiny ws)
__global__ __launch_bounds__(256) void k_msgC(
    const float* __restrict__ t, const int* __restrict__ src, const int* __restrict__ dst,
    const float* __restrict__ h, const float* __restrict__ W2ext, float* __restrict__ agg) {
    __shared__ float sT[32][33], sH[32][33];
    __shared__ int sSrc[32], sDst[32];
    int tid = threadIdx.x;
    int e0 = blockIdx.x * 32;
    if (tid < 32) sSrc[tid] = src[e0 + tid];
    else if (tid < 64) sDst[tid - 32] = dst[e0 + tid - 32];
    __syncthreads();
    for (int idx = tid; idx < 1024; idx += 256) {
        int el = idx >> 5, k = idx & 31;
        sT[el][k] = t[(e0 + el) * 32 + k];
        sH[el][k] = h[(size_t)sSrc[el] * 32 + k];
    }
    __syncthreads();
    int el = tid >> 3, l8 = tid & 7;
    int c0 = l8 * 4;
    float m0 = 0.f, m1 = 0.f, m2 = 0.f, m3 = 0.f;
    for (int i = 0; i < 32; ++i) {
        const float* wrow = W2ext + i * QC;
        float4 wb = *(const float4*)(wrow + 1024 + c0);
        float w0 = wb.x, w1 = wb.y, w2 = wb.z, w3 = wb.w;
        #pragma unroll 8
        for (int k = 0; k < 32; ++k) {
            float tk = sT[el][k];
            float4 w = *(const float4*)(wrow + k * 32 + c0);
            w0 += tk * w.x; w1 += tk * w.y; w2 += tk * w.z; w3 += tk * w.w;
        }
        float hi = sH[el][i];
        m0 += hi * w0; m1 += hi * w1; m2 += hi * w2; m3 += hi * w3;
    }
    float* ap = agg + (size_t)sDst[el] * 32 + c0;
    atomicAdd(ap + 0, m0); atomicAdd(ap + 1, m1);
    atomicAdd(ap + 2, m2); atomicAdd(ap + 3, m3);
}

// ---- GRU step reading agg[] (MODE 0 / fallback)
__global__ __launch_bounds__(256) void k_gru(
    const float* __restrict__ agg, const float* __restrict__ convB,
    const float* __restrict__ Wi, const float* __restrict__ Wh,
    const float* __restrict__ bi, const float* __restrict__ bh,
    float* __restrict__ h) {
    __shared__ float sWi[3072], sWh[3072], sBi[96], sBh[96], sCb[32];
    __shared__ float sX[8][33], sH[8][33];
    int tid = threadIdx.x;
    for (int i = tid; i < 3072; i += 256) { sWi[i] = Wi[i]; sWh[i] = Wh[i]; }
    if (tid < 96) { sBi[tid] = bi[tid]; sBh[tid] = bh[tid]; }
    if (tid < 32) sCb[tid] = convB[tid];
    int ln = tid >> 5, o = tid & 31;
    for (int g = 0; g < 4; ++g) {
        int node = blockIdx.x * 32 + g * 8 + ln;
        float hv = h[node * 32 + o];
        float av = agg[node * 32 + o];
        __syncthreads();
        sX[ln][o] = fmaxf(av + sCb[o], 0.f);
        sH[ln][o] = hv;
        __syncthreads();
        float air = sBi[o], aiz = sBi[o + 32], ain = sBi[o + 64];
        float ahr = sBh[o], ahz = sBh[o + 32], ahn = sBh[o + 64];
        #pragma unroll 8
        for (int i = 0; i < 32; ++i) {
            float x = sX[ln][i], hh = sH[ln][i];
            air += x * sWi[i * 96 + o];      ahr += hh * sWh[i * 96 + o];
            aiz += x * sWi[i * 96 + o + 32]; ahz += hh * sWh[i * 96 + o + 32];
            ain += x * sWi[i * 96 + o + 64]; ahn += hh * sWh[i * 96 + o + 64];
        }
        float r = sigm(air + ahr);
        float zz = sigm(aiz + ahz);
        float ng = tanhf(ain + r * ahn);
        h[node * 32 + o] = (1.f - zz) * ng + zz * hv;
    }
}

// ---- MODE 1: per 32-node dst tile: segment-sum -> X in LDS, GRU via split-bf16 MFMA.
// DEC=1 (last step): fused 4-layer decoder from the new h held in LDS.
template<int DEC>
__global__ __launch_bounds__(256) void k_gruAgg4(
    const float* __restrict__ msgbuf, const int* __restrict__ nodeOffs,
    const float* __restrict__ convB,
    const unsigned short* __restrict__ Whi, const unsigned short* __restrict__ Wlo,
    const float* __restrict__ bi, const float* __restrict__ bh,
    float* __restrict__ h,
    const float* __restrict__ W1, const float* __restrict__ b1, const float* __restrict__ a1,
    const float* __restrict__ W2, const float* __restrict__ b2, const float* __restrict__ a2,
    const float* __restrict__ W3, const float* __restrict__ b3, const float* __restrict__ a3,
    const float* __restrict__ W4, const float* __restrict__ b4,
    float* __restrict__ out) {
    __shared__ float sAgg[32 * 33];
    int tid = threadIdx.x;
    int d = blockIdx.x;
    int base = d * 32;

    {
        int n8 = tid >> 3, l8 = tid & 7;
        int node = base + n8;
        int nb = nodeOffs[node], ne2 = nodeOffs[node + 1];
        float a0 = 0.f, a1v = 0.f, a2v = 0.f, a3v = 0.f;
        for (int p = nb; p < ne2; ++p) {
            float4 v = *(const float4*)(msgbuf + (size_t)p * 32 + (l8 << 2));
            a0 += v.x; a1v += v.y; a2v += v.z; a3v += v.w;
        }
        int c0 = l8 << 2;
        float4 cb = *(const float4*)(convB + c0);
        float* sp = sAgg + n8 * 33 + c0;
        sp[0] = fmaxf(a0 + cb.x, 0.f);
        sp[1] = fmaxf(a1v + cb.y, 0.f);
        sp[2] = fmaxf(a2v + cb.z, 0.f);
        sp[3] = fmaxf(a3v + cb.w, 0.f);
    }
    __syncthreads();

    int wave = tid >> 6, lane = tid & 63;
    int m = wave >> 1, c = wave & 1;
    int arow = lane & 15, kg = (lane >> 4) << 2;

    bf16x8 xhi, xlo, hhi, hlo;
    {
        const float* xp = sAgg + (m * 16 + arow) * 33 + kg;
        float4 v0 = *(const float4*)xp;
        float4 v1 = *(const float4*)(xp + 16);
        float xv[8] = {v0.x, v0.y, v0.z, v0.w, v1.x, v1.y, v1.z, v1.w};
        #pragma unroll
        for (int j = 0; j < 8; ++j) {
            unsigned short hi16 = f2bf(xv[j]);
            xhi[j] = (short)hi16;
            xlo[j] = (short)f2bf(xv[j] - bf2f(hi16));
        }
        const float* hp = h + (size_t)(base + m * 16 + arow) * 32 + kg;
        float4 w0 = *(const float4*)hp;
        float4 w1 = *(const float4*)(hp + 16);
        float hv8[8] = {w0.x, w0.y, w0.z, w0.w, w1.x, w1.y, w1.z, w1.w};
        #pragma unroll
        for (int j = 0; j < 8; ++j) {
            unsigned short hi16 = f2bf(hv8[j]);
            hhi[j] = (short)hi16;
            hlo[j] = (short)f2bf(hv8[j] - bf2f(hi16));
        }
    }

    int ccol = lane & 15, crow0 = (lane >> 4) << 2;
    int o = c * 16 + ccol;
    auto Bf = [&](int nt, int kt, const unsigned short* W) {
        return *(const bf16x8*)(W + (size_t)(((nt * 2 + kt) * 64 + lane) << 3));
    };
    f32x4 accR = {0.f, 0.f, 0.f, 0.f}, accZ = {0.f, 0.f, 0.f, 0.f};
    f32x4 accIN = {0.f, 0.f, 0.f, 0.f}, accHN = {0.f, 0.f, 0.f, 0.f};
    {
        int nt = c;
        bf16x8 b0h = Bf(nt, 0, Whi), b0l = Bf(nt, 0, Wlo);
        bf16x8 b1h = Bf(nt, 1, Whi), b1l = Bf(nt, 1, Wlo);
        accR = __builtin_amdgcn_mfma_f32_16x16x32_bf16(xhi, b0h, accR, 0, 0, 0);
        accR = __builtin_amdgcn_mfma_f32_16x16x32_bf16(xlo, b0h, accR, 0, 0, 0);
        accR = __builtin_amdgcn_mfma_f32_16x16x32_bf16(xhi, b0l, accR, 0, 0, 0);
        accR = __builtin_amdgcn_mfma_f32_16x16x32_bf16(hhi, b1h, accR, 0, 0, 0);
        accR = __builtin_amdgcn_mfma_f32_16x16x32_bf16(hlo, b1h, accR, 0, 0, 0);
        accR = __builtin_amdgcn_mfma_f32_16x16x32_bf16(hhi, b1l, accR, 0, 0, 0);
    }
    {
        int nt = 2 + c;
        bf16x8 b0h = Bf(nt, 0, Whi), b0l = Bf(nt, 0, Wlo);
        bf16x8 b1h = Bf(nt, 1, Whi), b1l = Bf(nt, 1, Wlo);
        accZ = __builtin_amdgcn_mfma_f32_16x16x32_bf16(xhi, b0h, accZ, 0, 0, 0);
        accZ = __builtin_amdgcn_mfma_f32_16x16x32_bf16(xlo, b0h, accZ, 0, 0, 0);
        accZ = __builtin_amdgcn_mfma_f32_16x16x32_bf16(xhi, b0l, accZ, 0, 0, 0);
        accZ = __builtin_amdgcn_mfma_f32_16x16x32_bf16(hhi, b1h, accZ, 0, 0, 0);
        accZ = __builtin_amdgcn_mfma_f32_16x16x32_bf16(hlo, b1h, accZ, 0, 0, 0);
        accZ = __builtin_amdgcn_mfma_f32_16x16x32_bf16(hhi, b1l, accZ, 0, 0, 0);
    }
    {
        int nt = 4 + c;
        bf16x8 b0h = Bf(nt, 0, Whi), b0l = Bf(nt, 0, Wlo);
        bf16x8 b1h = Bf(nt, 1, Whi), b1l = Bf(nt, 1, Wlo);
        accIN = __builtin_amdgcn_mfma_f32_16x16x32_bf16(xhi, b0h, accIN, 0, 0, 0);
        accIN = __builtin_amdgcn_mfma_f32_16x16x32_bf16(xlo, b0h, accIN, 0, 0, 0);
        accIN = __builtin_amdgcn_mfma_f32_16x16x32_bf16(xhi, b0l, accIN, 0, 0, 0);
        accHN = __builtin_amdgcn_mfma_f32_16x16x32_bf16(hhi, b1h, accHN, 0, 0, 0);
        accHN = __builtin_amdgcn_mfma_f32_16x16x32_bf16(hlo, b1h, accHN, 0, 0, 0);
        accHN = __builtin_amdgcn_mfma_f32_16x16x32_bf16(hhi, b1l, accHN, 0, 0, 0);
    }

    float bir = bi[o], biz = bi[32 + o], bin = bi[64 + o];
    float bhr = bh[o], bhz = bh[32 + o], bhn = bh[64 + o];
    float hv[4];
    #pragma unroll
    for (int j = 0; j < 4; ++j)
        hv[j] = h[(size_t)(base + m * 16 + crow0 + j) * 32 + o];
    __syncthreads();    // all h reads complete before any h writes
    float nh[4];
    #pragma unroll
    for (int j = 0; j < 4; ++j) {
        float r  = sigm(accR[j] + bir + bhr);
        float zz = sigm(accZ[j] + biz + bhz);
        float ng = tanhf(accIN[j] + bin + r * (accHN[j] + bhn));
        nh[j] = (1.f - zz) * ng + zz * hv[j];
        h[(size_t)(base + m * 16 + crow0 + j) * 32 + o] = nh[j];
    }

    if constexpr (DEC) {
        __shared__ float sH2[32 * 33];
        __shared__ float sW1[1024], sW2[1024], sW3[1024], sW4[96];
        __shared__ float sB1[32], sB2[32], sB3[32], sB4[3];
        __shared__ float sYa[8][33], sYb[8][33];
        #pragma unroll
        for (int j = 0; j < 4; ++j)
            sH2[(m * 16 + crow0 + j) * 33 + o] = nh[j];
        for (int i = tid; i < 1024; i += 256) { sW1[i] = W1[i]; sW2[i] = W2[i]; sW3[i] = W3[i]; }
        if (tid < 96) sW4[tid] = W4[tid];
        if (tid < 32) { sB1[tid] = b1[tid]; sB2[tid] = b2[tid]; sB3[tid] = b3[tid]; }
        if (tid < 3) sB4[tid] = b4[tid];
        float A1 = a1[0], A2 = a2[0], A3 = a3[0];
        __syncthreads();
        int ln = tid >> 5, o2 = tid & 31;
        for (int g = 0; g < 4; ++g) {
            int row = g * 8 + ln;
            float hvv = sH2[row * 33 + o2];
            __syncthreads();
            sYa[ln][o2] = hvv;
            __syncthreads();
            float acc = sB1[o2];
            #pragma unroll
            for (int i = 0; i < 32; ++i) acc += sYa[ln][i] * sW1[i * 32 + o2];
            acc = acc >= 0.f ? acc : A1 * acc;
            sYb[ln][o2] = acc;
            __syncthreads();
            acc = sB2[o2];
            #pragma unroll
            for (int i = 0; i < 32; ++i) acc += sYb[ln][i] * sW2[i * 32 + o2];
            acc = acc >= 0.f ? acc : A2 * acc;
            __syncthreads();
            sYa[ln][o2] = acc;
            __syncthreads();
            acc = sB3[o2];
            #pragma unroll
            for (int i = 0; i < 32; ++i) acc += sYa[ln][i] * sW3[i * 32 + o2];
            acc = acc >= 0.f ? acc : A3 * acc;
            __syncthreads();
            sYb[ln][o2] = acc;
            __syncthreads();
            if (o2 < 3) {
                float r = sB4[o2];
                #pragma unroll
                for (int i = 0; i < 32; ++i) r += sYb[ln][i] * sW4[i * 3 + o2];
                out[(size_t)(base + row) * 3 + o2] = r;
            }
        }
    }
}

// ---- decoder (fallback modes only)
__global__ __launch_bounds__(256) void k_dec(
    const float* __restrict__ h,
    const float* __restrict__ W1, const float* __restrict__ b1, const float* __restrict__ a1,
    const float* __restrict__ W2, const float* __restrict__ b2, const float* __restrict__ a2,
    const float* __restrict__ W3, const float* __restrict__ b3, const float* __restrict__ a3,
    const float* __restrict__ W4, const float* __restrict__ b4,
    float* __restrict__ out) {
    __shared__ float sW1[1024], sW2[1024], sW3[1024], sW4[96];
    __shared__ float sB1[32], sB2[32], sB3[32], sB4[3];
    __shared__ float sYa[8][33], sYb[8][33];
    int tid = threadIdx.x;
    for (int i = tid; i < 1024; i += 256) { sW1[i] = W1[i]; sW2[i] = W2[i]; sW3[i] = W3[i]; }
    if (tid < 96) sW4[tid] = W4[tid];
    if (tid < 32) { sB1[tid] = b1[tid]; sB2[tid] = b2[tid]; sB3[tid] = b3[tid]; }
    if (tid < 3) sB4[tid] = b4[tid];
    float A1 = a1[0], A2 = a2[0], A3 = a3[0];
    int ln = tid >> 5, o = tid & 31;
    for (int g = 0; g < 4; ++g) {
        int node = blockIdx.x * 32 + g * 8 + ln;
        float hv = h[node * 32 + o];
        __syncthreads();
        sYa[ln][o] = hv;
        __syncthreads();
        float acc = sB1[o];
        #pragma unroll
        for (int i = 0; i < 32; ++i) acc += sYa[ln][i] * sW1[i * 32 + o];
        acc = acc >= 0.f ? acc : A1 * acc;
        sYb[ln][o] = acc;
        __syncthreads();
        acc = sB2[o];
        #pragma unroll
        for (int i = 0; i < 32; ++i) acc += sYb[ln][i] * sW2[i * 32 + o];
        acc = acc >= 0.f ? acc : A2 * acc;
        __syncthreads();
        sYa[ln][o] = acc;
        __syncthreads();
        acc = sB3[o];
        #pragma unroll
        for (int i = 0; i < 32; ++i) acc += sYa[ln][i] * sW3[i * 32 + o];
        acc = acc >= 0.f ? acc : A3 * acc;
        __syncthreads();
        sYb[ln][o] = acc;
        __syncthreads();
        if (o < 3) {
            float r = sB4[o];
            #pragma unroll
            for (int i = 0; i < 32; ++i) r += sYb[ln][i] * sW4[i * 3 + o];
            out[node * 3 + o] = r;
        }
    }
}

extern "C" void kernel_launch(void* const* d_in, const int* in_sizes, int n_in,
                              void* d_out, int out_size, void* d_ws, size_t ws_size,
                              hipStream_t stream) {
    const int*   nfeats = (const int*)d_in[0];
    const float* efeats = (const float*)d_in[1];
    const int*   src    = (const int*)d_in[2];
    const int*   dst    = (const int*)d_in[3];
    const float* emb    = (const float*)d_in[4];
    const float* encW   = (const float*)d_in[5];
    const float* encB   = (const float*)d_in[6];
    const float* eencW  = (const float*)d_in[7];
    const float* eencB  = (const float*)d_in[8];
    const float* projW  = (const float*)d_in[9];
    const float* projB  = (const float*)d_in[10];
    const float* enW1   = (const float*)d_in[11];
    const float* enB1   = (const float*)d_in[12];
    const float* enW2   = (const float*)d_in[13];
    const float* enB2   = (const float*)d_in[14];
    const float* convB  = (const float*)d_in[15];
    const float* gruWi  = (const float*)d_in[16];
    const float* gruWh  = (const float*)d_in[17];
    const float* gruBi  = (const float*)d_in[18];
    const float* gruBh  = (const float*)d_in[19];
    const float* dW1 = (const float*)d_in[20]; const float* db1 = (const float*)d_in[21]; const float* da1 = (const float*)d_in[22];
    const float* dW2 = (const float*)d_in[23]; const float* db2 = (const float*)d_in[24]; const float* da2 = (const float*)d_in[25];
    const float* dW3 = (const float*)d_in[26]; const float* db3 = (const float*)d_in[27]; const float* da3 = (const float*)d_in[28];
    const float* dW4 = (const float*)d_in[29]; const float* db4 = (const float*)d_in[30];
    float* out = (float*)d_out;
    char* ws = (char*)d_ws;

    // bump allocator (256-B aligned)
    size_t cur = 0;
    auto alloc = [&](size_t n) { size_t p = cur; cur = (cur + n + 255) & ~(size_t)255; return p; };
    size_t o_h   = alloc((size_t)NN * 32 * 4);
    size_t o_t   = alloc((size_t)NE * 32 * 4);
    size_t o_w2e = alloc((size_t)32 * QC * 4);
    size_t afterCommon = cur;
    size_t o_w2b = alloc((size_t)66 * 512 * 2);
    size_t o_epS = alloc((size_t)NE * 4);
    size_t o_ofS = alloc((size_t)(NTS + 1) * 4);
    size_t o_posS = alloc((size_t)NE * 4);
    size_t o_srcS = alloc((size_t)NE * 4);
    size_t o_idxS = alloc((size_t)NE * 4);
    size_t o_wcomb = alloc((size_t)(512 + 32) * 4);
    size_t baseEnd = cur;
    size_t o_epD  = alloc((size_t)NE * 4);
    size_t o_ofD  = alloc((size_t)(NT_D + 1) * 4);
    size_t o_epD2 = alloc((size_t)NE * 4);
    size_t o_noff = alloc((size_t)(NN + 1) * 4);
    size_t o_whi  = alloc((size_t)6144 * 2);
    size_t o_wlo  = alloc((size_t)6144 * 2);
    size_t o_msg  = alloc((size_t)NE * 32 * 4);
    size_t need1 = cur;
    size_t need0 = baseEnd + (size_t)NN * 32 * 4;

    int mode;
    if (ws_size >= need1) mode = 1;
    else if (ws_size >= need0) mode = 0;
    else mode = -1;

    float* h     = (float*)(ws + o_h);
    float* tSf   = (float*)(ws + o_t);
    unsigned short* tSh = (unsigned short*)(ws + o_t);
    float* W2ext = (float*)(ws + o_w2e);
    unsigned short* W2bf = (unsigned short*)(ws + o_w2b);
    int* epermS  = (int*)(ws + o_epS);
    int* offsS   = (int*)(ws + o_ofS);
    int* posS    = (int*)(ws + o_posS);
    int* srcS    = (int*)(ws + o_srcS);
    int* idxS    = (int*)(ws + o_idxS);
    float* Wcomb = (float*)(ws + o_wcomb);
    float* bcomb = Wcomb + 512;
    int* epermD  = (int*)(ws + o_epD);
    int* offsD   = (int*)(ws + o_ofD);
    int* epermD2 = (int*)(ws + o_epD2);
    int* nodeOffs = (int*)(ws + o_noff);
    unsigned short* gWhi = (unsigned short*)(ws + o_whi);
    unsigned short* gWlo = (unsigned short*)(ws + o_wlo);
    float* outbuf = (mode == 1) ? (float*)(ws + o_msg)
                  : (mode == 0) ? (float*)(ws + baseEnd)
                                : (float*)(ws + afterCommon);
    int* bcS = (int*)outbuf;
    int* bsS = bcS + (size_t)HB * NTS;
    int* bcD = bsS + (size_t)HB * NTS;
    int* bsD = bcD + (size_t)HB * NT_D;
    int* totS = bsD + (size_t)HB * NT_D;
    int* totD = totS + NTS;

    k_node_enc<<<NN / 32, 256, 0, stream>>>(nfeats, emb, encW, encB, projW, projB, h);

    if (mode == 1) {
        k_prepAll<<<(66 * 512 + 6144 + 544 + 255) / 256, 256, 0, stream>>>(
            enW2, enB2, W2bf, gruWi, gruWh, gWhi, gWlo,
            eencW, eencB, enW1, enB1, Wcomb, bcomb);
        k_histB<<<2 * HB, 256, 0, stream>>>(src, dst, bcS, bcD);
        k_colsumB<<<(NTS + NT_D + 255) / 256, 256, 0, stream>>>(bcS, bcD, bsS, bsD, totS, totD);
        k_scanB<<<2, 256, 0, stream>>>(totS, totD, offsS, offsD);
        k_scatterB<<<2 * HB, 256, 0, stream>>>(src, dst, bsS, bsD, offsS, offsD, epermS, epermD);
        k_invgather<<<(NE + 255) / 256, 256, 0, stream>>>(epermS, src, posS, srcS);
        k_sortNode<<<NT_D, 256, 0, stream>>>(epermD, dst, offsD, epermD2, nodeOffs);
        k_scatterIdx<<<(NE + 255) / 256, 256, 0, stream>>>(epermD2, posS, idxS);
        k_edge_t3h<<<NE / 128, 256, 0, stream>>>(efeats, Wcomb, bcomb, epermS, tSh);
        for (int s = 0; s < 3; ++s) {
            k_msgF16<1><<<NTS, 256, 0, stream>>>(h, W2bf, tSh, srcS, idxS, offsS, outbuf);
            if (s < 2) {
                k_gruAgg4<0><<<NT_D, 256, 0, stream>>>(outbuf, nodeOffs, convB,
                    gWhi, gWlo, gruBi, gruBh, h,
                    dW1, db1, da1, dW2, db2, da2, dW3, db3, da3, dW4, db4, out);
            } else {
                k_gruAgg4<1><<<NT_D, 256, 0, stream>>>(outbuf, nodeOffs, convB,
                    gWhi, gWlo, gruBi, gruBh, h,
                    dW1, db1, da1, dW2, db2, da2, dW3, db3, da3, dW4, db4, out);
            }
        }
    } else if (mode == 0) {
        int* blockCounts = (int*)outbuf;
        int* blockStart  = blockCounts + (size_t)HB * NTS;
        int* tileTot     = blockStart + (size_t)HB * NTS;
        k_prepAll<<<(66 * 512 + 6144 + 544 + 255) / 256, 256, 0, stream>>>(
            enW2, enB2, W2bf, gruWi, gruWh, gWhi, gWlo,
            eencW, eencB, enW1, enB1, Wcomb, bcomb);
        k_histT<NTS, 4><<<HB, 256, 0, stream>>>(src, blockCounts);
        k_colsumT<NTS><<<(NTS + 255) / 256, 256, 0, stream>>>(blockCounts, blockStart, tileTot);
        k_scanT<NTS, 25><<<1, 256, 0, stream>>>(tileTot, offsS);
        k_scatterT<NTS, 4><<<HB, 256, 0, stream>>>(src, blockStart, offsS, epermS);
        k_invperm<<<(NE + 255) / 256, 256, 0, stream>>>(epermS, posS);
        k_gatherKey<<<(NE + 255) / 256, 256, 0, stream>>>(epermS, src, srcS);
        k_gatherKey<<<(NE + 255) / 256, 256, 0, stream>>>(epermS, dst, idxS);
        k_edge_t3h<<<NE / 128, 256, 0, stream>>>(efeats, Wcomb, bcomb, epermS, tSh);
        for (int s = 0; s < 3; ++s) {
            hipMemsetAsync(outbuf, 0, (size_t)NN * 32 * 4, stream);
            k_msgF16<0><<<NTS, 256, 0, stream>>>(h, W2bf, tSh, srcS, idxS, offsS, outbuf);
            k_gru<<<NN / 32, 256, 0, stream>>>(outbuf, convB, gruWi, gruWh, gruBi, gruBh, h);
        }
        k_dec<<<NN / 32, 256, 0, stream>>>(h, dW1, db1, da1, dW2, db2, da2, dW3, db3, da3, dW4, db4, out);
    } else {
        k_prepAll<<<(66 * 512 + 6144 + 544 + 255) / 256, 256, 0, stream>>>(
            enW2, enB2, W2bf, gruWi, gruWh, gWhi, gWlo,
            eencW, eencB, enW1, enB1, Wcomb, bcomb);
        k_w2ext<<<(32 * QC + 255) / 256, 256, 0, stream>>>(enW2, enB2, W2ext);
        k_edge_t3<<<NE / 128, 256, 0, stream>>>(efeats, Wcomb, bcomb, nullptr, tSf);
        for (int s = 0; s < 3; ++s) {
            hipMemsetAsync(outbuf, 0, (size_t)NN * 32 * 4, stream);
            k_msgC<<<NE / 32, 256, 0, stream>>>(tSf, src, dst, h, W2ext, outbuf);
            k_gru<<<NN / 32, 256, 0, stream>>>(outbuf, convB, gruWi, gruWh, gruBi, gruBh, h);
        }
        k_dec<<<NN / 32, 256, 0, stream>>>(h, dW1, db1, da1, dW2, db2, da2, dW3, db3, da3, dW4, db4, out);
    }
}

// Round 22
// 354.489 us; speedup vs baseline: 1.4378x; 1.0768x over previous
//
#include <hip/hip_runtime.h>
#include <hip/hip_bf16.h>

// MPNN on MI355X — fused 16-node-tile msg kernel + MFMA GRU, fully pre-sorted streams.
// msg[e,o] = sum_k t[e,k]*Q[src,k,o] + q0[src,o],  Q[n] = h[n] @ W2ext
// k_msgF16: per 16-node src tile, MFMA Q (16x1056) into LDS as F16 (k-pair
// interleaved); barrier-free edge stream via v_dot2_f32_f16 (t stored f16).
// Edge encoder folded. k_gruAgg4<DEC>: split-bf16 MFMA GRU; last step fuses the
// 4-layer decoder in-block with all 32 nodes in parallel (4 barriers total).

#define NN 100000
#define NE 320000
#define QC 1056
#define NTS 6250      // NN/16 src tiles
#define NT_D 3125     // NN/32 dst tiles
#define HB 256        // bucketing blocks
#define EPB (NE / HB) // 1250
#define QSTRH 1072    // sQ row stride (halves)

typedef short bf16x8 __attribute__((ext_vector_type(8)));
typedef float f32x4  __attribute__((ext_vector_type(4)));
typedef _Float16 h16x2 __attribute__((ext_vector_type(2)));
typedef _Float16 h16x8 __attribute__((ext_vector_type(8)));

__device__ __forceinline__ float bf2f(unsigned short u) {
    return __uint_as_float(((unsigned int)u) << 16);
}
__device__ __forceinline__ unsigned short f2bf(float f) {
    unsigned int x = __float_as_uint(f);
    unsigned int r = (x + 0x7fffu + ((x >> 16) & 1u)) >> 16;
    return (unsigned short)r;
}
__device__ __forceinline__ float sigm(float x) {
    return 1.f / (1.f + __expf(-x));
}
__device__ __forceinline__ float dot2h(h16x2 a, h16x2 b, float c) {
#if __has_builtin(__builtin_amdgcn_fdot2)
    return __builtin_amdgcn_fdot2(a, b, c, false);
#else
    return c + (float)a[0] * (float)b[0] + (float)a[1] * (float)b[1];
#endif
}

// ---- build W2ext [32][1056] (fp32, msgC fallback only)
__global__ __launch_bounds__(256) void k_w2ext(const float* __restrict__ W2,
                                               const float* __restrict__ b2,
                                               float* __restrict__ W2ext) {
    int idx = blockIdx.x * 256 + threadIdx.x;
    if (idx >= 32 * QC) return;
    int i = idx / QC, c = idx % QC;
    float v;
    if (c < 1024) { int k = c >> 5, o = c & 31; v = W2[k * 1024 + i * 32 + o]; }
    else          { v = b2[i * 32 + (c - 1024)]; }
    W2ext[idx] = v;
}

// ---- merged weight prep
__global__ __launch_bounds__(256) void k_prepAll(
    const float* __restrict__ W2, const float* __restrict__ b2,
    unsigned short* __restrict__ W2bf,
    const float* __restrict__ Wi, const float* __restrict__ Wh,
    unsigned short* __restrict__ Whi, unsigned short* __restrict__ Wlo,
    const float* __restrict__ eencW, const float* __restrict__ eencB,
    const float* __restrict__ enW1, const float* __restrict__ enB1,
    float* __restrict__ Wcomb, float* __restrict__ bcomb) {
    int idx = blockIdx.x * 256 + threadIdx.x;
    if (idx < 66 * 512) {
        int ct = idx >> 9, l = (idx >> 3) & 63, j = idx & 7;
        int kk = ((j >> 2) << 4) + ((l >> 4) << 2) + (j & 3);
        int c = ct * 16 + (l & 15);
        float v;
        if (c < 1024) { int kb = c >> 5, o = c & 31; v = W2[kb * 1024 + kk * 32 + o]; }
        else          { v = b2[kk * 32 + (c - 1024)]; }
        W2bf[idx] = f2bf(v);
    } else if (idx < 66 * 512 + 6144) {
        int q = idx - 66 * 512;
        int j = q & 7, l = (q >> 3) & 63, kt = (q >> 9) & 1, nt = q >> 10;
        int k = ((j >> 2) << 4) + ((l >> 4) << 2) + (j & 3);
        int col = nt * 16 + (l & 15);
        float v = kt ? Wh[k * 96 + col] : Wi[k * 96 + col];
        unsigned short hi = f2bf(v);
        Whi[q] = hi;
        Wlo[q] = f2bf(v - bf2f(hi));
    } else if (idx < 66 * 512 + 6144 + 544) {
        int q = idx - 66 * 512 - 6144;
        if (q < 512) {
            int i = q >> 5, o = q & 31;
            float acc = 0.f;
            #pragma unroll 8
            for (int j = 0; j < 32; ++j) acc += eencW[i * 32 + j] * enW1[j * 32 + o];
            Wcomb[i * 32 + o] = acc;
        } else {
            int o = q - 512;
            float acc = enB1[o];
            #pragma unroll 8
            for (int j = 0; j < 32; ++j) acc += eencB[j] * enW1[j * 32 + o];
            bcomb[o] = acc;
        }
    }
}

// ---- merged histograms
__global__ __launch_bounds__(256) void k_histB(const int* __restrict__ src,
                                               const int* __restrict__ dst,
                                               int* __restrict__ bcS,
                                               int* __restrict__ bcD) {
    __shared__ int sHist[NTS];
    int tid = threadIdx.x, b = blockIdx.x;
    bool isS = b < HB;
    int bb = isS ? b : b - HB;
    const int* keys = isS ? src : dst;
    int NT = isS ? NTS : NT_D;
    int SH = isS ? 4 : 5;
    for (int c = tid; c < NT; c += 256) sHist[c] = 0;
    __syncthreads();
    int beg = bb * EPB, end = min(beg + EPB, NE);
    for (int e = beg + tid; e < end; e += 256)
        atomicAdd(&sHist[keys[e] >> SH], 1);
    __syncthreads();
    int* out = isS ? bcS : bcD;
    for (int c = tid; c < NT; c += 256) out[bb * NT + c] = sHist[c];
}

// ---- merged column sums
__global__ __launch_bounds__(256) void k_colsumB(const int* __restrict__ bcS,
                                                 const int* __restrict__ bcD,
                                                 int* __restrict__ bsS,
                                                 int* __restrict__ bsD,
                                                 int* __restrict__ totS,
                                                 int* __restrict__ totD) {
    int c = blockIdx.x * 256 + threadIdx.x;
    if (c < NTS) {
        int running = 0;
        #pragma unroll 8
        for (int b = 0; b < HB; ++b) {
            bsS[b * NTS + c] = running;
            running += bcS[b * NTS + c];
        }
        totS[c] = running;
    } else if (c < NTS + NT_D) {
        int cc = c - NTS;
        int running = 0;
        #pragma unroll 8
        for (int b = 0; b < HB; ++b) {
            bsD[b * NT_D + cc] = running;
            running += bcD[b * NT_D + cc];
        }
        totD[cc] = running;
    }
}

// ---- merged scans
__global__ __launch_bounds__(256) void k_scanB(const int* __restrict__ totS,
                                               const int* __restrict__ totD,
                                               int* __restrict__ offS,
                                               int* __restrict__ offD) {
    __shared__ int sTot[NTS];
    __shared__ int sPart[257];
    int tid = threadIdx.x;
    const int* tot = (blockIdx.x == 0) ? totS : totD;
    int* offs = (blockIdx.x == 0) ? offS : offD;
    int NT = (blockIdx.x == 0) ? NTS : NT_D;
    int SEG = (blockIdx.x == 0) ? 25 : 13;
    for (int c = tid; c < NT; c += 256) sTot[c] = tot[c];
    __syncthreads();
    int base = tid * SEG;
    int loc = 0;
    for (int j = 0; j < SEG; ++j) {
        int c = base + j;
        if (c < NT) { int v = sTot[c]; sTot[c] = loc; loc += v; }
    }
    sPart[tid] = loc;
    __syncthreads();
    if (tid == 0) {
        int s = 0;
        for (int i = 0; i < 256; ++i) { int v = sPart[i]; sPart[i] = s; s += v; }
        sPart[256] = s;
    }
    __syncthreads();
    int add = sPart[tid];
    for (int j = 0; j < SEG; ++j) {
        int c = base + j;
        if (c < NT) sTot[c] += add;
    }
    __syncthreads();
    for (int c = tid; c < NT; c += 256) offs[c] = sTot[c];
    if (tid == 0) offs[NT] = sPart[256];
}

// ---- merged scatters
__global__ __launch_bounds__(256) void k_scatterB(const int* __restrict__ src,
                                                  const int* __restrict__ dst,
                                                  const int* __restrict__ bsS,
                                                  const int* __restrict__ bsD,
                                                  const int* __restrict__ offS,
                                                  const int* __restrict__ offD,
                                                  int* __restrict__ epS,
                                                  int* __restrict__ epD) {
    __shared__ int sCur[NTS];
    int tid = threadIdx.x, b = blockIdx.x;
    bool isS = b < HB;
    int bb = isS ? b : b - HB;
    const int* keys = isS ? src : dst;
    const int* bs = isS ? bsS : bsD;
    const int* offs = isS ? offS : offD;
    int* ep = isS ? epS : epD;
    int NT = isS ? NTS : NT_D;
    int SH = isS ? 4 : 5;
    for (int c = tid; c < NT; c += 256)
        sCur[c] = offs[c] + bs[bb * NT + c];
    __syncthreads();
    int beg = bb * EPB, end = min(beg + EPB, NE);
    for (int e = beg + tid; e < end; e += 256) {
        int pos = atomicAdd(&sCur[keys[e] >> SH], 1);
        ep[pos] = e;
    }
}

// ---- merged invperm + src gather
__global__ __launch_bounds__(256) void k_invgather(const int* __restrict__ epermS,
                                                   const int* __restrict__ src,
                                                   int* __restrict__ posS,
                                                   int* __restrict__ srcS) {
    int p = blockIdx.x * 256 + threadIdx.x;
    if (p < NE) {
        int e = epermS[p];
        posS[e] = p;
        srcS[p] = src[e];
    }
}

// ---- node encoder + projection: 32 nodes/block
__global__ __launch_bounds__(256) void k_node_enc(
    const int* __restrict__ nfeats, const float* __restrict__ emb,
    const float* __restrict__ encW, const float* __restrict__ encB,
    const float* __restrict__ projW, const float* __restrict__ projB,
    float* __restrict__ h) {
    __shared__ float sEncW[1024], sProjW[1024], sEncB[32], sProjB[32];
    __shared__ float sEmb[8][33], sNh[8][33];
    int tid = threadIdx.x;
    for (int i = tid; i < 1024; i += 256) { sEncW[i] = encW[i]; sProjW[i] = projW[i]; }
    if (tid < 32) { sEncB[tid] = encB[tid]; sProjB[tid] = projB[tid]; }
    int ln = tid >> 5, o = tid & 31;
    for (int g = 0; g < 4; ++g) {
        int node = blockIdx.x * 32 + g * 8 + ln;
        int nt = nfeats[node];
        float ev = fmaxf(emb[nt * 32 + o], 0.f);
        __syncthreads();
        sEmb[ln][o] = ev;
        __syncthreads();
        float acc = sEncB[o];
        #pragma unroll
        for (int i = 0; i < 32; ++i) acc += sEmb[ln][i] * sEncW[i * 32 + o];
        sNh[ln][o] = fmaxf(acc, 0.f);
        __syncthreads();
        float acc2 = sProjB[o];
        #pragma unroll
        for (int i = 0; i < 32; ++i) acc2 += sNh[ln][i] * sProjW[i * 32 + o];
        h[node * 32 + o] = fmaxf(acc2, 0.f);
    }
}

// ---- edge encoder (folded), f16 output
__global__ __launch_bounds__(256) void k_edge_t3h(
    const float* __restrict__ efeats, const float* __restrict__ Wcomb,
    const float* __restrict__ bcomb, const int* __restrict__ eperm,
    unsigned short* __restrict__ tS) {
    int tid = threadIdx.x;
    int el = tid >> 3, l8 = tid & 7;
    int gbase = (tid & 63) & 56;
    int c0 = l8 << 2;
    float4 w[16];
    #pragma unroll
    for (int i = 0; i < 16; ++i) w[i] = *(const float4*)(Wcomb + i * 32 + c0);
    float4 bb = *(const float4*)(bcomb + c0);
    #pragma unroll
    for (int it = 0; it < 4; ++it) {
        int p = blockIdx.x * 128 + it * 32 + el;
        int e = eperm ? eperm[p] : p;
        float2 efv = *(const float2*)(efeats + (size_t)e * 16 + (l8 << 1));
        float a0 = bb.x, a1 = bb.y, a2 = bb.z, a3 = bb.w;
        #pragma unroll
        for (int i = 0; i < 8; ++i) {
            float f0 = __shfl(efv.x, gbase + i, 64);
            float f1 = __shfl(efv.y, gbase + i, 64);
            float4 w0 = w[2 * i], w1 = w[2 * i + 1];
            a0 += f0 * w0.x + f1 * w1.x;
            a1 += f0 * w0.y + f1 * w1.y;
            a2 += f0 * w0.z + f1 * w1.z;
            a3 += f0 * w0.w + f1 * w1.w;
        }
        _Float16 h0 = (_Float16)fmaxf(a0, 0.f);
        _Float16 h1 = (_Float16)fmaxf(a1, 0.f);
        _Float16 h2 = (_Float16)fmaxf(a2, 0.f);
        _Float16 h3 = (_Float16)fmaxf(a3, 0.f);
        ushort4 o4;
        o4.x = *(unsigned short*)&h0; o4.y = *(unsigned short*)&h1;
        o4.z = *(unsigned short*)&h2; o4.w = *(unsigned short*)&h3;
        *(ushort4*)(tS + (size_t)p * 32 + c0) = o4;
    }
}

// ---- edge encoder fp32 output (msgC fallback only)
__global__ __launch_bounds__(256) void k_edge_t3(
    const float* __restrict__ efeats, const float* __restrict__ Wcomb,
    const float* __restrict__ bcomb, const int* __restrict__ eperm,
    float* __restrict__ tS) {
    int tid = threadIdx.x;
    int el = tid >> 3, l8 = tid & 7;
    int gbase = (tid & 63) & 56;
    int c0 = l8 << 2;
    float4 w[16];
    #pragma unroll
    for (int i = 0; i < 16; ++i) w[i] = *(const float4*)(Wcomb + i * 32 + c0);
    float4 bb = *(const float4*)(bcomb + c0);
    #pragma unroll
    for (int it = 0; it < 4; ++it) {
        int p = blockIdx.x * 128 + it * 32 + el;
        int e = eperm ? eperm[p] : p;
        float2 efv = *(const float2*)(efeats + (size_t)e * 16 + (l8 << 1));
        float a0 = bb.x, a1 = bb.y, a2 = bb.z, a3 = bb.w;
        #pragma unroll
        for (int i = 0; i < 8; ++i) {
            float f0 = __shfl(efv.x, gbase + i, 64);
            float f1 = __shfl(efv.y, gbase + i, 64);
            float4 w0 = w[2 * i], w1 = w[2 * i + 1];
            a0 += f0 * w0.x + f1 * w1.x;
            a1 += f0 * w0.y + f1 * w1.y;
            a2 += f0 * w0.z + f1 * w1.z;
            a3 += f0 * w0.w + f1 * w1.w;
        }
        *(float4*)(tS + (size_t)p * 32 + c0) =
            make_float4(fmaxf(a0, 0.f), fmaxf(a1, 0.f), fmaxf(a2, 0.f), fmaxf(a3, 0.f));
    }
}

// ---- legacy single-purpose bucketing kernels (fallback modes only)
template<int NT, int SHIFT>
__global__ __launch_bounds__(256) void k_histT(const int* __restrict__ keys,
                                               int* __restrict__ blockCounts) {
    __shared__ int sHist[NT];
    int tid = threadIdx.x, b = blockIdx.x;
    for (int c = tid; c < NT; c += 256) sHist[c] = 0;
    __syncthreads();
    int beg = b * EPB, end = min(beg + EPB, NE);
    for (int e = beg + tid; e < end; e += 256)
        atomicAdd(&sHist[keys[e] >> SHIFT], 1);
    __syncthreads();
    for (int c = tid; c < NT; c += 256) blockCounts[b * NT + c] = sHist[c];
}

template<int NT>
__global__ __launch_bounds__(256) void k_colsumT(const int* __restrict__ blockCounts,
                                                 int* __restrict__ blockStart,
                                                 int* __restrict__ tileTot) {
    int c = blockIdx.x * 256 + threadIdx.x;
    if (c >= NT) return;
    int running = 0;
    #pragma unroll 8
    for (int b = 0; b < HB; ++b) {
        blockStart[b * NT + c] = running;
        running += blockCounts[b * NT + c];
    }
    tileTot[c] = running;
}

template<int NT, int SEG>
__global__ __launch_bounds__(256) void k_scanT(const int* __restrict__ tileTot,
                                               int* __restrict__ offs) {
    __shared__ int sTot[NT];
    __shared__ int sPart[257];
    int tid = threadIdx.x;
    for (int c = tid; c < NT; c += 256) sTot[c] = tileTot[c];
    __syncthreads();
    int base = tid * SEG;
    int loc = 0;
    for (int j = 0; j < SEG; ++j) {
        int c = base + j;
        if (c < NT) { int v = sTot[c]; sTot[c] = loc; loc += v; }
    }
    sPart[tid] = loc;
    __syncthreads();
    if (tid == 0) {
        int s = 0;
        for (int i = 0; i < 256; ++i) { int v = sPart[i]; sPart[i] = s; s += v; }
        sPart[256] = s;
    }
    __syncthreads();
    int add = sPart[tid];
    for (int j = 0; j < SEG; ++j) {
        int c = base + j;
        if (c < NT) sTot[c] += add;
    }
    __syncthreads();
    for (int c = tid; c < NT; c += 256) offs[c] = sTot[c];
    if (tid == 0) offs[NT] = sPart[256];
}

template<int NT, int SHIFT>
__global__ __launch_bounds__(256) void k_scatterT(const int* __restrict__ keys,
                                                  const int* __restrict__ blockStart,
                                                  const int* __restrict__ offs,
                                                  int* __restrict__ eperm) {
    __shared__ int sCur[NT];
    int tid = threadIdx.x, b = blockIdx.x;
    for (int c = tid; c < NT; c += 256)
        sCur[c] = offs[c] + blockStart[b * NT + c];
    __syncthreads();
    int beg = b * EPB, end = min(beg + EPB, NE);
    for (int e = beg + tid; e < end; e += 256) {
        int pos = atomicAdd(&sCur[keys[e] >> SHIFT], 1);
        eperm[pos] = e;
    }
}

// ---- second-level sort: within each dst tile, sort by node (32 LDS bins)
__global__ __launch_bounds__(256) void k_sortNode(
    const int* __restrict__ epermD, const int* __restrict__ dst,
    const int* __restrict__ offsD, int* __restrict__ epermD2,
    int* __restrict__ nodeOffs) {
    __shared__ int sCnt[32], sStart[32];
    int tid = threadIdx.x, d = blockIdx.x;
    int beg = offsD[d], end = offsD[d + 1];
    if (tid < 32) sCnt[tid] = 0;
    __syncthreads();
    for (int p = beg + tid; p < end; p += 256)
        atomicAdd(&sCnt[dst[epermD[p]] & 31], 1);
    __syncthreads();
    if (tid == 0) {
        int s = beg;
        for (int r = 0; r < 32; ++r) { sStart[r] = s; s += sCnt[r]; }
    }
    __syncthreads();
    if (tid < 32) {
        nodeOffs[d * 32 + tid] = sStart[tid];
        sCnt[tid] = sStart[tid];
    }
    if (d == NT_D - 1 && tid == 0) nodeOffs[NN] = end;
    __syncthreads();
    for (int p = beg + tid; p < end; p += 256) {
        int e = epermD[p];
        int pos = atomicAdd(&sCnt[dst[e] & 31], 1);
        epermD2[pos] = e;
    }
}

// ---- inverse permutation (fallback path)
__global__ __launch_bounds__(256) void k_invperm(const int* __restrict__ eperm,
                                                 int* __restrict__ pos) {
    int p = blockIdx.x * 256 + threadIdx.x;
    if (p < NE) pos[eperm[p]] = p;
}

// ---- gather key (fallback path)
__global__ __launch_bounds__(256) void k_gatherKey(const int* __restrict__ epermS,
                                                   const int* __restrict__ key,
                                                   int* __restrict__ out) {
    int p = blockIdx.x * 256 + threadIdx.x;
    if (p < NE) out[p] = key[epermS[p]];
}

// ---- idxS[posS[epermD2[q]]] = q
__global__ __launch_bounds__(256) void k_scatterIdx(const int* __restrict__ epermD2,
                                                    const int* __restrict__ posS,
                                                    int* __restrict__ idxS) {
    int q = blockIdx.x * 256 + threadIdx.x;
    if (q < NE) idxS[posS[epermD2[q]]] = q;
}

// ---- fused per-16-node-src-tile: MFMA Q -> f16 LDS (k-pair interleaved),
// edge stream: 4 lanes/edge x 8 outputs via v_dot2_f32_f16.
template<int MODE>
__global__ __launch_bounds__(256) void k_msgF16(
    const float* __restrict__ h, const unsigned short* __restrict__ W2bf,
    const unsigned short* __restrict__ tS, const int* __restrict__ srcS,
    const int* __restrict__ idxS, const int* __restrict__ offs,
    float* __restrict__ outbuf) {
    __shared__ unsigned short sQ[16 * QSTRH];
    int tid = threadIdx.x;
    int tile = blockIdx.x;
    int beg = offs[tile], end = offs[tile + 1];
    if (beg >= end) return;
    int nodeBase = tile * 16;
    int wave = tid >> 6, lane = tid & 63;

    int arow = lane & 15;
    const float* hp = h + (size_t)(nodeBase + arow) * 32 + ((lane >> 4) << 2);
    float4 x0 = *(const float4*)hp;
    float4 x1 = *(const float4*)(hp + 16);
    bf16x8 a;
    a[0] = (short)f2bf(x0.x); a[1] = (short)f2bf(x0.y);
    a[2] = (short)f2bf(x0.z); a[3] = (short)f2bf(x0.w);
    a[4] = (short)f2bf(x1.x); a[5] = (short)f2bf(x1.y);
    a[6] = (short)f2bf(x1.z); a[7] = (short)f2bf(x1.w);

    f32x4 z = {0.f, 0.f, 0.f, 0.f};
    int crow0 = (lane >> 4) << 2;
    int ccol = lane & 15;
    for (int ct = wave; ct < 66; ct += 4) {
        bf16x8 b = *(const bf16x8*)(W2bf + (size_t)((ct << 6) + lane) * 8);
        f32x4 acc = __builtin_amdgcn_mfma_f32_16x16x32_bf16(a, b, z, 0, 0, 0);
        int c = (ct << 4) + ccol;
        int idx;
        if (c < 1024) {
            int k = c >> 5, o = c & 31;
            idx = ((k >> 1) << 6) + (o << 1) + (k & 1);
        } else {
            idx = 1024 + (c - 1024);
        }
        unsigned short* qp = sQ + crow0 * QSTRH + idx;
        _Float16 v0 = (_Float16)acc[0], v1 = (_Float16)acc[1];
        _Float16 v2 = (_Float16)acc[2], v3 = (_Float16)acc[3];
        qp[0 * QSTRH] = *(unsigned short*)&v0;
        qp[1 * QSTRH] = *(unsigned short*)&v1;
        qp[2 * QSTRH] = *(unsigned short*)&v2;
        qp[3 * QSTRH] = *(unsigned short*)&v3;
    }
    __syncthreads();

    int el = tid >> 2, l4 = tid & 3;
    int o0 = l4 << 3;
    for (int p = beg + el; p < end; p += 64) {
        int row = srcS[p] - nodeBase;
        int widx = idxS[p];
        h16x8 trow[4];
        #pragma unroll
        for (int i = 0; i < 4; ++i)
            trow[i] = *(const h16x8*)(tS + (size_t)p * 32 + (i << 3));
        const unsigned short* qp = sQ + row * QSTRH;
        h16x8 qb = *(const h16x8*)(qp + 1024 + o0);
        float acc[8];
        #pragma unroll
        for (int j = 0; j < 8; ++j) acc[j] = (float)qb[j];
        #pragma unroll
        for (int kp = 0; kp < 16; ++kp) {
            h16x2 t2;
            t2[0] = trow[kp >> 2][(kp & 3) * 2];
            t2[1] = trow[kp >> 2][(kp & 3) * 2 + 1];
            h16x8 qa = *(const h16x8*)(qp + (kp << 6) + (o0 << 1));
            h16x8 qc = *(const h16x8*)(qp + (kp << 6) + (o0 << 1) + 8);
            #pragma unroll
            for (int j = 0; j < 4; ++j) {
                h16x2 q2a; q2a[0] = qa[2 * j]; q2a[1] = qa[2 * j + 1];
                h16x2 q2c; q2c[0] = qc[2 * j]; q2c[1] = qc[2 * j + 1];
                acc[j]     = dot2h(t2, q2a, acc[j]);
                acc[4 + j] = dot2h(t2, q2c, acc[4 + j]);
            }
        }
        if (MODE) {
            float* op = outbuf + (size_t)widx * 32 + o0;
            *(float4*)op = make_float4(acc[0], acc[1], acc[2], acc[3]);
            *(float4*)(op + 4) = make_float4(acc[4], acc[5], acc[6], acc[7]);
        } else {
            float* op = outbuf + (size_t)widx * 32 + o0;
            #pragma unroll
            for (int j = 0; j < 8; ++j) atomicAdd(op + j, acc[j]);
        }
    }
}

// ---- fallback msg (tiny ws)
__global__ __launch_bounds__(256) void k_msgC(
    const float* __restrict__ t, const int* __restrict__ src, const int* __restrict__ dst,
    const float* __restrict__ h, const float* __restrict__ W2ext, float* __restrict__ agg) {
    __shared__ float sT[32][33], sH[32][33];
    __shared__ int sSrc[32], sDst[32];
    int tid = threadIdx.x;
    int e0 = blockIdx.x * 32;
    if (tid < 32) sSrc[tid] = src[e0 + tid];
    else if (tid < 64) sDst[tid - 32] = dst[e0 + tid - 32];
    __syncthreads();
    for (int idx = tid; idx < 1024; idx += 256) {
        int el = idx >> 5, k = idx & 31;
        sT[el][k] = t[(e0 + el) * 32 + k];
        sH[el][k] = h[(size_t)sSrc[el] * 32 + k];
    }
    __syncthreads();
    int el = tid >> 3, l8 = tid & 7;
    int c0 = l8 * 4;
    float m0 = 0.f, m1 = 0.f, m2 = 0.f, m3 = 0.f;
    for (int i = 0; i < 32; ++i) {
        const float* wrow = W2ext + i * QC;
        float4 wb = *(const float4*)(wrow + 1024 + c0);
        float w0 = wb.x, w1 = wb.y, w2 = wb.z, w3 = wb.w;
        #pragma unroll 8
        for (int k = 0; k < 32; ++k) {
            float tk = sT[el][k];
            float4 w = *(const float4*)(wrow + k * 32 + c0);
            w0 += tk * w.x; w1 += tk * w.y; w2 += tk * w.z; w3 += tk * w.w;
        }
        float hi = sH[el][i];
        m0 += hi * w0; m1 += hi * w1; m2 += hi * w2; m3 += hi * w3;
    }
    float* ap = agg + (size_t)sDst[el] * 32 + c0;
    atomicAdd(ap + 0, m0); atomicAdd(ap + 1, m1);
    atomicAdd(ap + 2, m2); atomicAdd(ap + 3, m3);
}

// ---- GRU step reading agg[] (MODE 0 / fallback)
__global__ __launch_bounds__(256) void k_gru(
    const float* __restrict__ agg, const float* __restrict__ convB,
    const float* __restrict__ Wi, const float* __restrict__ Wh,
    const float* __restrict__ bi, const float* __restrict__ bh,
    float* __restrict__ h) {
    __shared__ float sWi[3072], sWh[3072], sBi[96], sBh[96], sCb[32];
    __shared__ float sX[8][33], sH[8][33];
    int tid = threadIdx.x;
    for (int i = tid; i < 3072; i += 256) { sWi[i] = Wi[i]; sWh[i] = Wh[i]; }
    if (tid < 96) { sBi[tid] = bi[tid]; sBh[tid] = bh[tid]; }
    if (tid < 32) sCb[tid] = convB[tid];
    int ln = tid >> 5, o = tid & 31;
    for (int g = 0; g < 4; ++g) {
        int node = blockIdx.x * 32 + g * 8 + ln;
        float hv = h[node * 32 + o];
        float av = agg[node * 32 + o];
        __syncthreads();
        sX[ln][o] = fmaxf(av + sCb[o], 0.f);
        sH[ln][o] = hv;
        __syncthreads();
        float air = sBi[o], aiz = sBi[o + 32], ain = sBi[o + 64];
        float ahr = sBh[o], ahz = sBh[o + 32], ahn = sBh[o + 64];
        #pragma unroll 8
        for (int i = 0; i < 32; ++i) {
            float x = sX[ln][i], hh = sH[ln][i];
            air += x * sWi[i * 96 + o];      ahr += hh * sWh[i * 96 + o];
            aiz += x * sWi[i * 96 + o + 32]; ahz += hh * sWh[i * 96 + o + 32];
            ain += x * sWi[i * 96 + o + 64]; ahn += hh * sWh[i * 96 + o + 64];
        }
        float r = sigm(air + ahr);
        float zz = sigm(aiz + ahz);
        float ng = tanhf(ain + r * ahn);
        h[node * 32 + o] = (1.f - zz) * ng + zz * hv;
    }
}

// ---- MODE 1: per 32-node dst tile: segment-sum -> X in LDS, GRU via split-bf16 MFMA.
// DEC=1 (last step): fused 4-layer decoder, all 32 nodes in parallel, 4 barriers.
template<int DEC>
__global__ __launch_bounds__(256) void k_gruAgg4(
    const float* __restrict__ msgbuf, const int* __restrict__ nodeOffs,
    const float* __restrict__ convB,
    const unsigned short* __restrict__ Whi, const unsigned short* __restrict__ Wlo,
    const float* __restrict__ bi, const float* __restrict__ bh,
    float* __restrict__ h,
    const float* __restrict__ W1, const float* __restrict__ b1, const float* __restrict__ a1,
    const float* __restrict__ W2, const float* __restrict__ b2, const float* __restrict__ a2,
    const float* __restrict__ W3, const float* __restrict__ b3, const float* __restrict__ a3,
    const float* __restrict__ W4, const float* __restrict__ b4,
    float* __restrict__ out) {
    __shared__ float sAgg[32 * 33];
    int tid = threadIdx.x;
    int d = blockIdx.x;
    int base = d * 32;

    {
        int n8 = tid >> 3, l8 = tid & 7;
        int node = base + n8;
        int nb = nodeOffs[node], ne2 = nodeOffs[node + 1];
        float a0 = 0.f, a1v = 0.f, a2v = 0.f, a3v = 0.f;
        for (int p = nb; p < ne2; ++p) {
            float4 v = *(const float4*)(msgbuf + (size_t)p * 32 + (l8 << 2));
            a0 += v.x; a1v += v.y; a2v += v.z; a3v += v.w;
        }
        int c0 = l8 << 2;
        float4 cb = *(const float4*)(convB + c0);
        float* sp = sAgg + n8 * 33 + c0;
        sp[0] = fmaxf(a0 + cb.x, 0.f);
        sp[1] = fmaxf(a1v + cb.y, 0.f);
        sp[2] = fmaxf(a2v + cb.z, 0.f);
        sp[3] = fmaxf(a3v + cb.w, 0.f);
    }
    __syncthreads();

    int wave = tid >> 6, lane = tid & 63;
    int m = wave >> 1, c = wave & 1;
    int arow = lane & 15, kg = (lane >> 4) << 2;

    bf16x8 xhi, xlo, hhi, hlo;
    {
        const float* xp = sAgg + (m * 16 + arow) * 33 + kg;
        float4 v0 = *(const float4*)xp;
        float4 v1 = *(const float4*)(xp + 16);
        float xv[8] = {v0.x, v0.y, v0.z, v0.w, v1.x, v1.y, v1.z, v1.w};
        #pragma unroll
        for (int j = 0; j < 8; ++j) {
            unsigned short hi16 = f2bf(xv[j]);
            xhi[j] = (short)hi16;
            xlo[j] = (short)f2bf(xv[j] - bf2f(hi16));
        }
        const float* hp = h + (size_t)(base + m * 16 + arow) * 32 + kg;
        float4 w0 = *(const float4*)hp;
        float4 w1 = *(const float4*)(hp + 16);
        float hv8[8] = {w0.x, w0.y, w0.z, w0.w, w1.x, w1.y, w1.z, w1.w};
        #pragma unroll
        for (int j = 0; j < 8; ++j) {
            unsigned short hi16 = f2bf(hv8[j]);
            hhi[j] = (short)hi16;
            hlo[j] = (short)f2bf(hv8[j] - bf2f(hi16));
        }
    }

    int ccol = lane & 15, crow0 = (lane >> 4) << 2;
    int o = c * 16 + ccol;
    auto Bf = [&](int nt, int kt, const unsigned short* W) {
        return *(const bf16x8*)(W + (size_t)(((nt * 2 + kt) * 64 + lane) << 3));
    };
    f32x4 accR = {0.f, 0.f, 0.f, 0.f}, accZ = {0.f, 0.f, 0.f, 0.f};
    f32x4 accIN = {0.f, 0.f, 0.f, 0.f}, accHN = {0.f, 0.f, 0.f, 0.f};
    {
        int nt = c;
        bf16x8 b0h = Bf(nt, 0, Whi), b0l = Bf(nt, 0, Wlo);
        bf16x8 b1h = Bf(nt, 1, Whi), b1l = Bf(nt, 1, Wlo);
        accR = __builtin_amdgcn_mfma_f32_16x16x32_bf16(xhi, b0h, accR, 0, 0, 0);
        accR = __builtin_amdgcn_mfma_f32_16x16x32_bf16(xlo, b0h, accR, 0, 0, 0);
        accR = __builtin_amdgcn_mfma_f32_16x16x32_bf16(xhi, b0l, accR, 0, 0, 0);
        accR = __builtin_amdgcn_mfma_f32_16x16x32_bf16(hhi, b1h, accR, 0, 0, 0);
        accR = __builtin_amdgcn_mfma_f32_16x16x32_bf16(hlo, b1h, accR, 0, 0, 0);
        accR = __builtin_amdgcn_mfma_f32_16x16x32_bf16(hhi, b1l, accR, 0, 0, 0);
    }
    {
        int nt = 2 + c;
        bf16x8 b0h = Bf(nt, 0, Whi), b0l = Bf(nt, 0, Wlo);
        bf16x8 b1h = Bf(nt, 1, Whi), b1l = Bf(nt, 1, Wlo);
        accZ = __builtin_amdgcn_mfma_f32_16x16x32_bf16(xhi, b0h, accZ, 0, 0, 0);
        accZ = __builtin_amdgcn_mfma_f32_16x16x32_bf16(xlo, b0h, accZ, 0, 0, 0);
        accZ = __builtin_amdgcn_mfma_f32_16x16x32_bf16(xhi, b0l, accZ, 0, 0, 0);
        accZ = __builtin_amdgcn_mfma_f32_16x16x32_bf16(hhi, b1h, accZ, 0, 0, 0);
        accZ = __builtin_amdgcn_mfma_f32_16x16x32_bf16(hlo, b1h, accZ, 0, 0, 0);
        accZ = __builtin_amdgcn_mfma_f32_16x16x32_bf16(hhi, b1l, accZ, 0, 0, 0);
    }
    {
        int nt = 4 + c;
        bf16x8 b0h = Bf(nt, 0, Whi), b0l = Bf(nt, 0, Wlo);
        bf16x8 b1h = Bf(nt, 1, Whi), b1l = Bf(nt, 1, Wlo);
        accIN = __builtin_amdgcn_mfma_f32_16x16x32_bf16(xhi, b0h, accIN, 0, 0, 0);
        accIN = __builtin_amdgcn_mfma_f32_16x16x32_bf16(xlo, b0h, accIN, 0, 0, 0);
        accIN = __builtin_amdgcn_mfma_f32_16x16x32_bf16(xhi, b0l, accIN, 0, 0, 0);
        accHN = __builtin_amdgcn_mfma_f32_16x16x32_bf16(hhi, b1h, accHN, 0, 0, 0);
        accHN = __builtin_amdgcn_mfma_f32_16x16x32_bf16(hlo, b1h, accHN, 0, 0, 0);
        accHN = __builtin_amdgcn_mfma_f32_16x16x32_bf16(hhi, b1l, accHN, 0, 0, 0);
    }

    float bir = bi[o], biz = bi[32 + o], bin = bi[64 + o];
    float bhr = bh[o], bhz = bh[32 + o], bhn = bh[64 + o];
    float hv[4];
    #pragma unroll
    for (int j = 0; j < 4; ++j)
        hv[j] = h[(size_t)(base + m * 16 + crow0 + j) * 32 + o];
    __syncthreads();    // all h reads complete before any h writes
    float nh[4];
    #pragma unroll
    for (int j = 0; j < 4; ++j) {
        float r  = sigm(accR[j] + bir + bhr);
        float zz = sigm(accZ[j] + biz + bhz);
        float ng = tanhf(accIN[j] + bin + r * (accHN[j] + bhn));
        nh[j] = (1.f - zz) * ng + zz * hv[j];
        h[(size_t)(base + m * 16 + crow0 + j) * 32 + o] = nh[j];
    }

    if constexpr (DEC) {
        // all-32-node parallel decoder: thread (n8 = tid>>3, l8 = tid&7) owns
        // node n8's outputs l8*4..l8*4+3 per layer; ping-pong sYa <-> sYb.
        __shared__ float sYa[32 * 33];
        __shared__ float sYb[32 * 33];
        __shared__ float sW1[1024], sW2[1024], sW3[1024], sW4[96];
        __shared__ float sB1[32], sB2[32], sB3[32], sB4[3];
        #pragma unroll
        for (int j = 0; j < 4; ++j)
            sYa[(m * 16 + crow0 + j) * 33 + o] = nh[j];
        for (int i = tid; i < 1024; i += 256) { sW1[i] = W1[i]; sW2[i] = W2[i]; sW3[i] = W3[i]; }
        if (tid < 96) sW4[tid] = W4[tid];
        if (tid < 32) { sB1[tid] = b1[tid]; sB2[tid] = b2[tid]; sB3[tid] = b3[tid]; }
        if (tid < 3) sB4[tid] = b4[tid];
        float A1 = a1[0], A2 = a2[0], A3 = a3[0];
        int n8 = tid >> 3, l8 = tid & 7, c0 = l8 << 2;
        __syncthreads();     // nh + weights staged
        // L1: sYa -> sYb
        {
            float y0 = sB1[c0], y1 = sB1[c0 + 1], y2 = sB1[c0 + 2], y3 = sB1[c0 + 3];
            const float* yp = sYa + n8 * 33;
            #pragma unroll 8
            for (int i = 0; i < 32; ++i) {
                float v = yp[i];
                float4 w = *(const float4*)(sW1 + i * 32 + c0);
                y0 += v * w.x; y1 += v * w.y; y2 += v * w.z; y3 += v * w.w;
            }
            float* op = sYb + n8 * 33 + c0;
            op[0] = y0 >= 0.f ? y0 : A1 * y0;
            op[1] = y1 >= 0.f ? y1 : A1 * y1;
            op[2] = y2 >= 0.f ? y2 : A1 * y2;
            op[3] = y3 >= 0.f ? y3 : A1 * y3;
        }
        __syncthreads();
        // L2: sYb -> sYa
        {
            float y0 = sB2[c0], y1 = sB2[c0 + 1], y2 = sB2[c0 + 2], y3 = sB2[c0 + 3];
            const float* yp = sYb + n8 * 33;
            #pragma unroll 8
            for (int i = 0; i < 32; ++i) {
                float v = yp[i];
                float4 w = *(const float4*)(sW2 + i * 32 + c0);
                y0 += v * w.x; y1 += v * w.y; y2 += v * w.z; y3 += v * w.w;
            }
            float* op = sYa + n8 * 33 + c0;
            op[0] = y0 >= 0.f ? y0 : A2 * y0;
            op[1] = y1 >= 0.f ? y1 : A2 * y1;
            op[2] = y2 >= 0.f ? y2 : A2 * y2;
            op[3] = y3 >= 0.f ? y3 : A2 * y3;
        }
        __syncthreads();
        // L3: sYa -> sYb
        {
            float y0 = sB3[c0], y1 = sB3[c0 + 1], y2 = sB3[c0 + 2], y3 = sB3[c0 + 3];
            const float* yp = sYa + n8 * 33;
            #pragma unroll 8
            for (int i = 0; i < 32; ++i) {
                float v = yp[i];
                float4 w = *(const float4*)(sW3 + i * 32 + c0);
                y0 += v * w.x; y1 += v * w.y; y2 += v * w.z; y3 += v * w.w;
            }
            float* op = sYb + n8 * 33 + c0;
            op[0] = y0 >= 0.f ? y0 : A3 * y0;
            op[1] = y1 >= 0.f ? y1 : A3 * y1;
            op[2] = y2 >= 0.f ? y2 : A3 * y2;
            op[3] = y3 >= 0.f ? y3 : A3 * y3;
        }
        __syncthreads();
        // L4: sYb -> out (lanes l8 < 3 produce one output each)
        if (l8 < 3) {
            float r = sB4[l8];
            const float* yp = sYb + n8 * 33;
            #pragma unroll 8
            for (int i = 0; i < 32; ++i) r += yp[i] * sW4[i * 3 + l8];
            out[(size_t)(base + n8) * 3 + l8] = r;
        }
    }
}

// ---- decoder (fallback modes only)
__global__ __launch_bounds__(256) void k_dec(
    const float* __restrict__ h,
    const float* __restrict__ W1, const float* __restrict__ b1, const float* __restrict__ a1,
    const float* __restrict__ W2, const float* __restrict__ b2, const float* __restrict__ a2,
    const float* __restrict__ W3, const float* __restrict__ b3, const float* __restrict__ a3,
    const float* __restrict__ W4, const float* __restrict__ b4,
    float* __restrict__ out) {
    __shared__ float sW1[1024], sW2[1024], sW3[1024], sW4[96];
    __shared__ float sB1[32], sB2[32], sB3[32], sB4[3];
    __shared__ float sYa[8][33], sYb[8][33];
    int tid = threadIdx.x;
    for (int i = tid; i < 1024; i += 256) { sW1[i] = W1[i]; sW2[i] = W2[i]; sW3[i] = W3[i]; }
    if (tid < 96) sW4[tid] = W4[tid];
    if (tid < 32) { sB1[tid] = b1[tid]; sB2[tid] = b2[tid]; sB3[tid] = b3[tid]; }
    if (tid < 3) sB4[tid] = b4[tid];
    float A1 = a1[0], A2 = a2[0], A3 = a3[0];
    int ln = tid >> 5, o = tid & 31;
    for (int g = 0; g < 4; ++g) {
        int node = blockIdx.x * 32 + g * 8 + ln;
        float hv = h[node * 32 + o];
        __syncthreads();
        sYa[ln][o] = hv;
        __syncthreads();
        float acc = sB1[o];
        #pragma unroll
        for (int i = 0; i < 32; ++i) acc += sYa[ln][i] * sW1[i * 32 + o];
        acc = acc >= 0.f ? acc : A1 * acc;
        sYb[ln][o] = acc;
        __syncthreads();
        acc = sB2[o];
        #pragma unroll
        for (int i = 0; i < 32; ++i) acc += sYb[ln][i] * sW2[i * 32 + o];
        acc = acc >= 0.f ? acc : A2 * acc;
        __syncthreads();
        sYa[ln][o] = acc;
        __syncthreads();
        acc = sB3[o];
        #pragma unroll
        for (int i = 0; i < 32; ++i) acc += sYa[ln][i] * sW3[i * 32 + o];
        acc = acc >= 0.f ? acc : A3 * acc;
        __syncthreads();
        sYb[ln][o] = acc;
        __syncthreads();
        if (o < 3) {
            float r = sB4[o];
            #pragma unroll
            for (int i = 0; i < 32; ++i) r += sYb[ln][i] * sW4[i * 3 + o];
            out[node * 3 + o] = r;
        }
    }
}

extern "C" void kernel_launch(void* const* d_in, const int* in_sizes, int n_in,
                              void* d_out, int out_size, void* d_ws, size_t ws_size,
                              hipStream_t stream) {
    const int*   nfeats = (const int*)d_in[0];
    const float* efeats = (const float*)d_in[1];
    const int*   src    = (const int*)d_in[2];
    const int*   dst    = (const int*)d_in[3];
    const float* emb    = (const float*)d_in[4];
    const float* encW   = (const float*)d_in[5];
    const float* encB   = (const float*)d_in[6];
    const float* eencW  = (const float*)d_in[7];
    const float* eencB  = (const float*)d_in[8];
    const float* projW  = (const float*)d_in[9];
    const float* projB  = (const float*)d_in[10];
    const float* enW1   = (const float*)d_in[11];
    const float* enB1   = (const float*)d_in[12];
    const float* enW2   = (const float*)d_in[13];
    const float* enB2   = (const float*)d_in[14];
    const float* convB  = (const float*)d_in[15];
    const float* gruWi  = (const float*)d_in[16];
    const float* gruWh  = (const float*)d_in[17];
    const float* gruBi  = (const float*)d_in[18];
    const float* gruBh  = (const float*)d_in[19];
    const float* dW1 = (const float*)d_in[20]; const float* db1 = (const float*)d_in[21]; const float* da1 = (const float*)d_in[22];
    const float* dW2 = (const float*)d_in[23]; const float* db2 = (const float*)d_in[24]; const float* da2 = (const float*)d_in[25];
    const float* dW3 = (const float*)d_in[26]; const float* db3 = (const float*)d_in[27]; const float* da3 = (const float*)d_in[28];
    const float* dW4 = (const float*)d_in[29]; const float* db4 = (const float*)d_in[30];
    float* out = (float*)d_out;
    char* ws = (char*)d_ws;

    // bump allocator (256-B aligned)
    size_t cur = 0;
    auto alloc = [&](size_t n) { size_t p = cur; cur = (cur + n + 255) & ~(size_t)255; return p; };
    size_t o_h   = alloc((size_t)NN * 32 * 4);
    size_t o_t   = alloc((size_t)NE * 32 * 4);
    size_t o_w2e = alloc((size_t)32 * QC * 4);
    size_t afterCommon = cur;
    size_t o_w2b = alloc((size_t)66 * 512 * 2);
    size_t o_epS = alloc((size_t)NE * 4);
    size_t o_ofS = alloc((size_t)(NTS + 1) * 4);
    size_t o_posS = alloc((size_t)NE * 4);
    size_t o_srcS = alloc((size_t)NE * 4);
    size_t o_idxS = alloc((size_t)NE * 4);
    size_t o_wcomb = alloc((size_t)(512 + 32) * 4);
    size_t baseEnd = cur;
    size_t o_epD  = alloc((size_t)NE * 4);
    size_t o_ofD  = alloc((size_t)(NT_D + 1) * 4);
    size_t o_epD2 = alloc((size_t)NE * 4);
    size_t o_noff = alloc((size_t)(NN + 1) * 4);
    size_t o_whi  = alloc((size_t)6144 * 2);
    size_t o_wlo  = alloc((size_t)6144 * 2);
    size_t o_msg  = alloc((size_t)NE * 32 * 4);
    size_t need1 = cur;
    size_t need0 = baseEnd + (size_t)NN * 32 * 4;

    int mode;
    if (ws_size >= need1) mode = 1;
    else if (ws_size >= need0) mode = 0;
    else mode = -1;

    float* h     = (float*)(ws + o_h);
    float* tSf   = (float*)(ws + o_t);
    unsigned short* tSh = (unsigned short*)(ws + o_t);
    float* W2ext = (float*)(ws + o_w2e);
    unsigned short* W2bf = (unsigned short*)(ws + o_w2b);
    int* epermS  = (int*)(ws + o_epS);
    int* offsS   = (int*)(ws + o_ofS);
    int* posS    = (int*)(ws + o_posS);
    int* srcS    = (int*)(ws + o_srcS);
    int* idxS    = (int*)(ws + o_idxS);
    float* Wcomb = (float*)(ws + o_wcomb);
    float* bcomb = Wcomb + 512;
    int* epermD  = (int*)(ws + o_epD);
    int* offsD   = (int*)(ws + o_ofD);
    int* epermD2 = (int*)(ws + o_epD2);
    int* nodeOffs = (int*)(ws + o_noff);
    unsigned short* gWhi = (unsigned short*)(ws + o_whi);
    unsigned short* gWlo = (unsigned short*)(ws + o_wlo);
    float* outbuf = (mode == 1) ? (float*)(ws + o_msg)
                  : (mode == 0) ? (float*)(ws + baseEnd)
                                : (float*)(ws + afterCommon);
    int* bcS = (int*)outbuf;
    int* bsS = bcS + (size_t)HB * NTS;
    int* bcD = bsS + (size_t)HB * NTS;
    int* bsD = bcD + (size_t)HB * NT_D;
    int* totS = bsD + (size_t)HB * NT_D;
    int* totD = totS + NTS;

    k_node_enc<<<NN / 32, 256, 0, stream>>>(nfeats, emb, encW, encB, projW, projB, h);

    if (mode == 1) {
        k_prepAll<<<(66 * 512 + 6144 + 544 + 255) / 256, 256, 0, stream>>>(
            enW2, enB2, W2bf, gruWi, gruWh, gWhi, gWlo,
            eencW, eencB, enW1, enB1, Wcomb, bcomb);
        k_histB<<<2 * HB, 256, 0, stream>>>(src, dst, bcS, bcD);
        k_colsumB<<<(NTS + NT_D + 255) / 256, 256, 0, stream>>>(bcS, bcD, bsS, bsD, totS, totD);
        k_scanB<<<2, 256, 0, stream>>>(totS, totD, offsS, offsD);
        k_scatterB<<<2 * HB, 256, 0, stream>>>(src, dst, bsS, bsD, offsS, offsD, epermS, epermD);
        k_invgather<<<(NE + 255) / 256, 256, 0, stream>>>(epermS, src, posS, srcS);
        k_sortNode<<<NT_D, 256, 0, stream>>>(epermD, dst, offsD, epermD2, nodeOffs);
        k_scatterIdx<<<(NE + 255) / 256, 256, 0, stream>>>(epermD2, posS, idxS);
        k_edge_t3h<<<NE / 128, 256, 0, stream>>>(efeats, Wcomb, bcomb, epermS, tSh);
        for (int s = 0; s < 3; ++s) {
            k_msgF16<1><<<NTS, 256, 0, stream>>>(h, W2bf, tSh, srcS, idxS, offsS, outbuf);
            if (s < 2) {
                k_gruAgg4<0><<<NT_D, 256, 0, stream>>>(outbuf, nodeOffs, convB,
                    gWhi, gWlo, gruBi, gruBh, h,
                    dW1, db1, da1, dW2, db2, da2, dW3, db3, da3, dW4, db4, out);
            } else {
                k_gruAgg4<1><<<NT_D, 256, 0, stream>>>(outbuf, nodeOffs, convB,
                    gWhi, gWlo, gruBi, gruBh, h,
                    dW1, db1, da1, dW2, db2, da2, dW3, db3, da3, dW4, db4, out);
            }
        }
    } else if (mode == 0) {
        int* blockCounts = (int*)outbuf;
        int* blockStart  = blockCounts + (size_t)HB * NTS;
        int* tileTot     = blockStart + (size_t)HB * NTS;
        k_prepAll<<<(66 * 512 + 6144 + 544 + 255) / 256, 256, 0, stream>>>(
            enW2, enB2, W2bf, gruWi, gruWh, gWhi, gWlo,
            eencW, eencB, enW1, enB1, Wcomb, bcomb);
        k_histT<NTS, 4><<<HB, 256, 0, stream>>>(src, blockCounts);
        k_colsumT<NTS><<<(NTS + 255) / 256, 256, 0, stream>>>(blockCounts, blockStart, tileTot);
        k_scanT<NTS, 25><<<1, 256, 0, stream>>>(tileTot, offsS);
        k_scatterT<NTS, 4><<<HB, 256, 0, stream>>>(src, blockStart, offsS, epermS);
        k_invperm<<<(NE + 255) / 256, 256, 0, stream>>>(epermS, posS);
        k_gatherKey<<<(NE + 255) / 256, 256, 0, stream>>>(epermS, src, srcS);
        k_gatherKey<<<(NE + 255) / 256, 256, 0, stream>>>(epermS, dst, idxS);
        k_edge_t3h<<<NE / 128, 256, 0, stream>>>(efeats, Wcomb, bcomb, epermS, tSh);
        for (int s = 0; s < 3; ++s) {
            hipMemsetAsync(outbuf, 0, (size_t)NN * 32 * 4, stream);
            k_msgF16<0><<<NTS, 256, 0, stream>>>(h, W2bf, tSh, srcS, idxS, offsS, outbuf);
            k_gru<<<NN / 32, 256, 0, stream>>>(outbuf, convB, gruWi, gruWh, gruBi, gruBh, h);
        }
        k_dec<<<NN / 32, 256, 0, stream>>>(h, dW1, db1, da1, dW2, db2, da2, dW3, db3, da3, dW4, db4, out);
    } else {
        k_prepAll<<<(66 * 512 + 6144 + 544 + 255) / 256, 256, 0, stream>>>(
            enW2, enB2, W2bf, gruWi, gruWh, gWhi, gWlo,
            eencW, eencB, enW1, enB1, Wcomb, bcomb);
        k_w2ext<<<(32 * QC + 255) / 256, 256, 0, stream>>>(enW2, enB2, W2ext);
        k_edge_t3<<<NE / 128, 256, 0, stream>>>(efeats, Wcomb, bcomb, nullptr, tSf);
        for (int s = 0; s < 3; ++s) {
            hipMemsetAsync(outbuf, 0, (size_t)NN * 32 * 4, stream);
            k_msgC<<<NE / 32, 256, 0, stream>>>(tSf, src, dst, h, W2ext, outbuf);
            k_gru<<<NN / 32, 256, 0, stream>>>(outbuf, convB, gruWi, gruWh, gruBi, gruBh, h);
        }
        k_dec<<<NN / 32, 256, 0, stream>>>(h, dW1, db1, da1, dW2, db2, da2, dW3, db3, da3, dW4, db4, out);
    }
}

// Round 23
// 347.839 us; speedup vs baseline: 1.4652x; 1.0191x over previous
//
#include <hip/hip_runtime.h>
#include <hip/hip_bf16.h>

// MPNN on MI355X — fused 16-node-tile msg kernel + MFMA GRU, fully pre-sorted streams.
// msg[e,o] = sum_k t[e,k]*Q[src,k,o] + q0[src,o],  Q[n] = h[n] @ W2ext
// k_msgF16: per 16-node src tile, MFMA Q (16x1056) into LDS as F16 (k-pair
// interleaved, QSTRH=1096 -> row bank-phase step 4 dwords, 8-row conflict period);
// barrier-free edge stream via v_dot2_f32_f16 (t stored f16). Edge encoder folded.
// k_gruAgg4<DEC>: split-bf16 MFMA GRU; last step fuses the 4-layer decoder
// in-block with all 32 nodes in parallel (4 barriers total). No global atomics.

#define NN 100000
#define NE 320000
#define QC 1056
#define NTS 6250      // NN/16 src tiles
#define NT_D 3125     // NN/32 dst tiles
#define HB 256        // bucketing blocks
#define EPB (NE / HB) // 1250
#define QSTRH 1096    // sQ row stride (halves); 548 dwords % 32 == 4

typedef short bf16x8 __attribute__((ext_vector_type(8)));
typedef float f32x4  __attribute__((ext_vector_type(4)));
typedef _Float16 h16x2 __attribute__((ext_vector_type(2)));
typedef _Float16 h16x8 __attribute__((ext_vector_type(8)));

__device__ __forceinline__ float bf2f(unsigned short u) {
    return __uint_as_float(((unsigned int)u) << 16);
}
__device__ __forceinline__ unsigned short f2bf(float f) {
    unsigned int x = __float_as_uint(f);
    unsigned int r = (x + 0x7fffu + ((x >> 16) & 1u)) >> 16;
    return (unsigned short)r;
}
__device__ __forceinline__ float sigm(float x) {
    return 1.f / (1.f + __expf(-x));
}
__device__ __forceinline__ float dot2h(h16x2 a, h16x2 b, float c) {
#if __has_builtin(__builtin_amdgcn_fdot2)
    return __builtin_amdgcn_fdot2(a, b, c, false);
#else
    return c + (float)a[0] * (float)b[0] + (float)a[1] * (float)b[1];
#endif
}

// ---- build W2ext [32][1056] (fp32, msgC fallback only)
__global__ __launch_bounds__(256) void k_w2ext(const float* __restrict__ W2,
                                               const float* __restrict__ b2,
                                               float* __restrict__ W2ext) {
    int idx = blockIdx.x * 256 + threadIdx.x;
    if (idx >= 32 * QC) return;
    int i = idx / QC, c = idx % QC;
    float v;
    if (c < 1024) { int k = c >> 5, o = c & 31; v = W2[k * 1024 + i * 32 + o]; }
    else          { v = b2[i * 32 + (c - 1024)]; }
    W2ext[idx] = v;
}

// ---- merged weight prep
__global__ __launch_bounds__(256) void k_prepAll(
    const float* __restrict__ W2, const float* __restrict__ b2,
    unsigned short* __restrict__ W2bf,
    const float* __restrict__ Wi, const float* __restrict__ Wh,
    unsigned short* __restrict__ Whi, unsigned short* __restrict__ Wlo,
    const float* __restrict__ eencW, const float* __restrict__ eencB,
    const float* __restrict__ enW1, const float* __restrict__ enB1,
    float* __restrict__ Wcomb, float* __restrict__ bcomb) {
    int idx = blockIdx.x * 256 + threadIdx.x;
    if (idx < 66 * 512) {
        int ct = idx >> 9, l = (idx >> 3) & 63, j = idx & 7;
        int kk = ((j >> 2) << 4) + ((l >> 4) << 2) + (j & 3);
        int c = ct * 16 + (l & 15);
        float v;
        if (c < 1024) { int kb = c >> 5, o = c & 31; v = W2[kb * 1024 + kk * 32 + o]; }
        else          { v = b2[kk * 32 + (c - 1024)]; }
        W2bf[idx] = f2bf(v);
    } else if (idx < 66 * 512 + 6144) {
        int q = idx - 66 * 512;
        int j = q & 7, l = (q >> 3) & 63, kt = (q >> 9) & 1, nt = q >> 10;
        int k = ((j >> 2) << 4) + ((l >> 4) << 2) + (j & 3);
        int col = nt * 16 + (l & 15);
        float v = kt ? Wh[k * 96 + col] : Wi[k * 96 + col];
        unsigned short hi = f2bf(v);
        Whi[q] = hi;
        Wlo[q] = f2bf(v - bf2f(hi));
    } else if (idx < 66 * 512 + 6144 + 544) {
        int q = idx - 66 * 512 - 6144;
        if (q < 512) {
            int i = q >> 5, o = q & 31;
            float acc = 0.f;
            #pragma unroll 8
            for (int j = 0; j < 32; ++j) acc += eencW[i * 32 + j] * enW1[j * 32 + o];
            Wcomb[i * 32 + o] = acc;
        } else {
            int o = q - 512;
            float acc = enB1[o];
            #pragma unroll 8
            for (int j = 0; j < 32; ++j) acc += eencB[j] * enW1[j * 32 + o];
            bcomb[o] = acc;
        }
    }
}

// ---- merged histograms
__global__ __launch_bounds__(256) void k_histB(const int* __restrict__ src,
                                               const int* __restrict__ dst,
                                               int* __restrict__ bcS,
                                               int* __restrict__ bcD) {
    __shared__ int sHist[NTS];
    int tid = threadIdx.x, b = blockIdx.x;
    bool isS = b < HB;
    int bb = isS ? b : b - HB;
    const int* keys = isS ? src : dst;
    int NT = isS ? NTS : NT_D;
    int SH = isS ? 4 : 5;
    for (int c = tid; c < NT; c += 256) sHist[c] = 0;
    __syncthreads();
    int beg = bb * EPB, end = min(beg + EPB, NE);
    for (int e = beg + tid; e < end; e += 256)
        atomicAdd(&sHist[keys[e] >> SH], 1);
    __syncthreads();
    int* out = isS ? bcS : bcD;
    for (int c = tid; c < NT; c += 256) out[bb * NT + c] = sHist[c];
}

// ---- merged column sums
__global__ __launch_bounds__(256) void k_colsumB(const int* __restrict__ bcS,
                                                 const int* __restrict__ bcD,
                                                 int* __restrict__ bsS,
                                                 int* __restrict__ bsD,
                                                 int* __restrict__ totS,
                                                 int* __restrict__ totD) {
    int c = blockIdx.x * 256 + threadIdx.x;
    if (c < NTS) {
        int running = 0;
        #pragma unroll 8
        for (int b = 0; b < HB; ++b) {
            bsS[b * NTS + c] = running;
            running += bcS[b * NTS + c];
        }
        totS[c] = running;
    } else if (c < NTS + NT_D) {
        int cc = c - NTS;
        int running = 0;
        #pragma unroll 8
        for (int b = 0; b < HB; ++b) {
            bsD[b * NT_D + cc] = running;
            running += bcD[b * NT_D + cc];
        }
        totD[cc] = running;
    }
}

// ---- merged scans
__global__ __launch_bounds__(256) void k_scanB(const int* __restrict__ totS,
                                               const int* __restrict__ totD,
                                               int* __restrict__ offS,
                                               int* __restrict__ offD) {
    __shared__ int sTot[NTS];
    __shared__ int sPart[257];
    int tid = threadIdx.x;
    const int* tot = (blockIdx.x == 0) ? totS : totD;
    int* offs = (blockIdx.x == 0) ? offS : offD;
    int NT = (blockIdx.x == 0) ? NTS : NT_D;
    int SEG = (blockIdx.x == 0) ? 25 : 13;
    for (int c = tid; c < NT; c += 256) sTot[c] = tot[c];
    __syncthreads();
    int base = tid * SEG;
    int loc = 0;
    for (int j = 0; j < SEG; ++j) {
        int c = base + j;
        if (c < NT) { int v = sTot[c]; sTot[c] = loc; loc += v; }
    }
    sPart[tid] = loc;
    __syncthreads();
    if (tid == 0) {
        int s = 0;
        for (int i = 0; i < 256; ++i) { int v = sPart[i]; sPart[i] = s; s += v; }
        sPart[256] = s;
    }
    __syncthreads();
    int add = sPart[tid];
    for (int j = 0; j < SEG; ++j) {
        int c = base + j;
        if (c < NT) sTot[c] += add;
    }
    __syncthreads();
    for (int c = tid; c < NT; c += 256) offs[c] = sTot[c];
    if (tid == 0) offs[NT] = sPart[256];
}

// ---- merged scatters
__global__ __launch_bounds__(256) void k_scatterB(const int* __restrict__ src,
                                                  const int* __restrict__ dst,
                                                  const int* __restrict__ bsS,
                                                  const int* __restrict__ bsD,
                                                  const int* __restrict__ offS,
                                                  const int* __restrict__ offD,
                                                  int* __restrict__ epS,
                                                  int* __restrict__ epD) {
    __shared__ int sCur[NTS];
    int tid = threadIdx.x, b = blockIdx.x;
    bool isS = b < HB;
    int bb = isS ? b : b - HB;
    const int* keys = isS ? src : dst;
    const int* bs = isS ? bsS : bsD;
    const int* offs = isS ? offS : offD;
    int* ep = isS ? epS : epD;
    int NT = isS ? NTS : NT_D;
    int SH = isS ? 4 : 5;
    for (int c = tid; c < NT; c += 256)
        sCur[c] = offs[c] + bs[bb * NT + c];
    __syncthreads();
    int beg = bb * EPB, end = min(beg + EPB, NE);
    for (int e = beg + tid; e < end; e += 256) {
        int pos = atomicAdd(&sCur[keys[e] >> SH], 1);
        ep[pos] = e;
    }
}

// ---- merged invperm + src gather
__global__ __launch_bounds__(256) void k_invgather(const int* __restrict__ epermS,
                                                   const int* __restrict__ src,
                                                   int* __restrict__ posS,
                                                   int* __restrict__ srcS) {
    int p = blockIdx.x * 256 + threadIdx.x;
    if (p < NE) {
        int e = epermS[p];
        posS[e] = p;
        srcS[p] = src[e];
    }
}

// ---- node encoder + projection: 32 nodes/block
__global__ __launch_bounds__(256) void k_node_enc(
    const int* __restrict__ nfeats, const float* __restrict__ emb,
    const float* __restrict__ encW, const float* __restrict__ encB,
    const float* __restrict__ projW, const float* __restrict__ projB,
    float* __restrict__ h) {
    __shared__ float sEncW[1024], sProjW[1024], sEncB[32], sProjB[32];
    __shared__ float sEmb[8][33], sNh[8][33];
    int tid = threadIdx.x;
    for (int i = tid; i < 1024; i += 256) { sEncW[i] = encW[i]; sProjW[i] = projW[i]; }
    if (tid < 32) { sEncB[tid] = encB[tid]; sProjB[tid] = projB[tid]; }
    int ln = tid >> 5, o = tid & 31;
    for (int g = 0; g < 4; ++g) {
        int node = blockIdx.x * 32 + g * 8 + ln;
        int nt = nfeats[node];
        float ev = fmaxf(emb[nt * 32 + o], 0.f);
        __syncthreads();
        sEmb[ln][o] = ev;
        __syncthreads();
        float acc = sEncB[o];
        #pragma unroll
        for (int i = 0; i < 32; ++i) acc += sEmb[ln][i] * sEncW[i * 32 + o];
        sNh[ln][o] = fmaxf(acc, 0.f);
        __syncthreads();
        float acc2 = sProjB[o];
        #pragma unroll
        for (int i = 0; i < 32; ++i) acc2 += sNh[ln][i] * sProjW[i * 32 + o];
        h[node * 32 + o] = fmaxf(acc2, 0.f);
    }
}

// ---- edge encoder (folded), f16 output
__global__ __launch_bounds__(256) void k_edge_t3h(
    const float* __restrict__ efeats, const float* __restrict__ Wcomb,
    const float* __restrict__ bcomb, const int* __restrict__ eperm,
    unsigned short* __restrict__ tS) {
    int tid = threadIdx.x;
    int el = tid >> 3, l8 = tid & 7;
    int gbase = (tid & 63) & 56;
    int c0 = l8 << 2;
    float4 w[16];
    #pragma unroll
    for (int i = 0; i < 16; ++i) w[i] = *(const float4*)(Wcomb + i * 32 + c0);
    float4 bb = *(const float4*)(bcomb + c0);
    #pragma unroll
    for (int it = 0; it < 4; ++it) {
        int p = blockIdx.x * 128 + it * 32 + el;
        int e = eperm ? eperm[p] : p;
        float2 efv = *(const float2*)(efeats + (size_t)e * 16 + (l8 << 1));
        float a0 = bb.x, a1 = bb.y, a2 = bb.z, a3 = bb.w;
        #pragma unroll
        for (int i = 0; i < 8; ++i) {
            float f0 = __shfl(efv.x, gbase + i, 64);
            float f1 = __shfl(efv.y, gbase + i, 64);
            float4 w0 = w[2 * i], w1 = w[2 * i + 1];
            a0 += f0 * w0.x + f1 * w1.x;
            a1 += f0 * w0.y + f1 * w1.y;
            a2 += f0 * w0.z + f1 * w1.z;
            a3 += f0 * w0.w + f1 * w1.w;
        }
        _Float16 h0 = (_Float16)fmaxf(a0, 0.f);
        _Float16 h1 = (_Float16)fmaxf(a1, 0.f);
        _Float16 h2 = (_Float16)fmaxf(a2, 0.f);
        _Float16 h3 = (_Float16)fmaxf(a3, 0.f);
        ushort4 o4;
        o4.x = *(unsigned short*)&h0; o4.y = *(unsigned short*)&h1;
        o4.z = *(unsigned short*)&h2; o4.w = *(unsigned short*)&h3;
        *(ushort4*)(tS + (size_t)p * 32 + c0) = o4;
    }
}

// ---- edge encoder fp32 output (msgC fallback only)
__global__ __launch_bounds__(256) void k_edge_t3(
    const float* __restrict__ efeats, const float* __restrict__ Wcomb,
    const float* __restrict__ bcomb, const int* __restrict__ eperm,
    float* __restrict__ tS) {
    int tid = threadIdx.x;
    int el = tid >> 3, l8 = tid & 7;
    int gbase = (tid & 63) & 56;
    int c0 = l8 << 2;
    float4 w[16];
    #pragma unroll
    for (int i = 0; i < 16; ++i) w[i] = *(const float4*)(Wcomb + i * 32 + c0);
    float4 bb = *(const float4*)(bcomb + c0);
    #pragma unroll
    for (int it = 0; it < 4; ++it) {
        int p = blockIdx.x * 128 + it * 32 + el;
        int e = eperm ? eperm[p] : p;
        float2 efv = *(const float2*)(efeats + (size_t)e * 16 + (l8 << 1));
        float a0 = bb.x, a1 = bb.y, a2 = bb.z, a3 = bb.w;
        #pragma unroll
        for (int i = 0; i < 8; ++i) {
            float f0 = __shfl(efv.x, gbase + i, 64);
            float f1 = __shfl(efv.y, gbase + i, 64);
            float4 w0 = w[2 * i], w1 = w[2 * i + 1];
            a0 += f0 * w0.x + f1 * w1.x;
            a1 += f0 * w0.y + f1 * w1.y;
            a2 += f0 * w0.z + f1 * w1.z;
            a3 += f0 * w0.w + f1 * w1.w;
        }
        *(float4*)(tS + (size_t)p * 32 + c0) =
            make_float4(fmaxf(a0, 0.f), fmaxf(a1, 0.f), fmaxf(a2, 0.f), fmaxf(a3, 0.f));
    }
}

// ---- legacy single-purpose bucketing kernels (fallback modes only)
template<int NT, int SHIFT>
__global__ __launch_bounds__(256) void k_histT(const int* __restrict__ keys,
                                               int* __restrict__ blockCounts) {
    __shared__ int sHist[NT];
    int tid = threadIdx.x, b = blockIdx.x;
    for (int c = tid; c < NT; c += 256) sHist[c] = 0;
    __syncthreads();
    int beg = b * EPB, end = min(beg + EPB, NE);
    for (int e = beg + tid; e < end; e += 256)
        atomicAdd(&sHist[keys[e] >> SHIFT], 1);
    __syncthreads();
    for (int c = tid; c < NT; c += 256) blockCounts[b * NT + c] = sHist[c];
}

template<int NT>
__global__ __launch_bounds__(256) void k_colsumT(const int* __restrict__ blockCounts,
                                                 int* __restrict__ blockStart,
                                                 int* __restrict__ tileTot) {
    int c = blockIdx.x * 256 + threadIdx.x;
    if (c >= NT) return;
    int running = 0;
    #pragma unroll 8
    for (int b = 0; b < HB; ++b) {
        blockStart[b * NT + c] = running;
        running += blockCounts[b * NT + c];
    }
    tileTot[c] = running;
}

template<int NT, int SEG>
__global__ __launch_bounds__(256) void k_scanT(const int* __restrict__ tileTot,
                                               int* __restrict__ offs) {
    __shared__ int sTot[NT];
    __shared__ int sPart[257];
    int tid = threadIdx.x;
    for (int c = tid; c < NT; c += 256) sTot[c] = tileTot[c];
    __syncthreads();
    int base = tid * SEG;
    int loc = 0;
    for (int j = 0; j < SEG; ++j) {
        int c = base + j;
        if (c < NT) { int v = sTot[c]; sTot[c] = loc; loc += v; }
    }
    sPart[tid] = loc;
    __syncthreads();
    if (tid == 0) {
        int s = 0;
        for (int i = 0; i < 256; ++i) { int v = sPart[i]; sPart[i] = s; s += v; }
        sPart[256] = s;
    }
    __syncthreads();
    int add = sPart[tid];
    for (int j = 0; j < SEG; ++j) {
        int c = base + j;
        if (c < NT) sTot[c] += add;
    }
    __syncthreads();
    for (int c = tid; c < NT; c += 256) offs[c] = sTot[c];
    if (tid == 0) offs[NT] = sPart[256];
}

template<int NT, int SHIFT>
__global__ __launch_bounds__(256) void k_scatterT(const int* __restrict__ keys,
                                                  const int* __restrict__ blockStart,
                                                  const int* __restrict__ offs,
                                                  int* __restrict__ eperm) {
    __shared__ int sCur[NT];
    int tid = threadIdx.x, b = blockIdx.x;
    for (int c = tid; c < NT; c += 256)
        sCur[c] = offs[c] + blockStart[b * NT + c];
    __syncthreads();
    int beg = b * EPB, end = min(beg + EPB, NE);
    for (int e = beg + tid; e < end; e += 256) {
        int pos = atomicAdd(&sCur[keys[e] >> SHIFT], 1);
        eperm[pos] = e;
    }
}

// ---- second-level sort: within each dst tile, sort by node (32 LDS bins)
__global__ __launch_bounds__(256) void k_sortNode(
    const int* __restrict__ epermD, const int* __restrict__ dst,
    const int* __restrict__ offsD, int* __restrict__ epermD2,
    int* __restrict__ nodeOffs) {
    __shared__ int sCnt[32], sStart[32];
    int tid = threadIdx.x, d = blockIdx.x;
    int beg = offsD[d], end = offsD[d + 1];
    if (tid < 32) sCnt[tid] = 0;
    __syncthreads();
    for (int p = beg + tid; p < end; p += 256)
        atomicAdd(&sCnt[dst[epermD[p]] & 31], 1);
    __syncthreads();
    if (tid == 0) {
        int s = beg;
        for (int r = 0; r < 32; ++r) { sStart[r] = s; s += sCnt[r]; }
    }
    __syncthreads();
    if (tid < 32) {
        nodeOffs[d * 32 + tid] = sStart[tid];
        sCnt[tid] = sStart[tid];
    }
    if (d == NT_D - 1 && tid == 0) nodeOffs[NN] = end;
    __syncthreads();
    for (int p = beg + tid; p < end; p += 256) {
        int e = epermD[p];
        int pos = atomicAdd(&sCnt[dst[e] & 31], 1);
        epermD2[pos] = e;
    }
}

// ---- inverse permutation (fallback path)
__global__ __launch_bounds__(256) void k_invperm(const int* __restrict__ eperm,
                                                 int* __restrict__ pos) {
    int p = blockIdx.x * 256 + threadIdx.x;
    if (p < NE) pos[eperm[p]] = p;
}

// ---- gather key (fallback path)
__global__ __launch_bounds__(256) void k_gatherKey(const int* __restrict__ epermS,
                                                   const int* __restrict__ key,
                                                   int* __restrict__ out) {
    int p = blockIdx.x * 256 + threadIdx.x;
    if (p < NE) out[p] = key[epermS[p]];
}

// ---- idxS[posS[epermD2[q]]] = q
__global__ __launch_bounds__(256) void k_scatterIdx(const int* __restrict__ epermD2,
                                                    const int* __restrict__ posS,
                                                    int* __restrict__ idxS) {
    int q = blockIdx.x * 256 + threadIdx.x;
    if (q < NE) idxS[posS[epermD2[q]]] = q;
}

// ---- fused per-16-node-src-tile: MFMA Q -> f16 LDS (k-pair interleaved),
// edge stream: 4 lanes/edge x 8 outputs via v_dot2_f32_f16.
template<int MODE>
__global__ __launch_bounds__(256) void k_msgF16(
    const float* __restrict__ h, const unsigned short* __restrict__ W2bf,
    const unsigned short* __restrict__ tS, const int* __restrict__ srcS,
    const int* __restrict__ idxS, const int* __restrict__ offs,
    float* __restrict__ outbuf) {
    __shared__ unsigned short sQ[16 * QSTRH];
    int tid = threadIdx.x;
    int tile = blockIdx.x;
    int beg = offs[tile], end = offs[tile + 1];
    if (beg >= end) return;
    int nodeBase = tile * 16;
    int wave = tid >> 6, lane = tid & 63;

    int arow = lane & 15;
    const float* hp = h + (size_t)(nodeBase + arow) * 32 + ((lane >> 4) << 2);
    float4 x0 = *(const float4*)hp;
    float4 x1 = *(const float4*)(hp + 16);
    bf16x8 a;
    a[0] = (short)f2bf(x0.x); a[1] = (short)f2bf(x0.y);
    a[2] = (short)f2bf(x0.z); a[3] = (short)f2bf(x0.w);
    a[4] = (short)f2bf(x1.x); a[5] = (short)f2bf(x1.y);
    a[6] = (short)f2bf(x1.z); a[7] = (short)f2bf(x1.w);

    f32x4 z = {0.f, 0.f, 0.f, 0.f};
    int crow0 = (lane >> 4) << 2;
    int ccol = lane & 15;
    for (int ct = wave; ct < 66; ct += 4) {
        bf16x8 b = *(const bf16x8*)(W2bf + (size_t)((ct << 6) + lane) * 8);
        f32x4 acc = __builtin_amdgcn_mfma_f32_16x16x32_bf16(a, b, z, 0, 0, 0);
        int c = (ct << 4) + ccol;
        int idx;
        if (c < 1024) {
            int k = c >> 5, o = c & 31;
            idx = ((k >> 1) << 6) + (o << 1) + (k & 1);
        } else {
            idx = 1024 + (c - 1024);
        }
        unsigned short* qp = sQ + crow0 * QSTRH + idx;
        _Float16 v0 = (_Float16)acc[0], v1 = (_Float16)acc[1];
        _Float16 v2 = (_Float16)acc[2], v3 = (_Float16)acc[3];
        qp[0 * QSTRH] = *(unsigned short*)&v0;
        qp[1 * QSTRH] = *(unsigned short*)&v1;
        qp[2 * QSTRH] = *(unsigned short*)&v2;
        qp[3 * QSTRH] = *(unsigned short*)&v3;
    }
    __syncthreads();

    int el = tid >> 2, l4 = tid & 3;
    int o0 = l4 << 3;
    for (int p = beg + el; p < end; p += 64) {
        int row = srcS[p] - nodeBase;
        int widx = idxS[p];
        h16x8 trow[4];
        #pragma unroll
        for (int i = 0; i < 4; ++i)
            trow[i] = *(const h16x8*)(tS + (size_t)p * 32 + (i << 3));
        const unsigned short* qp = sQ + row * QSTRH;
        h16x8 qb = *(const h16x8*)(qp + 1024 + o0);
        float acc[8];
        #pragma unroll
        for (int j = 0; j < 8; ++j) acc[j] = (float)qb[j];
        #pragma unroll
        for (int kp = 0; kp < 16; ++kp) {
            h16x2 t2;
            t2[0] = trow[kp >> 2][(kp & 3) * 2];
            t2[1] = trow[kp >> 2][(kp & 3) * 2 + 1];
            h16x8 qa = *(const h16x8*)(qp + (kp << 6) + (o0 << 1));
            h16x8 qc = *(const h16x8*)(qp + (kp << 6) + (o0 << 1) + 8);
            #pragma unroll
            for (int j = 0; j < 4; ++j) {
                h16x2 q2a; q2a[0] = qa[2 * j]; q2a[1] = qa[2 * j + 1];
                h16x2 q2c; q2c[0] = qc[2 * j]; q2c[1] = qc[2 * j + 1];
                acc[j]     = dot2h(t2, q2a, acc[j]);
                acc[4 + j] = dot2h(t2, q2c, acc[4 + j]);
            }
        }
        if (MODE) {
            float* op = outbuf + (size_t)widx * 32 + o0;
            *(float4*)op = make_float4(acc[0], acc[1], acc[2], acc[3]);
            *(float4*)(op + 4) = make_float4(acc[4], acc[5], acc[6], acc[7]);
        } else {
            float* op = outbuf + (size_t)widx * 32 + o0;
            #pragma unroll
            for (int j = 0; j < 8; ++j) atomicAdd(op + j, acc[j]);
        }
    }
}

// ---- fallback msg (tiny ws)
__global__ __launch_bounds__(256) void k_msgC(
    const float* __restrict__ t, const int* __restrict__ src, const int* __restrict__ dst,
    const float* __restrict__ h, const float* __restrict__ W2ext, float* __restrict__ agg) {
    __shared__ float sT[32][33], sH[32][33];
    __shared__ int sSrc[32], sDst[32];
    int tid = threadIdx.x;
    int e0 = blockIdx.x * 32;
    if (tid < 32) sSrc[tid] = src[e0 + tid];
    else if (tid < 64) sDst[tid - 32] = dst[e0 + tid - 32];
    __syncthreads();
    for (int idx = tid; idx < 1024; idx += 256) {
        int el = idx >> 5, k = idx & 31;
        sT[el][k] = t[(e0 + el) * 32 + k];
        sH[el][k] = h[(size_t)sSrc[el] * 32 + k];
    }
    __syncthreads();
    int el = tid >> 3, l8 = tid & 7;
    int c0 = l8 * 4;
    float m0 = 0.f, m1 = 0.f, m2 = 0.f, m3 = 0.f;
    for (int i = 0; i < 32; ++i) {
        const float* wrow = W2ext + i * QC;
        float4 wb = *(const float4*)(wrow + 1024 + c0);
        float w0 = wb.x, w1 = wb.y, w2 = wb.z, w3 = wb.w;
        #pragma unroll 8
        for (int k = 0; k < 32; ++k) {
            float tk = sT[el][k];
            float4 w = *(const float4*)(wrow + k * 32 + c0);
            w0 += tk * w.x; w1 += tk * w.y; w2 += tk * w.z; w3 += tk * w.w;
        }
        float hi = sH[el][i];
        m0 += hi * w0; m1 += hi * w1; m2 += hi * w2; m3 += hi * w3;
    }
    float* ap = agg + (size_t)sDst[el] * 32 + c0;
    atomicAdd(ap + 0, m0); atomicAdd(ap + 1, m1);
    atomicAdd(ap + 2, m2); atomicAdd(ap + 3, m3);
}

// ---- GRU step reading agg[] (MODE 0 / fallback)
__global__ __launch_bounds__(256) void k_gru(
    const float* __restrict__ agg, const float* __restrict__ convB,
    const float* __restrict__ Wi, const float* __restrict__ Wh,
    const float* __restrict__ bi, const float* __restrict__ bh,
    float* __restrict__ h) {
    __shared__ float sWi[3072], sWh[3072], sBi[96], sBh[96], sCb[32];
    __shared__ float sX[8][33], sH[8][33];
    int tid = threadIdx.x;
    for (int i = tid; i < 3072; i += 256) { sWi[i] = Wi[i]; sWh[i] = Wh[i]; }
    if (tid < 96) { sBi[tid] = bi[tid]; sBh[tid] = bh[tid]; }
    if (tid < 32) sCb[tid] = convB[tid];
    int ln = tid >> 5, o = tid & 31;
    for (int g = 0; g < 4; ++g) {
        int node = blockIdx.x * 32 + g * 8 + ln;
        float hv = h[node * 32 + o];
        float av = agg[node * 32 + o];
        __syncthreads();
        sX[ln][o] = fmaxf(av + sCb[o], 0.f);
        sH[ln][o] = hv;
        __syncthreads();
        float air = sBi[o], aiz = sBi[o + 32], ain = sBi[o + 64];
        float ahr = sBh[o], ahz = sBh[o + 32], ahn = sBh[o + 64];
        #pragma unroll 8
        for (int i = 0; i < 32; ++i) {
            float x = sX[ln][i], hh = sH[ln][i];
            air += x * sWi[i * 96 + o];      ahr += hh * sWh[i * 96 + o];
            aiz += x * sWi[i * 96 + o + 32]; ahz += hh * sWh[i * 96 + o + 32];
            ain += x * sWi[i * 96 + o + 64]; ahn += hh * sWh[i * 96 + o + 64];
        }
        float r = sigm(air + ahr);
        float zz = sigm(aiz + ahz);
        float ng = tanhf(ain + r * ahn);
        h[node * 32 + o] = (1.f - zz) * ng + zz * hv;
    }
}

// ---- MODE 1: per 32-node dst tile: segment-sum -> X in LDS, GRU via split-bf16 MFMA.
// DEC=1 (last step): fused 4-layer decoder, all 32 nodes in parallel, 4 barriers.
template<int DEC>
__global__ __launch_bounds__(256) void k_gruAgg4(
    const float* __restrict__ msgbuf, const int* __restrict__ nodeOffs,
    const float* __restrict__ convB,
    const unsigned short* __restrict__ Whi, const unsigned short* __restrict__ Wlo,
    const float* __restrict__ bi, const float* __restrict__ bh,
    float* __restrict__ h,
    const float* __restrict__ W1, const float* __restrict__ b1, const float* __restrict__ a1,
    const float* __restrict__ W2, const float* __restrict__ b2, const float* __restrict__ a2,
    const float* __restrict__ W3, const float* __restrict__ b3, const float* __restrict__ a3,
    const float* __restrict__ W4, const float* __restrict__ b4,
    float* __restrict__ out) {
    __shared__ float sAgg[32 * 33];
    int tid = threadIdx.x;
    int d = blockIdx.x;
    int base = d * 32;

    {
        int n8 = tid >> 3, l8 = tid & 7;
        int node = base + n8;
        int nb = nodeOffs[node], ne2 = nodeOffs[node + 1];
        float a0 = 0.f, a1v = 0.f, a2v = 0.f, a3v = 0.f;
        for (int p = nb; p < ne2; ++p) {
            float4 v = *(const float4*)(msgbuf + (size_t)p * 32 + (l8 << 2));
            a0 += v.x; a1v += v.y; a2v += v.z; a3v += v.w;
        }
        int c0 = l8 << 2;
        float4 cb = *(const float4*)(convB + c0);
        float* sp = sAgg + n8 * 33 + c0;
        sp[0] = fmaxf(a0 + cb.x, 0.f);
        sp[1] = fmaxf(a1v + cb.y, 0.f);
        sp[2] = fmaxf(a2v + cb.z, 0.f);
        sp[3] = fmaxf(a3v + cb.w, 0.f);
    }
    __syncthreads();

    int wave = tid >> 6, lane = tid & 63;
    int m = wave >> 1, c = wave & 1;
    int arow = lane & 15, kg = (lane >> 4) << 2;

    bf16x8 xhi, xlo, hhi, hlo;
    {
        const float* xp = sAgg + (m * 16 + arow) * 33 + kg;
        float4 v0 = *(const float4*)xp;
        float4 v1 = *(const float4*)(xp + 16);
        float xv[8] = {v0.x, v0.y, v0.z, v0.w, v1.x, v1.y, v1.z, v1.w};
        #pragma unroll
        for (int j = 0; j < 8; ++j) {
            unsigned short hi16 = f2bf(xv[j]);
            xhi[j] = (short)hi16;
            xlo[j] = (short)f2bf(xv[j] - bf2f(hi16));
        }
        const float* hp = h + (size_t)(base + m * 16 + arow) * 32 + kg;
        float4 w0 = *(const float4*)hp;
        float4 w1 = *(const float4*)(hp + 16);
        float hv8[8] = {w0.x, w0.y, w0.z, w0.w, w1.x, w1.y, w1.z, w1.w};
        #pragma unroll
        for (int j = 0; j < 8; ++j) {
            unsigned short hi16 = f2bf(hv8[j]);
            hhi[j] = (short)hi16;
            hlo[j] = (short)f2bf(hv8[j] - bf2f(hi16));
        }
    }

    int ccol = lane & 15, crow0 = (lane >> 4) << 2;
    int o = c * 16 + ccol;
    auto Bf = [&](int nt, int kt, const unsigned short* W) {
        return *(const bf16x8*)(W + (size_t)(((nt * 2 + kt) * 64 + lane) << 3));
    };
    f32x4 accR = {0.f, 0.f, 0.f, 0.f}, accZ = {0.f, 0.f, 0.f, 0.f};
    f32x4 accIN = {0.f, 0.f, 0.f, 0.f}, accHN = {0.f, 0.f, 0.f, 0.f};
    {
        int nt = c;
        bf16x8 b0h = Bf(nt, 0, Whi), b0l = Bf(nt, 0, Wlo);
        bf16x8 b1h = Bf(nt, 1, Whi), b1l = Bf(nt, 1, Wlo);
        accR = __builtin_amdgcn_mfma_f32_16x16x32_bf16(xhi, b0h, accR, 0, 0, 0);
        accR = __builtin_amdgcn_mfma_f32_16x16x32_bf16(xlo, b0h, accR, 0, 0, 0);
        accR = __builtin_amdgcn_mfma_f32_16x16x32_bf16(xhi, b0l, accR, 0, 0, 0);
        accR = __builtin_amdgcn_mfma_f32_16x16x32_bf16(hhi, b1h, accR, 0, 0, 0);
        accR = __builtin_amdgcn_mfma_f32_16x16x32_bf16(hlo, b1h, accR, 0, 0, 0);
        accR = __builtin_amdgcn_mfma_f32_16x16x32_bf16(hhi, b1l, accR, 0, 0, 0);
    }
    {
        int nt = 2 + c;
        bf16x8 b0h = Bf(nt, 0, Whi), b0l = Bf(nt, 0, Wlo);
        bf16x8 b1h = Bf(nt, 1, Whi), b1l = Bf(nt, 1, Wlo);
        accZ = __builtin_amdgcn_mfma_f32_16x16x32_bf16(xhi, b0h, accZ, 0, 0, 0);
        accZ = __builtin_amdgcn_mfma_f32_16x16x32_bf16(xlo, b0h, accZ, 0, 0, 0);
        accZ = __builtin_amdgcn_mfma_f32_16x16x32_bf16(xhi, b0l, accZ, 0, 0, 0);
        accZ = __builtin_amdgcn_mfma_f32_16x16x32_bf16(hhi, b1h, accZ, 0, 0, 0);
        accZ = __builtin_amdgcn_mfma_f32_16x16x32_bf16(hlo, b1h, accZ, 0, 0, 0);
        accZ = __builtin_amdgcn_mfma_f32_16x16x32_bf16(hhi, b1l, accZ, 0, 0, 0);
    }
    {
        int nt = 4 + c;
        bf16x8 b0h = Bf(nt, 0, Whi), b0l = Bf(nt, 0, Wlo);
        bf16x8 b1h = Bf(nt, 1, Whi), b1l = Bf(nt, 1, Wlo);
        accIN = __builtin_amdgcn_mfma_f32_16x16x32_bf16(xhi, b0h, accIN, 0, 0, 0);
        accIN = __builtin_amdgcn_mfma_f32_16x16x32_bf16(xlo, b0h, accIN, 0, 0, 0);
        accIN = __builtin_amdgcn_mfma_f32_16x16x32_bf16(xhi, b0l, accIN, 0, 0, 0);
        accHN = __builtin_amdgcn_mfma_f32_16x16x32_bf16(hhi, b1h, accHN, 0, 0, 0);
        accHN = __builtin_amdgcn_mfma_f32_16x16x32_bf16(hlo, b1h, accHN, 0, 0, 0);
        accHN = __builtin_amdgcn_mfma_f32_16x16x32_bf16(hhi, b1l, accHN, 0, 0, 0);
    }

    float bir = bi[o], biz = bi[32 + o], bin = bi[64 + o];
    float bhr = bh[o], bhz = bh[32 + o], bhn = bh[64 + o];
    float hv[4];
    #pragma unroll
    for (int j = 0; j < 4; ++j)
        hv[j] = h[(size_t)(base + m * 16 + crow0 + j) * 32 + o];
    __syncthreads();    // all h reads complete before any h writes
    float nh[4];
    #pragma unroll
    for (int j = 0; j < 4; ++j) {
        float r  = sigm(accR[j] + bir + bhr);
        float zz = sigm(accZ[j] + biz + bhz);
        float ng = tanhf(accIN[j] + bin + r * (accHN[j] + bhn));
        nh[j] = (1.f - zz) * ng + zz * hv[j];
        h[(size_t)(base + m * 16 + crow0 + j) * 32 + o] = nh[j];
    }

    if constexpr (DEC) {
        __shared__ float sYa[32 * 33];
        __shared__ float sYb[32 * 33];
        __shared__ float sW1[1024], sW2[1024], sW3[1024], sW4[96];
        __shared__ float sB1[32], sB2[32], sB3[32], sB4[3];
        #pragma unroll
        for (int j = 0; j < 4; ++j)
            sYa[(m * 16 + crow0 + j) * 33 + o] = nh[j];
        for (int i = tid; i < 1024; i += 256) { sW1[i] = W1[i]; sW2[i] = W2[i]; sW3[i] = W3[i]; }
        if (tid < 96) sW4[tid] = W4[tid];
        if (tid < 32) { sB1[tid] = b1[tid]; sB2[tid] = b2[tid]; sB3[tid] = b3[tid]; }
        if (tid < 3) sB4[tid] = b4[tid];
        float A1 = a1[0], A2 = a2[0], A3 = a3[0];
        int n8 = tid >> 3, l8 = tid & 7, c0 = l8 << 2;
        __syncthreads();
        {
            float y0 = sB1[c0], y1 = sB1[c0 + 1], y2 = sB1[c0 + 2], y3 = sB1[c0 + 3];
            const float* yp = sYa + n8 * 33;
            #pragma unroll 8
            for (int i = 0; i < 32; ++i) {
                float v = yp[i];
                float4 w = *(const float4*)(sW1 + i * 32 + c0);
                y0 += v * w.x; y1 += v * w.y; y2 += v * w.z; y3 += v * w.w;
            }
            float* op = sYb + n8 * 33 + c0;
            op[0] = y0 >= 0.f ? y0 : A1 * y0;
            op[1] = y1 >= 0.f ? y1 : A1 * y1;
            op[2] = y2 >= 0.f ? y2 : A1 * y2;
            op[3] = y3 >= 0.f ? y3 : A1 * y3;
        }
        __syncthreads();
        {
            float y0 = sB2[c0], y1 = sB2[c0 + 1], y2 = sB2[c0 + 2], y3 = sB2[c0 + 3];
            const float* yp = sYb + n8 * 33;
            #pragma unroll 8
            for (int i = 0; i < 32; ++i) {
                float v = yp[i];
                float4 w = *(const float4*)(sW2 + i * 32 + c0);
                y0 += v * w.x; y1 += v * w.y; y2 += v * w.z; y3 += v * w.w;
            }
            float* op = sYa + n8 * 33 + c0;
            op[0] = y0 >= 0.f ? y0 : A2 * y0;
            op[1] = y1 >= 0.f ? y1 : A2 * y1;
            op[2] = y2 >= 0.f ? y2 : A2 * y2;
            op[3] = y3 >= 0.f ? y3 : A2 * y3;
        }
        __syncthreads();
        {
            float y0 = sB3[c0], y1 = sB3[c0 + 1], y2 = sB3[c0 + 2], y3 = sB3[c0 + 3];
            const float* yp = sYa + n8 * 33;
            #pragma unroll 8
            for (int i = 0; i < 32; ++i) {
                float v = yp[i];
                float4 w = *(const float4*)(sW3 + i * 32 + c0);
                y0 += v * w.x; y1 += v * w.y; y2 += v * w.z; y3 += v * w.w;
            }
            float* op = sYb + n8 * 33 + c0;
            op[0] = y0 >= 0.f ? y0 : A3 * y0;
            op[1] = y1 >= 0.f ? y1 : A3 * y1;
            op[2] = y2 >= 0.f ? y2 : A3 * y2;
            op[3] = y3 >= 0.f ? y3 : A3 * y3;
        }
        __syncthreads();
        if (l8 < 3) {
            float r = sB4[l8];
            const float* yp = sYb + n8 * 33;
            #pragma unroll 8
            for (int i = 0; i < 32; ++i) r += yp[i] * sW4[i * 3 + l8];
            out[(size_t)(base + n8) * 3 + l8] = r;
        }
    }
}

// ---- decoder (fallback modes only)
__global__ __launch_bounds__(256) void k_dec(
    const float* __restrict__ h,
    const float* __restrict__ W1, const float* __restrict__ b1, const float* __restrict__ a1,
    const float* __restrict__ W2, const float* __restrict__ b2, const float* __restrict__ a2,
    const float* __restrict__ W3, const float* __restrict__ b3, const float* __restrict__ a3,
    const float* __restrict__ W4, const float* __restrict__ b4,
    float* __restrict__ out) {
    __shared__ float sW1[1024], sW2[1024], sW3[1024], sW4[96];
    __shared__ float sB1[32], sB2[32], sB3[32], sB4[3];
    __shared__ float sYa[8][33], sYb[8][33];
    int tid = threadIdx.x;
    for (int i = tid; i < 1024; i += 256) { sW1[i] = W1[i]; sW2[i] = W2[i]; sW3[i] = W3[i]; }
    if (tid < 96) sW4[tid] = W4[tid];
    if (tid < 32) { sB1[tid] = b1[tid]; sB2[tid] = b2[tid]; sB3[tid] = b3[tid]; }
    if (tid < 3) sB4[tid] = b4[tid];
    float A1 = a1[0], A2 = a2[0], A3 = a3[0];
    int ln = tid >> 5, o = tid & 31;
    for (int g = 0; g < 4; ++g) {
        int node = blockIdx.x * 32 + g * 8 + ln;
        float hv = h[node * 32 + o];
        __syncthreads();
        sYa[ln][o] = hv;
        __syncthreads();
        float acc = sB1[o];
        #pragma unroll
        for (int i = 0; i < 32; ++i) acc += sYa[ln][i] * sW1[i * 32 + o];
        acc = acc >= 0.f ? acc : A1 * acc;
        sYb[ln][o] = acc;
        __syncthreads();
        acc = sB2[o];
        #pragma unroll
        for (int i = 0; i < 32; ++i) acc += sYb[ln][i] * sW2[i * 32 + o];
        acc = acc >= 0.f ? acc : A2 * acc;
        __syncthreads();
        sYa[ln][o] = acc;
        __syncthreads();
        acc = sB3[o];
        #pragma unroll
        for (int i = 0; i < 32; ++i) acc += sYa[ln][i] * sW3[i * 32 + o];
        acc = acc >= 0.f ? acc : A3 * acc;
        __syncthreads();
        sYb[ln][o] = acc;
        __syncthreads();
        if (o < 3) {
            float r = sB4[o];
            #pragma unroll
            for (int i = 0; i < 32; ++i) r += sYb[ln][i] * sW4[i * 3 + o];
            out[node * 3 + o] = r;
        }
    }
}

extern "C" void kernel_launch(void* const* d_in, const int* in_sizes, int n_in,
                              void* d_out, int out_size, void* d_ws, size_t ws_size,
                              hipStream_t stream) {
    const int*   nfeats = (const int*)d_in[0];
    const float* efeats = (const float*)d_in[1];
    const int*   src    = (const int*)d_in[2];
    const int*   dst    = (const int*)d_in[3];
    const float* emb    = (const float*)d_in[4];
    const float* encW   = (const float*)d_in[5];
    const float* encB   = (const float*)d_in[6];
    const float* eencW  = (const float*)d_in[7];
    const float* eencB  = (const float*)d_in[8];
    const float* projW  = (const float*)d_in[9];
    const float* projB  = (const float*)d_in[10];
    const float* enW1   = (const float*)d_in[11];
    const float* enB1   = (const float*)d_in[12];
    const float* enW2   = (const float*)d_in[13];
    const float* enB2   = (const float*)d_in[14];
    const float* convB  = (const float*)d_in[15];
    const float* gruWi  = (const float*)d_in[16];
    const float* gruWh  = (const float*)d_in[17];
    const float* gruBi  = (const float*)d_in[18];
    const float* gruBh  = (const float*)d_in[19];
    const float* dW1 = (const float*)d_in[20]; const float* db1 = (const float*)d_in[21]; const float* da1 = (const float*)d_in[22];
    const float* dW2 = (const float*)d_in[23]; const float* db2 = (const float*)d_in[24]; const float* da2 = (const float*)d_in[25];
    const float* dW3 = (const float*)d_in[26]; const float* db3 = (const float*)d_in[27]; const float* da3 = (const float*)d_in[28];
    const float* dW4 = (const float*)d_in[29]; const float* db4 = (const float*)d_in[30];
    float* out = (float*)d_out;
    char* ws = (char*)d_ws;

    // bump allocator (256-B aligned)
    size_t cur = 0;
    auto alloc = [&](size_t n) { size_t p = cur; cur = (cur + n + 255) & ~(size_t)255; return p; };
    size_t o_h   = alloc((size_t)NN * 32 * 4);
    size_t o_t   = alloc((size_t)NE * 32 * 4);
    size_t o_w2e = alloc((size_t)32 * QC * 4);
    size_t afterCommon = cur;
    size_t o_w2b = alloc((size_t)66 * 512 * 2);
    size_t o_epS = alloc((size_t)NE * 4);
    size_t o_ofS = alloc((size_t)(NTS + 1) * 4);
    size_t o_posS = alloc((size_t)NE * 4);
    size_t o_srcS = alloc((size_t)NE * 4);
    size_t o_idxS = alloc((size_t)NE * 4);
    size_t o_wcomb = alloc((size_t)(512 + 32) * 4);
    size_t baseEnd = cur;
    size_t o_epD  = alloc((size_t)NE * 4);
    size_t o_ofD  = alloc((size_t)(NT_D + 1) * 4);
    size_t o_epD2 = alloc((size_t)NE * 4);
    size_t o_noff = alloc((size_t)(NN + 1) * 4);
    size_t o_whi  = alloc((size_t)6144 * 2);
    size_t o_wlo  = alloc((size_t)6144 * 2);
    size_t o_msg  = alloc((size_t)NE * 32 * 4);
    size_t need1 = cur;
    size_t need0 = baseEnd + (size_t)NN * 32 * 4;

    int mode;
    if (ws_size >= need1) mode = 1;
    else if (ws_size >= need0) mode = 0;
    else mode = -1;

    float* h     = (float*)(ws + o_h);
    float* tSf   = (float*)(ws + o_t);
    unsigned short* tSh = (unsigned short*)(ws + o_t);
    float* W2ext = (float*)(ws + o_w2e);
    unsigned short* W2bf = (unsigned short*)(ws + o_w2b);
    int* epermS  = (int*)(ws + o_epS);
    int* offsS   = (int*)(ws + o_ofS);
    int* posS    = (int*)(ws + o_posS);
    int* srcS    = (int*)(ws + o_srcS);
    int* idxS    = (int*)(ws + o_idxS);
    float* Wcomb = (float*)(ws + o_wcomb);
    float* bcomb = Wcomb + 512;
    int* epermD  = (int*)(ws + o_epD);
    int* offsD   = (int*)(ws + o_ofD);
    int* epermD2 = (int*)(ws + o_epD2);
    int* nodeOffs = (int*)(ws + o_noff);
    unsigned short* gWhi = (unsigned short*)(ws + o_whi);
    unsigned short* gWlo = (unsigned short*)(ws + o_wlo);
    float* outbuf = (mode == 1) ? (float*)(ws + o_msg)
                  : (mode == 0) ? (float*)(ws + baseEnd)
                                : (float*)(ws + afterCommon);
    int* bcS = (int*)outbuf;
    int* bsS = bcS + (size_t)HB * NTS;
    int* bcD = bsS + (size_t)HB * NTS;
    int* bsD = bcD + (size_t)HB * NT_D;
    int* totS = bsD + (size_t)HB * NT_D;
    int* totD = totS + NTS;

    k_node_enc<<<NN / 32, 256, 0, stream>>>(nfeats, emb, encW, encB, projW, projB, h);

    if (mode == 1) {
        k_prepAll<<<(66 * 512 + 6144 + 544 + 255) / 256, 256, 0, stream>>>(
            enW2, enB2, W2bf, gruWi, gruWh, gWhi, gWlo,
            eencW, eencB, enW1, enB1, Wcomb, bcomb);
        k_histB<<<2 * HB, 256, 0, stream>>>(src, dst, bcS, bcD);
        k_colsumB<<<(NTS + NT_D + 255) / 256, 256, 0, stream>>>(bcS, bcD, bsS, bsD, totS, totD);
        k_scanB<<<2, 256, 0, stream>>>(totS, totD, offsS, offsD);
        k_scatterB<<<2 * HB, 256, 0, stream>>>(src, dst, bsS, bsD, offsS, offsD, epermS, epermD);
        k_invgather<<<(NE + 255) / 256, 256, 0, stream>>>(epermS, src, posS, srcS);
        k_sortNode<<<NT_D, 256, 0, stream>>>(epermD, dst, offsD, epermD2, nodeOffs);
        k_scatterIdx<<<(NE + 255) / 256, 256, 0, stream>>>(epermD2, posS, idxS);
        k_edge_t3h<<<NE / 128, 256, 0, stream>>>(efeats, Wcomb, bcomb, epermS, tSh);
        for (int s = 0; s < 3; ++s) {
            k_msgF16<1><<<NTS, 256, 0, stream>>>(h, W2bf, tSh, srcS, idxS, offsS, outbuf);
            if (s < 2) {
                k_gruAgg4<0><<<NT_D, 256, 0, stream>>>(outbuf, nodeOffs, convB,
                    gWhi, gWlo, gruBi, gruBh, h,
                    dW1, db1, da1, dW2, db2, da2, dW3, db3, da3, dW4, db4, out);
            } else {
                k_gruAgg4<1><<<NT_D, 256, 0, stream>>>(outbuf, nodeOffs, convB,
                    gWhi, gWlo, gruBi, gruBh, h,
                    dW1, db1, da1, dW2, db2, da2, dW3, db3, da3, dW4, db4, out);
            }
        }
    } else if (mode == 0) {
        int* blockCounts = (int*)outbuf;
        int* blockStart  = blockCounts + (size_t)HB * NTS;
        int* tileTot     = blockStart + (size_t)HB * NTS;
        k_prepAll<<<(66 * 512 + 6144 + 544 + 255) / 256, 256, 0, stream>>>(
            enW2, enB2, W2bf, gruWi, gruWh, gWhi, gWlo,
            eencW, eencB, enW1, enB1, Wcomb, bcomb);
        k_histT<NTS, 4><<<HB, 256, 0, stream>>>(src, blockCounts);
        k_colsumT<NTS><<<(NTS + 255) / 256, 256, 0, stream>>>(blockCounts, blockStart, tileTot);
        k_scanT<NTS, 25><<<1, 256, 0, stream>>>(tileTot, offsS);
        k_scatterT<NTS, 4><<<HB, 256, 0, stream>>>(src, blockStart, offsS, epermS);
        k_invperm<<<(NE + 255) / 256, 256, 0, stream>>>(epermS, posS);
        k_gatherKey<<<(NE + 255) / 256, 256, 0, stream>>>(epermS, src, srcS);
        k_gatherKey<<<(NE + 255) / 256, 256, 0, stream>>>(epermS, dst, idxS);
        k_edge_t3h<<<NE / 128, 256, 0, stream>>>(efeats, Wcomb, bcomb, epermS, tSh);
        for (int s = 0; s < 3; ++s) {
            hipMemsetAsync(outbuf, 0, (size_t)NN * 32 * 4, stream);
            k_msgF16<0><<<NTS, 256, 0, stream>>>(h, W2bf, tSh, srcS, idxS, offsS, outbuf);
            k_gru<<<NN / 32, 256, 0, stream>>>(outbuf, convB, gruWi, gruWh, gruBi, gruBh, h);
        }
        k_dec<<<NN / 32, 256, 0, stream>>>(h, dW1, db1, da1, dW2, db2, da2, dW3, db3, da3, dW4, db4, out);
    } else {
        k_prepAll<<<(66 * 512 + 6144 + 544 + 255) / 256, 256, 0, stream>>>(
            enW2, enB2, W2bf, gruWi, gruWh, gWhi, gWlo,
            eencW, eencB, enW1, enB1, Wcomb, bcomb);
        k_w2ext<<<(32 * QC + 255) / 256, 256, 0, stream>>>(enW2, enB2, W2ext);
        k_edge_t3<<<NE / 128, 256, 0, stream>>>(efeats, Wcomb, bcomb, nullptr, tSf);
        for (int s = 0; s < 3; ++s) {
            hipMemsetAsync(outbuf, 0, (size_t)NN * 32 * 4, stream);
            k_msgC<<<NE / 32, 256, 0, stream>>>(tSf, src, dst, h, W2ext, outbuf);
            k_gru<<<NN / 32, 256, 0, stream>>>(outbuf, convB, gruWi, gruWh, gruBi, gruBh, h);
        }
        k_dec<<<NN / 32, 256, 0, stream>>>(h, dW1, db1, da1, dW2, db2, da2, dW3, db3, da3, dW4, db4, out);
    }
}

// Round 24
// 340.196 us; speedup vs baseline: 1.4982x; 1.0225x over previous
//
#include <hip/hip_runtime.h>
#include <hip/hip_bf16.h>

// MPNN on MI355X — fused 16-node-tile msg kernel + MFMA GRU, fully pre-sorted streams.
// msg[e,o] = sum_k t[e,k]*Q[src,k,o] + q0[src,o],  Q[n] = h[n] @ W2ext
// k_msgF16: per 16-node src tile, MFMA Q (16x1056) into LDS as F16 (k-pair
// interleaved, QSTRH=1096); barrier-free edge stream via v_dot2_f32_f16.
// msgbuf stored f16 (64B/edge). k_gruAgg4<DEC>: f16 segment-sum -> split-bf16
// MFMA GRU; last step fuses the 4-layer decoder (all 32 nodes parallel).

#define NN 100000
#define NE 320000
#define QC 1056
#define NTS 6250      // NN/16 src tiles
#define NT_D 3125     // NN/32 dst tiles
#define HB 256        // bucketing blocks
#define EPB (NE / HB) // 1250
#define QSTRH 1096    // sQ row stride (halves); 548 dwords % 32 == 4

typedef short bf16x8 __attribute__((ext_vector_type(8)));
typedef float f32x4  __attribute__((ext_vector_type(4)));
typedef _Float16 h16x2 __attribute__((ext_vector_type(2)));
typedef _Float16 h16x4 __attribute__((ext_vector_type(4)));
typedef _Float16 h16x8 __attribute__((ext_vector_type(8)));

__device__ __forceinline__ float bf2f(unsigned short u) {
    return __uint_as_float(((unsigned int)u) << 16);
}
__device__ __forceinline__ unsigned short f2bf(float f) {
    unsigned int x = __float_as_uint(f);
    unsigned int r = (x + 0x7fffu + ((x >> 16) & 1u)) >> 16;
    return (unsigned short)r;
}
__device__ __forceinline__ float sigm(float x) {
    return 1.f / (1.f + __expf(-x));
}
__device__ __forceinline__ float dot2h(h16x2 a, h16x2 b, float c) {
#if __has_builtin(__builtin_amdgcn_fdot2)
    return __builtin_amdgcn_fdot2(a, b, c, false);
#else
    return c + (float)a[0] * (float)b[0] + (float)a[1] * (float)b[1];
#endif
}

// ---- build W2ext [32][1056] (fp32, msgC fallback only)
__global__ __launch_bounds__(256) void k_w2ext(const float* __restrict__ W2,
                                               const float* __restrict__ b2,
                                               float* __restrict__ W2ext) {
    int idx = blockIdx.x * 256 + threadIdx.x;
    if (idx >= 32 * QC) return;
    int i = idx / QC, c = idx % QC;
    float v;
    if (c < 1024) { int k = c >> 5, o = c & 31; v = W2[k * 1024 + i * 32 + o]; }
    else          { v = b2[i * 32 + (c - 1024)]; }
    W2ext[idx] = v;
}

// ---- merged weight prep
__global__ __launch_bounds__(256) void k_prepAll(
    const float* __restrict__ W2, const float* __restrict__ b2,
    unsigned short* __restrict__ W2bf,
    const float* __restrict__ Wi, const float* __restrict__ Wh,
    unsigned short* __restrict__ Whi, unsigned short* __restrict__ Wlo,
    const float* __restrict__ eencW, const float* __restrict__ eencB,
    const float* __restrict__ enW1, const float* __restrict__ enB1,
    float* __restrict__ Wcomb, float* __restrict__ bcomb) {
    int idx = blockIdx.x * 256 + threadIdx.x;
    if (idx < 66 * 512) {
        int ct = idx >> 9, l = (idx >> 3) & 63, j = idx & 7;
        int kk = ((j >> 2) << 4) + ((l >> 4) << 2) + (j & 3);
        int c = ct * 16 + (l & 15);
        float v;
        if (c < 1024) { int kb = c >> 5, o = c & 31; v = W2[kb * 1024 + kk * 32 + o]; }
        else          { v = b2[kk * 32 + (c - 1024)]; }
        W2bf[idx] = f2bf(v);
    } else if (idx < 66 * 512 + 6144) {
        int q = idx - 66 * 512;
        int j = q & 7, l = (q >> 3) & 63, kt = (q >> 9) & 1, nt = q >> 10;
        int k = ((j >> 2) << 4) + ((l >> 4) << 2) + (j & 3);
        int col = nt * 16 + (l & 15);
        float v = kt ? Wh[k * 96 + col] : Wi[k * 96 + col];
        unsigned short hi = f2bf(v);
        Whi[q] = hi;
        Wlo[q] = f2bf(v - bf2f(hi));
    } else if (idx < 66 * 512 + 6144 + 544) {
        int q = idx - 66 * 512 - 6144;
        if (q < 512) {
            int i = q >> 5, o = q & 31;
            float acc = 0.f;
            #pragma unroll 8
            for (int j = 0; j < 32; ++j) acc += eencW[i * 32 + j] * enW1[j * 32 + o];
            Wcomb[i * 32 + o] = acc;
        } else {
            int o = q - 512;
            float acc = enB1[o];
            #pragma unroll 8
            for (int j = 0; j < 32; ++j) acc += eencB[j] * enW1[j * 32 + o];
            bcomb[o] = acc;
        }
    }
}

// ---- merged histograms
__global__ __launch_bounds__(256) void k_histB(const int* __restrict__ src,
                                               const int* __restrict__ dst,
                                               int* __restrict__ bcS,
                                               int* __restrict__ bcD) {
    __shared__ int sHist[NTS];
    int tid = threadIdx.x, b = blockIdx.x;
    bool isS = b < HB;
    int bb = isS ? b : b - HB;
    const int* keys = isS ? src : dst;
    int NT = isS ? NTS : NT_D;
    int SH = isS ? 4 : 5;
    for (int c = tid; c < NT; c += 256) sHist[c] = 0;
    __syncthreads();
    int beg = bb * EPB, end = min(beg + EPB, NE);
    for (int e = beg + tid; e < end; e += 256)
        atomicAdd(&sHist[keys[e] >> SH], 1);
    __syncthreads();
    int* out = isS ? bcS : bcD;
    for (int c = tid; c < NT; c += 256) out[bb * NT + c] = sHist[c];
}

// ---- merged column sums
__global__ __launch_bounds__(256) void k_colsumB(const int* __restrict__ bcS,
                                                 const int* __restrict__ bcD,
                                                 int* __restrict__ bsS,
                                                 int* __restrict__ bsD,
                                                 int* __restrict__ totS,
                                                 int* __restrict__ totD) {
    int c = blockIdx.x * 256 + threadIdx.x;
    if (c < NTS) {
        int running = 0;
        #pragma unroll 8
        for (int b = 0; b < HB; ++b) {
            bsS[b * NTS + c] = running;
            running += bcS[b * NTS + c];
        }
        totS[c] = running;
    } else if (c < NTS + NT_D) {
        int cc = c - NTS;
        int running = 0;
        #pragma unroll 8
        for (int b = 0; b < HB; ++b) {
            bsD[b * NT_D + cc] = running;
            running += bcD[b * NT_D + cc];
        }
        totD[cc] = running;
    }
}

// ---- merged scans
__global__ __launch_bounds__(256) void k_scanB(const int* __restrict__ totS,
                                               const int* __restrict__ totD,
                                               int* __restrict__ offS,
                                               int* __restrict__ offD) {
    __shared__ int sTot[NTS];
    __shared__ int sPart[257];
    int tid = threadIdx.x;
    const int* tot = (blockIdx.x == 0) ? totS : totD;
    int* offs = (blockIdx.x == 0) ? offS : offD;
    int NT = (blockIdx.x == 0) ? NTS : NT_D;
    int SEG = (blockIdx.x == 0) ? 25 : 13;
    for (int c = tid; c < NT; c += 256) sTot[c] = tot[c];
    __syncthreads();
    int base = tid * SEG;
    int loc = 0;
    for (int j = 0; j < SEG; ++j) {
        int c = base + j;
        if (c < NT) { int v = sTot[c]; sTot[c] = loc; loc += v; }
    }
    sPart[tid] = loc;
    __syncthreads();
    if (tid == 0) {
        int s = 0;
        for (int i = 0; i < 256; ++i) { int v = sPart[i]; sPart[i] = s; s += v; }
        sPart[256] = s;
    }
    __syncthreads();
    int add = sPart[tid];
    for (int j = 0; j < SEG; ++j) {
        int c = base + j;
        if (c < NT) sTot[c] += add;
    }
    __syncthreads();
    for (int c = tid; c < NT; c += 256) offs[c] = sTot[c];
    if (tid == 0) offs[NT] = sPart[256];
}

// ---- merged scatters
__global__ __launch_bounds__(256) void k_scatterB(const int* __restrict__ src,
                                                  const int* __restrict__ dst,
                                                  const int* __restrict__ bsS,
                                                  const int* __restrict__ bsD,
                                                  const int* __restrict__ offS,
                                                  const int* __restrict__ offD,
                                                  int* __restrict__ epS,
                                                  int* __restrict__ epD) {
    __shared__ int sCur[NTS];
    int tid = threadIdx.x, b = blockIdx.x;
    bool isS = b < HB;
    int bb = isS ? b : b - HB;
    const int* keys = isS ? src : dst;
    const int* bs = isS ? bsS : bsD;
    const int* offs = isS ? offS : offD;
    int* ep = isS ? epS : epD;
    int NT = isS ? NTS : NT_D;
    int SH = isS ? 4 : 5;
    for (int c = tid; c < NT; c += 256)
        sCur[c] = offs[c] + bs[bb * NT + c];
    __syncthreads();
    int beg = bb * EPB, end = min(beg + EPB, NE);
    for (int e = beg + tid; e < end; e += 256) {
        int pos = atomicAdd(&sCur[keys[e] >> SH], 1);
        ep[pos] = e;
    }
}

// ---- merged invperm + src gather
__global__ __launch_bounds__(256) void k_invgather(const int* __restrict__ epermS,
                                                   const int* __restrict__ src,
                                                   int* __restrict__ posS,
                                                   int* __restrict__ srcS) {
    int p = blockIdx.x * 256 + threadIdx.x;
    if (p < NE) {
        int e = epermS[p];
        posS[e] = p;
        srcS[p] = src[e];
    }
}

// ---- node encoder + projection: 32 nodes/block
__global__ __launch_bounds__(256) void k_node_enc(
    const int* __restrict__ nfeats, const float* __restrict__ emb,
    const float* __restrict__ encW, const float* __restrict__ encB,
    const float* __restrict__ projW, const float* __restrict__ projB,
    float* __restrict__ h) {
    __shared__ float sEncW[1024], sProjW[1024], sEncB[32], sProjB[32];
    __shared__ float sEmb[8][33], sNh[8][33];
    int tid = threadIdx.x;
    for (int i = tid; i < 1024; i += 256) { sEncW[i] = encW[i]; sProjW[i] = projW[i]; }
    if (tid < 32) { sEncB[tid] = encB[tid]; sProjB[tid] = projB[tid]; }
    int ln = tid >> 5, o = tid & 31;
    for (int g = 0; g < 4; ++g) {
        int node = blockIdx.x * 32 + g * 8 + ln;
        int nt = nfeats[node];
        float ev = fmaxf(emb[nt * 32 + o], 0.f);
        __syncthreads();
        sEmb[ln][o] = ev;
        __syncthreads();
        float acc = sEncB[o];
        #pragma unroll
        for (int i = 0; i < 32; ++i) acc += sEmb[ln][i] * sEncW[i * 32 + o];
        sNh[ln][o] = fmaxf(acc, 0.f);
        __syncthreads();
        float acc2 = sProjB[o];
        #pragma unroll
        for (int i = 0; i < 32; ++i) acc2 += sNh[ln][i] * sProjW[i * 32 + o];
        h[node * 32 + o] = fmaxf(acc2, 0.f);
    }
}

// ---- edge encoder (folded), f16 output
__global__ __launch_bounds__(256) void k_edge_t3h(
    const float* __restrict__ efeats, const float* __restrict__ Wcomb,
    const float* __restrict__ bcomb, const int* __restrict__ eperm,
    unsigned short* __restrict__ tS) {
    int tid = threadIdx.x;
    int el = tid >> 3, l8 = tid & 7;
    int gbase = (tid & 63) & 56;
    int c0 = l8 << 2;
    float4 w[16];
    #pragma unroll
    for (int i = 0; i < 16; ++i) w[i] = *(const float4*)(Wcomb + i * 32 + c0);
    float4 bb = *(const float4*)(bcomb + c0);
    #pragma unroll
    for (int it = 0; it < 4; ++it) {
        int p = blockIdx.x * 128 + it * 32 + el;
        int e = eperm ? eperm[p] : p;
        float2 efv = *(const float2*)(efeats + (size_t)e * 16 + (l8 << 1));
        float a0 = bb.x, a1 = bb.y, a2 = bb.z, a3 = bb.w;
        #pragma unroll
        for (int i = 0; i < 8; ++i) {
            float f0 = __shfl(efv.x, gbase + i, 64);
            float f1 = __shfl(efv.y, gbase + i, 64);
            float4 w0 = w[2 * i], w1 = w[2 * i + 1];
            a0 += f0 * w0.x + f1 * w1.x;
            a1 += f0 * w0.y + f1 * w1.y;
            a2 += f0 * w0.z + f1 * w1.z;
            a3 += f0 * w0.w + f1 * w1.w;
        }
        _Float16 h0 = (_Float16)fmaxf(a0, 0.f);
        _Float16 h1 = (_Float16)fmaxf(a1, 0.f);
        _Float16 h2 = (_Float16)fmaxf(a2, 0.f);
        _Float16 h3 = (_Float16)fmaxf(a3, 0.f);
        ushort4 o4;
        o4.x = *(unsigned short*)&h0; o4.y = *(unsigned short*)&h1;
        o4.z = *(unsigned short*)&h2; o4.w = *(unsigned short*)&h3;
        *(ushort4*)(tS + (size_t)p * 32 + c0) = o4;
    }
}

// ---- edge encoder fp32 output (msgC fallback only)
__global__ __launch_bounds__(256) void k_edge_t3(
    const float* __restrict__ efeats, const float* __restrict__ Wcomb,
    const float* __restrict__ bcomb, const int* __restrict__ eperm,
    float* __restrict__ tS) {
    int tid = threadIdx.x;
    int el = tid >> 3, l8 = tid & 7;
    int gbase = (tid & 63) & 56;
    int c0 = l8 << 2;
    float4 w[16];
    #pragma unroll
    for (int i = 0; i < 16; ++i) w[i] = *(const float4*)(Wcomb + i * 32 + c0);
    float4 bb = *(const float4*)(bcomb + c0);
    #pragma unroll
    for (int it = 0; it < 4; ++it) {
        int p = blockIdx.x * 128 + it * 32 + el;
        int e = eperm ? eperm[p] : p;
        float2 efv = *(const float2*)(efeats + (size_t)e * 16 + (l8 << 1));
        float a0 = bb.x, a1 = bb.y, a2 = bb.z, a3 = bb.w;
        #pragma unroll
        for (int i = 0; i < 8; ++i) {
            float f0 = __shfl(efv.x, gbase + i, 64);
            float f1 = __shfl(efv.y, gbase + i, 64);
            float4 w0 = w[2 * i], w1 = w[2 * i + 1];
            a0 += f0 * w0.x + f1 * w1.x;
            a1 += f0 * w0.y + f1 * w1.y;
            a2 += f0 * w0.z + f1 * w1.z;
            a3 += f0 * w0.w + f1 * w1.w;
        }
        *(float4*)(tS + (size_t)p * 32 + c0) =
            make_float4(fmaxf(a0, 0.f), fmaxf(a1, 0.f), fmaxf(a2, 0.f), fmaxf(a3, 0.f));
    }
}

// ---- legacy single-purpose bucketing kernels (fallback modes only)
template<int NT, int SHIFT>
__global__ __launch_bounds__(256) void k_histT(const int* __restrict__ keys,
                                               int* __restrict__ blockCounts) {
    __shared__ int sHist[NT];
    int tid = threadIdx.x, b = blockIdx.x;
    for (int c = tid; c < NT; c += 256) sHist[c] = 0;
    __syncthreads();
    int beg = b * EPB, end = min(beg + EPB, NE);
    for (int e = beg + tid; e < end; e += 256)
        atomicAdd(&sHist[keys[e] >> SHIFT], 1);
    __syncthreads();
    for (int c = tid; c < NT; c += 256) blockCounts[b * NT + c] = sHist[c];
}

template<int NT>
__global__ __launch_bounds__(256) void k_colsumT(const int* __restrict__ blockCounts,
                                                 int* __restrict__ blockStart,
                                                 int* __restrict__ tileTot) {
    int c = blockIdx.x * 256 + threadIdx.x;
    if (c >= NT) return;
    int running = 0;
    #pragma unroll 8
    for (int b = 0; b < HB; ++b) {
        blockStart[b * NT + c] = running;
        running += blockCounts[b * NT + c];
    }
    tileTot[c] = running;
}

template<int NT, int SEG>
__global__ __launch_bounds__(256) void k_scanT(const int* __restrict__ tileTot,
                                               int* __restrict__ offs) {
    __shared__ int sTot[NT];
    __shared__ int sPart[257];
    int tid = threadIdx.x;
    for (int c = tid; c < NT; c += 256) sTot[c] = tileTot[c];
    __syncthreads();
    int base = tid * SEG;
    int loc = 0;
    for (int j = 0; j < SEG; ++j) {
        int c = base + j;
        if (c < NT) { int v = sTot[c]; sTot[c] = loc; loc += v; }
    }
    sPart[tid] = loc;
    __syncthreads();
    if (tid == 0) {
        int s = 0;
        for (int i = 0; i < 256; ++i) { int v = sPart[i]; sPart[i] = s; s += v; }
        sPart[256] = s;
    }
    __syncthreads();
    int add = sPart[tid];
    for (int j = 0; j < SEG; ++j) {
        int c = base + j;
        if (c < NT) sTot[c] += add;
    }
    __syncthreads();
    for (int c = tid; c < NT; c += 256) offs[c] = sTot[c];
    if (tid == 0) offs[NT] = sPart[256];
}

template<int NT, int SHIFT>
__global__ __launch_bounds__(256) void k_scatterT(const int* __restrict__ keys,
                                                  const int* __restrict__ blockStart,
                                                  const int* __restrict__ offs,
                                                  int* __restrict__ eperm) {
    __shared__ int sCur[NT];
    int tid = threadIdx.x, b = blockIdx.x;
    for (int c = tid; c < NT; c += 256)
        sCur[c] = offs[c] + blockStart[b * NT + c];
    __syncthreads();
    int beg = b * EPB, end = min(beg + EPB, NE);
    for (int e = beg + tid; e < end; e += 256) {
        int pos = atomicAdd(&sCur[keys[e] >> SHIFT], 1);
        eperm[pos] = e;
    }
}

// ---- second-level sort: within each dst tile, sort by node (32 LDS bins)
__global__ __launch_bounds__(256) void k_sortNode(
    const int* __restrict__ epermD, const int* __restrict__ dst,
    const int* __restrict__ offsD, int* __restrict__ epermD2,
    int* __restrict__ nodeOffs) {
    __shared__ int sCnt[32], sStart[32];
    int tid = threadIdx.x, d = blockIdx.x;
    int beg = offsD[d], end = offsD[d + 1];
    if (tid < 32) sCnt[tid] = 0;
    __syncthreads();
    for (int p = beg + tid; p < end; p += 256)
        atomicAdd(&sCnt[dst[epermD[p]] & 31], 1);
    __syncthreads();
    if (tid == 0) {
        int s = beg;
        for (int r = 0; r < 32; ++r) { sStart[r] = s; s += sCnt[r]; }
    }
    __syncthreads();
    if (tid < 32) {
        nodeOffs[d * 32 + tid] = sStart[tid];
        sCnt[tid] = sStart[tid];
    }
    if (d == NT_D - 1 && tid == 0) nodeOffs[NN] = end;
    __syncthreads();
    for (int p = beg + tid; p < end; p += 256) {
        int e = epermD[p];
        int pos = atomicAdd(&sCnt[dst[e] & 31], 1);
        epermD2[pos] = e;
    }
}

// ---- inverse permutation (fallback path)
__global__ __launch_bounds__(256) void k_invperm(const int* __restrict__ eperm,
                                                 int* __restrict__ pos) {
    int p = blockIdx.x * 256 + threadIdx.x;
    if (p < NE) pos[eperm[p]] = p;
}

// ---- gather key (fallback path)
__global__ __launch_bounds__(256) void k_gatherKey(const int* __restrict__ epermS,
                                                   const int* __restrict__ key,
                                                   int* __restrict__ out) {
    int p = blockIdx.x * 256 + threadIdx.x;
    if (p < NE) out[p] = key[epermS[p]];
}

// ---- idxS[posS[epermD2[q]]] = q
__global__ __launch_bounds__(256) void k_scatterIdx(const int* __restrict__ epermD2,
                                                    const int* __restrict__ posS,
                                                    int* __restrict__ idxS) {
    int q = blockIdx.x * 256 + threadIdx.x;
    if (q < NE) idxS[posS[epermD2[q]]] = q;
}

// ---- fused per-16-node-src-tile: MFMA Q -> f16 LDS (k-pair interleaved),
// edge stream: 4 lanes/edge x 8 outputs via v_dot2_f32_f16.
// MODE 1: f16 msgbuf store (64B/edge); MODE 0: f32 atomicAdd into agg.
template<int MODE>
__global__ __launch_bounds__(256) void k_msgF16(
    const float* __restrict__ h, const unsigned short* __restrict__ W2bf,
    const unsigned short* __restrict__ tS, const int* __restrict__ srcS,
    const int* __restrict__ idxS, const int* __restrict__ offs,
    float* __restrict__ outbuf) {
    __shared__ unsigned short sQ[16 * QSTRH];
    int tid = threadIdx.x;
    int tile = blockIdx.x;
    int beg = offs[tile], end = offs[tile + 1];
    if (beg >= end) return;
    int nodeBase = tile * 16;
    int wave = tid >> 6, lane = tid & 63;

    int arow = lane & 15;
    const float* hp = h + (size_t)(nodeBase + arow) * 32 + ((lane >> 4) << 2);
    float4 x0 = *(const float4*)hp;
    float4 x1 = *(const float4*)(hp + 16);
    bf16x8 a;
    a[0] = (short)f2bf(x0.x); a[1] = (short)f2bf(x0.y);
    a[2] = (short)f2bf(x0.z); a[3] = (short)f2bf(x0.w);
    a[4] = (short)f2bf(x1.x); a[5] = (short)f2bf(x1.y);
    a[6] = (short)f2bf(x1.z); a[7] = (short)f2bf(x1.w);

    f32x4 z = {0.f, 0.f, 0.f, 0.f};
    int crow0 = (lane >> 4) << 2;
    int ccol = lane & 15;
    for (int ct = wave; ct < 66; ct += 4) {
        bf16x8 b = *(const bf16x8*)(W2bf + (size_t)((ct << 6) + lane) * 8);
        f32x4 acc = __builtin_amdgcn_mfma_f32_16x16x32_bf16(a, b, z, 0, 0, 0);
        int c = (ct << 4) + ccol;
        int idx;
        if (c < 1024) {
            int k = c >> 5, o = c & 31;
            idx = ((k >> 1) << 6) + (o << 1) + (k & 1);
        } else {
            idx = 1024 + (c - 1024);
        }
        unsigned short* qp = sQ + crow0 * QSTRH + idx;
        _Float16 v0 = (_Float16)acc[0], v1 = (_Float16)acc[1];
        _Float16 v2 = (_Float16)acc[2], v3 = (_Float16)acc[3];
        qp[0 * QSTRH] = *(unsigned short*)&v0;
        qp[1 * QSTRH] = *(unsigned short*)&v1;
        qp[2 * QSTRH] = *(unsigned short*)&v2;
        qp[3 * QSTRH] = *(unsigned short*)&v3;
    }
    __syncthreads();

    int el = tid >> 2, l4 = tid & 3;
    int o0 = l4 << 3;
    for (int p = beg + el; p < end; p += 64) {
        int row = srcS[p] - nodeBase;
        int widx = idxS[p];
        h16x8 trow[4];
        #pragma unroll
        for (int i = 0; i < 4; ++i)
            trow[i] = *(const h16x8*)(tS + (size_t)p * 32 + (i << 3));
        const unsigned short* qp = sQ + row * QSTRH;
        h16x8 qb = *(const h16x8*)(qp + 1024 + o0);
        float acc[8];
        #pragma unroll
        for (int j = 0; j < 8; ++j) acc[j] = (float)qb[j];
        #pragma unroll
        for (int kp = 0; kp < 16; ++kp) {
            h16x2 t2;
            t2[0] = trow[kp >> 2][(kp & 3) * 2];
            t2[1] = trow[kp >> 2][(kp & 3) * 2 + 1];
            h16x8 qa = *(const h16x8*)(qp + (kp << 6) + (o0 << 1));
            h16x8 qc = *(const h16x8*)(qp + (kp << 6) + (o0 << 1) + 8);
            #pragma unroll
            for (int j = 0; j < 4; ++j) {
                h16x2 q2a; q2a[0] = qa[2 * j]; q2a[1] = qa[2 * j + 1];
                h16x2 q2c; q2c[0] = qc[2 * j]; q2c[1] = qc[2 * j + 1];
                acc[j]     = dot2h(t2, q2a, acc[j]);
                acc[4 + j] = dot2h(t2, q2c, acc[4 + j]);
            }
        }
        if (MODE) {
            h16x8 mv;
            #pragma unroll
            for (int j = 0; j < 8; ++j) mv[j] = (_Float16)acc[j];
            *(h16x8*)((unsigned short*)outbuf + (size_t)widx * 32 + o0) = mv;
        } else {
            float* op = outbuf + (size_t)widx * 32 + o0;
            #pragma unroll
            for (int j = 0; j < 8; ++j) atomicAdd(op + j, acc[j]);
        }
    }
}

// ---- fallback msg (tiny ws)
__global__ __launch_bounds__(256) void k_msgC(
    const float* __restrict__ t, const int* __restrict__ src, const int* __restrict__ dst,
    const float* __restrict__ h, const float* __restrict__ W2ext, float* __restrict__ agg) {
    __shared__ float sT[32][33], sH[32][33];
    __shared__ int sSrc[32], sDst[32];
    int tid = threadIdx.x;
    int e0 = blockIdx.x * 32;
    if (tid < 32) sSrc[tid] = src[e0 + tid];
    else if (tid < 64) sDst[tid - 32] = dst[e0 + tid - 32];
    __syncthreads();
    for (int idx = tid; idx < 1024; idx += 256) {
        int el = idx >> 5, k = idx & 31;
        sT[el][k] = t[(e0 + el) * 32 + k];
        sH[el][k] = h[(size_t)sSrc[el] * 32 + k];
    }
    __syncthreads();
    int el = tid >> 3, l8 = tid & 7;
    int c0 = l8 * 4;
    float m0 = 0.f, m1 = 0.f, m2 = 0.f, m3 = 0.f;
    for (int i = 0; i < 32; ++i) {
        const float* wrow = W2ext + i * QC;
        float4 wb = *(const float4*)(wrow + 1024 + c0);
        float w0 = wb.x, w1 = wb.y, w2 = wb.z, w3 = wb.w;
        #pragma unroll 8
        for (int k = 0; k < 32; ++k) {
            float tk = sT[el][k];
            float4 w = *(const float4*)(wrow + k * 32 + c0);
            w0 += tk * w.x; w1 += tk * w.y; w2 += tk * w.z; w3 += tk * w.w;
        }
        float hi = sH[el][i];
        m0 += hi * w0; m1 += hi * w1; m2 += hi * w2; m3 += hi * w3;
    }
    float* ap = agg + (size_t)sDst[el] * 32 + c0;
    atomicAdd(ap + 0, m0); atomicAdd(ap + 1, m1);
    atomicAdd(ap + 2, m2); atomicAdd(ap + 3, m3);
}

// ---- GRU step reading agg[] (MODE 0 / fallback)
__global__ __launch_bounds__(256) void k_gru(
    const float* __restrict__ agg, const float* __restrict__ convB,
    const float* __restrict__ Wi, const float* __restrict__ Wh,
    const float* __restrict__ bi, const float* __restrict__ bh,
    float* __restrict__ h) {
    __shared__ float sWi[3072], sWh[3072], sBi[96], sBh[96], sCb[32];
    __shared__ float sX[8][33], sH[8][33];
    int tid = threadIdx.x;
    for (int i = tid; i < 3072; i += 256) { sWi[i] = Wi[i]; sWh[i] = Wh[i]; }
    if (tid < 96) { sBi[tid] = bi[tid]; sBh[tid] = bh[tid]; }
    if (tid < 32) sCb[tid] = convB[tid];
    int ln = tid >> 5, o = tid & 31;
    for (int g = 0; g < 4; ++g) {
        int node = blockIdx.x * 32 + g * 8 + ln;
        float hv = h[node * 32 + o];
        float av = agg[node * 32 + o];
        __syncthreads();
        sX[ln][o] = fmaxf(av + sCb[o], 0.f);
        sH[ln][o] = hv;
        __syncthreads();
        float air = sBi[o], aiz = sBi[o + 32], ain = sBi[o + 64];
        float ahr = sBh[o], ahz = sBh[o + 32], ahn = sBh[o + 64];
        #pragma unroll 8
        for (int i = 0; i < 32; ++i) {
            float x = sX[ln][i], hh = sH[ln][i];
            air += x * sWi[i * 96 + o];      ahr += hh * sWh[i * 96 + o];
            aiz += x * sWi[i * 96 + o + 32]; ahz += hh * sWh[i * 96 + o + 32];
            ain += x * sWi[i * 96 + o + 64]; ahn += hh * sWh[i * 96 + o + 64];
        }
        float r = sigm(air + ahr);
        float zz = sigm(aiz + ahz);
        float ng = tanhf(ain + r * ahn);
        h[node * 32 + o] = (1.f - zz) * ng + zz * hv;
    }
}

// ---- MODE 1: per 32-node dst tile: f16 segment-sum -> X in LDS, GRU via split-bf16 MFMA.
// DEC=1 (last step): fused 4-layer decoder, all 32 nodes in parallel, 4 barriers.
template<int DEC>
__global__ __launch_bounds__(256) void k_gruAgg4(
    const unsigned short* __restrict__ msgbuf, const int* __restrict__ nodeOffs,
    const float* __restrict__ convB,
    const unsigned short* __restrict__ Whi, const unsigned short* __restrict__ Wlo,
    const float* __restrict__ bi, const float* __restrict__ bh,
    float* __restrict__ h,
    const float* __restrict__ W1, const float* __restrict__ b1, const float* __restrict__ a1,
    const float* __restrict__ W2, const float* __restrict__ b2, const float* __restrict__ a2,
    const float* __restrict__ W3, const float* __restrict__ b3, const float* __restrict__ a3,
    const float* __restrict__ W4, const float* __restrict__ b4,
    float* __restrict__ out) {
    __shared__ float sAgg[32 * 33];
    int tid = threadIdx.x;
    int d = blockIdx.x;
    int base = d * 32;

    {
        int n8 = tid >> 3, l8 = tid & 7;
        int node = base + n8;
        int nb = nodeOffs[node], ne2 = nodeOffs[node + 1];
        float a0 = 0.f, a1v = 0.f, a2v = 0.f, a3v = 0.f;
        for (int p = nb; p < ne2; ++p) {
            h16x4 v = *(const h16x4*)(msgbuf + (size_t)p * 32 + (l8 << 2));
            a0 += (float)v[0]; a1v += (float)v[1];
            a2v += (float)v[2]; a3v += (float)v[3];
        }
        int c0 = l8 << 2;
        float4 cb = *(const float4*)(convB + c0);
        float* sp = sAgg + n8 * 33 + c0;
        sp[0] = fmaxf(a0 + cb.x, 0.f);
        sp[1] = fmaxf(a1v + cb.y, 0.f);
        sp[2] = fmaxf(a2v + cb.z, 0.f);
        sp[3] = fmaxf(a3v + cb.w, 0.f);
    }
    __syncthreads();

    int wave = tid >> 6, lane = tid & 63;
    int m = wave >> 1, c = wave & 1;
    int arow = lane & 15, kg = (lane >> 4) << 2;

    bf16x8 xhi, xlo, hhi, hlo;
    {
        const float* xp = sAgg + (m * 16 + arow) * 33 + kg;
        float4 v0 = *(const float4*)xp;
        float4 v1 = *(const float4*)(xp + 16);
        float xv[8] = {v0.x, v0.y, v0.z, v0.w, v1.x, v1.y, v1.z, v1.w};
        #pragma unroll
        for (int j = 0; j < 8; ++j) {
            unsigned short hi16 = f2bf(xv[j]);
            xhi[j] = (short)hi16;
            xlo[j] = (short)f2bf(xv[j] - bf2f(hi16));
        }
        const float* hp = h + (size_t)(base + m * 16 + arow) * 32 + kg;
        float4 w0 = *(const float4*)hp;
        float4 w1 = *(const float4*)(hp + 16);
        float hv8[8] = {w0.x, w0.y, w0.z, w0.w, w1.x, w1.y, w1.z, w1.w};
        #pragma unroll
        for (int j = 0; j < 8; ++j) {
            unsigned short hi16 = f2bf(hv8[j]);
            hhi[j] = (short)hi16;
            hlo[j] = (short)f2bf(hv8[j] - bf2f(hi16));
        }
    }

    int ccol = lane & 15, crow0 = (lane >> 4) << 2;
    int o = c * 16 + ccol;
    auto Bf = [&](int nt, int kt, const unsigned short* W) {
        return *(const bf16x8*)(W + (size_t)(((nt * 2 + kt) * 64 + lane) << 3));
    };
    f32x4 accR = {0.f, 0.f, 0.f, 0.f}, accZ = {0.f, 0.f, 0.f, 0.f};
    f32x4 accIN = {0.f, 0.f, 0.f, 0.f}, accHN = {0.f, 0.f, 0.f, 0.f};
    {
        int nt = c;
        bf16x8 b0h = Bf(nt, 0, Whi), b0l = Bf(nt, 0, Wlo);
        bf16x8 b1h = Bf(nt, 1, Whi), b1l = Bf(nt, 1, Wlo);
        accR = __builtin_amdgcn_mfma_f32_16x16x32_bf16(xhi, b0h, accR, 0, 0, 0);
        accR = __builtin_amdgcn_mfma_f32_16x16x32_bf16(xlo, b0h, accR, 0, 0, 0);
        accR = __builtin_amdgcn_mfma_f32_16x16x32_bf16(xhi, b0l, accR, 0, 0, 0);
        accR = __builtin_amdgcn_mfma_f32_16x16x32_bf16(hhi, b1h, accR, 0, 0, 0);
        accR = __builtin_amdgcn_mfma_f32_16x16x32_bf16(hlo, b1h, accR, 0, 0, 0);
        accR = __builtin_amdgcn_mfma_f32_16x16x32_bf16(hhi, b1l, accR, 0, 0, 0);
    }
    {
        int nt = 2 + c;
        bf16x8 b0h = Bf(nt, 0, Whi), b0l = Bf(nt, 0, Wlo);
        bf16x8 b1h = Bf(nt, 1, Whi), b1l = Bf(nt, 1, Wlo);
        accZ = __builtin_amdgcn_mfma_f32_16x16x32_bf16(xhi, b0h, accZ, 0, 0, 0);
        accZ = __builtin_amdgcn_mfma_f32_16x16x32_bf16(xlo, b0h, accZ, 0, 0, 0);
        accZ = __builtin_amdgcn_mfma_f32_16x16x32_bf16(xhi, b0l, accZ, 0, 0, 0);
        accZ = __builtin_amdgcn_mfma_f32_16x16x32_bf16(hhi, b1h, accZ, 0, 0, 0);
        accZ = __builtin_amdgcn_mfma_f32_16x16x32_bf16(hlo, b1h, accZ, 0, 0, 0);
        accZ = __builtin_amdgcn_mfma_f32_16x16x32_bf16(hhi, b1l, accZ, 0, 0, 0);
    }
    {
        int nt = 4 + c;
        bf16x8 b0h = Bf(nt, 0, Whi), b0l = Bf(nt, 0, Wlo);
        bf16x8 b1h = Bf(nt, 1, Whi), b1l = Bf(nt, 1, Wlo);
        accIN = __builtin_amdgcn_mfma_f32_16x16x32_bf16(xhi, b0h, accIN, 0, 0, 0);
        accIN = __builtin_amdgcn_mfma_f32_16x16x32_bf16(xlo, b0h, accIN, 0, 0, 0);
        accIN = __builtin_amdgcn_mfma_f32_16x16x32_bf16(xhi, b0l, accIN, 0, 0, 0);
        accHN = __builtin_amdgcn_mfma_f32_16x16x32_bf16(hhi, b1h, accHN, 0, 0, 0);
        accHN = __builtin_amdgcn_mfma_f32_16x16x32_bf16(hlo, b1h, accHN, 0, 0, 0);
        accHN = __builtin_amdgcn_mfma_f32_16x16x32_bf16(hhi, b1l, accHN, 0, 0, 0);
    }

    float bir = bi[o], biz = bi[32 + o], bin = bi[64 + o];
    float bhr = bh[o], bhz = bh[32 + o], bhn = bh[64 + o];
    float hv[4];
    #pragma unroll
    for (int j = 0; j < 4; ++j)
        hv[j] = h[(size_t)(base + m * 16 + crow0 + j) * 32 + o];
    __syncthreads();    // all h reads complete before any h writes
    float nh[4];
    #pragma unroll
    for (int j = 0; j < 4; ++j) {
        float r  = sigm(accR[j] + bir + bhr);
        float zz = sigm(accZ[j] + biz + bhz);
        float ng = tanhf(accIN[j] + bin + r * (accHN[j] + bhn));
        nh[j] = (1.f - zz) * ng + zz * hv[j];
        h[(size_t)(base + m * 16 + crow0 + j) * 32 + o] = nh[j];
    }

    if constexpr (DEC) {
        __shared__ float sYa[32 * 33];
        __shared__ float sYb[32 * 33];
        __shared__ float sW1[1024], sW2[1024], sW3[1024], sW4[96];
        __shared__ float sB1[32], sB2[32], sB3[32], sB4[3];
        #pragma unroll
        for (int j = 0; j < 4; ++j)
            sYa[(m * 16 + crow0 + j) * 33 + o] = nh[j];
        for (int i = tid; i < 1024; i += 256) { sW1[i] = W1[i]; sW2[i] = W2[i]; sW3[i] = W3[i]; }
        if (tid < 96) sW4[tid] = W4[tid];
        if (tid < 32) { sB1[tid] = b1[tid]; sB2[tid] = b2[tid]; sB3[tid] = b3[tid]; }
        if (tid < 3) sB4[tid] = b4[tid];
        float A1 = a1[0], A2 = a2[0], A3 = a3[0];
        int n8 = tid >> 3, l8 = tid & 7, c0 = l8 << 2;
        __syncthreads();
        {
            float y0 = sB1[c0], y1 = sB1[c0 + 1], y2 = sB1[c0 + 2], y3 = sB1[c0 + 3];
            const float* yp = sYa + n8 * 33;
            #pragma unroll 8
            for (int i = 0; i < 32; ++i) {
                float v = yp[i];
                float4 w = *(const float4*)(sW1 + i * 32 + c0);
                y0 += v * w.x; y1 += v * w.y; y2 += v * w.z; y3 += v * w.w;
            }
            float* op = sYb + n8 * 33 + c0;
            op[0] = y0 >= 0.f ? y0 : A1 * y0;
            op[1] = y1 >= 0.f ? y1 : A1 * y1;
            op[2] = y2 >= 0.f ? y2 : A1 * y2;
            op[3] = y3 >= 0.f ? y3 : A1 * y3;
        }
        __syncthreads();
        {
            float y0 = sB2[c0], y1 = sB2[c0 + 1], y2 = sB2[c0 + 2], y3 = sB2[c0 + 3];
            const float* yp = sYb + n8 * 33;
            #pragma unroll 8
            for (int i = 0; i < 32; ++i) {
                float v = yp[i];
                float4 w = *(const float4*)(sW2 + i * 32 + c0);
                y0 += v * w.x; y1 += v * w.y; y2 += v * w.z; y3 += v * w.w;
            }
            float* op = sYa + n8 * 33 + c0;
            op[0] = y0 >= 0.f ? y0 : A2 * y0;
            op[1] = y1 >= 0.f ? y1 : A2 * y1;
            op[2] = y2 >= 0.f ? y2 : A2 * y2;
            op[3] = y3 >= 0.f ? y3 : A2 * y3;
        }
        __syncthreads();
        {
            float y0 = sB3[c0], y1 = sB3[c0 + 1], y2 = sB3[c0 + 2], y3 = sB3[c0 + 3];
            const float* yp = sYa + n8 * 33;
            #pragma unroll 8
            for (int i = 0; i < 32; ++i) {
                float v = yp[i];
                float4 w = *(const float4*)(sW3 + i * 32 + c0);
                y0 += v * w.x; y1 += v * w.y; y2 += v * w.z; y3 += v * w.w;
            }
            float* op = sYb + n8 * 33 + c0;
            op[0] = y0 >= 0.f ? y0 : A3 * y0;
            op[1] = y1 >= 0.f ? y1 : A3 * y1;
            op[2] = y2 >= 0.f ? y2 : A3 * y2;
            op[3] = y3 >= 0.f ? y3 : A3 * y3;
        }
        __syncthreads();
        if (l8 < 3) {
            float r = sB4[l8];
            const float* yp = sYb + n8 * 33;
            #pragma unroll 8
            for (int i = 0; i < 32; ++i) r += yp[i] * sW4[i * 3 + l8];
            out[(size_t)(base + n8) * 3 + l8] = r;
        }
    }
}

// ---- decoder (fallback modes only)
__global__ __launch_bounds__(256) void k_dec(
    const float* __restrict__ h,
    const float* __restrict__ W1, const float* __restrict__ b1, const float* __restrict__ a1,
    const float* __restrict__ W2, const float* __restrict__ b2, const float* __restrict__ a2,
    const float* __restrict__ W3, const float* __restrict__ b3, const float* __restrict__ a3,
    const float* __restrict__ W4, const float* __restrict__ b4,
    float* __restrict__ out) {
    __shared__ float sW1[1024], sW2[1024], sW3[1024], sW4[96];
    __shared__ float sB1[32], sB2[32], sB3[32], sB4[3];
    __shared__ float sYa[8][33], sYb[8][33];
    int tid = threadIdx.x;
    for (int i = tid; i < 1024; i += 256) { sW1[i] = W1[i]; sW2[i] = W2[i]; sW3[i] = W3[i]; }
    if (tid < 96) sW4[tid] = W4[tid];
    if (tid < 32) { sB1[tid] = b1[tid]; sB2[tid] = b2[tid]; sB3[tid] = b3[tid]; }
    if (tid < 3) sB4[tid] = b4[tid];
    float A1 = a1[0], A2 = a2[0], A3 = a3[0];
    int ln = tid >> 5, o = tid & 31;
    for (int g = 0; g < 4; ++g) {
        int node = blockIdx.x * 32 + g * 8 + ln;
        float hv = h[node * 32 + o];
        __syncthreads();
        sYa[ln][o] = hv;
        __syncthreads();
        float acc = sB1[o];
        #pragma unroll
        for (int i = 0; i < 32; ++i) acc += sYa[ln][i] * sW1[i * 32 + o];
        acc = acc >= 0.f ? acc : A1 * acc;
        sYb[ln][o] = acc;
        __syncthreads();
        acc = sB2[o];
        #pragma unroll
        for (int i = 0; i < 32; ++i) acc += sYb[ln][i] * sW2[i * 32 + o];
        acc = acc >= 0.f ? acc : A2 * acc;
        __syncthreads();
        sYa[ln][o] = acc;
        __syncthreads();
        acc = sB3[o];
        #pragma unroll
        for (int i = 0; i < 32; ++i) acc += sYa[ln][i] * sW3[i * 32 + o];
        acc = acc >= 0.f ? acc : A3 * acc;
        __syncthreads();
        sYb[ln][o] = acc;
        __syncthreads();
        if (o < 3) {
            float r = sB4[o];
            #pragma unroll
            for (int i = 0; i < 32; ++i) r += sYb[ln][i] * sW4[i * 3 + o];
            out[node * 3 + o] = r;
        }
    }
}

extern "C" void kernel_launch(void* const* d_in, const int* in_sizes, int n_in,
                              void* d_out, int out_size, void* d_ws, size_t ws_size,
                              hipStream_t stream) {
    const int*   nfeats = (const int*)d_in[0];
    const float* efeats = (const float*)d_in[1];
    const int*   src    = (const int*)d_in[2];
    const int*   dst    = (const int*)d_in[3];
    const float* emb    = (const float*)d_in[4];
    const float* encW   = (const float*)d_in[5];
    const float* encB   = (const float*)d_in[6];
    const float* eencW  = (const float*)d_in[7];
    const float* eencB  = (const float*)d_in[8];
    const float* projW  = (const float*)d_in[9];
    const float* projB  = (const float*)d_in[10];
    const float* enW1   = (const float*)d_in[11];
    const float* enB1   = (const float*)d_in[12];
    const float* enW2   = (const float*)d_in[13];
    const float* enB2   = (const float*)d_in[14];
    const float* convB  = (const float*)d_in[15];
    const float* gruWi  = (const float*)d_in[16];
    const float* gruWh  = (const float*)d_in[17];
    const float* gruBi  = (const float*)d_in[18];
    const float* gruBh  = (const float*)d_in[19];
    const float* dW1 = (const float*)d_in[20]; const float* db1 = (const float*)d_in[21]; const float* da1 = (const float*)d_in[22];
    const float* dW2 = (const float*)d_in[23]; const float* db2 = (const float*)d_in[24]; const float* da2 = (const float*)d_in[25];
    const float* dW3 = (const float*)d_in[26]; const float* db3 = (const float*)d_in[27]; const float* da3 = (const float*)d_in[28];
    const float* dW4 = (const float*)d_in[29]; const float* db4 = (const float*)d_in[30];
    float* out = (float*)d_out;
    char* ws = (char*)d_ws;

    // bump allocator (256-B aligned)
    size_t cur = 0;
    auto alloc = [&](size_t n) { size_t p = cur; cur = (cur + n + 255) & ~(size_t)255; return p; };
    size_t o_h   = alloc((size_t)NN * 32 * 4);
    size_t o_t   = alloc((size_t)NE * 32 * 4);
    size_t o_w2e = alloc((size_t)32 * QC * 4);
    size_t afterCommon = cur;
    size_t o_w2b = alloc((size_t)66 * 512 * 2);
    size_t o_epS = alloc((size_t)NE * 4);
    size_t o_ofS = alloc((size_t)(NTS + 1) * 4);
    size_t o_posS = alloc((size_t)NE * 4);
    size_t o_srcS = alloc((size_t)NE * 4);
    size_t o_idxS = alloc((size_t)NE * 4);
    size_t o_wcomb = alloc((size_t)(512 + 32) * 4);
    size_t baseEnd = cur;
    size_t o_epD  = alloc((size_t)NE * 4);
    size_t o_ofD  = alloc((size_t)(NT_D + 1) * 4);
    size_t o_epD2 = alloc((size_t)NE * 4);
    size_t o_noff = alloc((size_t)(NN + 1) * 4);
    size_t o_whi  = alloc((size_t)6144 * 2);
    size_t o_wlo  = alloc((size_t)6144 * 2);
    size_t o_msg  = alloc((size_t)NE * 32 * 2);     // f16 msgbuf (also prologue scratch)
    size_t need1 = cur;
    size_t need0 = baseEnd + (size_t)NN * 32 * 4;

    int mode;
    if (ws_size >= need1) mode = 1;
    else if (ws_size >= need0) mode = 0;
    else mode = -1;

    float* h     = (float*)(ws + o_h);
    float* tSf   = (float*)(ws + o_t);
    unsigned short* tSh = (unsigned short*)(ws + o_t);
    float* W2ext = (float*)(ws + o_w2e);
    unsigned short* W2bf = (unsigned short*)(ws + o_w2b);
    int* epermS  = (int*)(ws + o_epS);
    int* offsS   = (int*)(ws + o_ofS);
    int* posS    = (int*)(ws + o_posS);
    int* srcS    = (int*)(ws + o_srcS);
    int* idxS    = (int*)(ws + o_idxS);
    float* Wcomb = (float*)(ws + o_wcomb);
    float* bcomb = Wcomb + 512;
    int* epermD  = (int*)(ws + o_epD);
    int* offsD   = (int*)(ws + o_ofD);
    int* epermD2 = (int*)(ws + o_epD2);
    int* nodeOffs = (int*)(ws + o_noff);
    unsigned short* gWhi = (unsigned short*)(ws + o_whi);
    unsigned short* gWlo = (unsigned short*)(ws + o_wlo);
    float* outbuf = (mode == 1) ? (float*)(ws + o_msg)
                  : (mode == 0) ? (float*)(ws + baseEnd)
                                : (float*)(ws + afterCommon);
    // prologue scratch (unions into msgbuf region; 19.2 MB <= 20.5 MB)
    int* bcS = (int*)outbuf;
    int* bsS = bcS + (size_t)HB * NTS;
    int* bcD = bsS + (size_t)HB * NTS;
    int* bsD = bcD + (size_t)HB * NT_D;
    int* totS = bsD + (size_t)HB * NT_D;
    int* totD = totS + NTS;

    k_node_enc<<<NN / 32, 256, 0, stream>>>(nfeats, emb, encW, encB, projW, projB, h);

    if (mode == 1) {
        k_prepAll<<<(66 * 512 + 6144 + 544 + 255) / 256, 256, 0, stream>>>(
            enW2, enB2, W2bf, gruWi, gruWh, gWhi, gWlo,
            eencW, eencB, enW1, enB1, Wcomb, bcomb);
        k_histB<<<2 * HB, 256, 0, stream>>>(src, dst, bcS, bcD);
        k_colsumB<<<(NTS + NT_D + 255) / 256, 256, 0, stream>>>(bcS, bcD, bsS, bsD, totS, totD);
        k_scanB<<<2, 256, 0, stream>>>(totS, totD, offsS, offsD);
        k_scatterB<<<2 * HB, 256, 0, stream>>>(src, dst, bsS, bsD, offsS, offsD, epermS, epermD);
        k_invgather<<<(NE + 255) / 256, 256, 0, stream>>>(epermS, src, posS, srcS);
        k_sortNode<<<NT_D, 256, 0, stream>>>(epermD, dst, offsD, epermD2, nodeOffs);
        k_scatterIdx<<<(NE + 255) / 256, 256, 0, stream>>>(epermD2, posS, idxS);
        k_edge_t3h<<<NE / 128, 256, 0, stream>>>(efeats, Wcomb, bcomb, epermS, tSh);
        for (int s = 0; s < 3; ++s) {
            k_msgF16<1><<<NTS, 256, 0, stream>>>(h, W2bf, tSh, srcS, idxS, offsS, outbuf);
            if (s < 2) {
                k_gruAgg4<0><<<NT_D, 256, 0, stream>>>((const unsigned short*)outbuf,
                    nodeOffs, convB, gWhi, gWlo, gruBi, gruBh, h,
                    dW1, db1, da1, dW2, db2, da2, dW3, db3, da3, dW4, db4, out);
            } else {
                k_gruAgg4<1><<<NT_D, 256, 0, stream>>>((const unsigned short*)outbuf,
                    nodeOffs, convB, gWhi, gWlo, gruBi, gruBh, h,
                    dW1, db1, da1, dW2, db2, da2, dW3, db3, da3, dW4, db4, out);
            }
        }
    } else if (mode == 0) {
        int* blockCounts = (int*)outbuf;
        int* blockStart  = blockCounts + (size_t)HB * NTS;
        int* tileTot     = blockStart + (size_t)HB * NTS;
        k_prepAll<<<(66 * 512 + 6144 + 544 + 255) / 256, 256, 0, stream>>>(
            enW2, enB2, W2bf, gruWi, gruWh, gWhi, gWlo,
            eencW, eencB, enW1, enB1, Wcomb, bcomb);
        k_histT<NTS, 4><<<HB, 256, 0, stream>>>(src, blockCounts);
        k_colsumT<NTS><<<(NTS + 255) / 256, 256, 0, stream>>>(blockCounts, blockStart, tileTot);
        k_scanT<NTS, 25><<<1, 256, 0, stream>>>(tileTot, offsS);
        k_scatterT<NTS, 4><<<HB, 256, 0, stream>>>(src, blockStart, offsS, epermS);
        k_invperm<<<(NE + 255) / 256, 256, 0, stream>>>(epermS, posS);
        k_gatherKey<<<(NE + 255) / 256, 256, 0, stream>>>(epermS, src, srcS);
        k_gatherKey<<<(NE + 255) / 256, 256, 0, stream>>>(epermS, dst, idxS);
        k_edge_t3h<<<NE / 128, 256, 0, stream>>>(efeats, Wcomb, bcomb, epermS, tSh);
        for (int s = 0; s < 3; ++s) {
            hipMemsetAsync(outbuf, 0, (size_t)NN * 32 * 4, stream);
            k_msgF16<0><<<NTS, 256, 0, stream>>>(h, W2bf, tSh, srcS, idxS, offsS, outbuf);
            k_gru<<<NN / 32, 256, 0, stream>>>(outbuf, convB, gruWi, gruWh, gruBi, gruBh, h);
        }
        k_dec<<<NN / 32, 256, 0, stream>>>(h, dW1, db1, da1, dW2, db2, da2, dW3, db3, da3, dW4, db4, out);
    } else {
        k_prepAll<<<(66 * 512 + 6144 + 544 + 255) / 256, 256, 0, stream>>>(
            enW2, enB2, W2bf, gruWi, gruWh, gWhi, gWlo,
            eencW, eencB, enW1, enB1, Wcomb, bcomb);
        k_w2ext<<<(32 * QC + 255) / 256, 256, 0, stream>>>(enW2, enB2, W2ext);
        k_edge_t3<<<NE / 128, 256, 0, stream>>>(efeats, Wcomb, bcomb, nullptr, tSf);
        for (int s = 0; s < 3; ++s) {
            hipMemsetAsync(outbuf, 0, (size_t)NN * 32 * 4, stream);
            k_msgC<<<NE / 32, 256, 0, stream>>>(tSf, src, dst, h, W2ext, outbuf);
            k_gru<<<NN / 32, 256, 0, stream>>>(outbuf, convB, gruWi, gruWh, gruBi, gruBh, h);
        }
        k_dec<<<NN / 32, 256, 0, stream>>>(h, dW1, db1, da1, dW2, db2, da2, dW3, db3, da3, dW4, db4, out);
    }
}